// Round 4
// baseline (745.179 us; speedup 1.0000x reference)
//
#include <hip/hip_runtime.h>
#include <hip/hip_bf16.h>
#include <math.h>

// ---------------- problem constants ----------------
#define B_    2
#define S_    2048
#define D_    1024
#define DI    2048      // D_INNER
#define NH    32        // NHEADS (mamba)
#define HD    64        // HEADDIM
#define DS    128       // D_STATE
#define CH    64        // CHUNK
#define NC    32        // S_/CH
#define DP    4384      // D_PROJ
#define HATT  16        // attention heads
#define KVH   4         // kv heads
#define RD    16        // rope dims
#define MLP   3072
#define ROWS  (B_*S_)   // 4096

typedef __bf16 bf16;
typedef __bf16 bf16x8 __attribute__((ext_vector_type(8)));
typedef __bf16 bf16x4 __attribute__((ext_vector_type(4)));
typedef float  f32x4  __attribute__((ext_vector_type(4)));

__device__ __forceinline__ void async_copy16(const void* g, void* l) {
  __builtin_amdgcn_global_load_lds(
      (const __attribute__((address_space(1))) unsigned int*)g,
      (__attribute__((address_space(3))) unsigned int*)l, 16, 0, 0);
}

// ---------------- reductions ----------------
__device__ __forceinline__ float waveReduceSum(float v) {
#pragma unroll
  for (int off = 32; off > 0; off >>= 1) v += __shfl_down(v, off, 64);
  return v;
}

template<int NW>
__device__ __forceinline__ float blockReduceSum(float v, float* sh) {
  v = waveReduceSum(v);
  int lane = threadIdx.x & 63, wid = threadIdx.x >> 6;
  if (lane == 0) sh[wid] = v;
  __syncthreads();
  float s = 0.f;
#pragma unroll
  for (int i = 0; i < NW; i++) s += sh[i];
  __syncthreads();
  return s;
}

// ---------------- merged weight cast f32 -> bf16 ----------------
struct CastSeg { const float* src; bf16* dst; int nval; int ntot; int blk0; };
struct CastArgs { CastSeg seg[8]; };

__global__ __launch_bounds__(256) void castw_all(CastArgs a) {
  int blk = blockIdx.x;
  int si = 0;
#pragma unroll
  for (int i = 1; i < 8; i++) if (blk >= a.seg[i].blk0) si = i;
  CastSeg s = a.seg[si];
  int i = ((blk - s.blk0) * 256 + threadIdx.x) * 4;
  if (i >= s.ntot) return;
  float4 v = {0.f, 0.f, 0.f, 0.f};
  if (i < s.nval) v = *(const float4*)(s.src + i);
  bf16x4 o;
  o[0] = (bf16)v.x; o[1] = (bf16)v.y; o[2] = (bf16)v.z; o[3] = (bf16)v.w;
  *(bf16x4*)(s.dst + i) = o;
}

// ---------------- rmsnorm (f32 in, bf16 out) ----------------
__global__ __launch_bounds__(256) void rmsnorm_k(const float* __restrict__ x,
                                                 const float* __restrict__ w,
                                                 bf16* __restrict__ y, int n) {
  __shared__ float sh[4];
  size_t row = blockIdx.x;
  const float* xr = x + row * n;
  bf16* yr = y + row * n;
  float ss = 0.f;
  for (int i = threadIdx.x; i < n; i += 256) { float v = xr[i]; ss += v * v; }
  ss = blockReduceSum<4>(ss, sh);
  float inv = rsqrtf(ss / n + 1e-5f);
  for (int i = threadIdx.x; i < n; i += 256) yr[i] = (bf16)(xr[i] * inv * w[i]);
}

// ---------------- generic bf16 MFMA GEMM: C = act(A @ W^T), bm-fastest 1D grid ----------------
template<int ACT, typename OT>
__global__ __launch_bounds__(256) void gemm_mfma(const bf16* __restrict__ A,
                                                 const bf16* __restrict__ W,
                                                 const float* __restrict__ R,
                                                 OT* __restrict__ C,
                                                 int M, int N, int K) {
  __shared__ bf16 As[128 * 32];
  __shared__ bf16 Ws[128 * 32];
  int tid = threadIdx.x, lane = tid & 63, wave = tid >> 6;
  int mt = M >> 7;
  int bid = blockIdx.x;
  int bm = (bid % mt) * 128, bn = (bid / mt) * 128;
  const bf16* gA0 = A + (size_t)(bm + wave * 32 + (lane >> 2)) * K + (lane & 3) * 8;
  const bf16* gA1 = gA0 + (size_t)16 * K;
  const bf16* gW0 = W + (size_t)(bn + wave * 32 + (lane >> 2)) * K + (lane & 3) * 8;
  const bf16* gW1 = gW0 + (size_t)16 * K;
  bf16* lA0 = As + wave * 32 * 32;
  bf16* lA1 = lA0 + 16 * 32;
  bf16* lW0 = Ws + wave * 32 * 32;
  bf16* lW1 = lW0 + 16 * 32;
  int fr = lane & 15, fq = lane >> 4;
  int wm = wave >> 1, wn = wave & 1;
  const bf16* pA = As + (wm * 64 + fr) * 32 + fq * 8;
  const bf16* pW = Ws + (wn * 64 + fr) * 32 + fq * 8;
  f32x4 acc[4][4] = {};
  for (int k0 = 0; k0 < K; k0 += 32) {
    async_copy16(gA0, lA0);
    async_copy16(gA1, lA1);
    async_copy16(gW0, lW0);
    async_copy16(gW1, lW1);
    gA0 += 32; gA1 += 32; gW0 += 32; gW1 += 32;
    __syncthreads();
    bf16x8 af[4], bfr[4];
#pragma unroll
    for (int mi = 0; mi < 4; mi++) af[mi] = *(const bf16x8*)(pA + mi * 16 * 32);
#pragma unroll
    for (int ni = 0; ni < 4; ni++) bfr[ni] = *(const bf16x8*)(pW + ni * 16 * 32);
#pragma unroll
    for (int mi = 0; mi < 4; mi++)
#pragma unroll
      for (int ni = 0; ni < 4; ni++)
        acc[mi][ni] = __builtin_amdgcn_mfma_f32_16x16x32_bf16(af[mi], bfr[ni], acc[mi][ni], 0, 0, 0);
    __syncthreads();
  }
#pragma unroll
  for (int mi = 0; mi < 4; mi++) {
    int row = bm + wm * 64 + mi * 16 + fq * 4;
#pragma unroll
    for (int ni = 0; ni < 4; ni++) {
      int col = bn + wn * 64 + ni * 16 + fr;
      if (col < N) {
#pragma unroll
        for (int r = 0; r < 4; r++) {
          float v = acc[mi][ni][r];
          if (ACT == 1) v = v / (1.f + __expf(-v));
          if (R) v += R[(size_t)(row + r) * N + col];
          C[(size_t)(row + r) * N + col] = (OT)v;
        }
      }
    }
  }
}

// ---------------- split-K bf16 MFMA GEMM: P[ks] = A @ W^T (bf16 partials) ----------------
__global__ __launch_bounds__(256) void gemm_sk(const bf16* __restrict__ A,
                                               const bf16* __restrict__ W,
                                               bf16* __restrict__ P,
                                               int M, int N, int K, int kchunk) {
  __shared__ bf16 As[128 * 32];
  __shared__ bf16 Ws[128 * 32];
  int tid = threadIdx.x, lane = tid & 63, wave = tid >> 6;
  int mt = M >> 7;
  int bid = blockIdx.x;
  int bm = (bid % mt) * 128, bn = (bid / mt) * 128;
  int ks = blockIdx.z;
  int kbeg = ks * kchunk;
  const bf16* gA0 = A + (size_t)(bm + wave * 32 + (lane >> 2)) * K + kbeg + (lane & 3) * 8;
  const bf16* gA1 = gA0 + (size_t)16 * K;
  const bf16* gW0 = W + (size_t)(bn + wave * 32 + (lane >> 2)) * K + kbeg + (lane & 3) * 8;
  const bf16* gW1 = gW0 + (size_t)16 * K;
  bf16* lA0 = As + wave * 32 * 32;
  bf16* lA1 = lA0 + 16 * 32;
  bf16* lW0 = Ws + wave * 32 * 32;
  bf16* lW1 = lW0 + 16 * 32;
  int fr = lane & 15, fq = lane >> 4;
  int wm = wave >> 1, wn = wave & 1;
  const bf16* pA = As + (wm * 64 + fr) * 32 + fq * 8;
  const bf16* pW = Ws + (wn * 64 + fr) * 32 + fq * 8;
  f32x4 acc[4][4] = {};
  for (int k0 = 0; k0 < kchunk; k0 += 32) {
    async_copy16(gA0, lA0);
    async_copy16(gA1, lA1);
    async_copy16(gW0, lW0);
    async_copy16(gW1, lW1);
    gA0 += 32; gA1 += 32; gW0 += 32; gW1 += 32;
    __syncthreads();
    bf16x8 af[4], bfr[4];
#pragma unroll
    for (int mi = 0; mi < 4; mi++) af[mi] = *(const bf16x8*)(pA + mi * 16 * 32);
#pragma unroll
    for (int ni = 0; ni < 4; ni++) bfr[ni] = *(const bf16x8*)(pW + ni * 16 * 32);
#pragma unroll
    for (int mi = 0; mi < 4; mi++)
#pragma unroll
      for (int ni = 0; ni < 4; ni++)
        acc[mi][ni] = __builtin_amdgcn_mfma_f32_16x16x32_bf16(af[mi], bfr[ni], acc[mi][ni], 0, 0, 0);
    __syncthreads();
  }
  bf16* Pp = P + (size_t)ks * M * N;
#pragma unroll
  for (int mi = 0; mi < 4; mi++) {
    int row = bm + wm * 64 + mi * 16 + fq * 4;
#pragma unroll
    for (int ni = 0; ni < 4; ni++) {
      int col = bn + wn * 64 + ni * 16 + fr;
#pragma unroll
      for (int r = 0; r < 4; r++)
        Pp[(size_t)(row + r) * N + col] = (bf16)acc[mi][ni][r];
    }
  }
}

// ---------------- reduce 2 bf16 partials + residual + layernorm -> x_out f32, h bf16 ----------------
__global__ __launch_bounds__(256) void reduce_ln2(const bf16* __restrict__ p0,
                                                  const bf16* __restrict__ p1,
                                                  const float* __restrict__ res,
                                                  const float* __restrict__ w,
                                                  const float* __restrict__ b,
                                                  float* __restrict__ xo,
                                                  bf16* __restrict__ ho) {
  __shared__ float sh[4];
  size_t o = (size_t)blockIdx.x * 1024;
  int i = threadIdx.x * 4;
  bf16x4 a = *(const bf16x4*)(p0 + o + i);
  bf16x4 c = *(const bf16x4*)(p1 + o + i);
  f32x4 rv = *(const f32x4*)(res + o + i);
  f32x4 v;
  float s = 0.f, s2 = 0.f;
#pragma unroll
  for (int j = 0; j < 4; j++) {
    v[j] = (float)a[j] + (float)c[j] + rv[j];
    s += v[j]; s2 += v[j] * v[j];
  }
  s  = blockReduceSum<4>(s,  sh);
  s2 = blockReduceSum<4>(s2, sh);
  float mean = s / 1024.f;
  float var  = s2 / 1024.f - mean * mean;
  float inv  = rsqrtf(var + 1e-5f);
  f32x4 wv = *(const f32x4*)(w + i);
  f32x4 bv = *(const f32x4*)(b + i);
  *(f32x4*)(xo + o + i) = v;
  bf16x4 hv;
#pragma unroll
  for (int j = 0; j < 4; j++) hv[j] = (bf16)((v[j] - mean) * inv * wv[j] + bv[j]);
  *(bf16x4*)(ho + o + i) = hv;
}

// ---------------- reduce 3 bf16 partials + residual -> out f32 ----------------
__global__ __launch_bounds__(256) void reduce_out3(const bf16* __restrict__ p0,
                                                   const bf16* __restrict__ p1,
                                                   const bf16* __restrict__ p2,
                                                   const float* __restrict__ res,
                                                   float* __restrict__ out) {
  int i = (blockIdx.x * 256 + threadIdx.x) * 4;
  bf16x4 a = *(const bf16x4*)(p0 + i);
  bf16x4 c = *(const bf16x4*)(p1 + i);
  bf16x4 d = *(const bf16x4*)(p2 + i);
  f32x4 v = *(const f32x4*)(res + i);
#pragma unroll
  for (int j = 0; j < 4; j++) v[j] += (float)a[j] + (float)c[j] + (float)d[j];
  *(f32x4*)(out + i) = v;
}

// ---------------- reduce qkv bf16 partials + q/k rmsnorm + rope + gain -> bf16 ----------------
__global__ __launch_bounds__(256) void reduce_qkv(const bf16* __restrict__ P,
                                                  const float* __restrict__ q_gain,
                                                  bf16* __restrict__ q,
                                                  bf16* __restrict__ k,
                                                  bf16* __restrict__ v) {
  __shared__ float buf[1536];
  size_t row = blockIdx.x;
  size_t o = row * 1536;
  const bf16* p0 = P + o;
  const bf16* p1 = P + (size_t)ROWS * 1536 + o;
  int tid = threadIdx.x;
  for (int i = tid; i < 384; i += 256) {
    bf16x4 a = *(const bf16x4*)(p0 + i * 4);
    bf16x4 c = *(const bf16x4*)(p1 + i * 4);
    f32x4 vv;
#pragma unroll
    for (int j = 0; j < 4; j++) vv[j] = (float)a[j] + (float)c[j];
    *(f32x4*)(buf + i * 4) = vv;
  }
  __syncthreads();
  int lane = tid & 63, w = tid >> 6;
  int s = (int)(row & (S_ - 1));
  int ri = lane & 7;
  float rinv = __expf(-(float)ri * (0.125f * 9.210340371976184f)); // 10000^(-i/8)
  float ang = (float)s * rinv;
  float cs = cosf(ang), sn = sinf(ang);
#pragma unroll
  for (int j = 0; j < 6; j++) {
    int hh = w * 6 + j;
    float val = buf[hh * 64 + lane];
    if (hh < 20) {
      float ss = val * val;
#pragma unroll
      for (int off = 32; off > 0; off >>= 1) ss += __shfl_xor(ss, off, 64);
      val *= rsqrtf(ss / 64.f + 1.1920929e-7f);
      float other = __shfl_xor(val, 8, 64);
      float res = val;
      if (lane < RD) res = (lane < 8) ? (val * cs + other * sn) : (val * cs - other * sn);
      if (hh < 16) {
        res *= q_gain[hh];
        q[row * (HATT * HD) + hh * HD + lane] = (bf16)res;
      } else {
        k[row * (KVH * HD) + (hh - 16) * HD + lane] = (bf16)res;
      }
    } else {
      v[row * (KVH * HD) + (hh - 20) * HD + lane] = (bf16)val;
    }
  }
}

// ---------------- in_proj GEMM: 256 heavy 256^2 blocks (z/x) + 96 light 128^2 blocks (bcdt) ----
// Heavy (bid<256): verified R3 counted-vmcnt core, now 2-buf (64KB -> 2 blocks/CU) and a
// tail-free 16x16 grid. Schedule per K-step: {vmcnt(4): tile t landed, t+1 in flight;
// barrier; 12 ds_read_b128 (swizzled); setprio(1); 32 MFMA; setprio(0); barrier (reads of
// buf t&1 done -> WAR safe); stage tile t+2 into buf t&1}. sched_barrier(0) pins reads
// before barrier2 (guide rule 18). vmcnt never drains mid-loop (T4).
// Light (bid>=256): same schedule at 128^2 (2 loads/tile, vmcnt(2)) for the 288 bcdt cols;
// rides as second block on 96 CUs (~+25% tail vs 2x-round tail of R3).
// LDS seg-swizzle: seg ^= row&3, inverse pre-applied to global source (both paths).
__global__ __launch_bounds__(512, 4) void gemm256_inproj(const bf16* __restrict__ A,
                                                         const bf16* __restrict__ W,
                                                         bf16* __restrict__ zt,
                                                         bf16* __restrict__ xt,
                                                         bf16* __restrict__ bcdt) {
  __shared__ bf16 lds[2 * 16384];          // 64 KB
  int tid = threadIdx.x;
  int lane = tid & 63, w = tid >> 6;       // 8 waves
  int fr = lane & 15, fq = lane >> 4;
  int rdswz = (fq ^ (fr & 3)) * 8;
  int sswz = (lane & 3) ^ ((lane >> 2) & 3);
  int bid = blockIdx.x;
  if (bid < 256) {
    int sb = (bid & 7) * 32 + (bid >> 3);  // XCD swizzle (256 = 8*32)
    int bm = (sb & 15) * 256;
    int bn = (sb >> 4) * 256;
    int wm = w >> 2, wn = w & 3;           // 2M x 4N waves: per wave 128x64
    int srow = w * 32 + (lane >> 2);
    const bf16* gA = A + (size_t)(bm + srow) * 1024 + sswz * 8;
    const bf16* gW = W + (size_t)(bn + srow) * 1024 + sswz * 8;
    int sbase = w * 1024;                  // wave's 32-row stage region (elems)
    f32x4 acc[8][4] = {};
    {
      bf16* bA = lds + sbase;
      bf16* bB = lds + 8192 + sbase;
      async_copy16(gA, bA);               async_copy16(gA + 16 * 1024, bA + 512);
      async_copy16(gW, bB);               async_copy16(gW + 16 * 1024, bB + 512);
      bf16* cA2 = bA + 16384; bf16* cB2 = bB + 16384;
      async_copy16(gA + 32, cA2);         async_copy16(gA + 32 + 16 * 1024, cA2 + 512);
      async_copy16(gW + 32, cB2);         async_copy16(gW + 32 + 16 * 1024, cB2 + 512);
    }
    for (int t = 0; t < 32; t++) {
      if (t < 31) asm volatile("s_waitcnt vmcnt(4)" ::: "memory");
      else        asm volatile("s_waitcnt vmcnt(0)" ::: "memory");
      __builtin_amdgcn_sched_barrier(0);
      __builtin_amdgcn_s_barrier();
      __builtin_amdgcn_sched_barrier(0);
      const bf16* cA = lds + (t & 1) * 16384;
      const bf16* cB = cA + 8192;
      bf16x8 af[8], bfv[4];
#pragma unroll
      for (int mi = 0; mi < 8; mi++)
        af[mi] = *(const bf16x8*)(cA + (wm * 128 + mi * 16 + fr) * 32 + rdswz);
#pragma unroll
      for (int ni = 0; ni < 4; ni++)
        bfv[ni] = *(const bf16x8*)(cB + (wn * 64 + ni * 16 + fr) * 32 + rdswz);
      __builtin_amdgcn_s_setprio(1);
#pragma unroll
      for (int mi = 0; mi < 8; mi++)
#pragma unroll
        for (int ni = 0; ni < 4; ni++)
          acc[mi][ni] = __builtin_amdgcn_mfma_f32_16x16x32_bf16(af[mi], bfv[ni], acc[mi][ni], 0, 0, 0);
      __builtin_amdgcn_s_setprio(0);
      __builtin_amdgcn_sched_barrier(0);
      __builtin_amdgcn_s_barrier();      // all reads of buf (t&1) complete
      __builtin_amdgcn_sched_barrier(0);
      if (t + 2 < 32) {
        const bf16* ga = gA + (t + 2) * 32;
        const bf16* gw = gW + (t + 2) * 32;
        bf16* bA = lds + (t & 1) * 16384 + sbase;
        bf16* bB = bA + 8192;
        async_copy16(ga, bA);             async_copy16(ga + 16 * 1024, bA + 512);
        async_copy16(gw, bB);             async_copy16(gw + 16 * 1024, bB + 512);
      }
    }
    // epilogue: LDS-transposed coalesced Zt/Xt stores (verified R3 path)
    bf16* base = (bn < 2048) ? zt : xt;
    int bq = bm >> 11, bmS = bm & 2047;
    bf16* Ts = lds;                        // 64 x 264 bf16 scratch (33.8 KB)
#pragma unroll 1
    for (int g = 0; g < 4; g++) {
      __syncthreads();
      if (wn == g) {
#pragma unroll
        for (int mi = 0; mi < 8; mi++)
#pragma unroll
          for (int ni = 0; ni < 4; ni++) {
            bf16x4 o;
#pragma unroll
            for (int r = 0; r < 4; r++) o[r] = (bf16)acc[mi][ni][r];
            *(bf16x4*)(Ts + (ni * 16 + fr) * 264 + wm * 128 + mi * 16 + fq * 4) = o;
          }
      }
      __syncthreads();
      int hh = ((bn & 2047) + g * 64) >> 6;
      bf16* dst = base + ((size_t)(bq * NH + hh) * HD) * S_ + bmS;
#pragma unroll
      for (int i = 0; i < 4; i++) {
        int idx = tid + i * 512;
        int p = idx >> 5, sc = (idx & 31) * 8;
        *(bf16x8*)(dst + (size_t)p * S_ + sc) = *(const bf16x8*)(Ts + p * 264 + sc);
      }
    }
  } else {
    // ---- light path: 128x128 tile over bcdt columns 4096..4383 (3rd tile masked) ----
    int lb = bid - 256;
    int bm = (lb & 31) * 128;
    int bn = 4096 + (lb >> 5) * 128;
    int wm = w >> 1, wn = w & 1;           // 4M x 2N waves: per wave 32x64
    int srow = w * 16 + (lane >> 2);
    const bf16* gA = A + (size_t)(bm + srow) * 1024 + sswz * 8;
    const bf16* gW = W + (size_t)(bn + srow) * 1024 + sswz * 8;
    int sbase = w * 512;                   // wave's 16-row stage region (elems)
    f32x4 acc[2][4] = {};
    {
      bf16* bA = lds + sbase;
      bf16* bB = lds + 4096 + sbase;
      async_copy16(gA, bA);
      async_copy16(gW, bB);
      async_copy16(gA + 32, bA + 8192);
      async_copy16(gW + 32, bB + 8192);
    }
    for (int t = 0; t < 32; t++) {
      if (t < 31) asm volatile("s_waitcnt vmcnt(2)" ::: "memory");
      else        asm volatile("s_waitcnt vmcnt(0)" ::: "memory");
      __builtin_amdgcn_sched_barrier(0);
      __builtin_amdgcn_s_barrier();
      __builtin_amdgcn_sched_barrier(0);
      const bf16* cA = lds + (t & 1) * 8192;
      const bf16* cB = cA + 4096;
      bf16x8 af[2], bfv[4];
#pragma unroll
      for (int mi = 0; mi < 2; mi++)
        af[mi] = *(const bf16x8*)(cA + (wm * 32 + mi * 16 + fr) * 32 + rdswz);
#pragma unroll
      for (int ni = 0; ni < 4; ni++)
        bfv[ni] = *(const bf16x8*)(cB + (wn * 64 + ni * 16 + fr) * 32 + rdswz);
#pragma unroll
      for (int mi = 0; mi < 2; mi++)
#pragma unroll
        for (int ni = 0; ni < 4; ni++)
          acc[mi][ni] = __builtin_amdgcn_mfma_f32_16x16x32_bf16(af[mi], bfv[ni], acc[mi][ni], 0, 0, 0);
      __builtin_amdgcn_sched_barrier(0);
      __builtin_amdgcn_s_barrier();
      __builtin_amdgcn_sched_barrier(0);
      if (t + 2 < 32) {
        const bf16* ga = gA + (t + 2) * 32;
        const bf16* gw = gW + (t + 2) * 32;
        bf16* bA = lds + (t & 1) * 8192 + sbase;
        bf16* bB = bA + 4096;
        async_copy16(ga, bA);
        async_copy16(gw, bB);
      }
    }
#pragma unroll
    for (int mi = 0; mi < 2; mi++) {
      int row = bm + wm * 32 + mi * 16 + fq * 4;
#pragma unroll
      for (int ni = 0; ni < 4; ni++) {
        int col = bn + wn * 64 + ni * 16 + fr;
        if (col < 4384) {
#pragma unroll
          for (int r = 0; r < 4; r++)
            bcdt[(size_t)(row + r) * 288 + (col - 4096)] = (bf16)acc[mi][ni][r];
        }
      }
    }
  }
}

// ---------------- generic 64x64 tiled transpose (bf16), out row stride 2048 ----------------
__global__ __launch_bounds__(256) void t64(const bf16* __restrict__ in, bf16* __restrict__ out,
                                           int istr, size_t io, size_t oo, int n_nt) {
  __shared__ bf16 T[64 * 72];
  int bid = blockIdx.x;
  int st = bid & 31;
  int nt = (bid >> 5) % n_nt;
  int outer = bid / (32 * n_nt);
  const bf16* ip = in + outer * io + (size_t)st * 64 * istr + nt * 64;
  int tid = threadIdx.x;
#pragma unroll
  for (int i = 0; i < 2; i++) {
    int cid = tid + i * 256; int s = cid >> 3, pc = (cid & 7) * 8;
    *(bf16x8*)(T + s * 72 + pc) = *(const bf16x8*)(ip + (size_t)s * istr + pc);
  }
  __syncthreads();
  bf16* op = out + outer * oo + (size_t)nt * 64 * 2048 + st * 64;
#pragma unroll
  for (int i = 0; i < 2; i++) {
    int cid = tid + i * 256; int p = cid >> 3, sc = (cid & 7) * 8;
    bf16x8 o;
#pragma unroll
    for (int j = 0; j < 8; j++) o[j] = T[(sc + j) * 72 + p];
    *(bf16x8*)(op + (size_t)p * 2048 + sc) = o;
  }
}

// ---------------- SSD prep: dt softplus, per-chunk cumsum, decay factors ----------------
__global__ __launch_bounds__(64) void ssd_prep(const bf16* __restrict__ bcdt,
                                               const float* __restrict__ dt_bias,
                                               const float* __restrict__ A_log,
                                               float* __restrict__ dt_c,
                                               float* __restrict__ ddc,
                                               float* __restrict__ ac_c,
                                               float* __restrict__ T_out) {
  int bid = blockIdx.x;
  int c = bid % NC, hh = (bid / NC) % NH, b = bid / (NC * NH);
  int l = threadIdx.x;
  size_t row = (size_t)b * S_ + c * 64 + l;
  float raw = (float)bcdt[row * 288 + 256 + hh] + dt_bias[hh];
  float dtv = (raw > 20.f) ? raw : log1pf(__expf(raw));
  float a = -__expf(A_log[hh]) * dtv;
  float ps = a;
#pragma unroll
  for (int off = 1; off < 64; off <<= 1) {
    float t = __shfl_up(ps, off, 64);
    if (l >= off) ps += t;
  }
  float a63 = __shfl(ps, 63, 64);
  size_t o = ((size_t)b * NH + hh) * S_ + c * 64 + l;
  dt_c[o] = dtv;
  ac_c[o] = ps;
  ddc[o] = __expf(a63 - ps) * dtv;
  if (l == 63) T_out[(b * NH + hh) * NC + c] = ps;
}

// ---------------- B/C rmsnorm (bf16 out) ----------------
__global__ __launch_bounds__(128) void bc_norm(const bf16* __restrict__ bcdt,
                                               const float* __restrict__ Bw,
                                               const float* __restrict__ Cw,
                                               bf16* __restrict__ Bn,
                                               bf16* __restrict__ Cn) {
  __shared__ float shb[2], shc[2];
  size_t row = blockIdx.x;
  int i = threadIdx.x;
  float bv = (float)bcdt[row * 288 + i];
  float cv = (float)bcdt[row * 288 + 128 + i];
  float sb = waveReduceSum(bv * bv);
  float sc = waveReduceSum(cv * cv);
  int lane = threadIdx.x & 63, wid = threadIdx.x >> 6;
  if (lane == 0) { shb[wid] = sb; shc[wid] = sc; }
  __syncthreads();
  float tb = shb[0] + shb[1];
  float tc = shc[0] + shc[1];
  Bn[row * DS + i] = (bf16)(bv * rsqrtf(tb / DS + 1e-5f) * Bw[i]);
  Cn[row * DS + i] = (bf16)(cv * rsqrtf(tc / DS + 1e-5f) * Cw[i]);
}

// ---------------- chunk states via MFMA (bf16 output) ----------------
__global__ __launch_bounds__(256) void ssd_states(const bf16* __restrict__ Xt,
                                                  const bf16* __restrict__ Btr,
                                                  const float* __restrict__ ddc,
                                                  bf16* __restrict__ states) {
  __shared__ bf16 Xs[64 * 72];    // [p][s]
  __shared__ bf16 Bs[128 * 72];   // [n][s]
  int bid = blockIdx.x;           // (b*NC + c)*NH + h
  int h = bid % NH;
  int c = (bid / NH) % NC;
  int b = bid / (NH * NC);
  int tid = threadIdx.x, lane = tid & 63, w = tid >> 6;
  int fr = lane & 15, fq = lane >> 4;
  const size_t xbase = (size_t)(b * NH + h) * HD * S_ + c * 64;
  const size_t dbase = (size_t)(b * NH + h) * S_ + c * 64;
#pragma unroll
  for (int i = 0; i < 2; i++) {
    int cid = tid + i * 256; int p = cid >> 3, sc = (cid & 7) * 8;
    bf16x8 xv = *(const bf16x8*)(Xt + xbase + (size_t)p * S_ + sc);
    f32x4 d0 = *(const f32x4*)(ddc + dbase + sc);
    f32x4 d1 = *(const f32x4*)(ddc + dbase + sc + 4);
    bf16x8 o;
#pragma unroll
    for (int j = 0; j < 4; j++) { o[j] = (bf16)((float)xv[j] * d0[j]); o[4 + j] = (bf16)((float)xv[4 + j] * d1[j]); }
    *(bf16x8*)(Xs + p * 72 + sc) = o;
  }
  const size_t bbase = (size_t)b * 128 * S_ + c * 64;
#pragma unroll
  for (int i = 0; i < 4; i++) {
    int cid = tid + i * 256; int n = cid >> 3, sc = (cid & 7) * 8;
    *(bf16x8*)(Bs + n * 72 + sc) = *(const bf16x8*)(Btr + bbase + (size_t)n * S_ + sc);
  }
  __syncthreads();
  f32x4 acc[4][2] = {};
#pragma unroll
  for (int ks = 0; ks < 2; ks++) {
    bf16x8 a[4], bb[2];
#pragma unroll
    for (int pt = 0; pt < 4; pt++) a[pt] = *(const bf16x8*)(Xs + (pt * 16 + fr) * 72 + ks * 32 + fq * 8);
#pragma unroll
    for (int n2 = 0; n2 < 2; n2++) bb[n2] = *(const bf16x8*)(Bs + ((2 * w + n2) * 16 + fr) * 72 + ks * 32 + fq * 8);
#pragma unroll
    for (int pt = 0; pt < 4; pt++)
#pragma unroll
      for (int n2 = 0; n2 < 2; n2++)
        acc[pt][n2] = __builtin_amdgcn_mfma_f32_16x16x32_bf16(a[pt], bb[n2], acc[pt][n2], 0, 0, 0);
  }
  bf16* outp = states + (size_t)bid * 8192;
#pragma unroll
  for (int pt = 0; pt < 4; pt++)
#pragma unroll
    for (int n2 = 0; n2 < 2; n2++) {
      int n = (2 * w + n2) * 16 + fr;
#pragma unroll
      for (int r = 0; r < 4; r++)
        outp[(size_t)(pt * 16 + fq * 4 + r) * 128 + n] = (bf16)acc[pt][n2][r];
    }
}

// ---------------- inter-chunk scan (in place, bf16 storage, f32 math) ----------------
__global__ __launch_bounds__(256) void ssd_scan(bf16* __restrict__ states,
                                                const float* __restrict__ T) {
  __shared__ float eT[NC];
  int part = blockIdx.x & 7;
  int bh = blockIdx.x >> 3;
  int b = bh / NH, h = bh % NH;
  if (threadIdx.x < NC) eT[threadIdx.x] = __expf(T[(size_t)(b * NH + h) * NC + threadIdx.x]);
  __syncthreads();
  const size_t cstride = (size_t)NH * HD * DS;
  size_t base = ((size_t)b * NC * NH + h) * (HD * DS);
#pragma unroll
  for (int j = 0; j < 4; j++) {
    int e = part * 1024 + threadIdx.x + j * 256;
    float carry = 0.f;
    size_t idx = base + e;
    for (int c = 0; c < NC; c++) {
      float sv = (float)states[idx];
      states[idx] = (bf16)carry;
      carry = sv + eT[c] * carry;
      idx += cstride;
    }
  }
}

// ---------------- fused SSD output: Ydiag + Yoff + D-skip + gate (all MFMA) ----------------
__global__ __launch_bounds__(256) void ssd_out(const bf16* __restrict__ Cn,
                                               const bf16* __restrict__ Bn,
                                               const bf16* __restrict__ Xt,
                                               const bf16* __restrict__ Zt,
                                               const float* __restrict__ dt_c,
                                               const float* __restrict__ ac_c,
                                               const bf16* __restrict__ states,
                                               const float* __restrict__ Dp,
                                               bf16* __restrict__ ybf) {
  __shared__ bf16 Cs[64 * 136];
  __shared__ bf16 BNs[64 * 136];
  __shared__ bf16 Xs[64 * 72];
  __shared__ bf16 G[64 * 72];
  __shared__ float acs[64];
  int bid = blockIdx.x;
  int h = bid % NH;
  int c = (bid / NH) % NC;
  int b = bid / (NH * NC);
  int tid = threadIdx.x, lane = tid & 63, w = tid >> 6;
  int fr = lane & 15, fq = lane >> 4;
  size_t row0 = (size_t)b * S_ + c * 64;
  const size_t abase = (size_t)(b * NH + h) * S_ + c * 64;
  if (tid < 64) acs[tid] = ac_c[abase + tid];
#pragma unroll
  for (int i = 0; i < 4; i++) {
    int cid = tid + i * 256; int l = cid >> 4, nc = (cid & 15) * 8;
    float e = __expf(ac_c[abase + l]);
    bf16x8 cv = *(const bf16x8*)(Cn + (row0 + l) * DS + nc);
    bf16x8 o;
#pragma unroll
    for (int j = 0; j < 8; j++) o[j] = (bf16)((float)cv[j] * e);
    *(bf16x8*)(Cs + l * 136 + nc) = o;
    *(bf16x8*)(BNs + l * 136 + nc) = *(const bf16x8*)(Bn + (row0 + l) * DS + nc);
  }
  const size_t xbase = (size_t)(b * NH + h) * HD * S_ + c * 64;
#pragma unroll
  for (int i = 0; i < 2; i++) {
    int cid = tid + i * 256; int p = cid >> 3, sc = (cid & 7) * 8;
    bf16x8 xv = *(const bf16x8*)(Xt + xbase + (size_t)p * S_ + sc);
    f32x4 d0 = *(const f32x4*)(dt_c + abase + sc);
    f32x4 d1 = *(const f32x4*)(dt_c + abase + sc + 4);
    bf16x8 o;
#pragma unroll
    for (int j = 0; j < 4; j++) { o[j] = (bf16)((float)xv[j] * d0[j]); o[4 + j] = (bf16)((float)xv[4 + j] * d1[j]); }
    *(bf16x8*)(Xs + p * 72 + sc) = o;
  }
  __syncthreads();
  bf16x8 ca[4];
#pragma unroll
  for (int ks = 0; ks < 4; ks++) ca[ks] = *(const bf16x8*)(Cs + (w * 16 + fr) * 136 + ks * 32 + fq * 8);
  f32x4 cb[4] = {};
  for (int st = 0; st <= w; st++)
#pragma unroll
    for (int ks = 0; ks < 4; ks++)
      cb[st] = __builtin_amdgcn_mfma_f32_16x16x32_bf16(ca[ks],
                 *(const bf16x8*)(BNs + (st * 16 + fr) * 136 + ks * 32 + fq * 8), cb[st], 0, 0, 0);
#pragma unroll
  for (int st = 0; st < 4; st++) {
    float es = (st <= w) ? __expf(-acs[st * 16 + fr]) : 0.f;
#pragma unroll
    for (int r = 0; r < 4; r++) {
      int lloc = fq * 4 + r;
      float g = 0.f;
      if (st < w) g = cb[st][r] * es;
      else if (st == w) g = (lloc >= fr) ? cb[st][r] * es : 0.f;
      G[(w * 16 + lloc) * 72 + st * 16 + fr] = (bf16)g;
    }
  }
  f32x4 acc[4] = {};
  {
    bf16x8 ga0 = *(const bf16x8*)(G + (w * 16 + fr) * 72 + fq * 8);
    bf16x8 ga1 = *(const bf16x8*)(G + (w * 16 + fr) * 72 + 32 + fq * 8);
#pragma unroll
    for (int pt = 0; pt < 4; pt++) {
      acc[pt] = __builtin_amdgcn_mfma_f32_16x16x32_bf16(ga0,
                  *(const bf16x8*)(Xs + (pt * 16 + fr) * 72 + fq * 8), acc[pt], 0, 0, 0);
      acc[pt] = __builtin_amdgcn_mfma_f32_16x16x32_bf16(ga1,
                  *(const bf16x8*)(Xs + (pt * 16 + fr) * 72 + 32 + fq * 8), acc[pt], 0, 0, 0);
    }
  }
  __syncthreads();
  const bf16* stp = states + (size_t)bid * 8192;
#pragma unroll
  for (int i = 0; i < 4; i++) {
    int cid = tid + i * 256; int p = cid >> 4, nc = (cid & 15) * 8;
    *(bf16x8*)(BNs + p * 136 + nc) = *(const bf16x8*)(stp + (size_t)p * 128 + nc);
  }
  __syncthreads();
#pragma unroll
  for (int pt = 0; pt < 4; pt++)
#pragma unroll
    for (int ks = 0; ks < 4; ks++)
      acc[pt] = __builtin_amdgcn_mfma_f32_16x16x32_bf16(ca[ks],
                  *(const bf16x8*)(BNs + (pt * 16 + fr) * 136 + ks * 32 + fq * 8), acc[pt], 0, 0, 0);
  float dph = Dp[h];
#pragma unroll
  for (int pt = 0; pt < 4; pt++) {
    int p = pt * 16 + fr;
    size_t tb = (xbase + (size_t)p * S_) + w * 16 + fq * 4;
    bf16x4 xs4 = *(const bf16x4*)(Xt + tb);
    bf16x4 z4  = *(const bf16x4*)(Zt + tb);
#pragma unroll
    for (int r = 0; r < 4; r++) {
      int l = w * 16 + fq * 4 + r;
      float yv = acc[pt][r] + (float)xs4[r] * dph;
      float z = (float)z4[r];
      yv *= z / (1.f + __expf(-z));
      ybf[((row0 + l) * NH + h) * HD + p] = (bf16)yv;
    }
  }
}

// ---------------- split-S MFMA flash attention (fixed-max softmax -> partials sum) ----------------
// Single-buffered K/V (LDS 36.9 KB -> 4 blocks/CU); prefetch issued after the
// second barrier so loads overlap compute and drain at next iter's first barrier.
#define KSTR 72
#define PSTR 72
__global__ __launch_bounds__(256) void attn_mfma(const bf16* __restrict__ q,
                                                 const bf16* __restrict__ k,
                                                 const bf16* __restrict__ vtr,
                                                 bf16* __restrict__ Po,
                                                 float* __restrict__ Ls) {
  __shared__ bf16 Ks[64 * KSTR];
  __shared__ bf16 Vs[64 * KSTR];
  __shared__ bf16 Pl[4][32 * PSTR];
  int c = 39 - blockIdx.x;                 // full 8-iter chunks first
  int g = (c < 4) ? 0 : (c < 12) ? 1 : (c < 24) ? 2 : 3;
  int gbase = (g == 0) ? 0 : (g == 1) ? 4 : (g == 2) ? 12 : 24;
  int d = c - gbase;
  int qt = 4 * g + d / (g + 1);
  int sk = d % (g + 1);
  int h = blockIdx.y, b = blockIdx.z;
  int kvh = h >> 2;
  int tid = threadIdx.x, lane = tid & 63, w = tid >> 6;
  int fr = lane & 15, fq = lane >> 4;
  const float SC = 0.18033688011112042f;   // 0.125 * log2(e)
  const float M2 = 62.0f;
  int kt0 = sk * 8;
  int ktend = min(kt0 + 8, 2 * qt + 2);
  int qbase = qt * 128 + w * 32;           // wave's first q row
  int qmaxw = qbase + 31;
  bf16x8 bq[2][2];
#pragma unroll
  for (int qc = 0; qc < 2; qc++)
#pragma unroll
    for (int ks = 0; ks < 2; ks++)
      bq[qc][ks] = *(const bf16x8*)(q + (size_t)(b * S_ + qbase + qc * 16 + fr) * (HATT * HD)
                                      + h * HD + ks * 32 + fq * 8);
  int sr = tid >> 3, sc8 = (tid & 7) * 8;
  const bf16* kg = k + ((size_t)(b * S_) + sr) * (KVH * HD) + kvh * HD + sc8;
  const bf16* vg = vtr + ((size_t)(b * KVH + kvh) * HD + sr) * S_ + sc8;
  bf16x8 krg0, krg1, vrg0, vrg1;
  {
    const bf16* kp = kg + (size_t)kt0 * 64 * (KVH * HD);
    const bf16* vp = vg + (size_t)kt0 * 64;
    krg0 = *(const bf16x8*)(kp);
    krg1 = *(const bf16x8*)(kp + (size_t)32 * (KVH * HD));
    vrg0 = *(const bf16x8*)(vp);
    vrg1 = *(const bf16x8*)(vp + (size_t)32 * S_);
  }
  float lsum[2] = {0.f, 0.f};
  f32x4 yacc[2][4] = {};
  bf16* Plw = Pl[w];
  for (int kt = kt0; kt < ktend; kt++) {
    __syncthreads();   // previous iteration's LDS reads complete
    *(bf16x8*)(&Ks[sr * KSTR + sc8]) = krg0;
    *(bf16x8*)(&Ks[(sr + 32) * KSTR + sc8]) = krg1;
    *(bf16x8*)(&Vs[sr * KSTR + sc8]) = vrg0;
    *(bf16x8*)(&Vs[(sr + 32) * KSTR + sc8]) = vrg1;
    __syncthreads();   // tile visible
    // prefetch next tile AFTER the barrier: loads overlap compute below
    if ((kt + 1) < ktend) {
      const bf16* kp = kg + (size_t)(kt + 1) * 64 * (KVH * HD);
      const bf16* vp = vg + (size_t)(kt + 1) * 64;
      krg0 = *(const bf16x8*)(kp);
      krg1 = *(const bf16x8*)(kp + (size_t)32 * (KVH * HD));
      vrg0 = *(const bf16x8*)(vp);
      vrg1 = *(const bf16x8*)(vp + (size_t)32 * S_);
    }
    if (kt * 64 <= qmaxw) {
      bool nomask = (kt * 64 + 63) <= qbase;
      if (nomask) {
#pragma unroll
        for (int mi = 0; mi < 4; mi++) {
          const bf16* krow = &Ks[(mi * 16 + fr) * KSTR];
          bf16x8 ak0 = *(const bf16x8*)(krow + fq * 8);
          bf16x8 ak1 = *(const bf16x8*)(krow + 32 + fq * 8);
#pragma unroll
          for (int qc = 0; qc < 2; qc++) {
            f32x4 s = {};
            s = __builtin_amdgcn_mfma_f32_16x16x32_bf16(ak0, bq[qc][0], s, 0, 0, 0);
            s = __builtin_amdgcn_mfma_f32_16x16x32_bf16(ak1, bq[qc][1], s, 0, 0, 0);
            bf16x4 pk;
#pragma unroll
            for (int r = 0; r < 4; r++) {
              float p = __builtin_amdgcn_exp2f(s[r] * SC - M2);
              lsum[qc] += p;
              pk[r] = (bf16)p;
            }
            *(bf16x4*)(Plw + (qc * 16 + fr) * PSTR + mi * 16 + fq * 4) = pk;
          }
        }
      } else {
#pragma unroll
        for (int mi = 0; mi < 4; mi++) {
          int s0 = kt * 64 + mi * 16;
          if (s0 > qmaxw) {
            bf16x4 zz = {};
#pragma unroll
            for (int qc = 0; qc < 2; qc++)
              *(bf16x4*)(Plw + (qc * 16 + fr) * PSTR + mi * 16 + fq * 4) = zz;
          } else {
            const bf16* krow = &Ks[(mi * 16 + fr) * KSTR];
            bf16x8 ak0 = *(const bf16x8*)(krow + fq * 8);
            bf16x8 ak1 = *(const bf16x8*)(krow + 32 + fq * 8);
#pragma unroll
            for (int qc = 0; qc < 2; qc++) {
              f32x4 s = {};
              s = __builtin_amdgcn_mfma_f32_16x16x32_bf16(ak0, bq[qc][0], s, 0, 0, 0);
              s = __builtin_amdgcn_mfma_f32_16x16x32_bf16(ak1, bq[qc][1], s, 0, 0, 0);
              int qq = qbase + qc * 16 + fr;
              bf16x4 pk;
#pragma unroll
              for (int r = 0; r < 4; r++) {
                int sp = s0 + fq * 4 + r;
                float p = (sp <= qq) ? __builtin_amdgcn_exp2f(s[r] * SC - M2) : 0.f;
                lsum[qc] += p;
                pk[r] = (bf16)p;
              }
              *(bf16x4*)(Plw + (qc * 16 + fr) * PSTR + mi * 16 + fq * 4) = pk;
            }
          }
        }
      }
#pragma unroll
      for (int ks2 = 0; ks2 < 2; ks2++) {
        bf16x8 bp[2];
#pragma unroll
        for (int qc = 0; qc < 2; qc++)
          bp[qc] = *(const bf16x8*)(Plw + (qc * 16 + fr) * PSTR + ks2 * 32 + fq * 8);
#pragma unroll
        for (int pi = 0; pi < 4; pi++) {
          bf16x8 av = *(const bf16x8*)(&Vs[(pi * 16 + fr) * KSTR + ks2 * 32 + fq * 8]);
#pragma unroll
          for (int qc = 0; qc < 2; qc++)
            yacc[qc][pi] = __builtin_amdgcn_mfma_f32_16x16x32_bf16(av, bp[qc], yacc[qc][pi], 0, 0, 0);
        }
      }
    }
  }
#pragma unroll
  for (int qc = 0; qc < 2; qc++) {
    lsum[qc] += __shfl_xor(lsum[qc], 16, 64);
    lsum[qc] += __shfl_xor(lsum[qc], 32, 64);
    int qrow = qt * 128 + w * 32 + qc * 16 + fr;
    if (fq == 0)
      Ls[((size_t)(b * 16 + h) * 2048 + qrow) * 4 + sk] = lsum[qc];
    bf16* pop = Po + ((((size_t)(b * 16 + h) * 16 + qt) * 4 + sk) * 128
                       + w * 32 + qc * 16 + fr) * 64 + fq * 4;
#pragma unroll
    for (int pi = 0; pi < 4; pi++) {
      bf16x4 o;
#pragma unroll
      for (int r = 0; r < 4; r++) o[r] = (bf16)yacc[qc][pi][r];
      *(bf16x4*)(pop + pi * 16) = o;
    }
  }
}

// ---------------- attention partial combine + normalize -> y2 bf16 ----------------
__global__ __launch_bounds__(256) void attn_red(const bf16* __restrict__ Po,
                                                const float* __restrict__ Ls,
                                                bf16* __restrict__ y2) {
  int row = blockIdx.x;            // 0..4095
  int b = row >> 11;
  int qrow = row & 2047;
  int qt = qrow >> 7, r = qrow & 127;
  int nch = (qt >> 2) + 1;
  int t = threadIdx.x;
  int h = t >> 4, e4 = (t & 15) << 2;
  const float* lp = Ls + ((size_t)(b * 16 + h) * 2048 + qrow) * 4;
  float ls = 0.f;
  f32x4 acc = {};
  for (int sk = 0; sk < nch; sk++) {
    ls += lp[sk];
    const bf16* pp = Po + ((((size_t)(b * 16 + h) * 16 + qt) * 4 + sk) * 128 + r) * 64 + e4;
    bf16x4 v = *(const bf16x4*)(pp);
#pragma unroll
    for (int j = 0; j < 4; j++) acc[j] += (float)v[j];
  }
  float inv = 1.f / ls;
  bf16x4 o;
#pragma unroll
  for (int j = 0; j < 4; j++) o[j] = (bf16)(acc[j] * inv);
  *(bf16x4*)(y2 + (size_t)row * 1024 + h * 64 + e4) = o;
}

// ---------------- workspace layout (byte offsets) ----------------
constexpr size_t OFF_WIN  = 0;                   // bf16 4480x1024
constexpr size_t OFF_WOUT = 9175040;             // bf16 1024x2048
constexpr size_t OFF_WQKV = 13369344;            // bf16 1536x1024 (q|k|v rows)
constexpr size_t OFF_WCP  = 16515072;            // bf16 1024x1024
constexpr size_t OFF_WFC  = 18612224;            // bf16 3072x1024
constexpr size_t OFF_WPR  = 24903680;            // bf16 1024x3072
constexpr size_t OFF_HBF  = 31195136;            // bf16 4096x1024
constexpr size_t OFF_BCDT = 39583744;            // bf16 4096x288; reused: Ls f32 (1 MiB)
constexpr size_t OFF_XT   = 41943040;            // bf16 [b][h][p][sg] (16.7 MB)
constexpr size_t OFF_ZT   = 58720256;            // bf16 [b][h][p][sg] (16.7 MB)
constexpr size_t OFF_DTC  = 75497472;            // f32 [b][h][sg]
constexpr size_t OFF_DDC  = 76546048;            // f32
constexpr size_t OFF_ACC  = 77594624;            // f32
constexpr size_t OFF_T    = 78643200;            // f32 2048
constexpr size_t OFF_BN   = 78651392;            // bf16 4096x128
constexpr size_t OFF_CN   = 79699968;            // bf16 4096x128
constexpr size_t OFF_BTR  = 80748544;            // bf16 [b][n][sg]
constexpr size_t OFF_ST   = 81797120;            // bf16 states (33.5 MB); reused: Po bf16 32 MiB
constexpr size_t OFF_YBF  = 148905984;           // bf16 4096x2048
constexpr size_t OFF_X1   = 165683200;           // f32 4096x1024 (end 182,460,416)
// phase-2 aliases
constexpr size_t OFF_P    = OFF_ST;              // bf16 split-K partials (<= 25.2 MB)
constexpr size_t OFF_PO   = OFF_ST;              // bf16 attn partials [b][h][qt][4][128][64] = 32 MiB
constexpr size_t OFF_LS   = OFF_BCDT;            // f32 attn lsums [b][h][2048][4] = 1 MiB
constexpr size_t OFF_QB   = OFF_XT;              // bf16 4096x1024 (8.4 MB)
constexpr size_t OFF_KB   = OFF_XT + 8388608;    // bf16 4096x256
constexpr size_t OFF_VB   = OFF_XT + 10485760;   // bf16 4096x256
constexpr size_t OFF_VTR  = OFF_XT + 12582912;   // bf16 [b][kvh][p][sg]
constexpr size_t OFF_Y2   = OFF_ZT;              // bf16 4096x1024
constexpr size_t OFF_X2   = 50331648;            // f32 4096x1024 (over dead kb/vb/vtr/y2)
constexpr size_t OFF_MLP  = 132128768;           // bf16 4096x3072 (over dead regions)

extern "C" void kernel_launch(void* const* d_in, const int* in_sizes, int n_in,
                              void* d_out, int out_size, void* d_ws, size_t ws_size,
                              hipStream_t stream) {
  (void)in_sizes; (void)n_in; (void)out_size; (void)ws_size;
  const float* x        = (const float*)d_in[0];
  const float* mnorm_w  = (const float*)d_in[1];
  const float* in_w     = (const float*)d_in[2];
  const float* out_w    = (const float*)d_in[3];
  const float* Dp       = (const float*)d_in[4];
  const float* dt_bias  = (const float*)d_in[5];
  const float* A_log    = (const float*)d_in[6];
  const float* Bn_w     = (const float*)d_in[7];
  const float* Cn_w     = (const float*)d_in[8];
  const float* ln1_w    = (const float*)d_in[9];
  const float* ln1_b    = (const float*)d_in[10];
  const float* cq_w     = (const float*)d_in[11];
  const float* ck_w     = (const float*)d_in[12];
  const float* cv_w     = (const float*)d_in[13];
  const float* cproj_w  = (const float*)d_in[14];
  const float* q_gain   = (const float*)d_in[15];
  const float* ln2_w    = (const float*)d_in[16];
  const float* ln2_b    = (const float*)d_in[17];
  const float* fc_w     = (const float*)d_in[18];
  const float* proj_w   = (const float*)d_in[19];
  float* out = (float*)d_out;
  char* W8 = (char*)d_ws;

  bf16* w_in   = (bf16*)(W8 + OFF_WIN);
  bf16* w_out  = (bf16*)(W8 + OFF_WOUT);
  bf16* w_qkv  = (bf16*)(W8 + OFF_WQKV);
  bf16* w_cp   = (bf16*)(W8 + OFF_WCP);
  bf16* w_fc   = (bf16*)(W8 + OFF_WFC);
  bf16* w_pr   = (bf16*)(W8 + OFF_WPR);
  bf16* h_bf   = (bf16*)(W8 + OFF_HBF);
  bf16* bcdt   = (bf16*)(W8 + OFF_BCDT);
  bf16* Xt     = (bf16*)(W8 + OFF_XT);
  bf16* Zt     = (bf16*)(W8 + OFF_ZT);
  float* dt_c  = (float*)(W8 + OFF_DTC);
  float* ddc   = (float*)(W8 + OFF_DDC);
  float* ac_c  = (float*)(W8 + OFF_ACC);
  float* Tb    = (float*)(W8 + OFF_T);
  bf16* Bn     = (bf16*)(W8 + OFF_BN);
  bf16* Cn     = (bf16*)(W8 + OFF_CN);
  bf16* Btr    = (bf16*)(W8 + OFF_BTR);
  bf16* st     = (bf16*)(W8 + OFF_ST);
  bf16* ybf    = (bf16*)(W8 + OFF_YBF);
  float* x1    = (float*)(W8 + OFF_X1);
  bf16* Pbuf   = (bf16*)(W8 + OFF_P);
  bf16* Po     = (bf16*)(W8 + OFF_PO);
  float* Ls    = (float*)(W8 + OFF_LS);
  bf16* qbf    = (bf16*)(W8 + OFF_QB);
  bf16* kbf    = (bf16*)(W8 + OFF_KB);
  bf16* vbf    = (bf16*)(W8 + OFF_VB);
  bf16* vtr    = (bf16*)(W8 + OFF_VTR);
  bf16* y2     = (bf16*)(W8 + OFF_Y2);
  float* x2    = (float*)(W8 + OFF_X2);
  bf16* mlp    = (bf16*)(W8 + OFF_MLP);

  // ---- weight casts (single launch; q/k/v cast into adjacent rows of w_qkv) ----
  CastArgs ca;
  ca.seg[0] = { in_w,    w_in,            4489216, 4587520, 0     };
  ca.seg[1] = { out_w,   w_out,           2097152, 2097152, 4480  };
  ca.seg[2] = { cq_w,    w_qkv,           1048576, 1048576, 6528  };
  ca.seg[3] = { ck_w,    w_qkv + 1048576,  262144,  262144, 7552  };
  ca.seg[4] = { cv_w,    w_qkv + 1310720,  262144,  262144, 7808  };
  ca.seg[5] = { cproj_w, w_cp,            1048576, 1048576, 8064  };
  ca.seg[6] = { fc_w,    w_fc,            3145728, 3145728, 9088  };
  ca.seg[7] = { proj_w,  w_pr,            3145728, 3145728, 12160 };
  castw_all<<<15232, 256, 0, stream>>>(ca);

  const size_t PS  = (size_t)ROWS * 1024;   // partial stride (elements) for N=1024 GEMMs

  // ---- mamba block ----
  rmsnorm_k<<<ROWS, 256, 0, stream>>>(x, mnorm_w, h_bf, D_);
  gemm256_inproj<<<352, 512, 0, stream>>>(h_bf, w_in, Zt, Xt, bcdt);
  ssd_prep<<<B_ * NH * NC, 64, 0, stream>>>(bcdt, dt_bias, A_log, dt_c, ddc, ac_c, Tb);
  bc_norm<<<ROWS, 128, 0, stream>>>(bcdt, Bn_w, Cn_w, Bn, Cn);
  t64<<<2 * 2 * 32, 256, 0, stream>>>(Bn, Btr, 128, (size_t)2048 * 128, (size_t)128 * 2048, 2);
  ssd_states<<<B_ * NC * NH, 256, 0, stream>>>(Xt, Btr, ddc, st);
  ssd_scan<<<B_ * NH * 8, 256, 0, stream>>>(st, Tb);
  ssd_out<<<B_ * NC * NH, 256, 0, stream>>>(Cn, Bn, Xt, Zt, dt_c, ac_c, st, Dp, ybf);
  // out_proj: split-K=2 then fused reduce+residual+LN1
  gemm_sk<<<dim3(32 * 8, 1, 2), 256, 0, stream>>>(ybf, w_out, Pbuf, ROWS, D_, DI, 1024);
  reduce_ln2<<<ROWS, 256, 0, stream>>>(Pbuf, Pbuf + PS, x, ln1_w, ln1_b, x1, h_bf);

  // ---- attention block ----
  gemm_sk<<<dim3(32 * 12, 1, 2), 256, 0, stream>>>(h_bf, w_qkv, Pbuf, ROWS, 1536, D_, 512);
  reduce_qkv<<<ROWS, 256, 0, stream>>>(Pbuf, q_gain, qbf, kbf, vbf);
  t64<<<2 * 4 * 32, 256, 0, stream>>>(vbf, vtr, 256, (size_t)2048 * 256, (size_t)256 * 2048, 4);
  attn_mfma<<<dim3(40, HATT, B_), 256, 0, stream>>>(qbf, kbf, vtr, Po, Ls);
  attn_red<<<ROWS, 256, 0, stream>>>(Po, Ls, y2);
  gemm_sk<<<dim3(32 * 8, 1, 2), 256, 0, stream>>>(y2, w_cp, Pbuf, ROWS, D_, D_, 512);
  reduce_ln2<<<ROWS, 256, 0, stream>>>(Pbuf, Pbuf + PS, x1, ln2_w, ln2_b, x2, h_bf);

  // ---- MLP ----
  gemm_mfma<1, bf16><<<32 * 24, 256, 0, stream>>>(h_bf, w_fc, nullptr, mlp, ROWS, MLP, D_);
  gemm_sk<<<dim3(32 * 8, 1, 3), 256, 0, stream>>>(mlp, w_pr, Pbuf, ROWS, D_, MLP, 1024);
  reduce_out3<<<ROWS, 256, 0, stream>>>(Pbuf, Pbuf + PS, Pbuf + 2 * PS, x2, out);
}

// Round 5
// 524.570 us; speedup vs baseline: 1.4206x; 1.4206x over previous
//
#include <hip/hip_runtime.h>
#include <hip/hip_bf16.h>
#include <math.h>

// ---------------- problem constants ----------------
#define B_    2
#define S_    2048
#define D_    1024
#define DI    2048      // D_INNER
#define NH    32        // NHEADS (mamba)
#define HD    64        // HEADDIM
#define DS    128       // D_STATE
#define CH    64        // CHUNK
#define NC    32        // S_/CH
#define DP    4384      // D_PROJ
#define HATT  16        // attention heads
#define KVH   4         // kv heads
#define RD    16        // rope dims
#define MLP   3072
#define ROWS  (B_*S_)   // 4096

typedef __bf16 bf16;
typedef __bf16 bf16x8 __attribute__((ext_vector_type(8)));
typedef __bf16 bf16x4 __attribute__((ext_vector_type(4)));
typedef float  f32x4  __attribute__((ext_vector_type(4)));

__device__ __forceinline__ void async_copy16(const void* g, void* l) {
  __builtin_amdgcn_global_load_lds(
      (const __attribute__((address_space(1))) unsigned int*)g,
      (__attribute__((address_space(3))) unsigned int*)l, 16, 0, 0);
}

// ---------------- reductions ----------------
__device__ __forceinline__ float waveReduceSum(float v) {
#pragma unroll
  for (int off = 32; off > 0; off >>= 1) v += __shfl_down(v, off, 64);
  return v;
}

template<int NW>
__device__ __forceinline__ float blockReduceSum(float v, float* sh) {
  v = waveReduceSum(v);
  int lane = threadIdx.x & 63, wid = threadIdx.x >> 6;
  if (lane == 0) sh[wid] = v;
  __syncthreads();
  float s = 0.f;
#pragma unroll
  for (int i = 0; i < NW; i++) s += sh[i];
  __syncthreads();
  return s;
}

// ---------------- merged weight cast f32 -> bf16 ----------------
struct CastSeg { const float* src; bf16* dst; int nval; int ntot; int blk0; };
struct CastArgs { CastSeg seg[8]; };

__global__ __launch_bounds__(256) void castw_all(CastArgs a) {
  int blk = blockIdx.x;
  int si = 0;
#pragma unroll
  for (int i = 1; i < 8; i++) if (blk >= a.seg[i].blk0) si = i;
  CastSeg s = a.seg[si];
  int i = ((blk - s.blk0) * 256 + threadIdx.x) * 4;
  if (i >= s.ntot) return;
  float4 v = {0.f, 0.f, 0.f, 0.f};
  if (i < s.nval) v = *(const float4*)(s.src + i);
  bf16x4 o;
  o[0] = (bf16)v.x; o[1] = (bf16)v.y; o[2] = (bf16)v.z; o[3] = (bf16)v.w;
  *(bf16x4*)(s.dst + i) = o;
}

// ---------------- rmsnorm (f32 in, bf16 out) ----------------
__global__ __launch_bounds__(256) void rmsnorm_k(const float* __restrict__ x,
                                                 const float* __restrict__ w,
                                                 bf16* __restrict__ y, int n) {
  __shared__ float sh[4];
  size_t row = blockIdx.x;
  const float* xr = x + row * n;
  bf16* yr = y + row * n;
  float ss = 0.f;
  for (int i = threadIdx.x; i < n; i += 256) { float v = xr[i]; ss += v * v; }
  ss = blockReduceSum<4>(ss, sh);
  float inv = rsqrtf(ss / n + 1e-5f);
  for (int i = threadIdx.x; i < n; i += 256) yr[i] = (bf16)(xr[i] * inv * w[i]);
}

// ---------------- generic bf16 MFMA GEMM: C = act(A @ W^T), bm-fastest 1D grid ----------------
template<int ACT, typename OT>
__global__ __launch_bounds__(256) void gemm_mfma(const bf16* __restrict__ A,
                                                 const bf16* __restrict__ W,
                                                 const float* __restrict__ R,
                                                 OT* __restrict__ C,
                                                 int M, int N, int K) {
  __shared__ bf16 As[128 * 32];
  __shared__ bf16 Ws[128 * 32];
  int tid = threadIdx.x, lane = tid & 63, wave = tid >> 6;
  int mt = M >> 7;
  int bid = blockIdx.x;
  int bm = (bid % mt) * 128, bn = (bid / mt) * 128;
  const bf16* gA0 = A + (size_t)(bm + wave * 32 + (lane >> 2)) * K + (lane & 3) * 8;
  const bf16* gA1 = gA0 + (size_t)16 * K;
  const bf16* gW0 = W + (size_t)(bn + wave * 32 + (lane >> 2)) * K + (lane & 3) * 8;
  const bf16* gW1 = gW0 + (size_t)16 * K;
  bf16* lA0 = As + wave * 32 * 32;
  bf16* lA1 = lA0 + 16 * 32;
  bf16* lW0 = Ws + wave * 32 * 32;
  bf16* lW1 = lW0 + 16 * 32;
  int fr = lane & 15, fq = lane >> 4;
  int wm = wave >> 1, wn = wave & 1;
  const bf16* pA = As + (wm * 64 + fr) * 32 + fq * 8;
  const bf16* pW = Ws + (wn * 64 + fr) * 32 + fq * 8;
  f32x4 acc[4][4] = {};
  for (int k0 = 0; k0 < K; k0 += 32) {
    async_copy16(gA0, lA0);
    async_copy16(gA1, lA1);
    async_copy16(gW0, lW0);
    async_copy16(gW1, lW1);
    gA0 += 32; gA1 += 32; gW0 += 32; gW1 += 32;
    __syncthreads();
    bf16x8 af[4], bfr[4];
#pragma unroll
    for (int mi = 0; mi < 4; mi++) af[mi] = *(const bf16x8*)(pA + mi * 16 * 32);
#pragma unroll
    for (int ni = 0; ni < 4; ni++) bfr[ni] = *(const bf16x8*)(pW + ni * 16 * 32);
#pragma unroll
    for (int mi = 0; mi < 4; mi++)
#pragma unroll
      for (int ni = 0; ni < 4; ni++)
        acc[mi][ni] = __builtin_amdgcn_mfma_f32_16x16x32_bf16(af[mi], bfr[ni], acc[mi][ni], 0, 0, 0);
    __syncthreads();
  }
#pragma unroll
  for (int mi = 0; mi < 4; mi++) {
    int row = bm + wm * 64 + mi * 16 + fq * 4;
#pragma unroll
    for (int ni = 0; ni < 4; ni++) {
      int col = bn + wn * 64 + ni * 16 + fr;
      if (col < N) {
#pragma unroll
        for (int r = 0; r < 4; r++) {
          float v = acc[mi][ni][r];
          if (ACT == 1) v = v / (1.f + __expf(-v));
          if (R) v += R[(size_t)(row + r) * N + col];
          C[(size_t)(row + r) * N + col] = (OT)v;
        }
      }
    }
  }
}

// ---------------- split-K bf16 MFMA GEMM: P[ks] = A @ W^T (bf16 partials) ----------------
__global__ __launch_bounds__(256) void gemm_sk(const bf16* __restrict__ A,
                                               const bf16* __restrict__ W,
                                               bf16* __restrict__ P,
                                               int M, int N, int K, int kchunk) {
  __shared__ bf16 As[128 * 32];
  __shared__ bf16 Ws[128 * 32];
  int tid = threadIdx.x, lane = tid & 63, wave = tid >> 6;
  int mt = M >> 7;
  int bid = blockIdx.x;
  int bm = (bid % mt) * 128, bn = (bid / mt) * 128;
  int ks = blockIdx.z;
  int kbeg = ks * kchunk;
  const bf16* gA0 = A + (size_t)(bm + wave * 32 + (lane >> 2)) * K + kbeg + (lane & 3) * 8;
  const bf16* gA1 = gA0 + (size_t)16 * K;
  const bf16* gW0 = W + (size_t)(bn + wave * 32 + (lane >> 2)) * K + kbeg + (lane & 3) * 8;
  const bf16* gW1 = gW0 + (size_t)16 * K;
  bf16* lA0 = As + wave * 32 * 32;
  bf16* lA1 = lA0 + 16 * 32;
  bf16* lW0 = Ws + wave * 32 * 32;
  bf16* lW1 = lW0 + 16 * 32;
  int fr = lane & 15, fq = lane >> 4;
  int wm = wave >> 1, wn = wave & 1;
  const bf16* pA = As + (wm * 64 + fr) * 32 + fq * 8;
  const bf16* pW = Ws + (wn * 64 + fr) * 32 + fq * 8;
  f32x4 acc[4][4] = {};
  for (int k0 = 0; k0 < kchunk; k0 += 32) {
    async_copy16(gA0, lA0);
    async_copy16(gA1, lA1);
    async_copy16(gW0, lW0);
    async_copy16(gW1, lW1);
    gA0 += 32; gA1 += 32; gW0 += 32; gW1 += 32;
    __syncthreads();
    bf16x8 af[4], bfr[4];
#pragma unroll
    for (int mi = 0; mi < 4; mi++) af[mi] = *(const bf16x8*)(pA + mi * 16 * 32);
#pragma unroll
    for (int ni = 0; ni < 4; ni++) bfr[ni] = *(const bf16x8*)(pW + ni * 16 * 32);
#pragma unroll
    for (int mi = 0; mi < 4; mi++)
#pragma unroll
      for (int ni = 0; ni < 4; ni++)
        acc[mi][ni] = __builtin_amdgcn_mfma_f32_16x16x32_bf16(af[mi], bfr[ni], acc[mi][ni], 0, 0, 0);
    __syncthreads();
  }
  bf16* Pp = P + (size_t)ks * M * N;
#pragma unroll
  for (int mi = 0; mi < 4; mi++) {
    int row = bm + wm * 64 + mi * 16 + fq * 4;
#pragma unroll
    for (int ni = 0; ni < 4; ni++) {
      int col = bn + wn * 64 + ni * 16 + fr;
#pragma unroll
      for (int r = 0; r < 4; r++)
        Pp[(size_t)(row + r) * N + col] = (bf16)acc[mi][ni][r];
    }
  }
}

// ---------------- reduce 2 bf16 partials + residual + layernorm -> x_out f32, h bf16 ----------------
__global__ __launch_bounds__(256) void reduce_ln2(const bf16* __restrict__ p0,
                                                  const bf16* __restrict__ p1,
                                                  const float* __restrict__ res,
                                                  const float* __restrict__ w,
                                                  const float* __restrict__ b,
                                                  float* __restrict__ xo,
                                                  bf16* __restrict__ ho) {
  __shared__ float sh[4];
  size_t o = (size_t)blockIdx.x * 1024;
  int i = threadIdx.x * 4;
  bf16x4 a = *(const bf16x4*)(p0 + o + i);
  bf16x4 c = *(const bf16x4*)(p1 + o + i);
  f32x4 rv = *(const f32x4*)(res + o + i);
  f32x4 v;
  float s = 0.f, s2 = 0.f;
#pragma unroll
  for (int j = 0; j < 4; j++) {
    v[j] = (float)a[j] + (float)c[j] + rv[j];
    s += v[j]; s2 += v[j] * v[j];
  }
  s  = blockReduceSum<4>(s,  sh);
  s2 = blockReduceSum<4>(s2, sh);
  float mean = s / 1024.f;
  float var  = s2 / 1024.f - mean * mean;
  float inv  = rsqrtf(var + 1e-5f);
  f32x4 wv = *(const f32x4*)(w + i);
  f32x4 bv = *(const f32x4*)(b + i);
  *(f32x4*)(xo + o + i) = v;
  bf16x4 hv;
#pragma unroll
  for (int j = 0; j < 4; j++) hv[j] = (bf16)((v[j] - mean) * inv * wv[j] + bv[j]);
  *(bf16x4*)(ho + o + i) = hv;
}

// ---------------- reduce 3 bf16 partials + residual -> out f32 ----------------
__global__ __launch_bounds__(256) void reduce_out3(const bf16* __restrict__ p0,
                                                   const bf16* __restrict__ p1,
                                                   const bf16* __restrict__ p2,
                                                   const float* __restrict__ res,
                                                   float* __restrict__ out) {
  int i = (blockIdx.x * 256 + threadIdx.x) * 4;
  bf16x4 a = *(const bf16x4*)(p0 + i);
  bf16x4 c = *(const bf16x4*)(p1 + i);
  bf16x4 d = *(const bf16x4*)(p2 + i);
  f32x4 v = *(const f32x4*)(res + i);
#pragma unroll
  for (int j = 0; j < 4; j++) v[j] += (float)a[j] + (float)c[j] + (float)d[j];
  *(f32x4*)(out + i) = v;
}

// ---------------- reduce qkv bf16 partials + q/k rmsnorm + rope + gain -> bf16 ----------------
__global__ __launch_bounds__(256) void reduce_qkv(const bf16* __restrict__ P,
                                                  const float* __restrict__ q_gain,
                                                  bf16* __restrict__ q,
                                                  bf16* __restrict__ k,
                                                  bf16* __restrict__ v) {
  __shared__ float buf[1536];
  size_t row = blockIdx.x;
  size_t o = row * 1536;
  const bf16* p0 = P + o;
  const bf16* p1 = P + (size_t)ROWS * 1536 + o;
  int tid = threadIdx.x;
  for (int i = tid; i < 384; i += 256) {
    bf16x4 a = *(const bf16x4*)(p0 + i * 4);
    bf16x4 c = *(const bf16x4*)(p1 + i * 4);
    f32x4 vv;
#pragma unroll
    for (int j = 0; j < 4; j++) vv[j] = (float)a[j] + (float)c[j];
    *(f32x4*)(buf + i * 4) = vv;
  }
  __syncthreads();
  int lane = tid & 63, w = tid >> 6;
  int s = (int)(row & (S_ - 1));
  int ri = lane & 7;
  float rinv = __expf(-(float)ri * (0.125f * 9.210340371976184f)); // 10000^(-i/8)
  float ang = (float)s * rinv;
  float cs = cosf(ang), sn = sinf(ang);
#pragma unroll
  for (int j = 0; j < 6; j++) {
    int hh = w * 6 + j;
    float val = buf[hh * 64 + lane];
    if (hh < 20) {
      float ss = val * val;
#pragma unroll
      for (int off = 32; off > 0; off >>= 1) ss += __shfl_xor(ss, off, 64);
      val *= rsqrtf(ss / 64.f + 1.1920929e-7f);
      float other = __shfl_xor(val, 8, 64);
      float res = val;
      if (lane < RD) res = (lane < 8) ? (val * cs + other * sn) : (val * cs - other * sn);
      if (hh < 16) {
        res *= q_gain[hh];
        q[row * (HATT * HD) + hh * HD + lane] = (bf16)res;
      } else {
        k[row * (KVH * HD) + (hh - 16) * HD + lane] = (bf16)res;
      }
    } else {
      v[row * (KVH * HD) + (hh - 20) * HD + lane] = (bf16)val;
    }
  }
}

// ---------------- in_proj GEMM: 256 heavy 256^2 blocks (z/x) + 96 light 128^2 blocks (bcdt) ----
// R4 post-mortem: __launch_bounds__(512,4) capped regs at ~128/wave -> accumulator spill to
// scratch (925 MB writes, 285us). Fix: (512,2) -> ~224 regs (96 arch + AGPR acc), no spill
// (R3's compile). Schedule (functionally verified in R4): per K-step {vmcnt(4): tile t
// landed, t+1 in flight; barrier; 12 swizzled ds_read_b128; setprio(1); 32 MFMA;
// setprio(0); barrier (buf t&1 reads done -> WAR safe); stage tile t+2 into buf t&1}.
// vmcnt never drains mid-loop (T4). Grid: 256 heavy (exactly 1 round at 1 block/CU)
// + 96 light 128^2 blocks for the bcdt strip.
__global__ __launch_bounds__(512, 2) void gemm256_inproj(const bf16* __restrict__ A,
                                                         const bf16* __restrict__ W,
                                                         bf16* __restrict__ zt,
                                                         bf16* __restrict__ xt,
                                                         bf16* __restrict__ bcdt) {
  __shared__ bf16 lds[2 * 16384];          // 64 KB
  int tid = threadIdx.x;
  int lane = tid & 63, w = tid >> 6;       // 8 waves
  int fr = lane & 15, fq = lane >> 4;
  int rdswz = (fq ^ (fr & 3)) * 8;
  int sswz = (lane & 3) ^ ((lane >> 2) & 3);
  int bid = blockIdx.x;
  if (bid < 256) {
    int sb = (bid & 7) * 32 + (bid >> 3);  // XCD swizzle (256 = 8*32)
    int bm = (sb & 15) * 256;
    int bn = (sb >> 4) * 256;
    int wm = w >> 2, wn = w & 3;           // 2M x 4N waves: per wave 128x64
    int srow = w * 32 + (lane >> 2);
    const bf16* gA = A + (size_t)(bm + srow) * 1024 + sswz * 8;
    const bf16* gW = W + (size_t)(bn + srow) * 1024 + sswz * 8;
    int sbase = w * 1024;                  // wave's 32-row stage region (elems)
    f32x4 acc[8][4] = {};
    {
      bf16* bA = lds + sbase;
      bf16* bB = lds + 8192 + sbase;
      async_copy16(gA, bA);               async_copy16(gA + 16 * 1024, bA + 512);
      async_copy16(gW, bB);               async_copy16(gW + 16 * 1024, bB + 512);
      bf16* cA2 = bA + 16384; bf16* cB2 = bB + 16384;
      async_copy16(gA + 32, cA2);         async_copy16(gA + 32 + 16 * 1024, cA2 + 512);
      async_copy16(gW + 32, cB2);         async_copy16(gW + 32 + 16 * 1024, cB2 + 512);
    }
    for (int t = 0; t < 32; t++) {
      if (t < 31) asm volatile("s_waitcnt vmcnt(4)" ::: "memory");
      else        asm volatile("s_waitcnt vmcnt(0)" ::: "memory");
      __builtin_amdgcn_sched_barrier(0);
      __builtin_amdgcn_s_barrier();
      __builtin_amdgcn_sched_barrier(0);
      const bf16* cA = lds + (t & 1) * 16384;
      const bf16* cB = cA + 8192;
      bf16x8 af[8], bfv[4];
#pragma unroll
      for (int mi = 0; mi < 8; mi++)
        af[mi] = *(const bf16x8*)(cA + (wm * 128 + mi * 16 + fr) * 32 + rdswz);
#pragma unroll
      for (int ni = 0; ni < 4; ni++)
        bfv[ni] = *(const bf16x8*)(cB + (wn * 64 + ni * 16 + fr) * 32 + rdswz);
      __builtin_amdgcn_s_setprio(1);
#pragma unroll
      for (int mi = 0; mi < 8; mi++)
#pragma unroll
        for (int ni = 0; ni < 4; ni++)
          acc[mi][ni] = __builtin_amdgcn_mfma_f32_16x16x32_bf16(af[mi], bfv[ni], acc[mi][ni], 0, 0, 0);
      __builtin_amdgcn_s_setprio(0);
      __builtin_amdgcn_sched_barrier(0);
      __builtin_amdgcn_s_barrier();      // all reads of buf (t&1) complete
      __builtin_amdgcn_sched_barrier(0);
      if (t + 2 < 32) {
        const bf16* ga = gA + (t + 2) * 32;
        const bf16* gw = gW + (t + 2) * 32;
        bf16* bA = lds + (t & 1) * 16384 + sbase;
        bf16* bB = bA + 8192;
        async_copy16(ga, bA);             async_copy16(ga + 16 * 1024, bA + 512);
        async_copy16(gw, bB);             async_copy16(gw + 16 * 1024, bB + 512);
      }
    }
    // epilogue: LDS-transposed coalesced Zt/Xt stores (verified R3 path)
    bf16* base = (bn < 2048) ? zt : xt;
    int bq = bm >> 11, bmS = bm & 2047;
    bf16* Ts = lds;                        // 64 x 264 bf16 scratch (33.8 KB)
#pragma unroll 1
    for (int g = 0; g < 4; g++) {
      __syncthreads();
      if (wn == g) {
#pragma unroll
        for (int mi = 0; mi < 8; mi++)
#pragma unroll
          for (int ni = 0; ni < 4; ni++) {
            bf16x4 o;
#pragma unroll
            for (int r = 0; r < 4; r++) o[r] = (bf16)acc[mi][ni][r];
            *(bf16x4*)(Ts + (ni * 16 + fr) * 264 + wm * 128 + mi * 16 + fq * 4) = o;
          }
      }
      __syncthreads();
      int hh = ((bn & 2047) + g * 64) >> 6;
      bf16* dst = base + ((size_t)(bq * NH + hh) * HD) * S_ + bmS;
#pragma unroll
      for (int i = 0; i < 4; i++) {
        int idx = tid + i * 512;
        int p = idx >> 5, sc = (idx & 31) * 8;
        *(bf16x8*)(dst + (size_t)p * S_ + sc) = *(const bf16x8*)(Ts + p * 264 + sc);
      }
    }
  } else {
    // ---- light path: 128x128 tile over bcdt columns 4096..4383 (3rd tile masked) ----
    int lb = bid - 256;
    int bm = (lb & 31) * 128;
    int bn = 4096 + (lb >> 5) * 128;
    int wm = w >> 1, wn = w & 1;           // 4M x 2N waves: per wave 32x64
    int srow = w * 16 + (lane >> 2);
    const bf16* gA = A + (size_t)(bm + srow) * 1024 + sswz * 8;
    const bf16* gW = W + (size_t)(bn + srow) * 1024 + sswz * 8;
    int sbase = w * 512;                   // wave's 16-row stage region (elems)
    f32x4 acc[2][4] = {};
    {
      bf16* bA = lds + sbase;
      bf16* bB = lds + 4096 + sbase;
      async_copy16(gA, bA);
      async_copy16(gW, bB);
      async_copy16(gA + 32, bA + 8192);
      async_copy16(gW + 32, bB + 8192);
    }
    for (int t = 0; t < 32; t++) {
      if (t < 31) asm volatile("s_waitcnt vmcnt(2)" ::: "memory");
      else        asm volatile("s_waitcnt vmcnt(0)" ::: "memory");
      __builtin_amdgcn_sched_barrier(0);
      __builtin_amdgcn_s_barrier();
      __builtin_amdgcn_sched_barrier(0);
      const bf16* cA = lds + (t & 1) * 8192;
      const bf16* cB = cA + 4096;
      bf16x8 af[2], bfv[4];
#pragma unroll
      for (int mi = 0; mi < 2; mi++)
        af[mi] = *(const bf16x8*)(cA + (wm * 32 + mi * 16 + fr) * 32 + rdswz);
#pragma unroll
      for (int ni = 0; ni < 4; ni++)
        bfv[ni] = *(const bf16x8*)(cB + (wn * 64 + ni * 16 + fr) * 32 + rdswz);
#pragma unroll
      for (int mi = 0; mi < 2; mi++)
#pragma unroll
        for (int ni = 0; ni < 4; ni++)
          acc[mi][ni] = __builtin_amdgcn_mfma_f32_16x16x32_bf16(af[mi], bfv[ni], acc[mi][ni], 0, 0, 0);
      __builtin_amdgcn_sched_barrier(0);
      __builtin_amdgcn_s_barrier();
      __builtin_amdgcn_sched_barrier(0);
      if (t + 2 < 32) {
        const bf16* ga = gA + (t + 2) * 32;
        const bf16* gw = gW + (t + 2) * 32;
        bf16* bA = lds + (t & 1) * 8192 + sbase;
        bf16* bB = bA + 4096;
        async_copy16(ga, bA);
        async_copy16(gw, bB);
      }
    }
#pragma unroll
    for (int mi = 0; mi < 2; mi++) {
      int row = bm + wm * 32 + mi * 16 + fq * 4;
#pragma unroll
      for (int ni = 0; ni < 4; ni++) {
        int col = bn + wn * 64 + ni * 16 + fr;
        if (col < 4384) {
#pragma unroll
          for (int r = 0; r < 4; r++)
            bcdt[(size_t)(row + r) * 288 + (col - 4096)] = (bf16)acc[mi][ni][r];
        }
      }
    }
  }
}

// ---------------- generic 64x64 tiled transpose (bf16), out row stride 2048 ----------------
__global__ __launch_bounds__(256) void t64(const bf16* __restrict__ in, bf16* __restrict__ out,
                                           int istr, size_t io, size_t oo, int n_nt) {
  __shared__ bf16 T[64 * 72];
  int bid = blockIdx.x;
  int st = bid & 31;
  int nt = (bid >> 5) % n_nt;
  int outer = bid / (32 * n_nt);
  const bf16* ip = in + outer * io + (size_t)st * 64 * istr + nt * 64;
  int tid = threadIdx.x;
#pragma unroll
  for (int i = 0; i < 2; i++) {
    int cid = tid + i * 256; int s = cid >> 3, pc = (cid & 7) * 8;
    *(bf16x8*)(T + s * 72 + pc) = *(const bf16x8*)(ip + (size_t)s * istr + pc);
  }
  __syncthreads();
  bf16* op = out + outer * oo + (size_t)nt * 64 * 2048 + st * 64;
#pragma unroll
  for (int i = 0; i < 2; i++) {
    int cid = tid + i * 256; int p = cid >> 3, sc = (cid & 7) * 8;
    bf16x8 o;
#pragma unroll
    for (int j = 0; j < 8; j++) o[j] = T[(sc + j) * 72 + p];
    *(bf16x8*)(op + (size_t)p * 2048 + sc) = o;
  }
}

// ---------------- SSD prep: dt softplus, per-chunk cumsum, decay factors ----------------
__global__ __launch_bounds__(64) void ssd_prep(const bf16* __restrict__ bcdt,
                                               const float* __restrict__ dt_bias,
                                               const float* __restrict__ A_log,
                                               float* __restrict__ dt_c,
                                               float* __restrict__ ddc,
                                               float* __restrict__ ac_c,
                                               float* __restrict__ T_out) {
  int bid = blockIdx.x;
  int c = bid % NC, hh = (bid / NC) % NH, b = bid / (NC * NH);
  int l = threadIdx.x;
  size_t row = (size_t)b * S_ + c * 64 + l;
  float raw = (float)bcdt[row * 288 + 256 + hh] + dt_bias[hh];
  float dtv = (raw > 20.f) ? raw : log1pf(__expf(raw));
  float a = -__expf(A_log[hh]) * dtv;
  float ps = a;
#pragma unroll
  for (int off = 1; off < 64; off <<= 1) {
    float t = __shfl_up(ps, off, 64);
    if (l >= off) ps += t;
  }
  float a63 = __shfl(ps, 63, 64);
  size_t o = ((size_t)b * NH + hh) * S_ + c * 64 + l;
  dt_c[o] = dtv;
  ac_c[o] = ps;
  ddc[o] = __expf(a63 - ps) * dtv;
  if (l == 63) T_out[(b * NH + hh) * NC + c] = ps;
}

// ---------------- B/C rmsnorm (bf16 out) ----------------
__global__ __launch_bounds__(128) void bc_norm(const bf16* __restrict__ bcdt,
                                               const float* __restrict__ Bw,
                                               const float* __restrict__ Cw,
                                               bf16* __restrict__ Bn,
                                               bf16* __restrict__ Cn) {
  __shared__ float shb[2], shc[2];
  size_t row = blockIdx.x;
  int i = threadIdx.x;
  float bv = (float)bcdt[row * 288 + i];
  float cv = (float)bcdt[row * 288 + 128 + i];
  float sb = waveReduceSum(bv * bv);
  float sc = waveReduceSum(cv * cv);
  int lane = threadIdx.x & 63, wid = threadIdx.x >> 6;
  if (lane == 0) { shb[wid] = sb; shc[wid] = sc; }
  __syncthreads();
  float tb = shb[0] + shb[1];
  float tc = shc[0] + shc[1];
  Bn[row * DS + i] = (bf16)(bv * rsqrtf(tb / DS + 1e-5f) * Bw[i]);
  Cn[row * DS + i] = (bf16)(cv * rsqrtf(tc / DS + 1e-5f) * Cw[i]);
}

// ---------------- chunk states via MFMA (bf16 output) ----------------
__global__ __launch_bounds__(256) void ssd_states(const bf16* __restrict__ Xt,
                                                  const bf16* __restrict__ Btr,
                                                  const float* __restrict__ ddc,
                                                  bf16* __restrict__ states) {
  __shared__ bf16 Xs[64 * 72];    // [p][s]
  __shared__ bf16 Bs[128 * 72];   // [n][s]
  int bid = blockIdx.x;           // (b*NC + c)*NH + h
  int h = bid % NH;
  int c = (bid / NH) % NC;
  int b = bid / (NH * NC);
  int tid = threadIdx.x, lane = tid & 63, w = tid >> 6;
  int fr = lane & 15, fq = lane >> 4;
  const size_t xbase = (size_t)(b * NH + h) * HD * S_ + c * 64;
  const size_t dbase = (size_t)(b * NH + h) * S_ + c * 64;
#pragma unroll
  for (int i = 0; i < 2; i++) {
    int cid = tid + i * 256; int p = cid >> 3, sc = (cid & 7) * 8;
    bf16x8 xv = *(const bf16x8*)(Xt + xbase + (size_t)p * S_ + sc);
    f32x4 d0 = *(const f32x4*)(ddc + dbase + sc);
    f32x4 d1 = *(const f32x4*)(ddc + dbase + sc + 4);
    bf16x8 o;
#pragma unroll
    for (int j = 0; j < 4; j++) { o[j] = (bf16)((float)xv[j] * d0[j]); o[4 + j] = (bf16)((float)xv[4 + j] * d1[j]); }
    *(bf16x8*)(Xs + p * 72 + sc) = o;
  }
  const size_t bbase = (size_t)b * 128 * S_ + c * 64;
#pragma unroll
  for (int i = 0; i < 4; i++) {
    int cid = tid + i * 256; int n = cid >> 3, sc = (cid & 7) * 8;
    *(bf16x8*)(Bs + n * 72 + sc) = *(const bf16x8*)(Btr + bbase + (size_t)n * S_ + sc);
  }
  __syncthreads();
  f32x4 acc[4][2] = {};
#pragma unroll
  for (int ks = 0; ks < 2; ks++) {
    bf16x8 a[4], bb[2];
#pragma unroll
    for (int pt = 0; pt < 4; pt++) a[pt] = *(const bf16x8*)(Xs + (pt * 16 + fr) * 72 + ks * 32 + fq * 8);
#pragma unroll
    for (int n2 = 0; n2 < 2; n2++) bb[n2] = *(const bf16x8*)(Bs + ((2 * w + n2) * 16 + fr) * 72 + ks * 32 + fq * 8);
#pragma unroll
    for (int pt = 0; pt < 4; pt++)
#pragma unroll
      for (int n2 = 0; n2 < 2; n2++)
        acc[pt][n2] = __builtin_amdgcn_mfma_f32_16x16x32_bf16(a[pt], bb[n2], acc[pt][n2], 0, 0, 0);
  }
  bf16* outp = states + (size_t)bid * 8192;
#pragma unroll
  for (int pt = 0; pt < 4; pt++)
#pragma unroll
    for (int n2 = 0; n2 < 2; n2++) {
      int n = (2 * w + n2) * 16 + fr;
#pragma unroll
      for (int r = 0; r < 4; r++)
        outp[(size_t)(pt * 16 + fq * 4 + r) * 128 + n] = (bf16)acc[pt][n2][r];
    }
}

// ---------------- inter-chunk scan (in place, bf16 storage, f32 math) ----------------
__global__ __launch_bounds__(256) void ssd_scan(bf16* __restrict__ states,
                                                const float* __restrict__ T) {
  __shared__ float eT[NC];
  int part = blockIdx.x & 7;
  int bh = blockIdx.x >> 3;
  int b = bh / NH, h = bh % NH;
  if (threadIdx.x < NC) eT[threadIdx.x] = __expf(T[(size_t)(b * NH + h) * NC + threadIdx.x]);
  __syncthreads();
  const size_t cstride = (size_t)NH * HD * DS;
  size_t base = ((size_t)b * NC * NH + h) * (HD * DS);
#pragma unroll
  for (int j = 0; j < 4; j++) {
    int e = part * 1024 + threadIdx.x + j * 256;
    float carry = 0.f;
    size_t idx = base + e;
    for (int c = 0; c < NC; c++) {
      float sv = (float)states[idx];
      states[idx] = (bf16)carry;
      carry = sv + eT[c] * carry;
      idx += cstride;
    }
  }
}

// ---------------- fused SSD output: Ydiag + Yoff + D-skip + gate (all MFMA) ----------------
__global__ __launch_bounds__(256) void ssd_out(const bf16* __restrict__ Cn,
                                               const bf16* __restrict__ Bn,
                                               const bf16* __restrict__ Xt,
                                               const bf16* __restrict__ Zt,
                                               const float* __restrict__ dt_c,
                                               const float* __restrict__ ac_c,
                                               const bf16* __restrict__ states,
                                               const float* __restrict__ Dp,
                                               bf16* __restrict__ ybf) {
  __shared__ bf16 Cs[64 * 136];
  __shared__ bf16 BNs[64 * 136];
  __shared__ bf16 Xs[64 * 72];
  __shared__ bf16 G[64 * 72];
  __shared__ float acs[64];
  int bid = blockIdx.x;
  int h = bid % NH;
  int c = (bid / NH) % NC;
  int b = bid / (NH * NC);
  int tid = threadIdx.x, lane = tid & 63, w = tid >> 6;
  int fr = lane & 15, fq = lane >> 4;
  size_t row0 = (size_t)b * S_ + c * 64;
  const size_t abase = (size_t)(b * NH + h) * S_ + c * 64;
  if (tid < 64) acs[tid] = ac_c[abase + tid];
#pragma unroll
  for (int i = 0; i < 4; i++) {
    int cid = tid + i * 256; int l = cid >> 4, nc = (cid & 15) * 8;
    float e = __expf(ac_c[abase + l]);
    bf16x8 cv = *(const bf16x8*)(Cn + (row0 + l) * DS + nc);
    bf16x8 o;
#pragma unroll
    for (int j = 0; j < 8; j++) o[j] = (bf16)((float)cv[j] * e);
    *(bf16x8*)(Cs + l * 136 + nc) = o;
    *(bf16x8*)(BNs + l * 136 + nc) = *(const bf16x8*)(Bn + (row0 + l) * DS + nc);
  }
  const size_t xbase = (size_t)(b * NH + h) * HD * S_ + c * 64;
#pragma unroll
  for (int i = 0; i < 2; i++) {
    int cid = tid + i * 256; int p = cid >> 3, sc = (cid & 7) * 8;
    bf16x8 xv = *(const bf16x8*)(Xt + xbase + (size_t)p * S_ + sc);
    f32x4 d0 = *(const f32x4*)(dt_c + abase + sc);
    f32x4 d1 = *(const f32x4*)(dt_c + abase + sc + 4);
    bf16x8 o;
#pragma unroll
    for (int j = 0; j < 4; j++) { o[j] = (bf16)((float)xv[j] * d0[j]); o[4 + j] = (bf16)((float)xv[4 + j] * d1[j]); }
    *(bf16x8*)(Xs + p * 72 + sc) = o;
  }
  __syncthreads();
  bf16x8 ca[4];
#pragma unroll
  for (int ks = 0; ks < 4; ks++) ca[ks] = *(const bf16x8*)(Cs + (w * 16 + fr) * 136 + ks * 32 + fq * 8);
  f32x4 cb[4] = {};
  for (int st = 0; st <= w; st++)
#pragma unroll
    for (int ks = 0; ks < 4; ks++)
      cb[st] = __builtin_amdgcn_mfma_f32_16x16x32_bf16(ca[ks],
                 *(const bf16x8*)(BNs + (st * 16 + fr) * 136 + ks * 32 + fq * 8), cb[st], 0, 0, 0);
#pragma unroll
  for (int st = 0; st < 4; st++) {
    float es = (st <= w) ? __expf(-acs[st * 16 + fr]) : 0.f;
#pragma unroll
    for (int r = 0; r < 4; r++) {
      int lloc = fq * 4 + r;
      float g = 0.f;
      if (st < w) g = cb[st][r] * es;
      else if (st == w) g = (lloc >= fr) ? cb[st][r] * es : 0.f;
      G[(w * 16 + lloc) * 72 + st * 16 + fr] = (bf16)g;
    }
  }
  f32x4 acc[4] = {};
  {
    bf16x8 ga0 = *(const bf16x8*)(G + (w * 16 + fr) * 72 + fq * 8);
    bf16x8 ga1 = *(const bf16x8*)(G + (w * 16 + fr) * 72 + 32 + fq * 8);
#pragma unroll
    for (int pt = 0; pt < 4; pt++) {
      acc[pt] = __builtin_amdgcn_mfma_f32_16x16x32_bf16(ga0,
                  *(const bf16x8*)(Xs + (pt * 16 + fr) * 72 + fq * 8), acc[pt], 0, 0, 0);
      acc[pt] = __builtin_amdgcn_mfma_f32_16x16x32_bf16(ga1,
                  *(const bf16x8*)(Xs + (pt * 16 + fr) * 72 + 32 + fq * 8), acc[pt], 0, 0, 0);
    }
  }
  __syncthreads();
  const bf16* stp = states + (size_t)bid * 8192;
#pragma unroll
  for (int i = 0; i < 4; i++) {
    int cid = tid + i * 256; int p = cid >> 4, nc = (cid & 15) * 8;
    *(bf16x8*)(BNs + p * 136 + nc) = *(const bf16x8*)(stp + (size_t)p * 128 + nc);
  }
  __syncthreads();
#pragma unroll
  for (int pt = 0; pt < 4; pt++)
#pragma unroll
    for (int ks = 0; ks < 4; ks++)
      acc[pt] = __builtin_amdgcn_mfma_f32_16x16x32_bf16(ca[ks],
                  *(const bf16x8*)(BNs + (pt * 16 + fr) * 136 + ks * 32 + fq * 8), acc[pt], 0, 0, 0);
  float dph = Dp[h];
#pragma unroll
  for (int pt = 0; pt < 4; pt++) {
    int p = pt * 16 + fr;
    size_t tb = (xbase + (size_t)p * S_) + w * 16 + fq * 4;
    bf16x4 xs4 = *(const bf16x4*)(Xt + tb);
    bf16x4 z4  = *(const bf16x4*)(Zt + tb);
#pragma unroll
    for (int r = 0; r < 4; r++) {
      int l = w * 16 + fq * 4 + r;
      float yv = acc[pt][r] + (float)xs4[r] * dph;
      float z = (float)z4[r];
      yv *= z / (1.f + __expf(-z));
      ybf[((row0 + l) * NH + h) * HD + p] = (bf16)yv;
    }
  }
}

// ---------------- split-S MFMA flash attention (fixed-max softmax -> partials sum) ----------------
// Single-buffered K/V (LDS 36.9 KB -> 4 blocks/CU); prefetch issued after the
// second barrier so loads overlap compute and drain at next iter's first barrier.
#define KSTR 72
#define PSTR 72
__global__ __launch_bounds__(256) void attn_mfma(const bf16* __restrict__ q,
                                                 const bf16* __restrict__ k,
                                                 const bf16* __restrict__ vtr,
                                                 bf16* __restrict__ Po,
                                                 float* __restrict__ Ls) {
  __shared__ bf16 Ks[64 * KSTR];
  __shared__ bf16 Vs[64 * KSTR];
  __shared__ bf16 Pl[4][32 * PSTR];
  int c = 39 - blockIdx.x;                 // full 8-iter chunks first
  int g = (c < 4) ? 0 : (c < 12) ? 1 : (c < 24) ? 2 : 3;
  int gbase = (g == 0) ? 0 : (g == 1) ? 4 : (g == 2) ? 12 : 24;
  int d = c - gbase;
  int qt = 4 * g + d / (g + 1);
  int sk = d % (g + 1);
  int h = blockIdx.y, b = blockIdx.z;
  int kvh = h >> 2;
  int tid = threadIdx.x, lane = tid & 63, w = tid >> 6;
  int fr = lane & 15, fq = lane >> 4;
  const float SC = 0.18033688011112042f;   // 0.125 * log2(e)
  const float M2 = 62.0f;
  int kt0 = sk * 8;
  int ktend = min(kt0 + 8, 2 * qt + 2);
  int qbase = qt * 128 + w * 32;           // wave's first q row
  int qmaxw = qbase + 31;
  bf16x8 bq[2][2];
#pragma unroll
  for (int qc = 0; qc < 2; qc++)
#pragma unroll
    for (int ks = 0; ks < 2; ks++)
      bq[qc][ks] = *(const bf16x8*)(q + (size_t)(b * S_ + qbase + qc * 16 + fr) * (HATT * HD)
                                      + h * HD + ks * 32 + fq * 8);
  int sr = tid >> 3, sc8 = (tid & 7) * 8;
  const bf16* kg = k + ((size_t)(b * S_) + sr) * (KVH * HD) + kvh * HD + sc8;
  const bf16* vg = vtr + ((size_t)(b * KVH + kvh) * HD + sr) * S_ + sc8;
  bf16x8 krg0, krg1, vrg0, vrg1;
  {
    const bf16* kp = kg + (size_t)kt0 * 64 * (KVH * HD);
    const bf16* vp = vg + (size_t)kt0 * 64;
    krg0 = *(const bf16x8*)(kp);
    krg1 = *(const bf16x8*)(kp + (size_t)32 * (KVH * HD));
    vrg0 = *(const bf16x8*)(vp);
    vrg1 = *(const bf16x8*)(vp + (size_t)32 * S_);
  }
  float lsum[2] = {0.f, 0.f};
  f32x4 yacc[2][4] = {};
  bf16* Plw = Pl[w];
  for (int kt = kt0; kt < ktend; kt++) {
    __syncthreads();   // previous iteration's LDS reads complete
    *(bf16x8*)(&Ks[sr * KSTR + sc8]) = krg0;
    *(bf16x8*)(&Ks[(sr + 32) * KSTR + sc8]) = krg1;
    *(bf16x8*)(&Vs[sr * KSTR + sc8]) = vrg0;
    *(bf16x8*)(&Vs[(sr + 32) * KSTR + sc8]) = vrg1;
    __syncthreads();   // tile visible
    // prefetch next tile AFTER the barrier: loads overlap compute below
    if ((kt + 1) < ktend) {
      const bf16* kp = kg + (size_t)(kt + 1) * 64 * (KVH * HD);
      const bf16* vp = vg + (size_t)(kt + 1) * 64;
      krg0 = *(const bf16x8*)(kp);
      krg1 = *(const bf16x8*)(kp + (size_t)32 * (KVH * HD));
      vrg0 = *(const bf16x8*)(vp);
      vrg1 = *(const bf16x8*)(vp + (size_t)32 * S_);
    }
    if (kt * 64 <= qmaxw) {
      bool nomask = (kt * 64 + 63) <= qbase;
      if (nomask) {
#pragma unroll
        for (int mi = 0; mi < 4; mi++) {
          const bf16* krow = &Ks[(mi * 16 + fr) * KSTR];
          bf16x8 ak0 = *(const bf16x8*)(krow + fq * 8);
          bf16x8 ak1 = *(const bf16x8*)(krow + 32 + fq * 8);
#pragma unroll
          for (int qc = 0; qc < 2; qc++) {
            f32x4 s = {};
            s = __builtin_amdgcn_mfma_f32_16x16x32_bf16(ak0, bq[qc][0], s, 0, 0, 0);
            s = __builtin_amdgcn_mfma_f32_16x16x32_bf16(ak1, bq[qc][1], s, 0, 0, 0);
            bf16x4 pk;
#pragma unroll
            for (int r = 0; r < 4; r++) {
              float p = __builtin_amdgcn_exp2f(s[r] * SC - M2);
              lsum[qc] += p;
              pk[r] = (bf16)p;
            }
            *(bf16x4*)(Plw + (qc * 16 + fr) * PSTR + mi * 16 + fq * 4) = pk;
          }
        }
      } else {
#pragma unroll
        for (int mi = 0; mi < 4; mi++) {
          int s0 = kt * 64 + mi * 16;
          if (s0 > qmaxw) {
            bf16x4 zz = {};
#pragma unroll
            for (int qc = 0; qc < 2; qc++)
              *(bf16x4*)(Plw + (qc * 16 + fr) * PSTR + mi * 16 + fq * 4) = zz;
          } else {
            const bf16* krow = &Ks[(mi * 16 + fr) * KSTR];
            bf16x8 ak0 = *(const bf16x8*)(krow + fq * 8);
            bf16x8 ak1 = *(const bf16x8*)(krow + 32 + fq * 8);
#pragma unroll
            for (int qc = 0; qc < 2; qc++) {
              f32x4 s = {};
              s = __builtin_amdgcn_mfma_f32_16x16x32_bf16(ak0, bq[qc][0], s, 0, 0, 0);
              s = __builtin_amdgcn_mfma_f32_16x16x32_bf16(ak1, bq[qc][1], s, 0, 0, 0);
              int qq = qbase + qc * 16 + fr;
              bf16x4 pk;
#pragma unroll
              for (int r = 0; r < 4; r++) {
                int sp = s0 + fq * 4 + r;
                float p = (sp <= qq) ? __builtin_amdgcn_exp2f(s[r] * SC - M2) : 0.f;
                lsum[qc] += p;
                pk[r] = (bf16)p;
              }
              *(bf16x4*)(Plw + (qc * 16 + fr) * PSTR + mi * 16 + fq * 4) = pk;
            }
          }
        }
      }
#pragma unroll
      for (int ks2 = 0; ks2 < 2; ks2++) {
        bf16x8 bp[2];
#pragma unroll
        for (int qc = 0; qc < 2; qc++)
          bp[qc] = *(const bf16x8*)(Plw + (qc * 16 + fr) * PSTR + ks2 * 32 + fq * 8);
#pragma unroll
        for (int pi = 0; pi < 4; pi++) {
          bf16x8 av = *(const bf16x8*)(&Vs[(pi * 16 + fr) * KSTR + ks2 * 32 + fq * 8]);
#pragma unroll
          for (int qc = 0; qc < 2; qc++)
            yacc[qc][pi] = __builtin_amdgcn_mfma_f32_16x16x32_bf16(av, bp[qc], yacc[qc][pi], 0, 0, 0);
        }
      }
    }
  }
#pragma unroll
  for (int qc = 0; qc < 2; qc++) {
    lsum[qc] += __shfl_xor(lsum[qc], 16, 64);
    lsum[qc] += __shfl_xor(lsum[qc], 32, 64);
    int qrow = qt * 128 + w * 32 + qc * 16 + fr;
    if (fq == 0)
      Ls[((size_t)(b * 16 + h) * 2048 + qrow) * 4 + sk] = lsum[qc];
    bf16* pop = Po + ((((size_t)(b * 16 + h) * 16 + qt) * 4 + sk) * 128
                       + w * 32 + qc * 16 + fr) * 64 + fq * 4;
#pragma unroll
    for (int pi = 0; pi < 4; pi++) {
      bf16x4 o;
#pragma unroll
      for (int r = 0; r < 4; r++) o[r] = (bf16)yacc[qc][pi][r];
      *(bf16x4*)(pop + pi * 16) = o;
    }
  }
}

// ---------------- attention partial combine + normalize -> y2 bf16 ----------------
__global__ __launch_bounds__(256) void attn_red(const bf16* __restrict__ Po,
                                                const float* __restrict__ Ls,
                                                bf16* __restrict__ y2) {
  int row = blockIdx.x;            // 0..4095
  int b = row >> 11;
  int qrow = row & 2047;
  int qt = qrow >> 7, r = qrow & 127;
  int nch = (qt >> 2) + 1;
  int t = threadIdx.x;
  int h = t >> 4, e4 = (t & 15) << 2;
  const float* lp = Ls + ((size_t)(b * 16 + h) * 2048 + qrow) * 4;
  float ls = 0.f;
  f32x4 acc = {};
  for (int sk = 0; sk < nch; sk++) {
    ls += lp[sk];
    const bf16* pp = Po + ((((size_t)(b * 16 + h) * 16 + qt) * 4 + sk) * 128 + r) * 64 + e4;
    bf16x4 v = *(const bf16x4*)(pp);
#pragma unroll
    for (int j = 0; j < 4; j++) acc[j] += (float)v[j];
  }
  float inv = 1.f / ls;
  bf16x4 o;
#pragma unroll
  for (int j = 0; j < 4; j++) o[j] = (bf16)(acc[j] * inv);
  *(bf16x4*)(y2 + (size_t)row * 1024 + h * 64 + e4) = o;
}

// ---------------- workspace layout (byte offsets) ----------------
constexpr size_t OFF_WIN  = 0;                   // bf16 4480x1024
constexpr size_t OFF_WOUT = 9175040;             // bf16 1024x2048
constexpr size_t OFF_WQKV = 13369344;            // bf16 1536x1024 (q|k|v rows)
constexpr size_t OFF_WCP  = 16515072;            // bf16 1024x1024
constexpr size_t OFF_WFC  = 18612224;            // bf16 3072x1024
constexpr size_t OFF_WPR  = 24903680;            // bf16 1024x3072
constexpr size_t OFF_HBF  = 31195136;            // bf16 4096x1024
constexpr size_t OFF_BCDT = 39583744;            // bf16 4096x288; reused: Ls f32 (1 MiB)
constexpr size_t OFF_XT   = 41943040;            // bf16 [b][h][p][sg] (16.7 MB)
constexpr size_t OFF_ZT   = 58720256;            // bf16 [b][h][p][sg] (16.7 MB)
constexpr size_t OFF_DTC  = 75497472;            // f32 [b][h][sg]
constexpr size_t OFF_DDC  = 76546048;            // f32
constexpr size_t OFF_ACC  = 77594624;            // f32
constexpr size_t OFF_T    = 78643200;            // f32 2048
constexpr size_t OFF_BN   = 78651392;            // bf16 4096x128
constexpr size_t OFF_CN   = 79699968;            // bf16 4096x128
constexpr size_t OFF_BTR  = 80748544;            // bf16 [b][n][sg]
constexpr size_t OFF_ST   = 81797120;            // bf16 states (33.5 MB); reused: Po bf16 32 MiB
constexpr size_t OFF_YBF  = 148905984;           // bf16 4096x2048
constexpr size_t OFF_X1   = 165683200;           // f32 4096x1024 (end 182,460,416)
// phase-2 aliases
constexpr size_t OFF_P    = OFF_ST;              // bf16 split-K partials (<= 25.2 MB)
constexpr size_t OFF_PO   = OFF_ST;              // bf16 attn partials [b][h][qt][4][128][64] = 32 MiB
constexpr size_t OFF_LS   = OFF_BCDT;            // f32 attn lsums [b][h][2048][4] = 1 MiB
constexpr size_t OFF_QB   = OFF_XT;              // bf16 4096x1024 (8.4 MB)
constexpr size_t OFF_KB   = OFF_XT + 8388608;    // bf16 4096x256
constexpr size_t OFF_VB   = OFF_XT + 10485760;   // bf16 4096x256
constexpr size_t OFF_VTR  = OFF_XT + 12582912;   // bf16 [b][kvh][p][sg]
constexpr size_t OFF_Y2   = OFF_ZT;              // bf16 4096x1024
constexpr size_t OFF_X2   = 50331648;            // f32 4096x1024 (over dead kb/vb/vtr/y2)
constexpr size_t OFF_MLP  = 132128768;           // bf16 4096x3072 (over dead regions)

extern "C" void kernel_launch(void* const* d_in, const int* in_sizes, int n_in,
                              void* d_out, int out_size, void* d_ws, size_t ws_size,
                              hipStream_t stream) {
  (void)in_sizes; (void)n_in; (void)out_size; (void)ws_size;
  const float* x        = (const float*)d_in[0];
  const float* mnorm_w  = (const float*)d_in[1];
  const float* in_w     = (const float*)d_in[2];
  const float* out_w    = (const float*)d_in[3];
  const float* Dp       = (const float*)d_in[4];
  const float* dt_bias  = (const float*)d_in[5];
  const float* A_log    = (const float*)d_in[6];
  const float* Bn_w     = (const float*)d_in[7];
  const float* Cn_w     = (const float*)d_in[8];
  const float* ln1_w    = (const float*)d_in[9];
  const float* ln1_b    = (const float*)d_in[10];
  const float* cq_w     = (const float*)d_in[11];
  const float* ck_w     = (const float*)d_in[12];
  const float* cv_w     = (const float*)d_in[13];
  const float* cproj_w  = (const float*)d_in[14];
  const float* q_gain   = (const float*)d_in[15];
  const float* ln2_w    = (const float*)d_in[16];
  const float* ln2_b    = (const float*)d_in[17];
  const float* fc_w     = (const float*)d_in[18];
  const float* proj_w   = (const float*)d_in[19];
  float* out = (float*)d_out;
  char* W8 = (char*)d_ws;

  bf16* w_in   = (bf16*)(W8 + OFF_WIN);
  bf16* w_out  = (bf16*)(W8 + OFF_WOUT);
  bf16* w_qkv  = (bf16*)(W8 + OFF_WQKV);
  bf16* w_cp   = (bf16*)(W8 + OFF_WCP);
  bf16* w_fc   = (bf16*)(W8 + OFF_WFC);
  bf16* w_pr   = (bf16*)(W8 + OFF_WPR);
  bf16* h_bf   = (bf16*)(W8 + OFF_HBF);
  bf16* bcdt   = (bf16*)(W8 + OFF_BCDT);
  bf16* Xt     = (bf16*)(W8 + OFF_XT);
  bf16* Zt     = (bf16*)(W8 + OFF_ZT);
  float* dt_c  = (float*)(W8 + OFF_DTC);
  float* ddc   = (float*)(W8 + OFF_DDC);
  float* ac_c  = (float*)(W8 + OFF_ACC);
  float* Tb    = (float*)(W8 + OFF_T);
  bf16* Bn     = (bf16*)(W8 + OFF_BN);
  bf16* Cn     = (bf16*)(W8 + OFF_CN);
  bf16* Btr    = (bf16*)(W8 + OFF_BTR);
  bf16* st     = (bf16*)(W8 + OFF_ST);
  bf16* ybf    = (bf16*)(W8 + OFF_YBF);
  float* x1    = (float*)(W8 + OFF_X1);
  bf16* Pbuf   = (bf16*)(W8 + OFF_P);
  bf16* Po     = (bf16*)(W8 + OFF_PO);
  float* Ls    = (float*)(W8 + OFF_LS);
  bf16* qbf    = (bf16*)(W8 + OFF_QB);
  bf16* kbf    = (bf16*)(W8 + OFF_KB);
  bf16* vbf    = (bf16*)(W8 + OFF_VB);
  bf16* vtr    = (bf16*)(W8 + OFF_VTR);
  bf16* y2     = (bf16*)(W8 + OFF_Y2);
  float* x2    = (float*)(W8 + OFF_X2);
  bf16* mlp    = (bf16*)(W8 + OFF_MLP);

  // ---- weight casts (single launch; q/k/v cast into adjacent rows of w_qkv) ----
  CastArgs ca;
  ca.seg[0] = { in_w,    w_in,            4489216, 4587520, 0     };
  ca.seg[1] = { out_w,   w_out,           2097152, 2097152, 4480  };
  ca.seg[2] = { cq_w,    w_qkv,           1048576, 1048576, 6528  };
  ca.seg[3] = { ck_w,    w_qkv + 1048576,  262144,  262144, 7552  };
  ca.seg[4] = { cv_w,    w_qkv + 1310720,  262144,  262144, 7808  };
  ca.seg[5] = { cproj_w, w_cp,            1048576, 1048576, 8064  };
  ca.seg[6] = { fc_w,    w_fc,            3145728, 3145728, 9088  };
  ca.seg[7] = { proj_w,  w_pr,            3145728, 3145728, 12160 };
  castw_all<<<15232, 256, 0, stream>>>(ca);

  const size_t PS  = (size_t)ROWS * 1024;   // partial stride (elements) for N=1024 GEMMs

  // ---- mamba block ----
  rmsnorm_k<<<ROWS, 256, 0, stream>>>(x, mnorm_w, h_bf, D_);
  gemm256_inproj<<<352, 512, 0, stream>>>(h_bf, w_in, Zt, Xt, bcdt);
  ssd_prep<<<B_ * NH * NC, 64, 0, stream>>>(bcdt, dt_bias, A_log, dt_c, ddc, ac_c, Tb);
  bc_norm<<<ROWS, 128, 0, stream>>>(bcdt, Bn_w, Cn_w, Bn, Cn);
  t64<<<2 * 2 * 32, 256, 0, stream>>>(Bn, Btr, 128, (size_t)2048 * 128, (size_t)128 * 2048, 2);
  ssd_states<<<B_ * NC * NH, 256, 0, stream>>>(Xt, Btr, ddc, st);
  ssd_scan<<<B_ * NH * 8, 256, 0, stream>>>(st, Tb);
  ssd_out<<<B_ * NC * NH, 256, 0, stream>>>(Cn, Bn, Xt, Zt, dt_c, ac_c, st, Dp, ybf);
  // out_proj: split-K=2 then fused reduce+residual+LN1
  gemm_sk<<<dim3(32 * 8, 1, 2), 256, 0, stream>>>(ybf, w_out, Pbuf, ROWS, D_, DI, 1024);
  reduce_ln2<<<ROWS, 256, 0, stream>>>(Pbuf, Pbuf + PS, x, ln1_w, ln1_b, x1, h_bf);

  // ---- attention block ----
  gemm_sk<<<dim3(32 * 12, 1, 2), 256, 0, stream>>>(h_bf, w_qkv, Pbuf, ROWS, 1536, D_, 512);
  reduce_qkv<<<ROWS, 256, 0, stream>>>(Pbuf, q_gain, qbf, kbf, vbf);
  t64<<<2 * 4 * 32, 256, 0, stream>>>(vbf, vtr, 256, (size_t)2048 * 256, (size_t)256 * 2048, 4);
  attn_mfma<<<dim3(40, HATT, B_), 256, 0, stream>>>(qbf, kbf, vtr, Po, Ls);
  attn_red<<<ROWS, 256, 0, stream>>>(Po, Ls, y2);
  gemm_sk<<<dim3(32 * 8, 1, 2), 256, 0, stream>>>(y2, w_cp, Pbuf, ROWS, D_, D_, 512);
  reduce_ln2<<<ROWS, 256, 0, stream>>>(Pbuf, Pbuf + PS, x1, ln2_w, ln2_b, x2, h_bf);

  // ---- MLP ----
  gemm_mfma<1, bf16><<<32 * 24, 256, 0, stream>>>(h_bf, w_fc, nullptr, mlp, ROWS, MLP, D_);
  gemm_sk<<<dim3(32 * 8, 1, 3), 256, 0, stream>>>(mlp, w_pr, Pbuf, ROWS, D_, MLP, 1024);
  reduce_out3<<<ROWS, 256, 0, stream>>>(Pbuf, Pbuf + PS, Pbuf + 2 * PS, x2, out);
}

// Round 6
// 510.941 us; speedup vs baseline: 1.4584x; 1.0267x over previous
//
#include <hip/hip_runtime.h>
#include <hip/hip_bf16.h>
#include <math.h>

// ---------------- problem constants ----------------
#define B_    2
#define S_    2048
#define D_    1024
#define DI    2048      // D_INNER
#define NH    32        // NHEADS (mamba)
#define HD    64        // HEADDIM
#define DS    128      // D_STATE
#define CH    64        // CHUNK
#define NC    32        // S_/CH
#define DP    4384      // D_PROJ
#define HATT  16        // attention heads
#define KVH   4         // kv heads
#define RD    16        // rope dims
#define MLP   3072
#define ROWS  (B_*S_)   // 4096

typedef __bf16 bf16;
typedef __bf16 bf16x8 __attribute__((ext_vector_type(8)));
typedef __bf16 bf16x4 __attribute__((ext_vector_type(4)));
typedef float  f32x4  __attribute__((ext_vector_type(4)));

__device__ __forceinline__ void async_copy16(const void* g, void* l) {
  __builtin_amdgcn_global_load_lds(
      (const __attribute__((address_space(1))) unsigned int*)g,
      (__attribute__((address_space(3))) unsigned int*)l, 16, 0, 0);
}

// ---------------- reductions ----------------
__device__ __forceinline__ float waveReduceSum(float v) {
#pragma unroll
  for (int off = 32; off > 0; off >>= 1) v += __shfl_down(v, off, 64);
  return v;
}

template<int NW>
__device__ __forceinline__ float blockReduceSum(float v, float* sh) {
  v = waveReduceSum(v);
  int lane = threadIdx.x & 63, wid = threadIdx.x >> 6;
  if (lane == 0) sh[wid] = v;
  __syncthreads();
  float s = 0.f;
#pragma unroll
  for (int i = 0; i < NW; i++) s += sh[i];
  __syncthreads();
  return s;
}

// ---------------- merged weight cast f32 -> bf16 ----------------
struct CastSeg { const float* src; bf16* dst; int nval; int ntot; int blk0; };
struct CastArgs { CastSeg seg[8]; };

__global__ __launch_bounds__(256) void castw_all(CastArgs a) {
  int blk = blockIdx.x;
  int si = 0;
#pragma unroll
  for (int i = 1; i < 8; i++) if (blk >= a.seg[i].blk0) si = i;
  CastSeg s = a.seg[si];
  int i = ((blk - s.blk0) * 256 + threadIdx.x) * 4;
  if (i >= s.ntot) return;
  float4 v = {0.f, 0.f, 0.f, 0.f};
  if (i < s.nval) v = *(const float4*)(s.src + i);
  bf16x4 o;
  o[0] = (bf16)v.x; o[1] = (bf16)v.y; o[2] = (bf16)v.z; o[3] = (bf16)v.w;
  *(bf16x4*)(s.dst + i) = o;
}

// ---------------- rmsnorm (f32 in, bf16 out) ----------------
__global__ __launch_bounds__(256) void rmsnorm_k(const float* __restrict__ x,
                                                 const float* __restrict__ w,
                                                 bf16* __restrict__ y, int n) {
  __shared__ float sh[4];
  size_t row = blockIdx.x;
  const float* xr = x + row * n;
  bf16* yr = y + row * n;
  float ss = 0.f;
  for (int i = threadIdx.x; i < n; i += 256) { float v = xr[i]; ss += v * v; }
  ss = blockReduceSum<4>(ss, sh);
  float inv = rsqrtf(ss / n + 1e-5f);
  for (int i = threadIdx.x; i < n; i += 256) yr[i] = (bf16)(xr[i] * inv * w[i]);
}

// ---------------- generic bf16 MFMA GEMM: C = act(A @ W^T), bm-fastest 1D grid ----------------
template<int ACT, typename OT>
__global__ __launch_bounds__(256) void gemm_mfma(const bf16* __restrict__ A,
                                                 const bf16* __restrict__ W,
                                                 const float* __restrict__ R,
                                                 OT* __restrict__ C,
                                                 int M, int N, int K) {
  __shared__ bf16 As[128 * 32];
  __shared__ bf16 Ws[128 * 32];
  int tid = threadIdx.x, lane = tid & 63, wave = tid >> 6;
  int mt = M >> 7;
  int bid = blockIdx.x;
  int bm = (bid % mt) * 128, bn = (bid / mt) * 128;
  const bf16* gA0 = A + (size_t)(bm + wave * 32 + (lane >> 2)) * K + (lane & 3) * 8;
  const bf16* gA1 = gA0 + (size_t)16 * K;
  const bf16* gW0 = W + (size_t)(bn + wave * 32 + (lane >> 2)) * K + (lane & 3) * 8;
  const bf16* gW1 = gW0 + (size_t)16 * K;
  bf16* lA0 = As + wave * 32 * 32;
  bf16* lA1 = lA0 + 16 * 32;
  bf16* lW0 = Ws + wave * 32 * 32;
  bf16* lW1 = lW0 + 16 * 32;
  int fr = lane & 15, fq = lane >> 4;
  int wm = wave >> 1, wn = wave & 1;
  const bf16* pA = As + (wm * 64 + fr) * 32 + fq * 8;
  const bf16* pW = Ws + (wn * 64 + fr) * 32 + fq * 8;
  f32x4 acc[4][4] = {};
  for (int k0 = 0; k0 < K; k0 += 32) {
    async_copy16(gA0, lA0);
    async_copy16(gA1, lA1);
    async_copy16(gW0, lW0);
    async_copy16(gW1, lW1);
    gA0 += 32; gA1 += 32; gW0 += 32; gW1 += 32;
    __syncthreads();
    bf16x8 af[4], bfr[4];
#pragma unroll
    for (int mi = 0; mi < 4; mi++) af[mi] = *(const bf16x8*)(pA + mi * 16 * 32);
#pragma unroll
    for (int ni = 0; ni < 4; ni++) bfr[ni] = *(const bf16x8*)(pW + ni * 16 * 32);
#pragma unroll
    for (int mi = 0; mi < 4; mi++)
#pragma unroll
      for (int ni = 0; ni < 4; ni++)
        acc[mi][ni] = __builtin_amdgcn_mfma_f32_16x16x32_bf16(af[mi], bfr[ni], acc[mi][ni], 0, 0, 0);
    __syncthreads();
  }
#pragma unroll
  for (int mi = 0; mi < 4; mi++) {
    int row = bm + wm * 64 + mi * 16 + fq * 4;
#pragma unroll
    for (int ni = 0; ni < 4; ni++) {
      int col = bn + wn * 64 + ni * 16 + fr;
      if (col < N) {
#pragma unroll
        for (int r = 0; r < 4; r++) {
          float v = acc[mi][ni][r];
          if (ACT == 1) v = v / (1.f + __expf(-v));
          if (R) v += R[(size_t)(row + r) * N + col];
          C[(size_t)(row + r) * N + col] = (OT)v;
        }
      }
    }
  }
}

// ---------------- split-K bf16 MFMA GEMM: P[ks] = A @ W^T (bf16 partials) ----------------
__global__ __launch_bounds__(256) void gemm_sk(const bf16* __restrict__ A,
                                               const bf16* __restrict__ W,
                                               bf16* __restrict__ P,
                                               int M, int N, int K, int kchunk) {
  __shared__ bf16 As[128 * 32];
  __shared__ bf16 Ws[128 * 32];
  int tid = threadIdx.x, lane = tid & 63, wave = tid >> 6;
  int mt = M >> 7;
  int bid = blockIdx.x;
  int bm = (bid % mt) * 128, bn = (bid / mt) * 128;
  int ks = blockIdx.z;
  int kbeg = ks * kchunk;
  const bf16* gA0 = A + (size_t)(bm + wave * 32 + (lane >> 2)) * K + kbeg + (lane & 3) * 8;
  const bf16* gA1 = gA0 + (size_t)16 * K;
  const bf16* gW0 = W + (size_t)(bn + wave * 32 + (lane >> 2)) * K + kbeg + (lane & 3) * 8;
  const bf16* gW1 = gW0 + (size_t)16 * K;
  bf16* lA0 = As + wave * 32 * 32;
  bf16* lA1 = lA0 + 16 * 32;
  bf16* lW0 = Ws + wave * 32 * 32;
  bf16* lW1 = lW0 + 16 * 32;
  int fr = lane & 15, fq = lane >> 4;
  int wm = wave >> 1, wn = wave & 1;
  const bf16* pA = As + (wm * 64 + fr) * 32 + fq * 8;
  const bf16* pW = Ws + (wn * 64 + fr) * 32 + fq * 8;
  f32x4 acc[4][4] = {};
  for (int k0 = 0; k0 < kchunk; k0 += 32) {
    async_copy16(gA0, lA0);
    async_copy16(gA1, lA1);
    async_copy16(gW0, lW0);
    async_copy16(gW1, lW1);
    gA0 += 32; gA1 += 32; gW0 += 32; gW1 += 32;
    __syncthreads();
    bf16x8 af[4], bfr[4];
#pragma unroll
    for (int mi = 0; mi < 4; mi++) af[mi] = *(const bf16x8*)(pA + mi * 16 * 32);
#pragma unroll
    for (int ni = 0; ni < 4; ni++) bfr[ni] = *(const bf16x8*)(pW + ni * 16 * 32);
#pragma unroll
    for (int mi = 0; mi < 4; mi++)
#pragma unroll
      for (int ni = 0; ni < 4; ni++)
        acc[mi][ni] = __builtin_amdgcn_mfma_f32_16x16x32_bf16(af[mi], bfr[ni], acc[mi][ni], 0, 0, 0);
    __syncthreads();
  }
  bf16* Pp = P + (size_t)ks * M * N;
#pragma unroll
  for (int mi = 0; mi < 4; mi++) {
    int row = bm + wm * 64 + mi * 16 + fq * 4;
#pragma unroll
    for (int ni = 0; ni < 4; ni++) {
      int col = bn + wn * 64 + ni * 16 + fr;
#pragma unroll
      for (int r = 0; r < 4; r++)
        Pp[(size_t)(row + r) * N + col] = (bf16)acc[mi][ni][r];
    }
  }
}

// ---------------- reduce 2 bf16 partials + residual + layernorm -> x_out f32, h bf16 ----------------
__global__ __launch_bounds__(256) void reduce_ln2(const bf16* __restrict__ p0,
                                                  const bf16* __restrict__ p1,
                                                  const float* __restrict__ res,
                                                  const float* __restrict__ w,
                                                  const float* __restrict__ b,
                                                  float* __restrict__ xo,
                                                  bf16* __restrict__ ho) {
  __shared__ float sh[4];
  size_t o = (size_t)blockIdx.x * 1024;
  int i = threadIdx.x * 4;
  bf16x4 a = *(const bf16x4*)(p0 + o + i);
  bf16x4 c = *(const bf16x4*)(p1 + o + i);
  f32x4 rv = *(const f32x4*)(res + o + i);
  f32x4 v;
  float s = 0.f, s2 = 0.f;
#pragma unroll
  for (int j = 0; j < 4; j++) {
    v[j] = (float)a[j] + (float)c[j] + rv[j];
    s += v[j]; s2 += v[j] * v[j];
  }
  s  = blockReduceSum<4>(s,  sh);
  s2 = blockReduceSum<4>(s2, sh);
  float mean = s / 1024.f;
  float var  = s2 / 1024.f - mean * mean;
  float inv  = rsqrtf(var + 1e-5f);
  f32x4 wv = *(const f32x4*)(w + i);
  f32x4 bv = *(const f32x4*)(b + i);
  *(f32x4*)(xo + o + i) = v;
  bf16x4 hv;
#pragma unroll
  for (int j = 0; j < 4; j++) hv[j] = (bf16)((v[j] - mean) * inv * wv[j] + bv[j]);
  *(bf16x4*)(ho + o + i) = hv;
}

// ---------------- reduce 3 bf16 partials + residual -> out f32 ----------------
__global__ __launch_bounds__(256) void reduce_out3(const bf16* __restrict__ p0,
                                                   const bf16* __restrict__ p1,
                                                   const bf16* __restrict__ p2,
                                                   const float* __restrict__ res,
                                                   float* __restrict__ out) {
  int i = (blockIdx.x * 256 + threadIdx.x) * 4;
  bf16x4 a = *(const bf16x4*)(p0 + i);
  bf16x4 c = *(const bf16x4*)(p1 + i);
  bf16x4 d = *(const bf16x4*)(p2 + i);
  f32x4 v = *(const f32x4*)(res + i);
#pragma unroll
  for (int j = 0; j < 4; j++) v[j] += (float)a[j] + (float)c[j] + (float)d[j];
  *(f32x4*)(out + i) = v;
}

// ---------------- reduce qkv bf16 partials + q/k rmsnorm + rope + gain -> bf16 ----------------
__global__ __launch_bounds__(256) void reduce_qkv(const bf16* __restrict__ P,
                                                  const float* __restrict__ q_gain,
                                                  bf16* __restrict__ q,
                                                  bf16* __restrict__ k,
                                                  bf16* __restrict__ v) {
  __shared__ float buf[1536];
  size_t row = blockIdx.x;
  size_t o = row * 1536;
  const bf16* p0 = P + o;
  const bf16* p1 = P + (size_t)ROWS * 1536 + o;
  int tid = threadIdx.x;
  for (int i = tid; i < 384; i += 256) {
    bf16x4 a = *(const bf16x4*)(p0 + i * 4);
    bf16x4 c = *(const bf16x4*)(p1 + i * 4);
    f32x4 vv;
#pragma unroll
    for (int j = 0; j < 4; j++) vv[j] = (float)a[j] + (float)c[j];
    *(f32x4*)(buf + i * 4) = vv;
  }
  __syncthreads();
  int lane = tid & 63, w = tid >> 6;
  int s = (int)(row & (S_ - 1));
  int ri = lane & 7;
  float rinv = __expf(-(float)ri * (0.125f * 9.210340371976184f)); // 10000^(-i/8)
  float ang = (float)s * rinv;
  float cs = cosf(ang), sn = sinf(ang);
#pragma unroll
  for (int j = 0; j < 6; j++) {
    int hh = w * 6 + j;
    float val = buf[hh * 64 + lane];
    if (hh < 20) {
      float ss = val * val;
#pragma unroll
      for (int off = 32; off > 0; off >>= 1) ss += __shfl_xor(ss, off, 64);
      val *= rsqrtf(ss / 64.f + 1.1920929e-7f);
      float other = __shfl_xor(val, 8, 64);
      float res = val;
      if (lane < RD) res = (lane < 8) ? (val * cs + other * sn) : (val * cs - other * sn);
      if (hh < 16) {
        res *= q_gain[hh];
        q[row * (HATT * HD) + hh * HD + lane] = (bf16)res;
      } else {
        k[row * (KVH * HD) + (hh - 16) * HD + lane] = (bf16)res;
      }
    } else {
      v[row * (KVH * HD) + (hh - 20) * HD + lane] = (bf16)val;
    }
  }
}

// ---------------- in_proj GEMM: R3-verified 3-buf single-barrier core + R5-verified grid ----
// Heavy (bid<256): 256x256 tile, 96KB 3-buf LDS rotation, per K-step {stage t+1 -> buf nxt;
// vmcnt(4) (t landed, t+1 in flight); barrier; 12 swizzled ds_read_b128; setprio(1);
// 32 MFMA; setprio(0)}. ONE barrier per step: 3 buffers make the WAR race-free (buf nxt
// last read in step t-2, all waves past barrier t-1). Measured 33.5us/round in R3 (50% of
// 16x16 MFMA ceiling) vs 56us for 2-buf/2-barrier (R5) and baseline 128^2.
// Grid 256 heavy = EXACTLY one dispatch round at 1 block/CU (R3's 288-grid cost 2 rounds).
// Light (bid>=256): same 3-buf/1-barrier schedule at 128^2 for the bcdt strip (short tail).
__global__ __launch_bounds__(512, 2) void gemm256_inproj(const bf16* __restrict__ A,
                                                         const bf16* __restrict__ W,
                                                         bf16* __restrict__ zt,
                                                         bf16* __restrict__ xt,
                                                         bf16* __restrict__ bcdt) {
  __shared__ bf16 lds[3 * 16384];          // 96 KB
  int tid = threadIdx.x;
  int lane = tid & 63, w = tid >> 6;       // 8 waves
  int fr = lane & 15, fq = lane >> 4;
  int rdswz = (fq ^ (fr & 3)) * 8;         // swizzled read offset
  int sswz = (lane & 3) ^ ((lane >> 2) & 3);   // inverse swizzle on global source
  int bid = blockIdx.x;
  if (bid < 256) {
    int sb = (bid & 7) * 32 + (bid >> 3);  // XCD swizzle (256 = 8*32, bijective)
    int bm = (sb & 15) * 256;              // 16 M tiles fastest (share W panel)
    int bn = (sb >> 4) * 256;              // 16 N tiles -> cols 0..4095 (z/x only)
    int wm = w >> 2, wn = w & 3;           // 2M x 4N waves: per wave 128x64
    int srow = w * 32 + (lane >> 2);
    const bf16* gA = A + (size_t)(bm + srow) * 1024 + sswz * 8;
    const bf16* gW = W + (size_t)(bn + srow) * 1024 + sswz * 8;
    int sbase = w * 1024;                  // wave's 32-row stage region (elements)
    f32x4 acc[8][4] = {};
    // prologue: stage tile 0 -> buf 0
    {
      bf16* bA = lds + sbase;
      bf16* bB = lds + 8192 + sbase;
      async_copy16(gA, bA);
      async_copy16(gA + 16 * 1024, bA + 512);
      async_copy16(gW, bB);
      async_copy16(gW + 16 * 1024, bB + 512);
    }
    int cur = 0, nxt = 1;
    for (int t = 0; t < 32; t++) {
      if (t + 1 < 32) {
        const bf16* ga = gA + (t + 1) * 32;
        const bf16* gw = gW + (t + 1) * 32;
        bf16* bA = lds + nxt * 16384 + sbase;
        bf16* bB = lds + nxt * 16384 + 8192 + sbase;
        async_copy16(ga, bA);
        async_copy16(ga + 16 * 1024, bA + 512);
        async_copy16(gw, bB);
        async_copy16(gw + 16 * 1024, bB + 512);
        asm volatile("s_waitcnt vmcnt(4)" ::: "memory");   // tile t done; t+1 flies
      } else {
        asm volatile("s_waitcnt vmcnt(0)" ::: "memory");
      }
      __builtin_amdgcn_sched_barrier(0);
      __builtin_amdgcn_s_barrier();
      __builtin_amdgcn_sched_barrier(0);
      const bf16* cA = lds + cur * 16384;
      const bf16* cB = cA + 8192;
      bf16x8 af[8], bfv[4];
#pragma unroll
      for (int mi = 0; mi < 8; mi++)
        af[mi] = *(const bf16x8*)(cA + (wm * 128 + mi * 16 + fr) * 32 + rdswz);
#pragma unroll
      for (int ni = 0; ni < 4; ni++)
        bfv[ni] = *(const bf16x8*)(cB + (wn * 64 + ni * 16 + fr) * 32 + rdswz);
      __builtin_amdgcn_s_setprio(1);
#pragma unroll
      for (int mi = 0; mi < 8; mi++)
#pragma unroll
        for (int ni = 0; ni < 4; ni++)
          acc[mi][ni] = __builtin_amdgcn_mfma_f32_16x16x32_bf16(af[mi], bfv[ni], acc[mi][ni], 0, 0, 0);
      __builtin_amdgcn_s_setprio(0);
      cur = nxt; nxt = nxt + 1; if (nxt == 3) nxt = 0;
    }
    // epilogue: LDS-transposed coalesced Zt/Xt stores (R3-verified path)
    bf16* base = (bn < 2048) ? zt : xt;
    int bq = bm >> 11, bmS = bm & 2047;
    bf16* Ts = lds;                        // 64 x 264 bf16 scratch (33.8 KB)
#pragma unroll 1
    for (int g = 0; g < 4; g++) {
      __syncthreads();
      if (wn == g) {
#pragma unroll
        for (int mi = 0; mi < 8; mi++)
#pragma unroll
          for (int ni = 0; ni < 4; ni++) {
            bf16x4 o;
#pragma unroll
            for (int r = 0; r < 4; r++) o[r] = (bf16)acc[mi][ni][r];
            *(bf16x4*)(Ts + (ni * 16 + fr) * 264 + wm * 128 + mi * 16 + fq * 4) = o;
          }
      }
      __syncthreads();
      int hh = ((bn & 2047) + g * 64) >> 6;
      bf16* dst = base + ((size_t)(bq * NH + hh) * HD) * S_ + bmS;
#pragma unroll
      for (int i = 0; i < 4; i++) {
        int idx = tid + i * 512;
        int p = idx >> 5, sc = (idx & 31) * 8;
        *(bf16x8*)(dst + (size_t)p * S_ + sc) = *(const bf16x8*)(Ts + p * 264 + sc);
      }
    }
  } else {
    // ---- light path: 128x128 tile over bcdt columns 4096..4383 (3rd tile masked) ----
    int lb = bid - 256;
    int bm = (lb & 31) * 128;
    int bn = 4096 + (lb >> 5) * 128;
    int wm = w >> 1, wn = w & 1;           // 4M x 2N waves: per wave 32x64
    int srow = w * 16 + (lane >> 2);
    const bf16* gA = A + (size_t)(bm + srow) * 1024 + sswz * 8;
    const bf16* gW = W + (size_t)(bn + srow) * 1024 + sswz * 8;
    int sbase = w * 512;                   // wave's 16-row stage region (elems)
    f32x4 acc[2][4] = {};
    {
      async_copy16(gA, lds + sbase);
      async_copy16(gW, lds + 4096 + sbase);
    }
    int cur = 0, nxt = 1;
    for (int t = 0; t < 32; t++) {
      if (t + 1 < 32) {
        const bf16* ga = gA + (t + 1) * 32;
        const bf16* gw = gW + (t + 1) * 32;
        async_copy16(ga, lds + nxt * 8192 + sbase);
        async_copy16(gw, lds + nxt * 8192 + 4096 + sbase);
        asm volatile("s_waitcnt vmcnt(2)" ::: "memory");
      } else {
        asm volatile("s_waitcnt vmcnt(0)" ::: "memory");
      }
      __builtin_amdgcn_sched_barrier(0);
      __builtin_amdgcn_s_barrier();
      __builtin_amdgcn_sched_barrier(0);
      const bf16* cA = lds + cur * 8192;
      const bf16* cB = cA + 4096;
      bf16x8 af[2], bfv[4];
#pragma unroll
      for (int mi = 0; mi < 2; mi++)
        af[mi] = *(const bf16x8*)(cA + (wm * 32 + mi * 16 + fr) * 32 + rdswz);
#pragma unroll
      for (int ni = 0; ni < 4; ni++)
        bfv[ni] = *(const bf16x8*)(cB + (wn * 64 + ni * 16 + fr) * 32 + rdswz);
#pragma unroll
      for (int mi = 0; mi < 2; mi++)
#pragma unroll
        for (int ni = 0; ni < 4; ni++)
          acc[mi][ni] = __builtin_amdgcn_mfma_f32_16x16x32_bf16(af[mi], bfv[ni], acc[mi][ni], 0, 0, 0);
      cur = nxt; nxt = nxt + 1; if (nxt == 3) nxt = 0;
    }
#pragma unroll
    for (int mi = 0; mi < 2; mi++) {
      int row = bm + wm * 32 + mi * 16 + fq * 4;
#pragma unroll
      for (int ni = 0; ni < 4; ni++) {
        int col = bn + wn * 64 + ni * 16 + fr;
        if (col < 4384) {
#pragma unroll
          for (int r = 0; r < 4; r++)
            bcdt[(size_t)(row + r) * 288 + (col - 4096)] = (bf16)acc[mi][ni][r];
        }
      }
    }
  }
}

// ---------------- generic 64x64 tiled transpose (bf16), out row stride 2048 ----------------
__global__ __launch_bounds__(256) void t64(const bf16* __restrict__ in, bf16* __restrict__ out,
                                           int istr, size_t io, size_t oo, int n_nt) {
  __shared__ bf16 T[64 * 72];
  int bid = blockIdx.x;
  int st = bid & 31;
  int nt = (bid >> 5) % n_nt;
  int outer = bid / (32 * n_nt);
  const bf16* ip = in + outer * io + (size_t)st * 64 * istr + nt * 64;
  int tid = threadIdx.x;
#pragma unroll
  for (int i = 0; i < 2; i++) {
    int cid = tid + i * 256; int s = cid >> 3, pc = (cid & 7) * 8;
    *(bf16x8*)(T + s * 72 + pc) = *(const bf16x8*)(ip + (size_t)s * istr + pc);
  }
  __syncthreads();
  bf16* op = out + outer * oo + (size_t)nt * 64 * 2048 + st * 64;
#pragma unroll
  for (int i = 0; i < 2; i++) {
    int cid = tid + i * 256; int p = cid >> 3, sc = (cid & 7) * 8;
    bf16x8 o;
#pragma unroll
    for (int j = 0; j < 8; j++) o[j] = T[(sc + j) * 72 + p];
    *(bf16x8*)(op + (size_t)p * 2048 + sc) = o;
  }
}

// ---------------- SSD prep: dt softplus, per-chunk cumsum, decay factors ----------------
__global__ __launch_bounds__(64) void ssd_prep(const bf16* __restrict__ bcdt,
                                               const float* __restrict__ dt_bias,
                                               const float* __restrict__ A_log,
                                               float* __restrict__ dt_c,
                                               float* __restrict__ ddc,
                                               float* __restrict__ ac_c,
                                               float* __restrict__ T_out) {
  int bid = blockIdx.x;
  int c = bid % NC, hh = (bid / NC) % NH, b = bid / (NC * NH);
  int l = threadIdx.x;
  size_t row = (size_t)b * S_ + c * 64 + l;
  float raw = (float)bcdt[row * 288 + 256 + hh] + dt_bias[hh];
  float dtv = (raw > 20.f) ? raw : log1pf(__expf(raw));
  float a = -__expf(A_log[hh]) * dtv;
  float ps = a;
#pragma unroll
  for (int off = 1; off < 64; off <<= 1) {
    float t = __shfl_up(ps, off, 64);
    if (l >= off) ps += t;
  }
  float a63 = __shfl(ps, 63, 64);
  size_t o = ((size_t)b * NH + hh) * S_ + c * 64 + l;
  dt_c[o] = dtv;
  ac_c[o] = ps;
  ddc[o] = __expf(a63 - ps) * dtv;
  if (l == 63) T_out[(b * NH + hh) * NC + c] = ps;
}

// ---------------- B/C rmsnorm (bf16 out) ----------------
__global__ __launch_bounds__(128) void bc_norm(const bf16* __restrict__ bcdt,
                                               const float* __restrict__ Bw,
                                               const float* __restrict__ Cw,
                                               bf16* __restrict__ Bn,
                                               bf16* __restrict__ Cn) {
  __shared__ float shb[2], shc[2];
  size_t row = blockIdx.x;
  int i = threadIdx.x;
  float bv = (float)bcdt[row * 288 + i];
  float cv = (float)bcdt[row * 288 + 128 + i];
  float sb = waveReduceSum(bv * bv);
  float sc = waveReduceSum(cv * cv);
  int lane = threadIdx.x & 63, wid = threadIdx.x >> 6;
  if (lane == 0) { shb[wid] = sb; shc[wid] = sc; }
  __syncthreads();
  float tb = shb[0] + shb[1];
  float tc = shc[0] + shc[1];
  Bn[row * DS + i] = (bf16)(bv * rsqrtf(tb / DS + 1e-5f) * Bw[i]);
  Cn[row * DS + i] = (bf16)(cv * rsqrtf(tc / DS + 1e-5f) * Cw[i]);
}

// ---------------- chunk states via MFMA (bf16 output) ----------------
__global__ __launch_bounds__(256) void ssd_states(const bf16* __restrict__ Xt,
                                                  const bf16* __restrict__ Btr,
                                                  const float* __restrict__ ddc,
                                                  bf16* __restrict__ states) {
  __shared__ bf16 Xs[64 * 72];    // [p][s]
  __shared__ bf16 Bs[128 * 72];   // [n][s]
  int bid = blockIdx.x;           // (b*NC + c)*NH + h
  int h = bid % NH;
  int c = (bid / NH) % NC;
  int b = bid / (NH * NC);
  int tid = threadIdx.x, lane = tid & 63, w = tid >> 6;
  int fr = lane & 15, fq = lane >> 4;
  const size_t xbase = (size_t)(b * NH + h) * HD * S_ + c * 64;
  const size_t dbase = (size_t)(b * NH + h) * S_ + c * 64;
#pragma unroll
  for (int i = 0; i < 2; i++) {
    int cid = tid + i * 256; int p = cid >> 3, sc = (cid & 7) * 8;
    bf16x8 xv = *(const bf16x8*)(Xt + xbase + (size_t)p * S_ + sc);
    f32x4 d0 = *(const f32x4*)(ddc + dbase + sc);
    f32x4 d1 = *(const f32x4*)(ddc + dbase + sc + 4);
    bf16x8 o;
#pragma unroll
    for (int j = 0; j < 4; j++) { o[j] = (bf16)((float)xv[j] * d0[j]); o[4 + j] = (bf16)((float)xv[4 + j] * d1[j]); }
    *(bf16x8*)(Xs + p * 72 + sc) = o;
  }
  const size_t bbase = (size_t)b * 128 * S_ + c * 64;
#pragma unroll
  for (int i = 0; i < 4; i++) {
    int cid = tid + i * 256; int n = cid >> 3, sc = (cid & 7) * 8;
    *(bf16x8*)(Bs + n * 72 + sc) = *(const bf16x8*)(Btr + bbase + (size_t)n * S_ + sc);
  }
  __syncthreads();
  f32x4 acc[4][2] = {};
#pragma unroll
  for (int ks = 0; ks < 2; ks++) {
    bf16x8 a[4], bb[2];
#pragma unroll
    for (int pt = 0; pt < 4; pt++) a[pt] = *(const bf16x8*)(Xs + (pt * 16 + fr) * 72 + ks * 32 + fq * 8);
#pragma unroll
    for (int n2 = 0; n2 < 2; n2++) bb[n2] = *(const bf16x8*)(Bs + ((2 * w + n2) * 16 + fr) * 72 + ks * 32 + fq * 8);
#pragma unroll
    for (int pt = 0; pt < 4; pt++)
#pragma unroll
      for (int n2 = 0; n2 < 2; n2++)
        acc[pt][n2] = __builtin_amdgcn_mfma_f32_16x16x32_bf16(a[pt], bb[n2], acc[pt][n2], 0, 0, 0);
  }
  bf16* outp = states + (size_t)bid * 8192;
#pragma unroll
  for (int pt = 0; pt < 4; pt++)
#pragma unroll
    for (int n2 = 0; n2 < 2; n2++) {
      int n = (2 * w + n2) * 16 + fr;
#pragma unroll
      for (int r = 0; r < 4; r++)
        outp[(size_t)(pt * 16 + fq * 4 + r) * 128 + n] = (bf16)acc[pt][n2][r];
    }
}

// ---------------- inter-chunk scan (in place, bf16 storage, f32 math) ----------------
__global__ __launch_bounds__(256) void ssd_scan(bf16* __restrict__ states,
                                                const float* __restrict__ T) {
  __shared__ float eT[NC];
  int part = blockIdx.x & 7;
  int bh = blockIdx.x >> 3;
  int b = bh / NH, h = bh % NH;
  if (threadIdx.x < NC) eT[threadIdx.x] = __expf(T[(size_t)(b * NH + h) * NC + threadIdx.x]);
  __syncthreads();
  const size_t cstride = (size_t)NH * HD * DS;
  size_t base = ((size_t)b * NC * NH + h) * (HD * DS);
#pragma unroll
  for (int j = 0; j < 4; j++) {
    int e = part * 1024 + threadIdx.x + j * 256;
    float carry = 0.f;
    size_t idx = base + e;
    for (int c = 0; c < NC; c++) {
      float sv = (float)states[idx];
      states[idx] = (bf16)carry;
      carry = sv + eT[c] * carry;
      idx += cstride;
    }
  }
}

// ---------------- fused SSD output: Ydiag + Yoff + D-skip + gate (all MFMA) ----------------
__global__ __launch_bounds__(256) void ssd_out(const bf16* __restrict__ Cn,
                                               const bf16* __restrict__ Bn,
                                               const bf16* __restrict__ Xt,
                                               const bf16* __restrict__ Zt,
                                               const float* __restrict__ dt_c,
                                               const float* __restrict__ ac_c,
                                               const bf16* __restrict__ states,
                                               const float* __restrict__ Dp,
                                               bf16* __restrict__ ybf) {
  __shared__ bf16 Cs[64 * 136];
  __shared__ bf16 BNs[64 * 136];
  __shared__ bf16 Xs[64 * 72];
  __shared__ bf16 G[64 * 72];
  __shared__ float acs[64];
  int bid = blockIdx.x;
  int h = bid % NH;
  int c = (bid / NH) % NC;
  int b = bid / (NH * NC);
  int tid = threadIdx.x, lane = tid & 63, w = tid >> 6;
  int fr = lane & 15, fq = lane >> 4;
  size_t row0 = (size_t)b * S_ + c * 64;
  const size_t abase = (size_t)(b * NH + h) * S_ + c * 64;
  if (tid < 64) acs[tid] = ac_c[abase + tid];
#pragma unroll
  for (int i = 0; i < 4; i++) {
    int cid = tid + i * 256; int l = cid >> 4, nc = (cid & 15) * 8;
    float e = __expf(ac_c[abase + l]);
    bf16x8 cv = *(const bf16x8*)(Cn + (row0 + l) * DS + nc);
    bf16x8 o;
#pragma unroll
    for (int j = 0; j < 8; j++) o[j] = (bf16)((float)cv[j] * e);
    *(bf16x8*)(Cs + l * 136 + nc) = o;
    *(bf16x8*)(BNs + l * 136 + nc) = *(const bf16x8*)(Bn + (row0 + l) * DS + nc);
  }
  const size_t xbase = (size_t)(b * NH + h) * HD * S_ + c * 64;
#pragma unroll
  for (int i = 0; i < 2; i++) {
    int cid = tid + i * 256; int p = cid >> 3, sc = (cid & 7) * 8;
    bf16x8 xv = *(const bf16x8*)(Xt + xbase + (size_t)p * S_ + sc);
    f32x4 d0 = *(const f32x4*)(dt_c + abase + sc);
    f32x4 d1 = *(const f32x4*)(dt_c + abase + sc + 4);
    bf16x8 o;
#pragma unroll
    for (int j = 0; j < 4; j++) { o[j] = (bf16)((float)xv[j] * d0[j]); o[4 + j] = (bf16)((float)xv[4 + j] * d1[j]); }
    *(bf16x8*)(Xs + p * 72 + sc) = o;
  }
  __syncthreads();
  bf16x8 ca[4];
#pragma unroll
  for (int ks = 0; ks < 4; ks++) ca[ks] = *(const bf16x8*)(Cs + (w * 16 + fr) * 136 + ks * 32 + fq * 8);
  f32x4 cb[4] = {};
  for (int st = 0; st <= w; st++)
#pragma unroll
    for (int ks = 0; ks < 4; ks++)
      cb[st] = __builtin_amdgcn_mfma_f32_16x16x32_bf16(ca[ks],
                 *(const bf16x8*)(BNs + (st * 16 + fr) * 136 + ks * 32 + fq * 8), cb[st], 0, 0, 0);
#pragma unroll
  for (int st = 0; st < 4; st++) {
    float es = (st <= w) ? __expf(-acs[st * 16 + fr]) : 0.f;
#pragma unroll
    for (int r = 0; r < 4; r++) {
      int lloc = fq * 4 + r;
      float g = 0.f;
      if (st < w) g = cb[st][r] * es;
      else if (st == w) g = (lloc >= fr) ? cb[st][r] * es : 0.f;
      G[(w * 16 + lloc) * 72 + st * 16 + fr] = (bf16)g;
    }
  }
  f32x4 acc[4] = {};
  {
    bf16x8 ga0 = *(const bf16x8*)(G + (w * 16 + fr) * 72 + fq * 8);
    bf16x8 ga1 = *(const bf16x8*)(G + (w * 16 + fr) * 72 + 32 + fq * 8);
#pragma unroll
    for (int pt = 0; pt < 4; pt++) {
      acc[pt] = __builtin_amdgcn_mfma_f32_16x16x32_bf16(ga0,
                  *(const bf16x8*)(Xs + (pt * 16 + fr) * 72 + fq * 8), acc[pt], 0, 0, 0);
      acc[pt] = __builtin_amdgcn_mfma_f32_16x16x32_bf16(ga1,
                  *(const bf16x8*)(Xs + (pt * 16 + fr) * 72 + 32 + fq * 8), acc[pt], 0, 0, 0);
    }
  }
  __syncthreads();
  const bf16* stp = states + (size_t)bid * 8192;
#pragma unroll
  for (int i = 0; i < 4; i++) {
    int cid = tid + i * 256; int p = cid >> 4, nc = (cid & 15) * 8;
    *(bf16x8*)(BNs + p * 136 + nc) = *(const bf16x8*)(stp + (size_t)p * 128 + nc);
  }
  __syncthreads();
#pragma unroll
  for (int pt = 0; pt < 4; pt++)
#pragma unroll
    for (int ks = 0; ks < 4; ks++)
      acc[pt] = __builtin_amdgcn_mfma_f32_16x16x32_bf16(ca[ks],
                  *(const bf16x8*)(BNs + (pt * 16 + fr) * 136 + ks * 32 + fq * 8), acc[pt], 0, 0, 0);
  float dph = Dp[h];
#pragma unroll
  for (int pt = 0; pt < 4; pt++) {
    int p = pt * 16 + fr;
    size_t tb = (xbase + (size_t)p * S_) + w * 16 + fq * 4;
    bf16x4 xs4 = *(const bf16x4*)(Xt + tb);
    bf16x4 z4  = *(const bf16x4*)(Zt + tb);
#pragma unroll
    for (int r = 0; r < 4; r++) {
      int l = w * 16 + fq * 4 + r;
      float yv = acc[pt][r] + (float)xs4[r] * dph;
      float z = (float)z4[r];
      yv *= z / (1.f + __expf(-z));
      ybf[((row0 + l) * NH + h) * HD + p] = (bf16)yv;
    }
  }
}

// ---------------- split-S MFMA flash attention (fixed-max softmax -> partials sum) ----------------
// Single-buffered K/V (LDS 36.9 KB -> 4 blocks/CU); prefetch issued after the
// second barrier so loads overlap compute and drain at next iter's first barrier.
#define KSTR 72
#define PSTR 72
__global__ __launch_bounds__(256) void attn_mfma(const bf16* __restrict__ q,
                                                 const bf16* __restrict__ k,
                                                 const bf16* __restrict__ vtr,
                                                 bf16* __restrict__ Po,
                                                 float* __restrict__ Ls) {
  __shared__ bf16 Ks[64 * KSTR];
  __shared__ bf16 Vs[64 * KSTR];
  __shared__ bf16 Pl[4][32 * PSTR];
  int c = 39 - blockIdx.x;                 // full 8-iter chunks first
  int g = (c < 4) ? 0 : (c < 12) ? 1 : (c < 24) ? 2 : 3;
  int gbase = (g == 0) ? 0 : (g == 1) ? 4 : (g == 2) ? 12 : 24;
  int d = c - gbase;
  int qt = 4 * g + d / (g + 1);
  int sk = d % (g + 1);
  int h = blockIdx.y, b = blockIdx.z;
  int kvh = h >> 2;
  int tid = threadIdx.x, lane = tid & 63, w = tid >> 6;
  int fr = lane & 15, fq = lane >> 4;
  const float SC = 0.18033688011112042f;   // 0.125 * log2(e)
  const float M2 = 62.0f;
  int kt0 = sk * 8;
  int ktend = min(kt0 + 8, 2 * qt + 2);
  int qbase = qt * 128 + w * 32;           // wave's first q row
  int qmaxw = qbase + 31;
  bf16x8 bq[2][2];
#pragma unroll
  for (int qc = 0; qc < 2; qc++)
#pragma unroll
    for (int ks = 0; ks < 2; ks++)
      bq[qc][ks] = *(const bf16x8*)(q + (size_t)(b * S_ + qbase + qc * 16 + fr) * (HATT * HD)
                                      + h * HD + ks * 32 + fq * 8);
  int sr = tid >> 3, sc8 = (tid & 7) * 8;
  const bf16* kg = k + ((size_t)(b * S_) + sr) * (KVH * HD) + kvh * HD + sc8;
  const bf16* vg = vtr + ((size_t)(b * KVH + kvh) * HD + sr) * S_ + sc8;
  bf16x8 krg0, krg1, vrg0, vrg1;
  {
    const bf16* kp = kg + (size_t)kt0 * 64 * (KVH * HD);
    const bf16* vp = vg + (size_t)kt0 * 64;
    krg0 = *(const bf16x8*)(kp);
    krg1 = *(const bf16x8*)(kp + (size_t)32 * (KVH * HD));
    vrg0 = *(const bf16x8*)(vp);
    vrg1 = *(const bf16x8*)(vp + (size_t)32 * S_);
  }
  float lsum[2] = {0.f, 0.f};
  f32x4 yacc[2][4] = {};
  bf16* Plw = Pl[w];
  for (int kt = kt0; kt < ktend; kt++) {
    __syncthreads();   // previous iteration's LDS reads complete
    *(bf16x8*)(&Ks[sr * KSTR + sc8]) = krg0;
    *(bf16x8*)(&Ks[(sr + 32) * KSTR + sc8]) = krg1;
    *(bf16x8*)(&Vs[sr * KSTR + sc8]) = vrg0;
    *(bf16x8*)(&Vs[(sr + 32) * KSTR + sc8]) = vrg1;
    __syncthreads();   // tile visible
    // prefetch next tile AFTER the barrier: loads overlap compute below
    if ((kt + 1) < ktend) {
      const bf16* kp = kg + (size_t)(kt + 1) * 64 * (KVH * HD);
      const bf16* vp = vg + (size_t)(kt + 1) * 64;
      krg0 = *(const bf16x8*)(kp);
      krg1 = *(const bf16x8*)(kp + (size_t)32 * (KVH * HD));
      vrg0 = *(const bf16x8*)(vp);
      vrg1 = *(const bf16x8*)(vp + (size_t)32 * S_);
    }
    if (kt * 64 <= qmaxw) {
      bool nomask = (kt * 64 + 63) <= qbase;
      if (nomask) {
#pragma unroll
        for (int mi = 0; mi < 4; mi++) {
          const bf16* krow = &Ks[(mi * 16 + fr) * KSTR];
          bf16x8 ak0 = *(const bf16x8*)(krow + fq * 8);
          bf16x8 ak1 = *(const bf16x8*)(krow + 32 + fq * 8);
#pragma unroll
          for (int qc = 0; qc < 2; qc++) {
            f32x4 s = {};
            s = __builtin_amdgcn_mfma_f32_16x16x32_bf16(ak0, bq[qc][0], s, 0, 0, 0);
            s = __builtin_amdgcn_mfma_f32_16x16x32_bf16(ak1, bq[qc][1], s, 0, 0, 0);
            bf16x4 pk;
#pragma unroll
            for (int r = 0; r < 4; r++) {
              float p = __builtin_amdgcn_exp2f(s[r] * SC - M2);
              lsum[qc] += p;
              pk[r] = (bf16)p;
            }
            *(bf16x4*)(Plw + (qc * 16 + fr) * PSTR + mi * 16 + fq * 4) = pk;
          }
        }
      } else {
#pragma unroll
        for (int mi = 0; mi < 4; mi++) {
          int s0 = kt * 64 + mi * 16;
          if (s0 > qmaxw) {
            bf16x4 zz = {};
#pragma unroll
            for (int qc = 0; qc < 2; qc++)
              *(bf16x4*)(Plw + (qc * 16 + fr) * PSTR + mi * 16 + fq * 4) = zz;
          } else {
            const bf16* krow = &Ks[(mi * 16 + fr) * KSTR];
            bf16x8 ak0 = *(const bf16x8*)(krow + fq * 8);
            bf16x8 ak1 = *(const bf16x8*)(krow + 32 + fq * 8);
#pragma unroll
            for (int qc = 0; qc < 2; qc++) {
              f32x4 s = {};
              s = __builtin_amdgcn_mfma_f32_16x16x32_bf16(ak0, bq[qc][0], s, 0, 0, 0);
              s = __builtin_amdgcn_mfma_f32_16x16x32_bf16(ak1, bq[qc][1], s, 0, 0, 0);
              int qq = qbase + qc * 16 + fr;
              bf16x4 pk;
#pragma unroll
              for (int r = 0; r < 4; r++) {
                int sp = s0 + fq * 4 + r;
                float p = (sp <= qq) ? __builtin_amdgcn_exp2f(s[r] * SC - M2) : 0.f;
                lsum[qc] += p;
                pk[r] = (bf16)p;
              }
              *(bf16x4*)(Plw + (qc * 16 + fr) * PSTR + mi * 16 + fq * 4) = pk;
            }
          }
        }
      }
#pragma unroll
      for (int ks2 = 0; ks2 < 2; ks2++) {
        bf16x8 bp[2];
#pragma unroll
        for (int qc = 0; qc < 2; qc++)
          bp[qc] = *(const bf16x8*)(Plw + (qc * 16 + fr) * PSTR + ks2 * 32 + fq * 8);
#pragma unroll
        for (int pi = 0; pi < 4; pi++) {
          bf16x8 av = *(const bf16x8*)(&Vs[(pi * 16 + fr) * KSTR + ks2 * 32 + fq * 8]);
#pragma unroll
          for (int qc = 0; qc < 2; qc++)
            yacc[qc][pi] = __builtin_amdgcn_mfma_f32_16x16x32_bf16(av, bp[qc], yacc[qc][pi], 0, 0, 0);
        }
      }
    }
  }
#pragma unroll
  for (int qc = 0; qc < 2; qc++) {
    lsum[qc] += __shfl_xor(lsum[qc], 16, 64);
    lsum[qc] += __shfl_xor(lsum[qc], 32, 64);
    int qrow = qt * 128 + w * 32 + qc * 16 + fr;
    if (fq == 0)
      Ls[((size_t)(b * 16 + h) * 2048 + qrow) * 4 + sk] = lsum[qc];
    bf16* pop = Po + ((((size_t)(b * 16 + h) * 16 + qt) * 4 + sk) * 128
                       + w * 32 + qc * 16 + fr) * 64 + fq * 4;
#pragma unroll
    for (int pi = 0; pi < 4; pi++) {
      bf16x4 o;
#pragma unroll
      for (int r = 0; r < 4; r++) o[r] = (bf16)yacc[qc][pi][r];
      *(bf16x4*)(pop + pi * 16) = o;
    }
  }
}

// ---------------- attention partial combine + normalize -> y2 bf16 ----------------
__global__ __launch_bounds__(256) void attn_red(const bf16* __restrict__ Po,
                                                const float* __restrict__ Ls,
                                                bf16* __restrict__ y2) {
  int row = blockIdx.x;            // 0..4095
  int b = row >> 11;
  int qrow = row & 2047;
  int qt = qrow >> 7, r = qrow & 127;
  int nch = (qt >> 2) + 1;
  int t = threadIdx.x;
  int h = t >> 4, e4 = (t & 15) << 2;
  const float* lp = Ls + ((size_t)(b * 16 + h) * 2048 + qrow) * 4;
  float ls = 0.f;
  f32x4 acc = {};
  for (int sk = 0; sk < nch; sk++) {
    ls += lp[sk];
    const bf16* pp = Po + ((((size_t)(b * 16 + h) * 16 + qt) * 4 + sk) * 128 + r) * 64 + e4;
    bf16x4 v = *(const bf16x4*)(pp);
#pragma unroll
    for (int j = 0; j < 4; j++) acc[j] += (float)v[j];
  }
  float inv = 1.f / ls;
  bf16x4 o;
#pragma unroll
  for (int j = 0; j < 4; j++) o[j] = (bf16)(acc[j] * inv);
  *(bf16x4*)(y2 + (size_t)row * 1024 + h * 64 + e4) = o;
}

// ---------------- workspace layout (byte offsets) ----------------
constexpr size_t OFF_WIN  = 0;                   // bf16 4480x1024
constexpr size_t OFF_WOUT = 9175040;             // bf16 1024x2048
constexpr size_t OFF_WQKV = 13369344;            // bf16 1536x1024 (q|k|v rows)
constexpr size_t OFF_WCP  = 16515072;            // bf16 1024x1024
constexpr size_t OFF_WFC  = 18612224;            // bf16 3072x1024
constexpr size_t OFF_WPR  = 24903680;            // bf16 1024x3072
constexpr size_t OFF_HBF  = 31195136;            // bf16 4096x1024
constexpr size_t OFF_BCDT = 39583744;            // bf16 4096x288; reused: Ls f32 (1 MiB)
constexpr size_t OFF_XT   = 41943040;            // bf16 [b][h][p][sg] (16.7 MB)
constexpr size_t OFF_ZT   = 58720256;            // bf16 [b][h][p][sg] (16.7 MB)
constexpr size_t OFF_DTC  = 75497472;            // f32 [b][h][sg]
constexpr size_t OFF_DDC  = 76546048;            // f32
constexpr size_t OFF_ACC  = 77594624;            // f32
constexpr size_t OFF_T    = 78643200;            // f32 2048
constexpr size_t OFF_BN   = 78651392;            // bf16 4096x128
constexpr size_t OFF_CN   = 79699968;            // bf16 4096x128
constexpr size_t OFF_BTR  = 80748544;            // bf16 [b][n][sg]
constexpr size_t OFF_ST   = 81797120;            // bf16 states (33.5 MB); reused: Po bf16 32 MiB
constexpr size_t OFF_YBF  = 148905984;           // bf16 4096x2048
constexpr size_t OFF_X1   = 165683200;           // f32 4096x1024 (end 182,460,416)
// phase-2 aliases
constexpr size_t OFF_P    = OFF_ST;              // bf16 split-K partials (<= 25.2 MB)
constexpr size_t OFF_PO   = OFF_ST;              // bf16 attn partials [b][h][qt][4][128][64] = 32 MiB
constexpr size_t OFF_LS   = OFF_BCDT;            // f32 attn lsums [b][h][2048][4] = 1 MiB
constexpr size_t OFF_QB   = OFF_XT;              // bf16 4096x1024 (8.4 MB)
constexpr size_t OFF_KB   = OFF_XT + 8388608;    // bf16 4096x256
constexpr size_t OFF_VB   = OFF_XT + 10485760;   // bf16 4096x256
constexpr size_t OFF_VTR  = OFF_XT + 12582912;   // bf16 [b][kvh][p][sg]
constexpr size_t OFF_Y2   = OFF_ZT;              // bf16 4096x1024
constexpr size_t OFF_X2   = 50331648;            // f32 4096x1024 (over dead kb/vb/vtr/y2)
constexpr size_t OFF_MLP  = 132128768;           // bf16 4096x3072 (over dead regions)

extern "C" void kernel_launch(void* const* d_in, const int* in_sizes, int n_in,
                              void* d_out, int out_size, void* d_ws, size_t ws_size,
                              hipStream_t stream) {
  (void)in_sizes; (void)n_in; (void)out_size; (void)ws_size;
  const float* x        = (const float*)d_in[0];
  const float* mnorm_w  = (const float*)d_in[1];
  const float* in_w     = (const float*)d_in[2];
  const float* out_w    = (const float*)d_in[3];
  const float* Dp       = (const float*)d_in[4];
  const float* dt_bias  = (const float*)d_in[5];
  const float* A_log    = (const float*)d_in[6];
  const float* Bn_w     = (const float*)d_in[7];
  const float* Cn_w     = (const float*)d_in[8];
  const float* ln1_w    = (const float*)d_in[9];
  const float* ln1_b    = (const float*)d_in[10];
  const float* cq_w     = (const float*)d_in[11];
  const float* ck_w     = (const float*)d_in[12];
  const float* cv_w     = (const float*)d_in[13];
  const float* cproj_w  = (const float*)d_in[14];
  const float* q_gain   = (const float*)d_in[15];
  const float* ln2_w    = (const float*)d_in[16];
  const float* ln2_b    = (const float*)d_in[17];
  const float* fc_w     = (const float*)d_in[18];
  const float* proj_w   = (const float*)d_in[19];
  float* out = (float*)d_out;
  char* W8 = (char*)d_ws;

  bf16* w_in   = (bf16*)(W8 + OFF_WIN);
  bf16* w_out  = (bf16*)(W8 + OFF_WOUT);
  bf16* w_qkv  = (bf16*)(W8 + OFF_WQKV);
  bf16* w_cp   = (bf16*)(W8 + OFF_WCP);
  bf16* w_fc   = (bf16*)(W8 + OFF_WFC);
  bf16* w_pr   = (bf16*)(W8 + OFF_WPR);
  bf16* h_bf   = (bf16*)(W8 + OFF_HBF);
  bf16* bcdt   = (bf16*)(W8 + OFF_BCDT);
  bf16* Xt     = (bf16*)(W8 + OFF_XT);
  bf16* Zt     = (bf16*)(W8 + OFF_ZT);
  float* dt_c  = (float*)(W8 + OFF_DTC);
  float* ddc   = (float*)(W8 + OFF_DDC);
  float* ac_c  = (float*)(W8 + OFF_ACC);
  float* Tb    = (float*)(W8 + OFF_T);
  bf16* Bn     = (bf16*)(W8 + OFF_BN);
  bf16* Cn     = (bf16*)(W8 + OFF_CN);
  bf16* Btr    = (bf16*)(W8 + OFF_BTR);
  bf16* st     = (bf16*)(W8 + OFF_ST);
  bf16* ybf    = (bf16*)(W8 + OFF_YBF);
  float* x1    = (float*)(W8 + OFF_X1);
  bf16* Pbuf   = (bf16*)(W8 + OFF_P);
  bf16* Po     = (bf16*)(W8 + OFF_PO);
  float* Ls    = (float*)(W8 + OFF_LS);
  bf16* qbf    = (bf16*)(W8 + OFF_QB);
  bf16* kbf    = (bf16*)(W8 + OFF_KB);
  bf16* vbf    = (bf16*)(W8 + OFF_VB);
  bf16* vtr    = (bf16*)(W8 + OFF_VTR);
  bf16* y2     = (bf16*)(W8 + OFF_Y2);
  float* x2    = (float*)(W8 + OFF_X2);
  bf16* mlp    = (bf16*)(W8 + OFF_MLP);

  // ---- weight casts (single launch; q/k/v cast into adjacent rows of w_qkv) ----
  CastArgs ca;
  ca.seg[0] = { in_w,    w_in,            4489216, 4587520, 0     };
  ca.seg[1] = { out_w,   w_out,           2097152, 2097152, 4480  };
  ca.seg[2] = { cq_w,    w_qkv,           1048576, 1048576, 6528  };
  ca.seg[3] = { ck_w,    w_qkv + 1048576,  262144,  262144, 7552  };
  ca.seg[4] = { cv_w,    w_qkv + 1310720,  262144,  262144, 7808  };
  ca.seg[5] = { cproj_w, w_cp,            1048576, 1048576, 8064  };
  ca.seg[6] = { fc_w,    w_fc,            3145728, 3145728, 9088  };
  ca.seg[7] = { proj_w,  w_pr,            3145728, 3145728, 12160 };
  castw_all<<<15232, 256, 0, stream>>>(ca);

  const size_t PS  = (size_t)ROWS * 1024;   // partial stride (elements) for N=1024 GEMMs

  // ---- mamba block ----
  rmsnorm_k<<<ROWS, 256, 0, stream>>>(x, mnorm_w, h_bf, D_);
  gemm256_inproj<<<352, 512, 0, stream>>>(h_bf, w_in, Zt, Xt, bcdt);
  ssd_prep<<<B_ * NH * NC, 64, 0, stream>>>(bcdt, dt_bias, A_log, dt_c, ddc, ac_c, Tb);
  bc_norm<<<ROWS, 128, 0, stream>>>(bcdt, Bn_w, Cn_w, Bn, Cn);
  t64<<<2 * 2 * 32, 256, 0, stream>>>(Bn, Btr, 128, (size_t)2048 * 128, (size_t)128 * 2048, 2);
  ssd_states<<<B_ * NC * NH, 256, 0, stream>>>(Xt, Btr, ddc, st);
  ssd_scan<<<B_ * NH * 8, 256, 0, stream>>>(st, Tb);
  ssd_out<<<B_ * NC * NH, 256, 0, stream>>>(Cn, Bn, Xt, Zt, dt_c, ac_c, st, Dp, ybf);
  // out_proj: split-K=2 then fused reduce+residual+LN1
  gemm_sk<<<dim3(32 * 8, 1, 2), 256, 0, stream>>>(ybf, w_out, Pbuf, ROWS, D_, DI, 1024);
  reduce_ln2<<<ROWS, 256, 0, stream>>>(Pbuf, Pbuf + PS, x, ln1_w, ln1_b, x1, h_bf);

  // ---- attention block ----
  gemm_sk<<<dim3(32 * 12, 1, 2), 256, 0, stream>>>(h_bf, w_qkv, Pbuf, ROWS, 1536, D_, 512);
  reduce_qkv<<<ROWS, 256, 0, stream>>>(Pbuf, q_gain, qbf, kbf, vbf);
  t64<<<2 * 4 * 32, 256, 0, stream>>>(vbf, vtr, 256, (size_t)2048 * 256, (size_t)256 * 2048, 4);
  attn_mfma<<<dim3(40, HATT, B_), 256, 0, stream>>>(qbf, kbf, vtr, Po, Ls);
  attn_red<<<ROWS, 256, 0, stream>>>(Po, Ls, y2);
  gemm_sk<<<dim3(32 * 8, 1, 2), 256, 0, stream>>>(y2, w_cp, Pbuf, ROWS, D_, D_, 512);
  reduce_ln2<<<ROWS, 256, 0, stream>>>(Pbuf, Pbuf + PS, x1, ln2_w, ln2_b, x2, h_bf);

  // ---- MLP ----
  gemm_mfma<1, bf16><<<32 * 24, 256, 0, stream>>>(h_bf, w_fc, nullptr, mlp, ROWS, MLP, D_);
  gemm_sk<<<dim3(32 * 8, 1, 3), 256, 0, stream>>>(mlp, w_pr, Pbuf, ROWS, D_, MLP, 1024);
  reduce_out3<<<ROWS, 256, 0, stream>>>(Pbuf, Pbuf + PS, Pbuf + 2 * PS, x2, out);
}

// Round 7
// 499.298 us; speedup vs baseline: 1.4925x; 1.0233x over previous
//
#include <hip/hip_runtime.h>
#include <hip/hip_bf16.h>
#include <math.h>

// ---------------- problem constants ----------------
#define B_    2
#define S_    2048
#define D_    1024
#define DI    2048      // D_INNER
#define NH    32        // NHEADS (mamba)
#define HD    64        // HEADDIM
#define DS    128       // D_STATE
#define CH    64        // CHUNK
#define NC    32        // S_/CH
#define DP    4384      // D_PROJ
#define HATT  16        // attention heads
#define KVH   4         // kv heads
#define RD    16        // rope dims
#define MLP   3072
#define ROWS  (B_*S_)   // 4096

typedef __bf16 bf16;
typedef __bf16 bf16x8 __attribute__((ext_vector_type(8)));
typedef __bf16 bf16x4 __attribute__((ext_vector_type(4)));
typedef float  f32x4  __attribute__((ext_vector_type(4)));

__device__ __forceinline__ void async_copy16(const void* g, void* l) {
  __builtin_amdgcn_global_load_lds(
      (const __attribute__((address_space(1))) unsigned int*)g,
      (__attribute__((address_space(3))) unsigned int*)l, 16, 0, 0);
}

// ---------------- reductions ----------------
__device__ __forceinline__ float waveReduceSum(float v) {
#pragma unroll
  for (int off = 32; off > 0; off >>= 1) v += __shfl_down(v, off, 64);
  return v;
}

template<int NW>
__device__ __forceinline__ float blockReduceSum(float v, float* sh) {
  v = waveReduceSum(v);
  int lane = threadIdx.x & 63, wid = threadIdx.x >> 6;
  if (lane == 0) sh[wid] = v;
  __syncthreads();
  float s = 0.f;
#pragma unroll
  for (int i = 0; i < NW; i++) s += sh[i];
  __syncthreads();
  return s;
}

// ---------------- merged weight cast f32 -> bf16 ----------------
struct CastSeg { const float* src; bf16* dst; int nval; int ntot; int blk0; };
struct CastArgs { CastSeg seg[8]; };

__global__ __launch_bounds__(256) void castw_all(CastArgs a) {
  int blk = blockIdx.x;
  int si = 0;
#pragma unroll
  for (int i = 1; i < 8; i++) if (blk >= a.seg[i].blk0) si = i;
  CastSeg s = a.seg[si];
  int i = ((blk - s.blk0) * 256 + threadIdx.x) * 4;
  if (i >= s.ntot) return;
  float4 v = {0.f, 0.f, 0.f, 0.f};
  if (i < s.nval) v = *(const float4*)(s.src + i);
  bf16x4 o;
  o[0] = (bf16)v.x; o[1] = (bf16)v.y; o[2] = (bf16)v.z; o[3] = (bf16)v.w;
  *(bf16x4*)(s.dst + i) = o;
}

// ---------------- rmsnorm (f32 in, bf16 out) ----------------
__global__ __launch_bounds__(256) void rmsnorm_k(const float* __restrict__ x,
                                                 const float* __restrict__ w,
                                                 bf16* __restrict__ y, int n) {
  __shared__ float sh[4];
  size_t row = blockIdx.x;
  const float* xr = x + row * n;
  bf16* yr = y + row * n;
  float ss = 0.f;
  for (int i = threadIdx.x; i < n; i += 256) { float v = xr[i]; ss += v * v; }
  ss = blockReduceSum<4>(ss, sh);
  float inv = rsqrtf(ss / n + 1e-5f);
  for (int i = threadIdx.x; i < n; i += 256) yr[i] = (bf16)(xr[i] * inv * w[i]);
}

// ---------------- generic bf16 MFMA GEMM: C = act(A @ W^T), 3-buf/1-barrier K-loop ----
// R6-verified schedule (measured 1.7x vs 2-barrier at 256^2): per K-step
// {stage t+1 -> buf nxt; vmcnt(4) (t landed, t+1 in flight); barrier; ds_read cur;
// setprio(1); 16 MFMA; setprio(0)}. 3 bufs make the WAR rotation race-free.
// Staging layout / fragment addressing / accumulation order identical to baseline.
// LDS 48 KB -> 3 blocks/CU.
template<int ACT, typename OT>
__global__ __launch_bounds__(256) void gemm_mfma(const bf16* __restrict__ A,
                                                 const bf16* __restrict__ W,
                                                 const float* __restrict__ R,
                                                 OT* __restrict__ C,
                                                 int M, int N, int K) {
  __shared__ bf16 lds[3 * 8192];
  int tid = threadIdx.x, lane = tid & 63, wave = tid >> 6;
  int mt = M >> 7;
  int bid = blockIdx.x;
  int bm = (bid % mt) * 128, bn = (bid / mt) * 128;
  const bf16* gA0 = A + (size_t)(bm + wave * 32 + (lane >> 2)) * K + (lane & 3) * 8;
  const bf16* gA1 = gA0 + (size_t)16 * K;
  const bf16* gW0 = W + (size_t)(bn + wave * 32 + (lane >> 2)) * K + (lane & 3) * 8;
  const bf16* gW1 = gW0 + (size_t)16 * K;
  int sA = wave * 1024;                    // wave's stage region within As (elems)
  int fr = lane & 15, fq = lane >> 4;
  int wm = wave >> 1, wn = wave & 1;
  int rdA = (wm * 64 + fr) * 32 + fq * 8;
  int rdW = (wn * 64 + fr) * 32 + fq * 8;
  f32x4 acc[4][4] = {};
  {
    bf16* bA = lds + sA;
    bf16* bW = lds + 4096 + sA;
    async_copy16(gA0, bA);  async_copy16(gA1, bA + 512);
    async_copy16(gW0, bW);  async_copy16(gW1, bW + 512);
  }
  int cur = 0, nxt = 1;
  int nsteps = K >> 5;
  for (int t = 0; t < nsteps; t++) {
    if (t + 1 < nsteps) {
      int off = (t + 1) * 32;
      bf16* bA = lds + nxt * 8192 + sA;
      bf16* bW = lds + nxt * 8192 + 4096 + sA;
      async_copy16(gA0 + off, bA);  async_copy16(gA1 + off, bA + 512);
      async_copy16(gW0 + off, bW);  async_copy16(gW1 + off, bW + 512);
      asm volatile("s_waitcnt vmcnt(4)" ::: "memory");
    } else {
      asm volatile("s_waitcnt vmcnt(0)" ::: "memory");
    }
    __builtin_amdgcn_sched_barrier(0);
    __builtin_amdgcn_s_barrier();
    __builtin_amdgcn_sched_barrier(0);
    const bf16* cA = lds + cur * 8192;
    const bf16* cW = cA + 4096;
    bf16x8 af[4], bfr[4];
#pragma unroll
    for (int mi = 0; mi < 4; mi++) af[mi] = *(const bf16x8*)(cA + rdA + mi * 512);
#pragma unroll
    for (int ni = 0; ni < 4; ni++) bfr[ni] = *(const bf16x8*)(cW + rdW + ni * 512);
    __builtin_amdgcn_s_setprio(1);
#pragma unroll
    for (int mi = 0; mi < 4; mi++)
#pragma unroll
      for (int ni = 0; ni < 4; ni++)
        acc[mi][ni] = __builtin_amdgcn_mfma_f32_16x16x32_bf16(af[mi], bfr[ni], acc[mi][ni], 0, 0, 0);
    __builtin_amdgcn_s_setprio(0);
    cur = nxt; nxt = nxt + 1; if (nxt == 3) nxt = 0;
  }
#pragma unroll
  for (int mi = 0; mi < 4; mi++) {
    int row = bm + wm * 64 + mi * 16 + fq * 4;
#pragma unroll
    for (int ni = 0; ni < 4; ni++) {
      int col = bn + wn * 64 + ni * 16 + fr;
      if (col < N) {
#pragma unroll
        for (int r = 0; r < 4; r++) {
          float v = acc[mi][ni][r];
          if (ACT == 1) v = v / (1.f + __expf(-v));
          if (R) v += R[(size_t)(row + r) * N + col];
          C[(size_t)(row + r) * N + col] = (OT)v;
        }
      }
    }
  }
}

// ---------------- split-K bf16 MFMA GEMM: P[ks] = A @ W^T, 3-buf/1-barrier K-loop ----
__global__ __launch_bounds__(256) void gemm_sk(const bf16* __restrict__ A,
                                               const bf16* __restrict__ W,
                                               bf16* __restrict__ P,
                                               int M, int N, int K, int kchunk) {
  __shared__ bf16 lds[3 * 8192];
  int tid = threadIdx.x, lane = tid & 63, wave = tid >> 6;
  int mt = M >> 7;
  int bid = blockIdx.x;
  int bm = (bid % mt) * 128, bn = (bid / mt) * 128;
  int ks = blockIdx.z;
  int kbeg = ks * kchunk;
  const bf16* gA0 = A + (size_t)(bm + wave * 32 + (lane >> 2)) * K + kbeg + (lane & 3) * 8;
  const bf16* gA1 = gA0 + (size_t)16 * K;
  const bf16* gW0 = W + (size_t)(bn + wave * 32 + (lane >> 2)) * K + kbeg + (lane & 3) * 8;
  const bf16* gW1 = gW0 + (size_t)16 * K;
  int sA = wave * 1024;
  int fr = lane & 15, fq = lane >> 4;
  int wm = wave >> 1, wn = wave & 1;
  int rdA = (wm * 64 + fr) * 32 + fq * 8;
  int rdW = (wn * 64 + fr) * 32 + fq * 8;
  f32x4 acc[4][4] = {};
  {
    bf16* bA = lds + sA;
    bf16* bW = lds + 4096 + sA;
    async_copy16(gA0, bA);  async_copy16(gA1, bA + 512);
    async_copy16(gW0, bW);  async_copy16(gW1, bW + 512);
  }
  int cur = 0, nxt = 1;
  int nsteps = kchunk >> 5;
  for (int t = 0; t < nsteps; t++) {
    if (t + 1 < nsteps) {
      int off = (t + 1) * 32;
      bf16* bA = lds + nxt * 8192 + sA;
      bf16* bW = lds + nxt * 8192 + 4096 + sA;
      async_copy16(gA0 + off, bA);  async_copy16(gA1 + off, bA + 512);
      async_copy16(gW0 + off, bW);  async_copy16(gW1 + off, bW + 512);
      asm volatile("s_waitcnt vmcnt(4)" ::: "memory");
    } else {
      asm volatile("s_waitcnt vmcnt(0)" ::: "memory");
    }
    __builtin_amdgcn_sched_barrier(0);
    __builtin_amdgcn_s_barrier();
    __builtin_amdgcn_sched_barrier(0);
    const bf16* cA = lds + cur * 8192;
    const bf16* cW = cA + 4096;
    bf16x8 af[4], bfr[4];
#pragma unroll
    for (int mi = 0; mi < 4; mi++) af[mi] = *(const bf16x8*)(cA + rdA + mi * 512);
#pragma unroll
    for (int ni = 0; ni < 4; ni++) bfr[ni] = *(const bf16x8*)(cW + rdW + ni * 512);
    __builtin_amdgcn_s_setprio(1);
#pragma unroll
    for (int mi = 0; mi < 4; mi++)
#pragma unroll
      for (int ni = 0; ni < 4; ni++)
        acc[mi][ni] = __builtin_amdgcn_mfma_f32_16x16x32_bf16(af[mi], bfr[ni], acc[mi][ni], 0, 0, 0);
    __builtin_amdgcn_s_setprio(0);
    cur = nxt; nxt = nxt + 1; if (nxt == 3) nxt = 0;
  }
  bf16* Pp = P + (size_t)ks * M * N;
#pragma unroll
  for (int mi = 0; mi < 4; mi++) {
    int row = bm + wm * 64 + mi * 16 + fq * 4;
#pragma unroll
    for (int ni = 0; ni < 4; ni++) {
      int col = bn + wn * 64 + ni * 16 + fr;
#pragma unroll
      for (int r = 0; r < 4; r++)
        Pp[(size_t)(row + r) * N + col] = (bf16)acc[mi][ni][r];
    }
  }
}

// ---------------- reduce 2 bf16 partials + residual + layernorm -> x_out f32, h bf16 ----------------
__global__ __launch_bounds__(256) void reduce_ln2(const bf16* __restrict__ p0,
                                                  const bf16* __restrict__ p1,
                                                  const float* __restrict__ res,
                                                  const float* __restrict__ w,
                                                  const float* __restrict__ b,
                                                  float* __restrict__ xo,
                                                  bf16* __restrict__ ho) {
  __shared__ float sh[4];
  size_t o = (size_t)blockIdx.x * 1024;
  int i = threadIdx.x * 4;
  bf16x4 a = *(const bf16x4*)(p0 + o + i);
  bf16x4 c = *(const bf16x4*)(p1 + o + i);
  f32x4 rv = *(const f32x4*)(res + o + i);
  f32x4 v;
  float s = 0.f, s2 = 0.f;
#pragma unroll
  for (int j = 0; j < 4; j++) {
    v[j] = (float)a[j] + (float)c[j] + rv[j];
    s += v[j]; s2 += v[j] * v[j];
  }
  s  = blockReduceSum<4>(s,  sh);
  s2 = blockReduceSum<4>(s2, sh);
  float mean = s / 1024.f;
  float var  = s2 / 1024.f - mean * mean;
  float inv  = rsqrtf(var + 1e-5f);
  f32x4 wv = *(const f32x4*)(w + i);
  f32x4 bv = *(const f32x4*)(b + i);
  *(f32x4*)(xo + o + i) = v;
  bf16x4 hv;
#pragma unroll
  for (int j = 0; j < 4; j++) hv[j] = (bf16)((v[j] - mean) * inv * wv[j] + bv[j]);
  *(bf16x4*)(ho + o + i) = hv;
}

// ---------------- reduce 3 bf16 partials + residual -> out f32 ----------------
__global__ __launch_bounds__(256) void reduce_out3(const bf16* __restrict__ p0,
                                                   const bf16* __restrict__ p1,
                                                   const bf16* __restrict__ p2,
                                                   const float* __restrict__ res,
                                                   float* __restrict__ out) {
  int i = (blockIdx.x * 256 + threadIdx.x) * 4;
  bf16x4 a = *(const bf16x4*)(p0 + i);
  bf16x4 c = *(const bf16x4*)(p1 + i);
  bf16x4 d = *(const bf16x4*)(p2 + i);
  f32x4 v = *(const f32x4*)(res + i);
#pragma unroll
  for (int j = 0; j < 4; j++) v[j] += (float)a[j] + (float)c[j] + (float)d[j];
  *(f32x4*)(out + i) = v;
}

// ---------------- reduce qkv bf16 partials + q/k rmsnorm + rope + gain -> bf16 ----------------
__global__ __launch_bounds__(256) void reduce_qkv(const bf16* __restrict__ P,
                                                  const float* __restrict__ q_gain,
                                                  bf16* __restrict__ q,
                                                  bf16* __restrict__ k,
                                                  bf16* __restrict__ v) {
  __shared__ float buf[1536];
  size_t row = blockIdx.x;
  size_t o = row * 1536;
  const bf16* p0 = P + o;
  const bf16* p1 = P + (size_t)ROWS * 1536 + o;
  int tid = threadIdx.x;
  for (int i = tid; i < 384; i += 256) {
    bf16x4 a = *(const bf16x4*)(p0 + i * 4);
    bf16x4 c = *(const bf16x4*)(p1 + i * 4);
    f32x4 vv;
#pragma unroll
    for (int j = 0; j < 4; j++) vv[j] = (float)a[j] + (float)c[j];
    *(f32x4*)(buf + i * 4) = vv;
  }
  __syncthreads();
  int lane = tid & 63, w = tid >> 6;
  int s = (int)(row & (S_ - 1));
  int ri = lane & 7;
  float rinv = __expf(-(float)ri * (0.125f * 9.210340371976184f)); // 10000^(-i/8)
  float ang = (float)s * rinv;
  float cs = cosf(ang), sn = sinf(ang);
#pragma unroll
  for (int j = 0; j < 6; j++) {
    int hh = w * 6 + j;
    float val = buf[hh * 64 + lane];
    if (hh < 20) {
      float ss = val * val;
#pragma unroll
      for (int off = 32; off > 0; off >>= 1) ss += __shfl_xor(ss, off, 64);
      val *= rsqrtf(ss / 64.f + 1.1920929e-7f);
      float other = __shfl_xor(val, 8, 64);
      float res = val;
      if (lane < RD) res = (lane < 8) ? (val * cs + other * sn) : (val * cs - other * sn);
      if (hh < 16) {
        res *= q_gain[hh];
        q[row * (HATT * HD) + hh * HD + lane] = (bf16)res;
      } else {
        k[row * (KVH * HD) + (hh - 16) * HD + lane] = (bf16)res;
      }
    } else {
      v[row * (KVH * HD) + (hh - 20) * HD + lane] = (bf16)val;
    }
  }
}

// ---------------- in_proj GEMM: R3-verified 3-buf single-barrier core + R5-verified grid ----
// Heavy (bid<256): 256x256 tile, 96KB 3-buf LDS rotation, per K-step {stage t+1 -> buf nxt;
// vmcnt(4) (t landed, t+1 in flight); barrier; 12 swizzled ds_read_b128; setprio(1);
// 32 MFMA; setprio(0)}. ONE barrier per step (R6: 50.5us vs 56.6 for 2-barrier).
// Grid 256 heavy = exactly one dispatch round at 1 block/CU; 96 light 128^2 tail (bcdt).
__global__ __launch_bounds__(512, 2) void gemm256_inproj(const bf16* __restrict__ A,
                                                         const bf16* __restrict__ W,
                                                         bf16* __restrict__ zt,
                                                         bf16* __restrict__ xt,
                                                         bf16* __restrict__ bcdt) {
  __shared__ bf16 lds[3 * 16384];          // 96 KB
  int tid = threadIdx.x;
  int lane = tid & 63, w = tid >> 6;       // 8 waves
  int fr = lane & 15, fq = lane >> 4;
  int rdswz = (fq ^ (fr & 3)) * 8;         // swizzled read offset
  int sswz = (lane & 3) ^ ((lane >> 2) & 3);   // inverse swizzle on global source
  int bid = blockIdx.x;
  if (bid < 256) {
    int sb = (bid & 7) * 32 + (bid >> 3);  // XCD swizzle (256 = 8*32, bijective)
    int bm = (sb & 15) * 256;              // 16 M tiles fastest (share W panel)
    int bn = (sb >> 4) * 256;              // 16 N tiles -> cols 0..4095 (z/x only)
    int wm = w >> 2, wn = w & 3;           // 2M x 4N waves: per wave 128x64
    int srow = w * 32 + (lane >> 2);
    const bf16* gA = A + (size_t)(bm + srow) * 1024 + sswz * 8;
    const bf16* gW = W + (size_t)(bn + srow) * 1024 + sswz * 8;
    int sbase = w * 1024;                  // wave's 32-row stage region (elements)
    f32x4 acc[8][4] = {};
    // prologue: stage tile 0 -> buf 0
    {
      bf16* bA = lds + sbase;
      bf16* bB = lds + 8192 + sbase;
      async_copy16(gA, bA);
      async_copy16(gA + 16 * 1024, bA + 512);
      async_copy16(gW, bB);
      async_copy16(gW + 16 * 1024, bB + 512);
    }
    int cur = 0, nxt = 1;
    for (int t = 0; t < 32; t++) {
      if (t + 1 < 32) {
        const bf16* ga = gA + (t + 1) * 32;
        const bf16* gw = gW + (t + 1) * 32;
        bf16* bA = lds + nxt * 16384 + sbase;
        bf16* bB = lds + nxt * 16384 + 8192 + sbase;
        async_copy16(ga, bA);
        async_copy16(ga + 16 * 1024, bA + 512);
        async_copy16(gw, bB);
        async_copy16(gw + 16 * 1024, bB + 512);
        asm volatile("s_waitcnt vmcnt(4)" ::: "memory");   // tile t done; t+1 flies
      } else {
        asm volatile("s_waitcnt vmcnt(0)" ::: "memory");
      }
      __builtin_amdgcn_sched_barrier(0);
      __builtin_amdgcn_s_barrier();
      __builtin_amdgcn_sched_barrier(0);
      const bf16* cA = lds + cur * 16384;
      const bf16* cB = cA + 8192;
      bf16x8 af[8], bfv[4];
#pragma unroll
      for (int mi = 0; mi < 8; mi++)
        af[mi] = *(const bf16x8*)(cA + (wm * 128 + mi * 16 + fr) * 32 + rdswz);
#pragma unroll
      for (int ni = 0; ni < 4; ni++)
        bfv[ni] = *(const bf16x8*)(cB + (wn * 64 + ni * 16 + fr) * 32 + rdswz);
      __builtin_amdgcn_s_setprio(1);
#pragma unroll
      for (int mi = 0; mi < 8; mi++)
#pragma unroll
        for (int ni = 0; ni < 4; ni++)
          acc[mi][ni] = __builtin_amdgcn_mfma_f32_16x16x32_bf16(af[mi], bfv[ni], acc[mi][ni], 0, 0, 0);
      __builtin_amdgcn_s_setprio(0);
      cur = nxt; nxt = nxt + 1; if (nxt == 3) nxt = 0;
    }
    // epilogue: LDS-transposed coalesced Zt/Xt stores (R3-verified path)
    bf16* base = (bn < 2048) ? zt : xt;
    int bq = bm >> 11, bmS = bm & 2047;
    bf16* Ts = lds;                        // 64 x 264 bf16 scratch (33.8 KB)
#pragma unroll 1
    for (int g = 0; g < 4; g++) {
      __syncthreads();
      if (wn == g) {
#pragma unroll
        for (int mi = 0; mi < 8; mi++)
#pragma unroll
          for (int ni = 0; ni < 4; ni++) {
            bf16x4 o;
#pragma unroll
            for (int r = 0; r < 4; r++) o[r] = (bf16)acc[mi][ni][r];
            *(bf16x4*)(Ts + (ni * 16 + fr) * 264 + wm * 128 + mi * 16 + fq * 4) = o;
          }
      }
      __syncthreads();
      int hh = ((bn & 2047) + g * 64) >> 6;
      bf16* dst = base + ((size_t)(bq * NH + hh) * HD) * S_ + bmS;
#pragma unroll
      for (int i = 0; i < 4; i++) {
        int idx = tid + i * 512;
        int p = idx >> 5, sc = (idx & 31) * 8;
        *(bf16x8*)(dst + (size_t)p * S_ + sc) = *(const bf16x8*)(Ts + p * 264 + sc);
      }
    }
  } else {
    // ---- light path: 128x128 tile over bcdt columns 4096..4383 (3rd tile masked) ----
    int lb = bid - 256;
    int bm = (lb & 31) * 128;
    int bn = 4096 + (lb >> 5) * 128;
    int wm = w >> 1, wn = w & 1;           // 4M x 2N waves: per wave 32x64
    int srow = w * 16 + (lane >> 2);
    const bf16* gA = A + (size_t)(bm + srow) * 1024 + sswz * 8;
    const bf16* gW = W + (size_t)(bn + srow) * 1024 + sswz * 8;
    int sbase = w * 512;                   // wave's 16-row stage region (elems)
    f32x4 acc[2][4] = {};
    {
      async_copy16(gA, lds + sbase);
      async_copy16(gW, lds + 4096 + sbase);
    }
    int cur = 0, nxt = 1;
    for (int t = 0; t < 32; t++) {
      if (t + 1 < 32) {
        const bf16* ga = gA + (t + 1) * 32;
        const bf16* gw = gW + (t + 1) * 32;
        async_copy16(ga, lds + nxt * 8192 + sbase);
        async_copy16(gw, lds + nxt * 8192 + 4096 + sbase);
        asm volatile("s_waitcnt vmcnt(2)" ::: "memory");
      } else {
        asm volatile("s_waitcnt vmcnt(0)" ::: "memory");
      }
      __builtin_amdgcn_sched_barrier(0);
      __builtin_amdgcn_s_barrier();
      __builtin_amdgcn_sched_barrier(0);
      const bf16* cA = lds + cur * 8192;
      const bf16* cB = cA + 4096;
      bf16x8 af[2], bfv[4];
#pragma unroll
      for (int mi = 0; mi < 2; mi++)
        af[mi] = *(const bf16x8*)(cA + (wm * 32 + mi * 16 + fr) * 32 + rdswz);
#pragma unroll
      for (int ni = 0; ni < 4; ni++)
        bfv[ni] = *(const bf16x8*)(cB + (wn * 64 + ni * 16 + fr) * 32 + rdswz);
#pragma unroll
      for (int mi = 0; mi < 2; mi++)
#pragma unroll
        for (int ni = 0; ni < 4; ni++)
          acc[mi][ni] = __builtin_amdgcn_mfma_f32_16x16x32_bf16(af[mi], bfv[ni], acc[mi][ni], 0, 0, 0);
      cur = nxt; nxt = nxt + 1; if (nxt == 3) nxt = 0;
    }
#pragma unroll
    for (int mi = 0; mi < 2; mi++) {
      int row = bm + wm * 32 + mi * 16 + fq * 4;
#pragma unroll
      for (int ni = 0; ni < 4; ni++) {
        int col = bn + wn * 64 + ni * 16 + fr;
        if (col < 4384) {
#pragma unroll
          for (int r = 0; r < 4; r++)
            bcdt[(size_t)(row + r) * 288 + (col - 4096)] = (bf16)acc[mi][ni][r];
        }
      }
    }
  }
}

// ---------------- generic 64x64 tiled transpose (bf16), out row stride 2048 ----------------
__global__ __launch_bounds__(256) void t64(const bf16* __restrict__ in, bf16* __restrict__ out,
                                           int istr, size_t io, size_t oo, int n_nt) {
  __shared__ bf16 T[64 * 72];
  int bid = blockIdx.x;
  int st = bid & 31;
  int nt = (bid >> 5) % n_nt;
  int outer = bid / (32 * n_nt);
  const bf16* ip = in + outer * io + (size_t)st * 64 * istr + nt * 64;
  int tid = threadIdx.x;
#pragma unroll
  for (int i = 0; i < 2; i++) {
    int cid = tid + i * 256; int s = cid >> 3, pc = (cid & 7) * 8;
    *(bf16x8*)(T + s * 72 + pc) = *(const bf16x8*)(ip + (size_t)s * istr + pc);
  }
  __syncthreads();
  bf16* op = out + outer * oo + (size_t)nt * 64 * 2048 + st * 64;
#pragma unroll
  for (int i = 0; i < 2; i++) {
    int cid = tid + i * 256; int p = cid >> 3, sc = (cid & 7) * 8;
    bf16x8 o;
#pragma unroll
    for (int j = 0; j < 8; j++) o[j] = T[(sc + j) * 72 + p];
    *(bf16x8*)(op + (size_t)p * 2048 + sc) = o;
  }
}

// ---------------- SSD prep: dt softplus, per-chunk cumsum, decay factors ----------------
__global__ __launch_bounds__(64) void ssd_prep(const bf16* __restrict__ bcdt,
                                               const float* __restrict__ dt_bias,
                                               const float* __restrict__ A_log,
                                               float* __restrict__ dt_c,
                                               float* __restrict__ ddc,
                                               float* __restrict__ ac_c,
                                               float* __restrict__ T_out) {
  int bid = blockIdx.x;
  int c = bid % NC, hh = (bid / NC) % NH, b = bid / (NC * NH);
  int l = threadIdx.x;
  size_t row = (size_t)b * S_ + c * 64 + l;
  float raw = (float)bcdt[row * 288 + 256 + hh] + dt_bias[hh];
  float dtv = (raw > 20.f) ? raw : log1pf(__expf(raw));
  float a = -__expf(A_log[hh]) * dtv;
  float ps = a;
#pragma unroll
  for (int off = 1; off < 64; off <<= 1) {
    float t = __shfl_up(ps, off, 64);
    if (l >= off) ps += t;
  }
  float a63 = __shfl(ps, 63, 64);
  size_t o = ((size_t)b * NH + hh) * S_ + c * 64 + l;
  dt_c[o] = dtv;
  ac_c[o] = ps;
  ddc[o] = __expf(a63 - ps) * dtv;
  if (l == 63) T_out[(b * NH + hh) * NC + c] = ps;
}

// ---------------- B/C rmsnorm (bf16 out) ----------------
__global__ __launch_bounds__(128) void bc_norm(const bf16* __restrict__ bcdt,
                                               const float* __restrict__ Bw,
                                               const float* __restrict__ Cw,
                                               bf16* __restrict__ Bn,
                                               bf16* __restrict__ Cn) {
  __shared__ float shb[2], shc[2];
  size_t row = blockIdx.x;
  int i = threadIdx.x;
  float bv = (float)bcdt[row * 288 + i];
  float cv = (float)bcdt[row * 288 + 128 + i];
  float sb = waveReduceSum(bv * bv);
  float sc = waveReduceSum(cv * cv);
  int lane = threadIdx.x & 63, wid = threadIdx.x >> 6;
  if (lane == 0) { shb[wid] = sb; shc[wid] = sc; }
  __syncthreads();
  float tb = shb[0] + shb[1];
  float tc = shc[0] + shc[1];
  Bn[row * DS + i] = (bf16)(bv * rsqrtf(tb / DS + 1e-5f) * Bw[i]);
  Cn[row * DS + i] = (bf16)(cv * rsqrtf(tc / DS + 1e-5f) * Cw[i]);
}

// ---------------- chunk states via MFMA (bf16 output) ----------------
__global__ __launch_bounds__(256) void ssd_states(const bf16* __restrict__ Xt,
                                                  const bf16* __restrict__ Btr,
                                                  const float* __restrict__ ddc,
                                                  bf16* __restrict__ states) {
  __shared__ bf16 Xs[64 * 72];    // [p][s]
  __shared__ bf16 Bs[128 * 72];   // [n][s]
  int bid = blockIdx.x;           // (b*NC + c)*NH + h
  int h = bid % NH;
  int c = (bid / NH) % NC;
  int b = bid / (NH * NC);
  int tid = threadIdx.x, lane = tid & 63, w = tid >> 6;
  int fr = lane & 15, fq = lane >> 4;
  const size_t xbase = (size_t)(b * NH + h) * HD * S_ + c * 64;
  const size_t dbase = (size_t)(b * NH + h) * S_ + c * 64;
#pragma unroll
  for (int i = 0; i < 2; i++) {
    int cid = tid + i * 256; int p = cid >> 3, sc = (cid & 7) * 8;
    bf16x8 xv = *(const bf16x8*)(Xt + xbase + (size_t)p * S_ + sc);
    f32x4 d0 = *(const f32x4*)(ddc + dbase + sc);
    f32x4 d1 = *(const f32x4*)(ddc + dbase + sc + 4);
    bf16x8 o;
#pragma unroll
    for (int j = 0; j < 4; j++) { o[j] = (bf16)((float)xv[j] * d0[j]); o[4 + j] = (bf16)((float)xv[4 + j] * d1[j]); }
    *(bf16x8*)(Xs + p * 72 + sc) = o;
  }
  const size_t bbase = (size_t)b * 128 * S_ + c * 64;
#pragma unroll
  for (int i = 0; i < 4; i++) {
    int cid = tid + i * 256; int n = cid >> 3, sc = (cid & 7) * 8;
    *(bf16x8*)(Bs + n * 72 + sc) = *(const bf16x8*)(Btr + bbase + (size_t)n * S_ + sc);
  }
  __syncthreads();
  f32x4 acc[4][2] = {};
#pragma unroll
  for (int ks = 0; ks < 2; ks++) {
    bf16x8 a[4], bb[2];
#pragma unroll
    for (int pt = 0; pt < 4; pt++) a[pt] = *(const bf16x8*)(Xs + (pt * 16 + fr) * 72 + ks * 32 + fq * 8);
#pragma unroll
    for (int n2 = 0; n2 < 2; n2++) bb[n2] = *(const bf16x8*)(Bs + ((2 * w + n2) * 16 + fr) * 72 + ks * 32 + fq * 8);
#pragma unroll
    for (int pt = 0; pt < 4; pt++)
#pragma unroll
      for (int n2 = 0; n2 < 2; n2++)
        acc[pt][n2] = __builtin_amdgcn_mfma_f32_16x16x32_bf16(a[pt], bb[n2], acc[pt][n2], 0, 0, 0);
  }
  bf16* outp = states + (size_t)bid * 8192;
#pragma unroll
  for (int pt = 0; pt < 4; pt++)
#pragma unroll
    for (int n2 = 0; n2 < 2; n2++) {
      int n = (2 * w + n2) * 16 + fr;
#pragma unroll
      for (int r = 0; r < 4; r++)
        outp[(size_t)(pt * 16 + fq * 4 + r) * 128 + n] = (bf16)acc[pt][n2][r];
    }
}

// ---------------- inter-chunk scan (in place, bf16 storage, f32 math) ----------------
__global__ __launch_bounds__(256) void ssd_scan(bf16* __restrict__ states,
                                                const float* __restrict__ T) {
  __shared__ float eT[NC];
  int part = blockIdx.x & 7;
  int bh = blockIdx.x >> 3;
  int b = bh / NH, h = bh % NH;
  if (threadIdx.x < NC) eT[threadIdx.x] = __expf(T[(size_t)(b * NH + h) * NC + threadIdx.x]);
  __syncthreads();
  const size_t cstride = (size_t)NH * HD * DS;
  size_t base = ((size_t)b * NC * NH + h) * (HD * DS);
#pragma unroll
  for (int j = 0; j < 4; j++) {
    int e = part * 1024 + threadIdx.x + j * 256;
    float carry = 0.f;
    size_t idx = base + e;
    for (int c = 0; c < NC; c++) {
      float sv = (float)states[idx];
      states[idx] = (bf16)carry;
      carry = sv + eT[c] * carry;
      idx += cstride;
    }
  }
}

// ---------------- fused SSD output: Ydiag + Yoff + D-skip + gate (all MFMA) ----------------
__global__ __launch_bounds__(256) void ssd_out(const bf16* __restrict__ Cn,
                                               const bf16* __restrict__ Bn,
                                               const bf16* __restrict__ Xt,
                                               const bf16* __restrict__ Zt,
                                               const float* __restrict__ dt_c,
                                               const float* __restrict__ ac_c,
                                               const bf16* __restrict__ states,
                                               const float* __restrict__ Dp,
                                               bf16* __restrict__ ybf) {
  __shared__ bf16 Cs[64 * 136];
  __shared__ bf16 BNs[64 * 136];
  __shared__ bf16 Xs[64 * 72];
  __shared__ bf16 G[64 * 72];
  __shared__ float acs[64];
  int bid = blockIdx.x;
  int h = bid % NH;
  int c = (bid / NH) % NC;
  int b = bid / (NH * NC);
  int tid = threadIdx.x, lane = tid & 63, w = tid >> 6;
  int fr = lane & 15, fq = lane >> 4;
  size_t row0 = (size_t)b * S_ + c * 64;
  const size_t abase = (size_t)(b * NH + h) * S_ + c * 64;
  if (tid < 64) acs[tid] = ac_c[abase + tid];
#pragma unroll
  for (int i = 0; i < 4; i++) {
    int cid = tid + i * 256; int l = cid >> 4, nc = (cid & 15) * 8;
    float e = __expf(ac_c[abase + l]);
    bf16x8 cv = *(const bf16x8*)(Cn + (row0 + l) * DS + nc);
    bf16x8 o;
#pragma unroll
    for (int j = 0; j < 8; j++) o[j] = (bf16)((float)cv[j] * e);
    *(bf16x8*)(Cs + l * 136 + nc) = o;
    *(bf16x8*)(BNs + l * 136 + nc) = *(const bf16x8*)(Bn + (row0 + l) * DS + nc);
  }
  const size_t xbase = (size_t)(b * NH + h) * HD * S_ + c * 64;
#pragma unroll
  for (int i = 0; i < 2; i++) {
    int cid = tid + i * 256; int p = cid >> 3, sc = (cid & 7) * 8;
    bf16x8 xv = *(const bf16x8*)(Xt + xbase + (size_t)p * S_ + sc);
    f32x4 d0 = *(const f32x4*)(dt_c + abase + sc);
    f32x4 d1 = *(const f32x4*)(dt_c + abase + sc + 4);
    bf16x8 o;
#pragma unroll
    for (int j = 0; j < 4; j++) { o[j] = (bf16)((float)xv[j] * d0[j]); o[4 + j] = (bf16)((float)xv[4 + j] * d1[j]); }
    *(bf16x8*)(Xs + p * 72 + sc) = o;
  }
  __syncthreads();
  bf16x8 ca[4];
#pragma unroll
  for (int ks = 0; ks < 4; ks++) ca[ks] = *(const bf16x8*)(Cs + (w * 16 + fr) * 136 + ks * 32 + fq * 8);
  f32x4 cb[4] = {};
  for (int st = 0; st <= w; st++)
#pragma unroll
    for (int ks = 0; ks < 4; ks++)
      cb[st] = __builtin_amdgcn_mfma_f32_16x16x32_bf16(ca[ks],
                 *(const bf16x8*)(BNs + (st * 16 + fr) * 136 + ks * 32 + fq * 8), cb[st], 0, 0, 0);
#pragma unroll
  for (int st = 0; st < 4; st++) {
    float es = (st <= w) ? __expf(-acs[st * 16 + fr]) : 0.f;
#pragma unroll
    for (int r = 0; r < 4; r++) {
      int lloc = fq * 4 + r;
      float g = 0.f;
      if (st < w) g = cb[st][r] * es;
      else if (st == w) g = (lloc >= fr) ? cb[st][r] * es : 0.f;
      G[(w * 16 + lloc) * 72 + st * 16 + fr] = (bf16)g;
    }
  }
  f32x4 acc[4] = {};
  {
    bf16x8 ga0 = *(const bf16x8*)(G + (w * 16 + fr) * 72 + fq * 8);
    bf16x8 ga1 = *(const bf16x8*)(G + (w * 16 + fr) * 72 + 32 + fq * 8);
#pragma unroll
    for (int pt = 0; pt < 4; pt++) {
      acc[pt] = __builtin_amdgcn_mfma_f32_16x16x32_bf16(ga0,
                  *(const bf16x8*)(Xs + (pt * 16 + fr) * 72 + fq * 8), acc[pt], 0, 0, 0);
      acc[pt] = __builtin_amdgcn_mfma_f32_16x16x32_bf16(ga1,
                  *(const bf16x8*)(Xs + (pt * 16 + fr) * 72 + 32 + fq * 8), acc[pt], 0, 0, 0);
    }
  }
  __syncthreads();
  const bf16* stp = states + (size_t)bid * 8192;
#pragma unroll
  for (int i = 0; i < 4; i++) {
    int cid = tid + i * 256; int p = cid >> 4, nc = (cid & 15) * 8;
    *(bf16x8*)(BNs + p * 136 + nc) = *(const bf16x8*)(stp + (size_t)p * 128 + nc);
  }
  __syncthreads();
#pragma unroll
  for (int pt = 0; pt < 4; pt++)
#pragma unroll
    for (int ks = 0; ks < 4; ks++)
      acc[pt] = __builtin_amdgcn_mfma_f32_16x16x32_bf16(ca[ks],
                  *(const bf16x8*)(BNs + (pt * 16 + fr) * 136 + ks * 32 + fq * 8), acc[pt], 0, 0, 0);
  float dph = Dp[h];
#pragma unroll
  for (int pt = 0; pt < 4; pt++) {
    int p = pt * 16 + fr;
    size_t tb = (xbase + (size_t)p * S_) + w * 16 + fq * 4;
    bf16x4 xs4 = *(const bf16x4*)(Xt + tb);
    bf16x4 z4  = *(const bf16x4*)(Zt + tb);
#pragma unroll
    for (int r = 0; r < 4; r++) {
      int l = w * 16 + fq * 4 + r;
      float yv = acc[pt][r] + (float)xs4[r] * dph;
      float z = (float)z4[r];
      yv *= z / (1.f + __expf(-z));
      ybf[((row0 + l) * NH + h) * HD + p] = (bf16)yv;
    }
  }
}

// ---------------- split-S MFMA flash attention (fixed-max softmax -> partials sum) ----------------
// Single-buffered K/V (LDS 36.9 KB -> 4 blocks/CU); prefetch issued after the
// second barrier so loads overlap compute and drain at next iter's first barrier.
#define KSTR 72
#define PSTR 72
__global__ __launch_bounds__(256) void attn_mfma(const bf16* __restrict__ q,
                                                 const bf16* __restrict__ k,
                                                 const bf16* __restrict__ vtr,
                                                 bf16* __restrict__ Po,
                                                 float* __restrict__ Ls) {
  __shared__ bf16 Ks[64 * KSTR];
  __shared__ bf16 Vs[64 * KSTR];
  __shared__ bf16 Pl[4][32 * PSTR];
  int c = 39 - blockIdx.x;                 // full 8-iter chunks first
  int g = (c < 4) ? 0 : (c < 12) ? 1 : (c < 24) ? 2 : 3;
  int gbase = (g == 0) ? 0 : (g == 1) ? 4 : (g == 2) ? 12 : 24;
  int d = c - gbase;
  int qt = 4 * g + d / (g + 1);
  int sk = d % (g + 1);
  int h = blockIdx.y, b = blockIdx.z;
  int kvh = h >> 2;
  int tid = threadIdx.x, lane = tid & 63, w = tid >> 6;
  int fr = lane & 15, fq = lane >> 4;
  const float SC = 0.18033688011112042f;   // 0.125 * log2(e)
  const float M2 = 62.0f;
  int kt0 = sk * 8;
  int ktend = min(kt0 + 8, 2 * qt + 2);
  int qbase = qt * 128 + w * 32;           // wave's first q row
  int qmaxw = qbase + 31;
  bf16x8 bq[2][2];
#pragma unroll
  for (int qc = 0; qc < 2; qc++)
#pragma unroll
    for (int ks = 0; ks < 2; ks++)
      bq[qc][ks] = *(const bf16x8*)(q + (size_t)(b * S_ + qbase + qc * 16 + fr) * (HATT * HD)
                                      + h * HD + ks * 32 + fq * 8);
  int sr = tid >> 3, sc8 = (tid & 7) * 8;
  const bf16* kg = k + ((size_t)(b * S_) + sr) * (KVH * HD) + kvh * HD + sc8;
  const bf16* vg = vtr + ((size_t)(b * KVH + kvh) * HD + sr) * S_ + sc8;
  bf16x8 krg0, krg1, vrg0, vrg1;
  {
    const bf16* kp = kg + (size_t)kt0 * 64 * (KVH * HD);
    const bf16* vp = vg + (size_t)kt0 * 64;
    krg0 = *(const bf16x8*)(kp);
    krg1 = *(const bf16x8*)(kp + (size_t)32 * (KVH * HD));
    vrg0 = *(const bf16x8*)(vp);
    vrg1 = *(const bf16x8*)(vp + (size_t)32 * S_);
  }
  float lsum[2] = {0.f, 0.f};
  f32x4 yacc[2][4] = {};
  bf16* Plw = Pl[w];
  for (int kt = kt0; kt < ktend; kt++) {
    __syncthreads();   // previous iteration's LDS reads complete
    *(bf16x8*)(&Ks[sr * KSTR + sc8]) = krg0;
    *(bf16x8*)(&Ks[(sr + 32) * KSTR + sc8]) = krg1;
    *(bf16x8*)(&Vs[sr * KSTR + sc8]) = vrg0;
    *(bf16x8*)(&Vs[(sr + 32) * KSTR + sc8]) = vrg1;
    __syncthreads();   // tile visible
    // prefetch next tile AFTER the barrier: loads overlap compute below
    if ((kt + 1) < ktend) {
      const bf16* kp = kg + (size_t)(kt + 1) * 64 * (KVH * HD);
      const bf16* vp = vg + (size_t)(kt + 1) * 64;
      krg0 = *(const bf16x8*)(kp);
      krg1 = *(const bf16x8*)(kp + (size_t)32 * (KVH * HD));
      vrg0 = *(const bf16x8*)(vp);
      vrg1 = *(const bf16x8*)(vp + (size_t)32 * S_);
    }
    if (kt * 64 <= qmaxw) {
      bool nomask = (kt * 64 + 63) <= qbase;
      if (nomask) {
#pragma unroll
        for (int mi = 0; mi < 4; mi++) {
          const bf16* krow = &Ks[(mi * 16 + fr) * KSTR];
          bf16x8 ak0 = *(const bf16x8*)(krow + fq * 8);
          bf16x8 ak1 = *(const bf16x8*)(krow + 32 + fq * 8);
#pragma unroll
          for (int qc = 0; qc < 2; qc++) {
            f32x4 s = {};
            s = __builtin_amdgcn_mfma_f32_16x16x32_bf16(ak0, bq[qc][0], s, 0, 0, 0);
            s = __builtin_amdgcn_mfma_f32_16x16x32_bf16(ak1, bq[qc][1], s, 0, 0, 0);
            bf16x4 pk;
#pragma unroll
            for (int r = 0; r < 4; r++) {
              float p = __builtin_amdgcn_exp2f(s[r] * SC - M2);
              lsum[qc] += p;
              pk[r] = (bf16)p;
            }
            *(bf16x4*)(Plw + (qc * 16 + fr) * PSTR + mi * 16 + fq * 4) = pk;
          }
        }
      } else {
#pragma unroll
        for (int mi = 0; mi < 4; mi++) {
          int s0 = kt * 64 + mi * 16;
          if (s0 > qmaxw) {
            bf16x4 zz = {};
#pragma unroll
            for (int qc = 0; qc < 2; qc++)
              *(bf16x4*)(Plw + (qc * 16 + fr) * PSTR + mi * 16 + fq * 4) = zz;
          } else {
            const bf16* krow = &Ks[(mi * 16 + fr) * KSTR];
            bf16x8 ak0 = *(const bf16x8*)(krow + fq * 8);
            bf16x8 ak1 = *(const bf16x8*)(krow + 32 + fq * 8);
#pragma unroll
            for (int qc = 0; qc < 2; qc++) {
              f32x4 s = {};
              s = __builtin_amdgcn_mfma_f32_16x16x32_bf16(ak0, bq[qc][0], s, 0, 0, 0);
              s = __builtin_amdgcn_mfma_f32_16x16x32_bf16(ak1, bq[qc][1], s, 0, 0, 0);
              int qq = qbase + qc * 16 + fr;
              bf16x4 pk;
#pragma unroll
              for (int r = 0; r < 4; r++) {
                int sp = s0 + fq * 4 + r;
                float p = (sp <= qq) ? __builtin_amdgcn_exp2f(s[r] * SC - M2) : 0.f;
                lsum[qc] += p;
                pk[r] = (bf16)p;
              }
              *(bf16x4*)(Plw + (qc * 16 + fr) * PSTR + mi * 16 + fq * 4) = pk;
            }
          }
        }
      }
#pragma unroll
      for (int ks2 = 0; ks2 < 2; ks2++) {
        bf16x8 bp[2];
#pragma unroll
        for (int qc = 0; qc < 2; qc++)
          bp[qc] = *(const bf16x8*)(Plw + (qc * 16 + fr) * PSTR + ks2 * 32 + fq * 8);
#pragma unroll
        for (int pi = 0; pi < 4; pi++) {
          bf16x8 av = *(const bf16x8*)(&Vs[(pi * 16 + fr) * KSTR + ks2 * 32 + fq * 8]);
#pragma unroll
          for (int qc = 0; qc < 2; qc++)
            yacc[qc][pi] = __builtin_amdgcn_mfma_f32_16x16x32_bf16(av, bp[qc], yacc[qc][pi], 0, 0, 0);
        }
      }
    }
  }
#pragma unroll
  for (int qc = 0; qc < 2; qc++) {
    lsum[qc] += __shfl_xor(lsum[qc], 16, 64);
    lsum[qc] += __shfl_xor(lsum[qc], 32, 64);
    int qrow = qt * 128 + w * 32 + qc * 16 + fr;
    if (fq == 0)
      Ls[((size_t)(b * 16 + h) * 2048 + qrow) * 4 + sk] = lsum[qc];
    bf16* pop = Po + ((((size_t)(b * 16 + h) * 16 + qt) * 4 + sk) * 128
                       + w * 32 + qc * 16 + fr) * 64 + fq * 4;
#pragma unroll
    for (int pi = 0; pi < 4; pi++) {
      bf16x4 o;
#pragma unroll
      for (int r = 0; r < 4; r++) o[r] = (bf16)yacc[qc][pi][r];
      *(bf16x4*)(pop + pi * 16) = o;
    }
  }
}

// ---------------- attention partial combine + normalize -> y2 bf16 ----------------
__global__ __launch_bounds__(256) void attn_red(const bf16* __restrict__ Po,
                                                const float* __restrict__ Ls,
                                                bf16* __restrict__ y2) {
  int row = blockIdx.x;            // 0..4095
  int b = row >> 11;
  int qrow = row & 2047;
  int qt = qrow >> 7, r = qrow & 127;
  int nch = (qt >> 2) + 1;
  int t = threadIdx.x;
  int h = t >> 4, e4 = (t & 15) << 2;
  const float* lp = Ls + ((size_t)(b * 16 + h) * 2048 + qrow) * 4;
  float ls = 0.f;
  f32x4 acc = {};
  for (int sk = 0; sk < nch; sk++) {
    ls += lp[sk];
    const bf16* pp = Po + ((((size_t)(b * 16 + h) * 16 + qt) * 4 + sk) * 128 + r) * 64 + e4;
    bf16x4 v = *(const bf16x4*)(pp);
#pragma unroll
    for (int j = 0; j < 4; j++) acc[j] += (float)v[j];
  }
  float inv = 1.f / ls;
  bf16x4 o;
#pragma unroll
  for (int j = 0; j < 4; j++) o[j] = (bf16)(acc[j] * inv);
  *(bf16x4*)(y2 + (size_t)row * 1024 + h * 64 + e4) = o;
}

// ---------------- workspace layout (byte offsets) ----------------
constexpr size_t OFF_WIN  = 0;                   // bf16 4480x1024
constexpr size_t OFF_WOUT = 9175040;             // bf16 1024x2048
constexpr size_t OFF_WQKV = 13369344;            // bf16 1536x1024 (q|k|v rows)
constexpr size_t OFF_WCP  = 16515072;            // bf16 1024x1024
constexpr size_t OFF_WFC  = 18612224;            // bf16 3072x1024
constexpr size_t OFF_WPR  = 24903680;            // bf16 1024x3072
constexpr size_t OFF_HBF  = 31195136;            // bf16 4096x1024
constexpr size_t OFF_BCDT = 39583744;            // bf16 4096x288; reused: Ls f32 (1 MiB)
constexpr size_t OFF_XT   = 41943040;            // bf16 [b][h][p][sg] (16.7 MB)
constexpr size_t OFF_ZT   = 58720256;            // bf16 [b][h][p][sg] (16.7 MB)
constexpr size_t OFF_DTC  = 75497472;            // f32 [b][h][sg]
constexpr size_t OFF_DDC  = 76546048;            // f32
constexpr size_t OFF_ACC  = 77594624;            // f32
constexpr size_t OFF_T    = 78643200;            // f32 2048
constexpr size_t OFF_BN   = 78651392;            // bf16 4096x128
constexpr size_t OFF_CN   = 79699968;            // bf16 4096x128
constexpr size_t OFF_BTR  = 80748544;            // bf16 [b][n][sg]
constexpr size_t OFF_ST   = 81797120;            // bf16 states (33.5 MB); reused: Po bf16 32 MiB
constexpr size_t OFF_YBF  = 148905984;           // bf16 4096x2048
constexpr size_t OFF_X1   = 165683200;           // f32 4096x1024 (end 182,460,416)
// phase-2 aliases
constexpr size_t OFF_P    = OFF_ST;              // bf16 split-K partials (<= 25.2 MB)
constexpr size_t OFF_PO   = OFF_ST;              // bf16 attn partials [b][h][qt][4][128][64] = 32 MiB
constexpr size_t OFF_LS   = OFF_BCDT;            // f32 attn lsums [b][h][2048][4] = 1 MiB
constexpr size_t OFF_QB   = OFF_XT;              // bf16 4096x1024 (8.4 MB)
constexpr size_t OFF_KB   = OFF_XT + 8388608;    // bf16 4096x256
constexpr size_t OFF_VB   = OFF_XT + 10485760;   // bf16 4096x256
constexpr size_t OFF_VTR  = OFF_XT + 12582912;   // bf16 [b][kvh][p][sg]
constexpr size_t OFF_Y2   = OFF_ZT;              // bf16 4096x1024
constexpr size_t OFF_X2   = 50331648;            // f32 4096x1024 (over dead kb/vb/vtr/y2)
constexpr size_t OFF_MLP  = 132128768;           // bf16 4096x3072 (over dead regions)

extern "C" void kernel_launch(void* const* d_in, const int* in_sizes, int n_in,
                              void* d_out, int out_size, void* d_ws, size_t ws_size,
                              hipStream_t stream) {
  (void)in_sizes; (void)n_in; (void)out_size; (void)ws_size;
  const float* x        = (const float*)d_in[0];
  const float* mnorm_w  = (const float*)d_in[1];
  const float* in_w     = (const float*)d_in[2];
  const float* out_w    = (const float*)d_in[3];
  const float* Dp       = (const float*)d_in[4];
  const float* dt_bias  = (const float*)d_in[5];
  const float* A_log    = (const float*)d_in[6];
  const float* Bn_w     = (const float*)d_in[7];
  const float* Cn_w     = (const float*)d_in[8];
  const float* ln1_w    = (const float*)d_in[9];
  const float* ln1_b    = (const float*)d_in[10];
  const float* cq_w     = (const float*)d_in[11];
  const float* ck_w     = (const float*)d_in[12];
  const float* cv_w     = (const float*)d_in[13];
  const float* cproj_w  = (const float*)d_in[14];
  const float* q_gain   = (const float*)d_in[15];
  const float* ln2_w    = (const float*)d_in[16];
  const float* ln2_b    = (const float*)d_in[17];
  const float* fc_w     = (const float*)d_in[18];
  const float* proj_w   = (const float*)d_in[19];
  float* out = (float*)d_out;
  char* W8 = (char*)d_ws;

  bf16* w_in   = (bf16*)(W8 + OFF_WIN);
  bf16* w_out  = (bf16*)(W8 + OFF_WOUT);
  bf16* w_qkv  = (bf16*)(W8 + OFF_WQKV);
  bf16* w_cp   = (bf16*)(W8 + OFF_WCP);
  bf16* w_fc   = (bf16*)(W8 + OFF_WFC);
  bf16* w_pr   = (bf16*)(W8 + OFF_WPR);
  bf16* h_bf   = (bf16*)(W8 + OFF_HBF);
  bf16* bcdt   = (bf16*)(W8 + OFF_BCDT);
  bf16* Xt     = (bf16*)(W8 + OFF_XT);
  bf16* Zt     = (bf16*)(W8 + OFF_ZT);
  float* dt_c  = (float*)(W8 + OFF_DTC);
  float* ddc   = (float*)(W8 + OFF_DDC);
  float* ac_c  = (float*)(W8 + OFF_ACC);
  float* Tb    = (float*)(W8 + OFF_T);
  bf16* Bn     = (bf16*)(W8 + OFF_BN);
  bf16* Cn     = (bf16*)(W8 + OFF_CN);
  bf16* Btr    = (bf16*)(W8 + OFF_BTR);
  bf16* st     = (bf16*)(W8 + OFF_ST);
  bf16* ybf    = (bf16*)(W8 + OFF_YBF);
  float* x1    = (float*)(W8 + OFF_X1);
  bf16* Pbuf   = (bf16*)(W8 + OFF_P);
  bf16* Po     = (bf16*)(W8 + OFF_PO);
  float* Ls    = (float*)(W8 + OFF_LS);
  bf16* qbf    = (bf16*)(W8 + OFF_QB);
  bf16* kbf    = (bf16*)(W8 + OFF_KB);
  bf16* vbf    = (bf16*)(W8 + OFF_VB);
  bf16* vtr    = (bf16*)(W8 + OFF_VTR);
  bf16* y2     = (bf16*)(W8 + OFF_Y2);
  float* x2    = (float*)(W8 + OFF_X2);
  bf16* mlp    = (bf16*)(W8 + OFF_MLP);

  // ---- weight casts (single launch; q/k/v cast into adjacent rows of w_qkv) ----
  CastArgs ca;
  ca.seg[0] = { in_w,    w_in,            4489216, 4587520, 0     };
  ca.seg[1] = { out_w,   w_out,           2097152, 2097152, 4480  };
  ca.seg[2] = { cq_w,    w_qkv,           1048576, 1048576, 6528  };
  ca.seg[3] = { ck_w,    w_qkv + 1048576,  262144,  262144, 7552  };
  ca.seg[4] = { cv_w,    w_qkv + 1310720,  262144,  262144, 7808  };
  ca.seg[5] = { cproj_w, w_cp,            1048576, 1048576, 8064  };
  ca.seg[6] = { fc_w,    w_fc,            3145728, 3145728, 9088  };
  ca.seg[7] = { proj_w,  w_pr,            3145728, 3145728, 12160 };
  castw_all<<<15232, 256, 0, stream>>>(ca);

  const size_t PS  = (size_t)ROWS * 1024;   // partial stride (elements) for N=1024 GEMMs

  // ---- mamba block ----
  rmsnorm_k<<<ROWS, 256, 0, stream>>>(x, mnorm_w, h_bf, D_);
  gemm256_inproj<<<352, 512, 0, stream>>>(h_bf, w_in, Zt, Xt, bcdt);
  ssd_prep<<<B_ * NH * NC, 64, 0, stream>>>(bcdt, dt_bias, A_log, dt_c, ddc, ac_c, Tb);
  bc_norm<<<ROWS, 128, 0, stream>>>(bcdt, Bn_w, Cn_w, Bn, Cn);
  t64<<<2 * 2 * 32, 256, 0, stream>>>(Bn, Btr, 128, (size_t)2048 * 128, (size_t)128 * 2048, 2);
  ssd_states<<<B_ * NC * NH, 256, 0, stream>>>(Xt, Btr, ddc, st);
  ssd_scan<<<B_ * NH * 8, 256, 0, stream>>>(st, Tb);
  ssd_out<<<B_ * NC * NH, 256, 0, stream>>>(Cn, Bn, Xt, Zt, dt_c, ac_c, st, Dp, ybf);
  // out_proj: split-K=2 then fused reduce+residual+LN1
  gemm_sk<<<dim3(32 * 8, 1, 2), 256, 0, stream>>>(ybf, w_out, Pbuf, ROWS, D_, DI, 1024);
  reduce_ln2<<<ROWS, 256, 0, stream>>>(Pbuf, Pbuf + PS, x, ln1_w, ln1_b, x1, h_bf);

  // ---- attention block ----
  gemm_sk<<<dim3(32 * 12, 1, 2), 256, 0, stream>>>(h_bf, w_qkv, Pbuf, ROWS, 1536, D_, 512);
  reduce_qkv<<<ROWS, 256, 0, stream>>>(Pbuf, q_gain, qbf, kbf, vbf);
  t64<<<2 * 4 * 32, 256, 0, stream>>>(vbf, vtr, 256, (size_t)2048 * 256, (size_t)256 * 2048, 4);
  attn_mfma<<<dim3(40, HATT, B_), 256, 0, stream>>>(qbf, kbf, vtr, Po, Ls);
  attn_red<<<ROWS, 256, 0, stream>>>(Po, Ls, y2);
  gemm_sk<<<dim3(32 * 8, 1, 2), 256, 0, stream>>>(y2, w_cp, Pbuf, ROWS, D_, D_, 512);
  reduce_ln2<<<ROWS, 256, 0, stream>>>(Pbuf, Pbuf + PS, x1, ln2_w, ln2_b, x2, h_bf);

  // ---- MLP ----
  gemm_mfma<1, bf16><<<32 * 24, 256, 0, stream>>>(h_bf, w_fc, nullptr, mlp, ROWS, MLP, D_);
  gemm_sk<<<dim3(32 * 8, 1, 3), 256, 0, stream>>>(mlp, w_pr, Pbuf, ROWS, D_, MLP, 1024);
  reduce_out3<<<ROWS, 256, 0, stream>>>(Pbuf, Pbuf + PS, Pbuf + 2 * PS, x2, out);
}

// Round 8
// 497.631 us; speedup vs baseline: 1.4975x; 1.0033x over previous
//
#include <hip/hip_runtime.h>
#include <hip/hip_bf16.h>
#include <math.h>

// ---------------- problem constants ----------------
#define B_    2
#define S_    2048
#define D_    1024
#define DI    2048      // D_INNER
#define NH    32        // NHEADS (mamba)
#define HD    64        // HEADDIM
#define DS    128       // D_STATE
#define CH    64        // CHUNK
#define NC    32        // S_/CH
#define DP    4384      // D_PROJ
#define HATT  16        // attention heads
#define KVH   4         // kv heads
#define RD    16        // rope dims
#define MLP   3072
#define ROWS  (B_*S_)   // 4096

typedef __bf16 bf16;
typedef __bf16 bf16x8 __attribute__((ext_vector_type(8)));
typedef __bf16 bf16x4 __attribute__((ext_vector_type(4)));
typedef float  f32x4  __attribute__((ext_vector_type(4)));

__device__ __forceinline__ void async_copy16(const void* g, void* l) {
  __builtin_amdgcn_global_load_lds(
      (const __attribute__((address_space(1))) unsigned int*)g,
      (__attribute__((address_space(3))) unsigned int*)l, 16, 0, 0);
}

// ---------------- reductions ----------------
__device__ __forceinline__ float waveReduceSum(float v) {
#pragma unroll
  for (int off = 32; off > 0; off >>= 1) v += __shfl_down(v, off, 64);
  return v;
}

template<int NW>
__device__ __forceinline__ float blockReduceSum(float v, float* sh) {
  v = waveReduceSum(v);
  int lane = threadIdx.x & 63, wid = threadIdx.x >> 6;
  if (lane == 0) sh[wid] = v;
  __syncthreads();
  float s = 0.f;
#pragma unroll
  for (int i = 0; i < NW; i++) s += sh[i];
  __syncthreads();
  return s;
}

// ---------------- merged weight cast f32 -> bf16 ----------------
struct CastSeg { const float* src; bf16* dst; int nval; int ntot; int blk0; };
struct CastArgs { CastSeg seg[8]; };

__global__ __launch_bounds__(256) void castw_all(CastArgs a) {
  int blk = blockIdx.x;
  int si = 0;
#pragma unroll
  for (int i = 1; i < 8; i++) if (blk >= a.seg[i].blk0) si = i;
  CastSeg s = a.seg[si];
  int i = ((blk - s.blk0) * 256 + threadIdx.x) * 4;
  if (i >= s.ntot) return;
  float4 v = {0.f, 0.f, 0.f, 0.f};
  if (i < s.nval) v = *(const float4*)(s.src + i);
  bf16x4 o;
  o[0] = (bf16)v.x; o[1] = (bf16)v.y; o[2] = (bf16)v.z; o[3] = (bf16)v.w;
  *(bf16x4*)(s.dst + i) = o;
}

// ---------------- rmsnorm (f32 in, bf16 out) ----------------
__global__ __launch_bounds__(256) void rmsnorm_k(const float* __restrict__ x,
                                                 const float* __restrict__ w,
                                                 bf16* __restrict__ y, int n) {
  __shared__ float sh[4];
  size_t row = blockIdx.x;
  const float* xr = x + row * n;
  bf16* yr = y + row * n;
  float ss = 0.f;
  for (int i = threadIdx.x; i < n; i += 256) { float v = xr[i]; ss += v * v; }
  ss = blockReduceSum<4>(ss, sh);
  float inv = rsqrtf(ss / n + 1e-5f);
  for (int i = threadIdx.x; i < n; i += 256) yr[i] = (bf16)(xr[i] * inv * w[i]);
}

// ---------------- generic bf16 MFMA GEMM: C = act(A @ W^T), 3-buf/1-barrier K-loop ----
// R7-verified schedule: per K-step {stage t+1 -> buf nxt; vmcnt(4); barrier; ds_read cur;
// setprio(1); 16 MFMA; setprio(0)}. LDS 48 KB -> 3 blocks/CU.
template<int ACT, typename OT>
__global__ __launch_bounds__(256) void gemm_mfma(const bf16* __restrict__ A,
                                                 const bf16* __restrict__ W,
                                                 const float* __restrict__ R,
                                                 OT* __restrict__ C,
                                                 int M, int N, int K) {
  __shared__ bf16 lds[3 * 8192];
  int tid = threadIdx.x, lane = tid & 63, wave = tid >> 6;
  int mt = M >> 7;
  int bid = blockIdx.x;
  int bm = (bid % mt) * 128, bn = (bid / mt) * 128;
  const bf16* gA0 = A + (size_t)(bm + wave * 32 + (lane >> 2)) * K + (lane & 3) * 8;
  const bf16* gA1 = gA0 + (size_t)16 * K;
  const bf16* gW0 = W + (size_t)(bn + wave * 32 + (lane >> 2)) * K + (lane & 3) * 8;
  const bf16* gW1 = gW0 + (size_t)16 * K;
  int sA = wave * 1024;                    // wave's stage region within As (elems)
  int fr = lane & 15, fq = lane >> 4;
  int wm = wave >> 1, wn = wave & 1;
  int rdA = (wm * 64 + fr) * 32 + fq * 8;
  int rdW = (wn * 64 + fr) * 32 + fq * 8;
  f32x4 acc[4][4] = {};
  {
    bf16* bA = lds + sA;
    bf16* bW = lds + 4096 + sA;
    async_copy16(gA0, bA);  async_copy16(gA1, bA + 512);
    async_copy16(gW0, bW);  async_copy16(gW1, bW + 512);
  }
  int cur = 0, nxt = 1;
  int nsteps = K >> 5;
  for (int t = 0; t < nsteps; t++) {
    if (t + 1 < nsteps) {
      int off = (t + 1) * 32;
      bf16* bA = lds + nxt * 8192 + sA;
      bf16* bW = lds + nxt * 8192 + 4096 + sA;
      async_copy16(gA0 + off, bA);  async_copy16(gA1 + off, bA + 512);
      async_copy16(gW0 + off, bW);  async_copy16(gW1 + off, bW + 512);
      asm volatile("s_waitcnt vmcnt(4)" ::: "memory");
    } else {
      asm volatile("s_waitcnt vmcnt(0)" ::: "memory");
    }
    __builtin_amdgcn_sched_barrier(0);
    __builtin_amdgcn_s_barrier();
    __builtin_amdgcn_sched_barrier(0);
    const bf16* cA = lds + cur * 8192;
    const bf16* cW = cA + 4096;
    bf16x8 af[4], bfr[4];
#pragma unroll
    for (int mi = 0; mi < 4; mi++) af[mi] = *(const bf16x8*)(cA + rdA + mi * 512);
#pragma unroll
    for (int ni = 0; ni < 4; ni++) bfr[ni] = *(const bf16x8*)(cW + rdW + ni * 512);
    __builtin_amdgcn_s_setprio(1);
#pragma unroll
    for (int mi = 0; mi < 4; mi++)
#pragma unroll
      for (int ni = 0; ni < 4; ni++)
        acc[mi][ni] = __builtin_amdgcn_mfma_f32_16x16x32_bf16(af[mi], bfr[ni], acc[mi][ni], 0, 0, 0);
    __builtin_amdgcn_s_setprio(0);
    cur = nxt; nxt = nxt + 1; if (nxt == 3) nxt = 0;
  }
#pragma unroll
  for (int mi = 0; mi < 4; mi++) {
    int row = bm + wm * 64 + mi * 16 + fq * 4;
#pragma unroll
    for (int ni = 0; ni < 4; ni++) {
      int col = bn + wn * 64 + ni * 16 + fr;
      if (col < N) {
#pragma unroll
        for (int r = 0; r < 4; r++) {
          float v = acc[mi][ni][r];
          if (ACT == 1) v = v / (1.f + __expf(-v));
          if (R) v += R[(size_t)(row + r) * N + col];
          C[(size_t)(row + r) * N + col] = (OT)v;
        }
      }
    }
  }
}

// ---------------- split-K bf16 MFMA GEMM: P[ks] = A @ W^T, 3-buf/1-barrier K-loop ----
__global__ __launch_bounds__(256) void gemm_sk(const bf16* __restrict__ A,
                                               const bf16* __restrict__ W,
                                               bf16* __restrict__ P,
                                               int M, int N, int K, int kchunk) {
  __shared__ bf16 lds[3 * 8192];
  int tid = threadIdx.x, lane = tid & 63, wave = tid >> 6;
  int mt = M >> 7;
  int bid = blockIdx.x;
  int bm = (bid % mt) * 128, bn = (bid / mt) * 128;
  int ks = blockIdx.z;
  int kbeg = ks * kchunk;
  const bf16* gA0 = A + (size_t)(bm + wave * 32 + (lane >> 2)) * K + kbeg + (lane & 3) * 8;
  const bf16* gA1 = gA0 + (size_t)16 * K;
  const bf16* gW0 = W + (size_t)(bn + wave * 32 + (lane >> 2)) * K + kbeg + (lane & 3) * 8;
  const bf16* gW1 = gW0 + (size_t)16 * K;
  int sA = wave * 1024;
  int fr = lane & 15, fq = lane >> 4;
  int wm = wave >> 1, wn = wave & 1;
  int rdA = (wm * 64 + fr) * 32 + fq * 8;
  int rdW = (wn * 64 + fr) * 32 + fq * 8;
  f32x4 acc[4][4] = {};
  {
    bf16* bA = lds + sA;
    bf16* bW = lds + 4096 + sA;
    async_copy16(gA0, bA);  async_copy16(gA1, bA + 512);
    async_copy16(gW0, bW);  async_copy16(gW1, bW + 512);
  }
  int cur = 0, nxt = 1;
  int nsteps = kchunk >> 5;
  for (int t = 0; t < nsteps; t++) {
    if (t + 1 < nsteps) {
      int off = (t + 1) * 32;
      bf16* bA = lds + nxt * 8192 + sA;
      bf16* bW = lds + nxt * 8192 + 4096 + sA;
      async_copy16(gA0 + off, bA);  async_copy16(gA1 + off, bA + 512);
      async_copy16(gW0 + off, bW);  async_copy16(gW1 + off, bW + 512);
      asm volatile("s_waitcnt vmcnt(4)" ::: "memory");
    } else {
      asm volatile("s_waitcnt vmcnt(0)" ::: "memory");
    }
    __builtin_amdgcn_sched_barrier(0);
    __builtin_amdgcn_s_barrier();
    __builtin_amdgcn_sched_barrier(0);
    const bf16* cA = lds + cur * 8192;
    const bf16* cW = cA + 4096;
    bf16x8 af[4], bfr[4];
#pragma unroll
    for (int mi = 0; mi < 4; mi++) af[mi] = *(const bf16x8*)(cA + rdA + mi * 512);
#pragma unroll
    for (int ni = 0; ni < 4; ni++) bfr[ni] = *(const bf16x8*)(cW + rdW + ni * 512);
    __builtin_amdgcn_s_setprio(1);
#pragma unroll
    for (int mi = 0; mi < 4; mi++)
#pragma unroll
      for (int ni = 0; ni < 4; ni++)
        acc[mi][ni] = __builtin_amdgcn_mfma_f32_16x16x32_bf16(af[mi], bfr[ni], acc[mi][ni], 0, 0, 0);
    __builtin_amdgcn_s_setprio(0);
    cur = nxt; nxt = nxt + 1; if (nxt == 3) nxt = 0;
  }
  bf16* Pp = P + (size_t)ks * M * N;
#pragma unroll
  for (int mi = 0; mi < 4; mi++) {
    int row = bm + wm * 64 + mi * 16 + fq * 4;
#pragma unroll
    for (int ni = 0; ni < 4; ni++) {
      int col = bn + wn * 64 + ni * 16 + fr;
#pragma unroll
      for (int r = 0; r < 4; r++)
        Pp[(size_t)(row + r) * N + col] = (bf16)acc[mi][ni][r];
    }
  }
}

// ---------------- reduce 2 bf16 partials + residual + layernorm -> x_out f32, h bf16 ----------------
__global__ __launch_bounds__(256) void reduce_ln2(const bf16* __restrict__ p0,
                                                  const bf16* __restrict__ p1,
                                                  const float* __restrict__ res,
                                                  const float* __restrict__ w,
                                                  const float* __restrict__ b,
                                                  float* __restrict__ xo,
                                                  bf16* __restrict__ ho) {
  __shared__ float sh[4];
  size_t o = (size_t)blockIdx.x * 1024;
  int i = threadIdx.x * 4;
  bf16x4 a = *(const bf16x4*)(p0 + o + i);
  bf16x4 c = *(const bf16x4*)(p1 + o + i);
  f32x4 rv = *(const f32x4*)(res + o + i);
  f32x4 v;
  float s = 0.f, s2 = 0.f;
#pragma unroll
  for (int j = 0; j < 4; j++) {
    v[j] = (float)a[j] + (float)c[j] + rv[j];
    s += v[j]; s2 += v[j] * v[j];
  }
  s  = blockReduceSum<4>(s,  sh);
  s2 = blockReduceSum<4>(s2, sh);
  float mean = s / 1024.f;
  float var  = s2 / 1024.f - mean * mean;
  float inv  = rsqrtf(var + 1e-5f);
  f32x4 wv = *(const f32x4*)(w + i);
  f32x4 bv = *(const f32x4*)(b + i);
  *(f32x4*)(xo + o + i) = v;
  bf16x4 hv;
#pragma unroll
  for (int j = 0; j < 4; j++) hv[j] = (bf16)((v[j] - mean) * inv * wv[j] + bv[j]);
  *(bf16x4*)(ho + o + i) = hv;
}

// ---------------- reduce 3 bf16 partials + residual -> out f32 ----------------
__global__ __launch_bounds__(256) void reduce_out3(const bf16* __restrict__ p0,
                                                   const bf16* __restrict__ p1,
                                                   const bf16* __restrict__ p2,
                                                   const float* __restrict__ res,
                                                   float* __restrict__ out) {
  int i = (blockIdx.x * 256 + threadIdx.x) * 4;
  bf16x4 a = *(const bf16x4*)(p0 + i);
  bf16x4 c = *(const bf16x4*)(p1 + i);
  bf16x4 d = *(const bf16x4*)(p2 + i);
  f32x4 v = *(const f32x4*)(res + i);
#pragma unroll
  for (int j = 0; j < 4; j++) v[j] += (float)a[j] + (float)c[j] + (float)d[j];
  *(f32x4*)(out + i) = v;
}

// ---------------- reduce qkv bf16 partials + q/k rmsnorm + rope + gain -> bf16 ----------------
__global__ __launch_bounds__(256) void reduce_qkv(const bf16* __restrict__ P,
                                                  const float* __restrict__ q_gain,
                                                  bf16* __restrict__ q,
                                                  bf16* __restrict__ k,
                                                  bf16* __restrict__ v) {
  __shared__ float buf[1536];
  size_t row = blockIdx.x;
  size_t o = row * 1536;
  const bf16* p0 = P + o;
  const bf16* p1 = P + (size_t)ROWS * 1536 + o;
  int tid = threadIdx.x;
  for (int i = tid; i < 384; i += 256) {
    bf16x4 a = *(const bf16x4*)(p0 + i * 4);
    bf16x4 c = *(const bf16x4*)(p1 + i * 4);
    f32x4 vv;
#pragma unroll
    for (int j = 0; j < 4; j++) vv[j] = (float)a[j] + (float)c[j];
    *(f32x4*)(buf + i * 4) = vv;
  }
  __syncthreads();
  int lane = tid & 63, w = tid >> 6;
  int s = (int)(row & (S_ - 1));
  int ri = lane & 7;
  float rinv = __expf(-(float)ri * (0.125f * 9.210340371976184f)); // 10000^(-i/8)
  float ang = (float)s * rinv;
  float cs = cosf(ang), sn = sinf(ang);
#pragma unroll
  for (int j = 0; j < 6; j++) {
    int hh = w * 6 + j;
    float val = buf[hh * 64 + lane];
    if (hh < 20) {
      float ss = val * val;
#pragma unroll
      for (int off = 32; off > 0; off >>= 1) ss += __shfl_xor(ss, off, 64);
      val *= rsqrtf(ss / 64.f + 1.1920929e-7f);
      float other = __shfl_xor(val, 8, 64);
      float res = val;
      if (lane < RD) res = (lane < 8) ? (val * cs + other * sn) : (val * cs - other * sn);
      if (hh < 16) {
        res *= q_gain[hh];
        q[row * (HATT * HD) + hh * HD + lane] = (bf16)res;
      } else {
        k[row * (KVH * HD) + (hh - 16) * HD + lane] = (bf16)res;
      }
    } else {
      v[row * (KVH * HD) + (hh - 20) * HD + lane] = (bf16)val;
    }
  }
}

// ---------------- in_proj GEMM: 3-buf 2-DEEP prefetch (stage-after-barrier) ----
// R8 change: stage tile t+2 AFTER barrier t (was: t+1 before vmcnt). Loads get 2 full
// steps to land. WAR-safe: buf (t+2)%3 == buf (t-1)%3, whose readers all finished step
// t-1 before reaching barrier t; stage is issued after that barrier. vmcnt(4) before the
// barrier still waits exactly for tile t (outstanding = tiles t, t+1). Targets the
// latency-bound 96-block light tail (~17us -> ~9); heavy round roughly neutral.
__global__ __launch_bounds__(512, 2) void gemm256_inproj(const bf16* __restrict__ A,
                                                         const bf16* __restrict__ W,
                                                         bf16* __restrict__ zt,
                                                         bf16* __restrict__ xt,
                                                         bf16* __restrict__ bcdt) {
  __shared__ bf16 lds[3 * 16384];          // 96 KB
  int tid = threadIdx.x;
  int lane = tid & 63, w = tid >> 6;       // 8 waves
  int fr = lane & 15, fq = lane >> 4;
  int rdswz = (fq ^ (fr & 3)) * 8;         // swizzled read offset
  int sswz = (lane & 3) ^ ((lane >> 2) & 3);   // inverse swizzle on global source
  int bid = blockIdx.x;
  if (bid < 256) {
    int sb = (bid & 7) * 32 + (bid >> 3);  // XCD swizzle (256 = 8*32, bijective)
    int bm = (sb & 15) * 256;              // 16 M tiles fastest (share W panel)
    int bn = (sb >> 4) * 256;              // 16 N tiles -> cols 0..4095 (z/x only)
    int wm = w >> 2, wn = w & 3;           // 2M x 4N waves: per wave 128x64
    int srow = w * 32 + (lane >> 2);
    const bf16* gA = A + (size_t)(bm + srow) * 1024 + sswz * 8;
    const bf16* gW = W + (size_t)(bn + srow) * 1024 + sswz * 8;
    int sbase = w * 1024;                  // wave's 32-row stage region (elements)
    f32x4 acc[8][4] = {};
    // prologue: stage tiles 0 -> buf 0, 1 -> buf 1
#pragma unroll
    for (int p = 0; p < 2; p++) {
      bf16* bA = lds + p * 16384 + sbase;
      bf16* bB = bA + 8192;
      async_copy16(gA + p * 32, bA);
      async_copy16(gA + p * 32 + 16 * 1024, bA + 512);
      async_copy16(gW + p * 32, bB);
      async_copy16(gW + p * 32 + 16 * 1024, bB + 512);
    }
    int cur = 0;
    for (int t = 0; t < 32; t++) {
      if (t + 1 < 32) asm volatile("s_waitcnt vmcnt(4)" ::: "memory");
      else            asm volatile("s_waitcnt vmcnt(0)" ::: "memory");
      __builtin_amdgcn_sched_barrier(0);
      __builtin_amdgcn_s_barrier();
      __builtin_amdgcn_sched_barrier(0);
      if (t + 2 < 32) {
        int b2 = cur + 2; if (b2 >= 3) b2 -= 3;     // (t+2)%3
        const bf16* ga = gA + (t + 2) * 32;
        const bf16* gw = gW + (t + 2) * 32;
        bf16* bA = lds + b2 * 16384 + sbase;
        bf16* bB = bA + 8192;
        async_copy16(ga, bA);
        async_copy16(ga + 16 * 1024, bA + 512);
        async_copy16(gw, bB);
        async_copy16(gw + 16 * 1024, bB + 512);
      }
      const bf16* cA = lds + cur * 16384;
      const bf16* cB = cA + 8192;
      bf16x8 af[8], bfv[4];
#pragma unroll
      for (int mi = 0; mi < 8; mi++)
        af[mi] = *(const bf16x8*)(cA + (wm * 128 + mi * 16 + fr) * 32 + rdswz);
#pragma unroll
      for (int ni = 0; ni < 4; ni++)
        bfv[ni] = *(const bf16x8*)(cB + (wn * 64 + ni * 16 + fr) * 32 + rdswz);
      __builtin_amdgcn_s_setprio(1);
#pragma unroll
      for (int mi = 0; mi < 8; mi++)
#pragma unroll
        for (int ni = 0; ni < 4; ni++)
          acc[mi][ni] = __builtin_amdgcn_mfma_f32_16x16x32_bf16(af[mi], bfv[ni], acc[mi][ni], 0, 0, 0);
      __builtin_amdgcn_s_setprio(0);
      cur = cur + 1; if (cur == 3) cur = 0;
    }
    // epilogue: LDS-transposed coalesced Zt/Xt stores (R3-verified path)
    bf16* base = (bn < 2048) ? zt : xt;
    int bq = bm >> 11, bmS = bm & 2047;
    bf16* Ts = lds;                        // 64 x 264 bf16 scratch (33.8 KB)
#pragma unroll 1
    for (int g = 0; g < 4; g++) {
      __syncthreads();
      if (wn == g) {
#pragma unroll
        for (int mi = 0; mi < 8; mi++)
#pragma unroll
          for (int ni = 0; ni < 4; ni++) {
            bf16x4 o;
#pragma unroll
            for (int r = 0; r < 4; r++) o[r] = (bf16)acc[mi][ni][r];
            *(bf16x4*)(Ts + (ni * 16 + fr) * 264 + wm * 128 + mi * 16 + fq * 4) = o;
          }
      }
      __syncthreads();
      int hh = ((bn & 2047) + g * 64) >> 6;
      bf16* dst = base + ((size_t)(bq * NH + hh) * HD) * S_ + bmS;
#pragma unroll
      for (int i = 0; i < 4; i++) {
        int idx = tid + i * 512;
        int p = idx >> 5, sc = (idx & 31) * 8;
        *(bf16x8*)(dst + (size_t)p * S_ + sc) = *(const bf16x8*)(Ts + p * 264 + sc);
      }
    }
  } else {
    // ---- light path: 128x128 tile over bcdt columns 4096..4383 (3rd tile masked) ----
    int lb = bid - 256;
    int bm = (lb & 31) * 128;
    int bn = 4096 + (lb >> 5) * 128;
    int wm = w >> 1, wn = w & 1;           // 4M x 2N waves: per wave 32x64
    int srow = w * 16 + (lane >> 2);
    const bf16* gA = A + (size_t)(bm + srow) * 1024 + sswz * 8;
    const bf16* gW = W + (size_t)(bn + srow) * 1024 + sswz * 8;
    int sbase = w * 512;                   // wave's 16-row stage region (elems)
    f32x4 acc[2][4] = {};
#pragma unroll
    for (int p = 0; p < 2; p++) {
      async_copy16(gA + p * 32, lds + p * 8192 + sbase);
      async_copy16(gW + p * 32, lds + p * 8192 + 4096 + sbase);
    }
    int cur = 0;
    for (int t = 0; t < 32; t++) {
      if (t + 1 < 32) asm volatile("s_waitcnt vmcnt(2)" ::: "memory");
      else            asm volatile("s_waitcnt vmcnt(0)" ::: "memory");
      __builtin_amdgcn_sched_barrier(0);
      __builtin_amdgcn_s_barrier();
      __builtin_amdgcn_sched_barrier(0);
      if (t + 2 < 32) {
        int b2 = cur + 2; if (b2 >= 3) b2 -= 3;
        async_copy16(gA + (t + 2) * 32, lds + b2 * 8192 + sbase);
        async_copy16(gW + (t + 2) * 32, lds + b2 * 8192 + 4096 + sbase);
      }
      const bf16* cA = lds + cur * 8192;
      const bf16* cB = cA + 4096;
      bf16x8 af[2], bfv[4];
#pragma unroll
      for (int mi = 0; mi < 2; mi++)
        af[mi] = *(const bf16x8*)(cA + (wm * 32 + mi * 16 + fr) * 32 + rdswz);
#pragma unroll
      for (int ni = 0; ni < 4; ni++)
        bfv[ni] = *(const bf16x8*)(cB + (wn * 64 + ni * 16 + fr) * 32 + rdswz);
#pragma unroll
      for (int mi = 0; mi < 2; mi++)
#pragma unroll
        for (int ni = 0; ni < 4; ni++)
          acc[mi][ni] = __builtin_amdgcn_mfma_f32_16x16x32_bf16(af[mi], bfv[ni], acc[mi][ni], 0, 0, 0);
      cur = cur + 1; if (cur == 3) cur = 0;
    }
#pragma unroll
    for (int mi = 0; mi < 2; mi++) {
      int row = bm + wm * 32 + mi * 16 + fq * 4;
#pragma unroll
      for (int ni = 0; ni < 4; ni++) {
        int col = bn + wn * 64 + ni * 16 + fr;
        if (col < 4384) {
#pragma unroll
          for (int r = 0; r < 4; r++)
            bcdt[(size_t)(row + r) * 288 + (col - 4096)] = (bf16)acc[mi][ni][r];
        }
      }
    }
  }
}

// ---------------- generic 64x64 tiled transpose (bf16), out row stride 2048 ----------------
__global__ __launch_bounds__(256) void t64(const bf16* __restrict__ in, bf16* __restrict__ out,
                                           int istr, size_t io, size_t oo, int n_nt) {
  __shared__ bf16 T[64 * 72];
  int bid = blockIdx.x;
  int st = bid & 31;
  int nt = (bid >> 5) % n_nt;
  int outer = bid / (32 * n_nt);
  const bf16* ip = in + outer * io + (size_t)st * 64 * istr + nt * 64;
  int tid = threadIdx.x;
#pragma unroll
  for (int i = 0; i < 2; i++) {
    int cid = tid + i * 256; int s = cid >> 3, pc = (cid & 7) * 8;
    *(bf16x8*)(T + s * 72 + pc) = *(const bf16x8*)(ip + (size_t)s * istr + pc);
  }
  __syncthreads();
  bf16* op = out + outer * oo + (size_t)nt * 64 * 2048 + st * 64;
#pragma unroll
  for (int i = 0; i < 2; i++) {
    int cid = tid + i * 256; int p = cid >> 3, sc = (cid & 7) * 8;
    bf16x8 o;
#pragma unroll
    for (int j = 0; j < 8; j++) o[j] = T[(sc + j) * 72 + p];
    *(bf16x8*)(op + (size_t)p * 2048 + sc) = o;
  }
}

// ---------------- SSD prep: dt softplus, per-chunk cumsum, decay factors ----------------
__global__ __launch_bounds__(64) void ssd_prep(const bf16* __restrict__ bcdt,
                                               const float* __restrict__ dt_bias,
                                               const float* __restrict__ A_log,
                                               float* __restrict__ dt_c,
                                               float* __restrict__ ddc,
                                               float* __restrict__ ac_c,
                                               float* __restrict__ T_out) {
  int bid = blockIdx.x;
  int c = bid % NC, hh = (bid / NC) % NH, b = bid / (NC * NH);
  int l = threadIdx.x;
  size_t row = (size_t)b * S_ + c * 64 + l;
  float raw = (float)bcdt[row * 288 + 256 + hh] + dt_bias[hh];
  float dtv = (raw > 20.f) ? raw : log1pf(__expf(raw));
  float a = -__expf(A_log[hh]) * dtv;
  float ps = a;
#pragma unroll
  for (int off = 1; off < 64; off <<= 1) {
    float t = __shfl_up(ps, off, 64);
    if (l >= off) ps += t;
  }
  float a63 = __shfl(ps, 63, 64);
  size_t o = ((size_t)b * NH + hh) * S_ + c * 64 + l;
  dt_c[o] = dtv;
  ac_c[o] = ps;
  ddc[o] = __expf(a63 - ps) * dtv;
  if (l == 63) T_out[(b * NH + hh) * NC + c] = ps;
}

// ---------------- B/C rmsnorm (bf16 out) ----------------
__global__ __launch_bounds__(128) void bc_norm(const bf16* __restrict__ bcdt,
                                               const float* __restrict__ Bw,
                                               const float* __restrict__ Cw,
                                               bf16* __restrict__ Bn,
                                               bf16* __restrict__ Cn) {
  __shared__ float shb[2], shc[2];
  size_t row = blockIdx.x;
  int i = threadIdx.x;
  float bv = (float)bcdt[row * 288 + i];
  float cv = (float)bcdt[row * 288 + 128 + i];
  float sb = waveReduceSum(bv * bv);
  float sc = waveReduceSum(cv * cv);
  int lane = threadIdx.x & 63, wid = threadIdx.x >> 6;
  if (lane == 0) { shb[wid] = sb; shc[wid] = sc; }
  __syncthreads();
  float tb = shb[0] + shb[1];
  float tc = shc[0] + shc[1];
  Bn[row * DS + i] = (bf16)(bv * rsqrtf(tb / DS + 1e-5f) * Bw[i]);
  Cn[row * DS + i] = (bf16)(cv * rsqrtf(tc / DS + 1e-5f) * Cw[i]);
}

// ---------------- chunk states via MFMA (bf16 output) ----------------
__global__ __launch_bounds__(256) void ssd_states(const bf16* __restrict__ Xt,
                                                  const bf16* __restrict__ Btr,
                                                  const float* __restrict__ ddc,
                                                  bf16* __restrict__ states) {
  __shared__ bf16 Xs[64 * 72];    // [p][s]
  __shared__ bf16 Bs[128 * 72];   // [n][s]
  int bid = blockIdx.x;           // (b*NC + c)*NH + h
  int h = bid % NH;
  int c = (bid / NH) % NC;
  int b = bid / (NH * NC);
  int tid = threadIdx.x, lane = tid & 63, w = tid >> 6;
  int fr = lane & 15, fq = lane >> 4;
  const size_t xbase = (size_t)(b * NH + h) * HD * S_ + c * 64;
  const size_t dbase = (size_t)(b * NH + h) * S_ + c * 64;
#pragma unroll
  for (int i = 0; i < 2; i++) {
    int cid = tid + i * 256; int p = cid >> 3, sc = (cid & 7) * 8;
    bf16x8 xv = *(const bf16x8*)(Xt + xbase + (size_t)p * S_ + sc);
    f32x4 d0 = *(const f32x4*)(ddc + dbase + sc);
    f32x4 d1 = *(const f32x4*)(ddc + dbase + sc + 4);
    bf16x8 o;
#pragma unroll
    for (int j = 0; j < 4; j++) { o[j] = (bf16)((float)xv[j] * d0[j]); o[4 + j] = (bf16)((float)xv[4 + j] * d1[j]); }
    *(bf16x8*)(Xs + p * 72 + sc) = o;
  }
  const size_t bbase = (size_t)b * 128 * S_ + c * 64;
#pragma unroll
  for (int i = 0; i < 4; i++) {
    int cid = tid + i * 256; int n = cid >> 3, sc = (cid & 7) * 8;
    *(bf16x8*)(Bs + n * 72 + sc) = *(const bf16x8*)(Btr + bbase + (size_t)n * S_ + sc);
  }
  __syncthreads();
  f32x4 acc[4][2] = {};
#pragma unroll
  for (int ks = 0; ks < 2; ks++) {
    bf16x8 a[4], bb[2];
#pragma unroll
    for (int pt = 0; pt < 4; pt++) a[pt] = *(const bf16x8*)(Xs + (pt * 16 + fr) * 72 + ks * 32 + fq * 8);
#pragma unroll
    for (int n2 = 0; n2 < 2; n2++) bb[n2] = *(const bf16x8*)(Bs + ((2 * w + n2) * 16 + fr) * 72 + ks * 32 + fq * 8);
#pragma unroll
    for (int pt = 0; pt < 4; pt++)
#pragma unroll
      for (int n2 = 0; n2 < 2; n2++)
        acc[pt][n2] = __builtin_amdgcn_mfma_f32_16x16x32_bf16(a[pt], bb[n2], acc[pt][n2], 0, 0, 0);
  }
  bf16* outp = states + (size_t)bid * 8192;
#pragma unroll
  for (int pt = 0; pt < 4; pt++)
#pragma unroll
    for (int n2 = 0; n2 < 2; n2++) {
      int n = (2 * w + n2) * 16 + fr;
#pragma unroll
      for (int r = 0; r < 4; r++)
        outp[(size_t)(pt * 16 + fq * 4 + r) * 128 + n] = (bf16)acc[pt][n2][r];
    }
}

// ---------------- inter-chunk scan (in place, bf16 storage, f32 math) ----------------
__global__ __launch_bounds__(256) void ssd_scan(bf16* __restrict__ states,
                                                const float* __restrict__ T) {
  __shared__ float eT[NC];
  int part = blockIdx.x & 7;
  int bh = blockIdx.x >> 3;
  int b = bh / NH, h = bh % NH;
  if (threadIdx.x < NC) eT[threadIdx.x] = __expf(T[(size_t)(b * NH + h) * NC + threadIdx.x]);
  __syncthreads();
  const size_t cstride = (size_t)NH * HD * DS;
  size_t base = ((size_t)b * NC * NH + h) * (HD * DS);
#pragma unroll
  for (int j = 0; j < 4; j++) {
    int e = part * 1024 + threadIdx.x + j * 256;
    float carry = 0.f;
    size_t idx = base + e;
    for (int c = 0; c < NC; c++) {
      float sv = (float)states[idx];
      states[idx] = (bf16)carry;
      carry = sv + eT[c] * carry;
      idx += cstride;
    }
  }
}

// ---------------- fused SSD output: Ydiag + Yoff + D-skip + gate (all MFMA) ----------------
__global__ __launch_bounds__(256) void ssd_out(const bf16* __restrict__ Cn,
                                               const bf16* __restrict__ Bn,
                                               const bf16* __restrict__ Xt,
                                               const bf16* __restrict__ Zt,
                                               const float* __restrict__ dt_c,
                                               const float* __restrict__ ac_c,
                                               const bf16* __restrict__ states,
                                               const float* __restrict__ Dp,
                                               bf16* __restrict__ ybf) {
  __shared__ bf16 Cs[64 * 136];
  __shared__ bf16 BNs[64 * 136];
  __shared__ bf16 Xs[64 * 72];
  __shared__ bf16 G[64 * 72];
  __shared__ float acs[64];
  int bid = blockIdx.x;
  int h = bid % NH;
  int c = (bid / NH) % NC;
  int b = bid / (NH * NC);
  int tid = threadIdx.x, lane = tid & 63, w = tid >> 6;
  int fr = lane & 15, fq = lane >> 4;
  size_t row0 = (size_t)b * S_ + c * 64;
  const size_t abase = (size_t)(b * NH + h) * S_ + c * 64;
  if (tid < 64) acs[tid] = ac_c[abase + tid];
#pragma unroll
  for (int i = 0; i < 4; i++) {
    int cid = tid + i * 256; int l = cid >> 4, nc = (cid & 15) * 8;
    float e = __expf(ac_c[abase + l]);
    bf16x8 cv = *(const bf16x8*)(Cn + (row0 + l) * DS + nc);
    bf16x8 o;
#pragma unroll
    for (int j = 0; j < 8; j++) o[j] = (bf16)((float)cv[j] * e);
    *(bf16x8*)(Cs + l * 136 + nc) = o;
    *(bf16x8*)(BNs + l * 136 + nc) = *(const bf16x8*)(Bn + (row0 + l) * DS + nc);
  }
  const size_t xbase = (size_t)(b * NH + h) * HD * S_ + c * 64;
#pragma unroll
  for (int i = 0; i < 2; i++) {
    int cid = tid + i * 256; int p = cid >> 3, sc = (cid & 7) * 8;
    bf16x8 xv = *(const bf16x8*)(Xt + xbase + (size_t)p * S_ + sc);
    f32x4 d0 = *(const f32x4*)(dt_c + abase + sc);
    f32x4 d1 = *(const f32x4*)(dt_c + abase + sc + 4);
    bf16x8 o;
#pragma unroll
    for (int j = 0; j < 4; j++) { o[j] = (bf16)((float)xv[j] * d0[j]); o[4 + j] = (bf16)((float)xv[4 + j] * d1[j]); }
    *(bf16x8*)(Xs + p * 72 + sc) = o;
  }
  __syncthreads();
  bf16x8 ca[4];
#pragma unroll
  for (int ks = 0; ks < 4; ks++) ca[ks] = *(const bf16x8*)(Cs + (w * 16 + fr) * 136 + ks * 32 + fq * 8);
  f32x4 cb[4] = {};
  for (int st = 0; st <= w; st++)
#pragma unroll
    for (int ks = 0; ks < 4; ks++)
      cb[st] = __builtin_amdgcn_mfma_f32_16x16x32_bf16(ca[ks],
                 *(const bf16x8*)(BNs + (st * 16 + fr) * 136 + ks * 32 + fq * 8), cb[st], 0, 0, 0);
#pragma unroll
  for (int st = 0; st < 4; st++) {
    float es = (st <= w) ? __expf(-acs[st * 16 + fr]) : 0.f;
#pragma unroll
    for (int r = 0; r < 4; r++) {
      int lloc = fq * 4 + r;
      float g = 0.f;
      if (st < w) g = cb[st][r] * es;
      else if (st == w) g = (lloc >= fr) ? cb[st][r] * es : 0.f;
      G[(w * 16 + lloc) * 72 + st * 16 + fr] = (bf16)g;
    }
  }
  f32x4 acc[4] = {};
  {
    bf16x8 ga0 = *(const bf16x8*)(G + (w * 16 + fr) * 72 + fq * 8);
    bf16x8 ga1 = *(const bf16x8*)(G + (w * 16 + fr) * 72 + 32 + fq * 8);
#pragma unroll
    for (int pt = 0; pt < 4; pt++) {
      acc[pt] = __builtin_amdgcn_mfma_f32_16x16x32_bf16(ga0,
                  *(const bf16x8*)(Xs + (pt * 16 + fr) * 72 + fq * 8), acc[pt], 0, 0, 0);
      acc[pt] = __builtin_amdgcn_mfma_f32_16x16x32_bf16(ga1,
                  *(const bf16x8*)(Xs + (pt * 16 + fr) * 72 + 32 + fq * 8), acc[pt], 0, 0, 0);
    }
  }
  __syncthreads();
  const bf16* stp = states + (size_t)bid * 8192;
#pragma unroll
  for (int i = 0; i < 4; i++) {
    int cid = tid + i * 256; int p = cid >> 4, nc = (cid & 15) * 8;
    *(bf16x8*)(BNs + p * 136 + nc) = *(const bf16x8*)(stp + (size_t)p * 128 + nc);
  }
  __syncthreads();
#pragma unroll
  for (int pt = 0; pt < 4; pt++)
#pragma unroll
    for (int ks = 0; ks < 4; ks++)
      acc[pt] = __builtin_amdgcn_mfma_f32_16x16x32_bf16(ca[ks],
                  *(const bf16x8*)(BNs + (pt * 16 + fr) * 136 + ks * 32 + fq * 8), acc[pt], 0, 0, 0);
  float dph = Dp[h];
#pragma unroll
  for (int pt = 0; pt < 4; pt++) {
    int p = pt * 16 + fr;
    size_t tb = (xbase + (size_t)p * S_) + w * 16 + fq * 4;
    bf16x4 xs4 = *(const bf16x4*)(Xt + tb);
    bf16x4 z4  = *(const bf16x4*)(Zt + tb);
#pragma unroll
    for (int r = 0; r < 4; r++) {
      int l = w * 16 + fq * 4 + r;
      float yv = acc[pt][r] + (float)xs4[r] * dph;
      float z = (float)z4[r];
      yv *= z / (1.f + __expf(-z));
      ybf[((row0 + l) * NH + h) * HD + p] = (bf16)yv;
    }
  }
}

// ---------------- split-S MFMA flash attention (fixed-max softmax -> partials sum) ----------------
// Single-buffered K/V (LDS 36.9 KB -> 4 blocks/CU); prefetch issued after the
// second barrier so loads overlap compute and drain at next iter's first barrier.
#define KSTR 72
#define PSTR 72
__global__ __launch_bounds__(256) void attn_mfma(const bf16* __restrict__ q,
                                                 const bf16* __restrict__ k,
                                                 const bf16* __restrict__ vtr,
                                                 bf16* __restrict__ Po,
                                                 float* __restrict__ Ls) {
  __shared__ bf16 Ks[64 * KSTR];
  __shared__ bf16 Vs[64 * KSTR];
  __shared__ bf16 Pl[4][32 * PSTR];
  int c = 39 - blockIdx.x;                 // full 8-iter chunks first
  int g = (c < 4) ? 0 : (c < 12) ? 1 : (c < 24) ? 2 : 3;
  int gbase = (g == 0) ? 0 : (g == 1) ? 4 : (g == 2) ? 12 : 24;
  int d = c - gbase;
  int qt = 4 * g + d / (g + 1);
  int sk = d % (g + 1);
  int h = blockIdx.y, b = blockIdx.z;
  int kvh = h >> 2;
  int tid = threadIdx.x, lane = tid & 63, w = tid >> 6;
  int fr = lane & 15, fq = lane >> 4;
  const float SC = 0.18033688011112042f;   // 0.125 * log2(e)
  const float M2 = 62.0f;
  int kt0 = sk * 8;
  int ktend = min(kt0 + 8, 2 * qt + 2);
  int qbase = qt * 128 + w * 32;           // wave's first q row
  int qmaxw = qbase + 31;
  bf16x8 bq[2][2];
#pragma unroll
  for (int qc = 0; qc < 2; qc++)
#pragma unroll
    for (int ks = 0; ks < 2; ks++)
      bq[qc][ks] = *(const bf16x8*)(q + (size_t)(b * S_ + qbase + qc * 16 + fr) * (HATT * HD)
                                      + h * HD + ks * 32 + fq * 8);
  int sr = tid >> 3, sc8 = (tid & 7) * 8;
  const bf16* kg = k + ((size_t)(b * S_) + sr) * (KVH * HD) + kvh * HD + sc8;
  const bf16* vg = vtr + ((size_t)(b * KVH + kvh) * HD + sr) * S_ + sc8;
  bf16x8 krg0, krg1, vrg0, vrg1;
  {
    const bf16* kp = kg + (size_t)kt0 * 64 * (KVH * HD);
    const bf16* vp = vg + (size_t)kt0 * 64;
    krg0 = *(const bf16x8*)(kp);
    krg1 = *(const bf16x8*)(kp + (size_t)32 * (KVH * HD));
    vrg0 = *(const bf16x8*)(vp);
    vrg1 = *(const bf16x8*)(vp + (size_t)32 * S_);
  }
  float lsum[2] = {0.f, 0.f};
  f32x4 yacc[2][4] = {};
  bf16* Plw = Pl[w];
  for (int kt = kt0; kt < ktend; kt++) {
    __syncthreads();   // previous iteration's LDS reads complete
    *(bf16x8*)(&Ks[sr * KSTR + sc8]) = krg0;
    *(bf16x8*)(&Ks[(sr + 32) * KSTR + sc8]) = krg1;
    *(bf16x8*)(&Vs[sr * KSTR + sc8]) = vrg0;
    *(bf16x8*)(&Vs[(sr + 32) * KSTR + sc8]) = vrg1;
    __syncthreads();   // tile visible
    // prefetch next tile AFTER the barrier: loads overlap compute below
    if ((kt + 1) < ktend) {
      const bf16* kp = kg + (size_t)(kt + 1) * 64 * (KVH * HD);
      const bf16* vp = vg + (size_t)(kt + 1) * 64;
      krg0 = *(const bf16x8*)(kp);
      krg1 = *(const bf16x8*)(kp + (size_t)32 * (KVH * HD));
      vrg0 = *(const bf16x8*)(vp);
      vrg1 = *(const bf16x8*)(vp + (size_t)32 * S_);
    }
    if (kt * 64 <= qmaxw) {
      bool nomask = (kt * 64 + 63) <= qbase;
      if (nomask) {
#pragma unroll
        for (int mi = 0; mi < 4; mi++) {
          const bf16* krow = &Ks[(mi * 16 + fr) * KSTR];
          bf16x8 ak0 = *(const bf16x8*)(krow + fq * 8);
          bf16x8 ak1 = *(const bf16x8*)(krow + 32 + fq * 8);
#pragma unroll
          for (int qc = 0; qc < 2; qc++) {
            f32x4 s = {};
            s = __builtin_amdgcn_mfma_f32_16x16x32_bf16(ak0, bq[qc][0], s, 0, 0, 0);
            s = __builtin_amdgcn_mfma_f32_16x16x32_bf16(ak1, bq[qc][1], s, 0, 0, 0);
            bf16x4 pk;
#pragma unroll
            for (int r = 0; r < 4; r++) {
              float p = __builtin_amdgcn_exp2f(s[r] * SC - M2);
              lsum[qc] += p;
              pk[r] = (bf16)p;
            }
            *(bf16x4*)(Plw + (qc * 16 + fr) * PSTR + mi * 16 + fq * 4) = pk;
          }
        }
      } else {
#pragma unroll
        for (int mi = 0; mi < 4; mi++) {
          int s0 = kt * 64 + mi * 16;
          if (s0 > qmaxw) {
            bf16x4 zz = {};
#pragma unroll
            for (int qc = 0; qc < 2; qc++)
              *(bf16x4*)(Plw + (qc * 16 + fr) * PSTR + mi * 16 + fq * 4) = zz;
          } else {
            const bf16* krow = &Ks[(mi * 16 + fr) * KSTR];
            bf16x8 ak0 = *(const bf16x8*)(krow + fq * 8);
            bf16x8 ak1 = *(const bf16x8*)(krow + 32 + fq * 8);
#pragma unroll
            for (int qc = 0; qc < 2; qc++) {
              f32x4 s = {};
              s = __builtin_amdgcn_mfma_f32_16x16x32_bf16(ak0, bq[qc][0], s, 0, 0, 0);
              s = __builtin_amdgcn_mfma_f32_16x16x32_bf16(ak1, bq[qc][1], s, 0, 0, 0);
              int qq = qbase + qc * 16 + fr;
              bf16x4 pk;
#pragma unroll
              for (int r = 0; r < 4; r++) {
                int sp = s0 + fq * 4 + r;
                float p = (sp <= qq) ? __builtin_amdgcn_exp2f(s[r] * SC - M2) : 0.f;
                lsum[qc] += p;
                pk[r] = (bf16)p;
              }
              *(bf16x4*)(Plw + (qc * 16 + fr) * PSTR + mi * 16 + fq * 4) = pk;
            }
          }
        }
      }
#pragma unroll
      for (int ks2 = 0; ks2 < 2; ks2++) {
        bf16x8 bp[2];
#pragma unroll
        for (int qc = 0; qc < 2; qc++)
          bp[qc] = *(const bf16x8*)(Plw + (qc * 16 + fr) * PSTR + ks2 * 32 + fq * 8);
#pragma unroll
        for (int pi = 0; pi < 4; pi++) {
          bf16x8 av = *(const bf16x8*)(&Vs[(pi * 16 + fr) * KSTR + ks2 * 32 + fq * 8]);
#pragma unroll
          for (int qc = 0; qc < 2; qc++)
            yacc[qc][pi] = __builtin_amdgcn_mfma_f32_16x16x32_bf16(av, bp[qc], yacc[qc][pi], 0, 0, 0);
        }
      }
    }
  }
#pragma unroll
  for (int qc = 0; qc < 2; qc++) {
    lsum[qc] += __shfl_xor(lsum[qc], 16, 64);
    lsum[qc] += __shfl_xor(lsum[qc], 32, 64);
    int qrow = qt * 128 + w * 32 + qc * 16 + fr;
    if (fq == 0)
      Ls[((size_t)(b * 16 + h) * 2048 + qrow) * 4 + sk] = lsum[qc];
    bf16* pop = Po + ((((size_t)(b * 16 + h) * 16 + qt) * 4 + sk) * 128
                       + w * 32 + qc * 16 + fr) * 64 + fq * 4;
#pragma unroll
    for (int pi = 0; pi < 4; pi++) {
      bf16x4 o;
#pragma unroll
      for (int r = 0; r < 4; r++) o[r] = (bf16)yacc[qc][pi][r];
      *(bf16x4*)(pop + pi * 16) = o;
    }
  }
}

// ---------------- attention partial combine + normalize -> y2 bf16 ----------------
__global__ __launch_bounds__(256) void attn_red(const bf16* __restrict__ Po,
                                                const float* __restrict__ Ls,
                                                bf16* __restrict__ y2) {
  int row = blockIdx.x;            // 0..4095
  int b = row >> 11;
  int qrow = row & 2047;
  int qt = qrow >> 7, r = qrow & 127;
  int nch = (qt >> 2) + 1;
  int t = threadIdx.x;
  int h = t >> 4, e4 = (t & 15) << 2;
  const float* lp = Ls + ((size_t)(b * 16 + h) * 2048 + qrow) * 4;
  float ls = 0.f;
  f32x4 acc = {};
  for (int sk = 0; sk < nch; sk++) {
    ls += lp[sk];
    const bf16* pp = Po + ((((size_t)(b * 16 + h) * 16 + qt) * 4 + sk) * 128 + r) * 64 + e4;
    bf16x4 v = *(const bf16x4*)(pp);
#pragma unroll
    for (int j = 0; j < 4; j++) acc[j] += (float)v[j];
  }
  float inv = 1.f / ls;
  bf16x4 o;
#pragma unroll
  for (int j = 0; j < 4; j++) o[j] = (bf16)(acc[j] * inv);
  *(bf16x4*)(y2 + (size_t)row * 1024 + h * 64 + e4) = o;
}

// ---------------- workspace layout (byte offsets) ----------------
constexpr size_t OFF_WIN  = 0;                   // bf16 4480x1024
constexpr size_t OFF_WOUT = 9175040;             // bf16 1024x2048
constexpr size_t OFF_WQKV = 13369344;            // bf16 1536x1024 (q|k|v rows)
constexpr size_t OFF_WCP  = 16515072;            // bf16 1024x1024
constexpr size_t OFF_WFC  = 18612224;            // bf16 3072x1024
constexpr size_t OFF_WPR  = 24903680;            // bf16 1024x3072
constexpr size_t OFF_HBF  = 31195136;            // bf16 4096x1024
constexpr size_t OFF_BCDT = 39583744;            // bf16 4096x288; reused: Ls f32 (1 MiB)
constexpr size_t OFF_XT   = 41943040;            // bf16 [b][h][p][sg] (16.7 MB)
constexpr size_t OFF_ZT   = 58720256;            // bf16 [b][h][p][sg] (16.7 MB)
constexpr size_t OFF_DTC  = 75497472;            // f32 [b][h][sg]
constexpr size_t OFF_DDC  = 76546048;            // f32
constexpr size_t OFF_ACC  = 77594624;            // f32
constexpr size_t OFF_T    = 78643200;            // f32 2048
constexpr size_t OFF_BN   = 78651392;            // bf16 4096x128
constexpr size_t OFF_CN   = 79699968;            // bf16 4096x128
constexpr size_t OFF_BTR  = 80748544;            // bf16 [b][n][sg]
constexpr size_t OFF_ST   = 81797120;            // bf16 states (33.5 MB); reused: Po bf16 32 MiB
constexpr size_t OFF_YBF  = 148905984;           // bf16 4096x2048
constexpr size_t OFF_X1   = 165683200;           // f32 4096x1024 (end 182,460,416)
// phase-2 aliases
constexpr size_t OFF_P    = OFF_ST;              // bf16 split-K partials (<= 25.2 MB)
constexpr size_t OFF_PO   = OFF_ST;              // bf16 attn partials [b][h][qt][4][128][64] = 32 MiB
constexpr size_t OFF_LS   = OFF_BCDT;            // f32 attn lsums [b][h][2048][4] = 1 MiB
constexpr size_t OFF_QB   = OFF_XT;              // bf16 4096x1024 (8.4 MB)
constexpr size_t OFF_KB   = OFF_XT + 8388608;    // bf16 4096x256
constexpr size_t OFF_VB   = OFF_XT + 10485760;   // bf16 4096x256
constexpr size_t OFF_VTR  = OFF_XT + 12582912;   // bf16 [b][kvh][p][sg]
constexpr size_t OFF_Y2   = OFF_ZT;              // bf16 4096x1024
constexpr size_t OFF_X2   = 50331648;            // f32 4096x1024 (over dead kb/vb/vtr/y2)
constexpr size_t OFF_MLP  = 132128768;           // bf16 4096x3072 (over dead regions)

extern "C" void kernel_launch(void* const* d_in, const int* in_sizes, int n_in,
                              void* d_out, int out_size, void* d_ws, size_t ws_size,
                              hipStream_t stream) {
  (void)in_sizes; (void)n_in; (void)out_size; (void)ws_size;
  const float* x        = (const float*)d_in[0];
  const float* mnorm_w  = (const float*)d_in[1];
  const float* in_w     = (const float*)d_in[2];
  const float* out_w    = (const float*)d_in[3];
  const float* Dp       = (const float*)d_in[4];
  const float* dt_bias  = (const float*)d_in[5];
  const float* A_log    = (const float*)d_in[6];
  const float* Bn_w     = (const float*)d_in[7];
  const float* Cn_w     = (const float*)d_in[8];
  const float* ln1_w    = (const float*)d_in[9];
  const float* ln1_b    = (const float*)d_in[10];
  const float* cq_w     = (const float*)d_in[11];
  const float* ck_w     = (const float*)d_in[12];
  const float* cv_w     = (const float*)d_in[13];
  const float* cproj_w  = (const float*)d_in[14];
  const float* q_gain   = (const float*)d_in[15];
  const float* ln2_w    = (const float*)d_in[16];
  const float* ln2_b    = (const float*)d_in[17];
  const float* fc_w     = (const float*)d_in[18];
  const float* proj_w   = (const float*)d_in[19];
  float* out = (float*)d_out;
  char* W8 = (char*)d_ws;

  bf16* w_in   = (bf16*)(W8 + OFF_WIN);
  bf16* w_out  = (bf16*)(W8 + OFF_WOUT);
  bf16* w_qkv  = (bf16*)(W8 + OFF_WQKV);
  bf16* w_cp   = (bf16*)(W8 + OFF_WCP);
  bf16* w_fc   = (bf16*)(W8 + OFF_WFC);
  bf16* w_pr   = (bf16*)(W8 + OFF_WPR);
  bf16* h_bf   = (bf16*)(W8 + OFF_HBF);
  bf16* bcdt   = (bf16*)(W8 + OFF_BCDT);
  bf16* Xt     = (bf16*)(W8 + OFF_XT);
  bf16* Zt     = (bf16*)(W8 + OFF_ZT);
  float* dt_c  = (float*)(W8 + OFF_DTC);
  float* ddc   = (float*)(W8 + OFF_DDC);
  float* ac_c  = (float*)(W8 + OFF_ACC);
  float* Tb    = (float*)(W8 + OFF_T);
  bf16* Bn     = (bf16*)(W8 + OFF_BN);
  bf16* Cn     = (bf16*)(W8 + OFF_CN);
  bf16* Btr    = (bf16*)(W8 + OFF_BTR);
  bf16* st     = (bf16*)(W8 + OFF_ST);
  bf16* ybf    = (bf16*)(W8 + OFF_YBF);
  float* x1    = (float*)(W8 + OFF_X1);
  bf16* Pbuf   = (bf16*)(W8 + OFF_P);
  bf16* Po     = (bf16*)(W8 + OFF_PO);
  float* Ls    = (float*)(W8 + OFF_LS);
  bf16* qbf    = (bf16*)(W8 + OFF_QB);
  bf16* kbf    = (bf16*)(W8 + OFF_KB);
  bf16* vbf    = (bf16*)(W8 + OFF_VB);
  bf16* vtr    = (bf16*)(W8 + OFF_VTR);
  bf16* y2     = (bf16*)(W8 + OFF_Y2);
  float* x2    = (float*)(W8 + OFF_X2);
  bf16* mlp    = (bf16*)(W8 + OFF_MLP);

  // ---- weight casts (single launch; q/k/v cast into adjacent rows of w_qkv) ----
  CastArgs ca;
  ca.seg[0] = { in_w,    w_in,            4489216, 4587520, 0     };
  ca.seg[1] = { out_w,   w_out,           2097152, 2097152, 4480  };
  ca.seg[2] = { cq_w,    w_qkv,           1048576, 1048576, 6528  };
  ca.seg[3] = { ck_w,    w_qkv + 1048576,  262144,  262144, 7552  };
  ca.seg[4] = { cv_w,    w_qkv + 1310720,  262144,  262144, 7808  };
  ca.seg[5] = { cproj_w, w_cp,            1048576, 1048576, 8064  };
  ca.seg[6] = { fc_w,    w_fc,            3145728, 3145728, 9088  };
  ca.seg[7] = { proj_w,  w_pr,            3145728, 3145728, 12160 };
  castw_all<<<15232, 256, 0, stream>>>(ca);

  const size_t PS  = (size_t)ROWS * 1024;   // partial stride (elements) for N=1024 GEMMs

  // ---- mamba block ----
  rmsnorm_k<<<ROWS, 256, 0, stream>>>(x, mnorm_w, h_bf, D_);
  gemm256_inproj<<<352, 512, 0, stream>>>(h_bf, w_in, Zt, Xt, bcdt);
  ssd_prep<<<B_ * NH * NC, 64, 0, stream>>>(bcdt, dt_bias, A_log, dt_c, ddc, ac_c, Tb);
  bc_norm<<<ROWS, 128, 0, stream>>>(bcdt, Bn_w, Cn_w, Bn, Cn);
  t64<<<2 * 2 * 32, 256, 0, stream>>>(Bn, Btr, 128, (size_t)2048 * 128, (size_t)128 * 2048, 2);
  ssd_states<<<B_ * NC * NH, 256, 0, stream>>>(Xt, Btr, ddc, st);
  ssd_scan<<<B_ * NH * 8, 256, 0, stream>>>(st, Tb);
  ssd_out<<<B_ * NC * NH, 256, 0, stream>>>(Cn, Bn, Xt, Zt, dt_c, ac_c, st, Dp, ybf);
  // out_proj: split-K=2 then fused reduce+residual+LN1
  gemm_sk<<<dim3(32 * 8, 1, 2), 256, 0, stream>>>(ybf, w_out, Pbuf, ROWS, D_, DI, 1024);
  reduce_ln2<<<ROWS, 256, 0, stream>>>(Pbuf, Pbuf + PS, x, ln1_w, ln1_b, x1, h_bf);

  // ---- attention block ----
  gemm_sk<<<dim3(32 * 12, 1, 2), 256, 0, stream>>>(h_bf, w_qkv, Pbuf, ROWS, 1536, D_, 512);
  reduce_qkv<<<ROWS, 256, 0, stream>>>(Pbuf, q_gain, qbf, kbf, vbf);
  t64<<<2 * 4 * 32, 256, 0, stream>>>(vbf, vtr, 256, (size_t)2048 * 256, (size_t)256 * 2048, 4);
  attn_mfma<<<dim3(40, HATT, B_), 256, 0, stream>>>(qbf, kbf, vtr, Po, Ls);
  attn_red<<<ROWS, 256, 0, stream>>>(Po, Ls, y2);
  gemm_sk<<<dim3(32 * 8, 1, 2), 256, 0, stream>>>(y2, w_cp, Pbuf, ROWS, D_, D_, 512);
  reduce_ln2<<<ROWS, 256, 0, stream>>>(Pbuf, Pbuf + PS, x1, ln2_w, ln2_b, x2, h_bf);

  // ---- MLP ----
  gemm_mfma<1, bf16><<<32 * 24, 256, 0, stream>>>(h_bf, w_fc, nullptr, mlp, ROWS, MLP, D_);
  gemm_sk<<<dim3(32 * 8, 1, 3), 256, 0, stream>>>(mlp, w_pr, Pbuf, ROWS, D_, MLP, 1024);
  reduce_out3<<<ROWS, 256, 0, stream>>>(Pbuf, Pbuf + PS, Pbuf + 2 * PS, x2, out);
}

// Round 9
// 496.045 us; speedup vs baseline: 1.5022x; 1.0032x over previous
//
#include <hip/hip_runtime.h>
#include <hip/hip_bf16.h>
#include <math.h>

// ---------------- problem constants ----------------
#define B_    2
#define S_    2048
#define D_    1024
#define DI    2048      // D_INNER
#define NH    32        // NHEADS (mamba)
#define HD    64        // HEADDIM
#define DS    128       // D_STATE
#define CH    64        // CHUNK
#define NC    32        // S_/CH
#define DP    4384      // D_PROJ
#define HATT  16        // attention heads
#define KVH   4         // kv heads
#define RD    16        // rope dims
#define MLP   3072
#define ROWS  (B_*S_)   // 4096
#define PSB   (ROWS*288)  // bcdt partial stride (elements)

typedef __bf16 bf16;
typedef __bf16 bf16x8 __attribute__((ext_vector_type(8)));
typedef __bf16 bf16x4 __attribute__((ext_vector_type(4)));
typedef float  f32x4  __attribute__((ext_vector_type(4)));

__device__ __forceinline__ void async_copy16(const void* g, void* l) {
  __builtin_amdgcn_global_load_lds(
      (const __attribute__((address_space(1))) unsigned int*)g,
      (__attribute__((address_space(3))) unsigned int*)l, 16, 0, 0);
}

// ---------------- reductions ----------------
__device__ __forceinline__ float waveReduceSum(float v) {
#pragma unroll
  for (int off = 32; off > 0; off >>= 1) v += __shfl_down(v, off, 64);
  return v;
}

template<int NW>
__device__ __forceinline__ float blockReduceSum(float v, float* sh) {
  v = waveReduceSum(v);
  int lane = threadIdx.x & 63, wid = threadIdx.x >> 6;
  if (lane == 0) sh[wid] = v;
  __syncthreads();
  float s = 0.f;
#pragma unroll
  for (int i = 0; i < NW; i++) s += sh[i];
  __syncthreads();
  return s;
}

// ---------------- merged weight cast f32 -> bf16 ----------------
struct CastSeg { const float* src; bf16* dst; int nval; int ntot; int blk0; };
struct CastArgs { CastSeg seg[8]; };

__global__ __launch_bounds__(256) void castw_all(CastArgs a) {
  int blk = blockIdx.x;
  int si = 0;
#pragma unroll
  for (int i = 1; i < 8; i++) if (blk >= a.seg[i].blk0) si = i;
  CastSeg s = a.seg[si];
  int i = ((blk - s.blk0) * 256 + threadIdx.x) * 4;
  if (i >= s.ntot) return;
  float4 v = {0.f, 0.f, 0.f, 0.f};
  if (i < s.nval) v = *(const float4*)(s.src + i);
  bf16x4 o;
  o[0] = (bf16)v.x; o[1] = (bf16)v.y; o[2] = (bf16)v.z; o[3] = (bf16)v.w;
  *(bf16x4*)(s.dst + i) = o;
}

// ---------------- rmsnorm (f32 in, bf16 out) ----------------
__global__ __launch_bounds__(256) void rmsnorm_k(const float* __restrict__ x,
                                                 const float* __restrict__ w,
                                                 bf16* __restrict__ y, int n) {
  __shared__ float sh[4];
  size_t row = blockIdx.x;
  const float* xr = x + row * n;
  bf16* yr = y + row * n;
  float ss = 0.f;
  for (int i = threadIdx.x; i < n; i += 256) { float v = xr[i]; ss += v * v; }
  ss = blockReduceSum<4>(ss, sh);
  float inv = rsqrtf(ss / n + 1e-5f);
  for (int i = threadIdx.x; i < n; i += 256) yr[i] = (bf16)(xr[i] * inv * w[i]);
}

// ---------------- generic bf16 MFMA GEMM: C = act(A @ W^T), 3-buf/1-barrier K-loop ----
// R7-verified schedule: per K-step {stage t+1 -> buf nxt; vmcnt(4); barrier; ds_read cur;
// setprio(1); 16 MFMA; setprio(0)}. LDS 48 KB -> 3 blocks/CU.
template<int ACT, typename OT>
__global__ __launch_bounds__(256) void gemm_mfma(const bf16* __restrict__ A,
                                                 const bf16* __restrict__ W,
                                                 const float* __restrict__ R,
                                                 OT* __restrict__ C,
                                                 int M, int N, int K) {
  __shared__ bf16 lds[3 * 8192];
  int tid = threadIdx.x, lane = tid & 63, wave = tid >> 6;
  int mt = M >> 7;
  int bid = blockIdx.x;
  int bm = (bid % mt) * 128, bn = (bid / mt) * 128;
  const bf16* gA0 = A + (size_t)(bm + wave * 32 + (lane >> 2)) * K + (lane & 3) * 8;
  const bf16* gA1 = gA0 + (size_t)16 * K;
  const bf16* gW0 = W + (size_t)(bn + wave * 32 + (lane >> 2)) * K + (lane & 3) * 8;
  const bf16* gW1 = gW0 + (size_t)16 * K;
  int sA = wave * 1024;
  int fr = lane & 15, fq = lane >> 4;
  int wm = wave >> 1, wn = wave & 1;
  int rdA = (wm * 64 + fr) * 32 + fq * 8;
  int rdW = (wn * 64 + fr) * 32 + fq * 8;
  f32x4 acc[4][4] = {};
  {
    bf16* bA = lds + sA;
    bf16* bW = lds + 4096 + sA;
    async_copy16(gA0, bA);  async_copy16(gA1, bA + 512);
    async_copy16(gW0, bW);  async_copy16(gW1, bW + 512);
  }
  int cur = 0, nxt = 1;
  int nsteps = K >> 5;
  for (int t = 0; t < nsteps; t++) {
    if (t + 1 < nsteps) {
      int off = (t + 1) * 32;
      bf16* bA = lds + nxt * 8192 + sA;
      bf16* bW = lds + nxt * 8192 + 4096 + sA;
      async_copy16(gA0 + off, bA);  async_copy16(gA1 + off, bA + 512);
      async_copy16(gW0 + off, bW);  async_copy16(gW1 + off, bW + 512);
      asm volatile("s_waitcnt vmcnt(4)" ::: "memory");
    } else {
      asm volatile("s_waitcnt vmcnt(0)" ::: "memory");
    }
    __builtin_amdgcn_sched_barrier(0);
    __builtin_amdgcn_s_barrier();
    __builtin_amdgcn_sched_barrier(0);
    const bf16* cA = lds + cur * 8192;
    const bf16* cW = cA + 4096;
    bf16x8 af[4], bfr[4];
#pragma unroll
    for (int mi = 0; mi < 4; mi++) af[mi] = *(const bf16x8*)(cA + rdA + mi * 512);
#pragma unroll
    for (int ni = 0; ni < 4; ni++) bfr[ni] = *(const bf16x8*)(cW + rdW + ni * 512);
    __builtin_amdgcn_s_setprio(1);
#pragma unroll
    for (int mi = 0; mi < 4; mi++)
#pragma unroll
      for (int ni = 0; ni < 4; ni++)
        acc[mi][ni] = __builtin_amdgcn_mfma_f32_16x16x32_bf16(af[mi], bfr[ni], acc[mi][ni], 0, 0, 0);
    __builtin_amdgcn_s_setprio(0);
    cur = nxt; nxt = nxt + 1; if (nxt == 3) nxt = 0;
  }
#pragma unroll
  for (int mi = 0; mi < 4; mi++) {
    int row = bm + wm * 64 + mi * 16 + fq * 4;
#pragma unroll
    for (int ni = 0; ni < 4; ni++) {
      int col = bn + wn * 64 + ni * 16 + fr;
      if (col < N) {
#pragma unroll
        for (int r = 0; r < 4; r++) {
          float v = acc[mi][ni][r];
          if (ACT == 1) v = v / (1.f + __expf(-v));
          if (R) v += R[(size_t)(row + r) * N + col];
          C[(size_t)(row + r) * N + col] = (OT)v;
        }
      }
    }
  }
}

// ---------------- split-K bf16 MFMA GEMM: P[ks] = A @ W^T, 3-buf/1-barrier K-loop ----
__global__ __launch_bounds__(256) void gemm_sk(const bf16* __restrict__ A,
                                               const bf16* __restrict__ W,
                                               bf16* __restrict__ P,
                                               int M, int N, int K, int kchunk) {
  __shared__ bf16 lds[3 * 8192];
  int tid = threadIdx.x, lane = tid & 63, wave = tid >> 6;
  int mt = M >> 7;
  int bid = blockIdx.x;
  int bm = (bid % mt) * 128, bn = (bid / mt) * 128;
  int ks = blockIdx.z;
  int kbeg = ks * kchunk;
  const bf16* gA0 = A + (size_t)(bm + wave * 32 + (lane >> 2)) * K + kbeg + (lane & 3) * 8;
  const bf16* gA1 = gA0 + (size_t)16 * K;
  const bf16* gW0 = W + (size_t)(bn + wave * 32 + (lane >> 2)) * K + kbeg + (lane & 3) * 8;
  const bf16* gW1 = gW0 + (size_t)16 * K;
  int sA = wave * 1024;
  int fr = lane & 15, fq = lane >> 4;
  int wm = wave >> 1, wn = wave & 1;
  int rdA = (wm * 64 + fr) * 32 + fq * 8;
  int rdW = (wn * 64 + fr) * 32 + fq * 8;
  f32x4 acc[4][4] = {};
  {
    bf16* bA = lds + sA;
    bf16* bW = lds + 4096 + sA;
    async_copy16(gA0, bA);  async_copy16(gA1, bA + 512);
    async_copy16(gW0, bW);  async_copy16(gW1, bW + 512);
  }
  int cur = 0, nxt = 1;
  int nsteps = kchunk >> 5;
  for (int t = 0; t < nsteps; t++) {
    if (t + 1 < nsteps) {
      int off = (t + 1) * 32;
      bf16* bA = lds + nxt * 8192 + sA;
      bf16* bW = lds + nxt * 8192 + 4096 + sA;
      async_copy16(gA0 + off, bA);  async_copy16(gA1 + off, bA + 512);
      async_copy16(gW0 + off, bW);  async_copy16(gW1 + off, bW + 512);
      asm volatile("s_waitcnt vmcnt(4)" ::: "memory");
    } else {
      asm volatile("s_waitcnt vmcnt(0)" ::: "memory");
    }
    __builtin_amdgcn_sched_barrier(0);
    __builtin_amdgcn_s_barrier();
    __builtin_amdgcn_sched_barrier(0);
    const bf16* cA = lds + cur * 8192;
    const bf16* cW = cA + 4096;
    bf16x8 af[4], bfr[4];
#pragma unroll
    for (int mi = 0; mi < 4; mi++) af[mi] = *(const bf16x8*)(cA + rdA + mi * 512);
#pragma unroll
    for (int ni = 0; ni < 4; ni++) bfr[ni] = *(const bf16x8*)(cW + rdW + ni * 512);
    __builtin_amdgcn_s_setprio(1);
#pragma unroll
    for (int mi = 0; mi < 4; mi++)
#pragma unroll
      for (int ni = 0; ni < 4; ni++)
        acc[mi][ni] = __builtin_amdgcn_mfma_f32_16x16x32_bf16(af[mi], bfr[ni], acc[mi][ni], 0, 0, 0);
    __builtin_amdgcn_s_setprio(0);
    cur = nxt; nxt = nxt + 1; if (nxt == 3) nxt = 0;
  }
  bf16* Pp = P + (size_t)ks * M * N;
#pragma unroll
  for (int mi = 0; mi < 4; mi++) {
    int row = bm + wm * 64 + mi * 16 + fq * 4;
#pragma unroll
    for (int ni = 0; ni < 4; ni++) {
      int col = bn + wn * 64 + ni * 16 + fr;
#pragma unroll
      for (int r = 0; r < 4; r++)
        Pp[(size_t)(row + r) * N + col] = (bf16)acc[mi][ni][r];
    }
  }
}

// ---------------- reduce 2 bf16 partials + residual + layernorm -> x_out f32, h bf16 ----------------
__global__ __launch_bounds__(256) void reduce_ln2(const bf16* __restrict__ p0,
                                                  const bf16* __restrict__ p1,
                                                  const float* __restrict__ res,
                                                  const float* __restrict__ w,
                                                  const float* __restrict__ b,
                                                  float* __restrict__ xo,
                                                  bf16* __restrict__ ho) {
  __shared__ float sh[4];
  size_t o = (size_t)blockIdx.x * 1024;
  int i = threadIdx.x * 4;
  bf16x4 a = *(const bf16x4*)(p0 + o + i);
  bf16x4 c = *(const bf16x4*)(p1 + o + i);
  f32x4 rv = *(const f32x4*)(res + o + i);
  f32x4 v;
  float s = 0.f, s2 = 0.f;
#pragma unroll
  for (int j = 0; j < 4; j++) {
    v[j] = (float)a[j] + (float)c[j] + rv[j];
    s += v[j]; s2 += v[j] * v[j];
  }
  s  = blockReduceSum<4>(s,  sh);
  s2 = blockReduceSum<4>(s2, sh);
  float mean = s / 1024.f;
  float var  = s2 / 1024.f - mean * mean;
  float inv  = rsqrtf(var + 1e-5f);
  f32x4 wv = *(const f32x4*)(w + i);
  f32x4 bv = *(const f32x4*)(b + i);
  *(f32x4*)(xo + o + i) = v;
  bf16x4 hv;
#pragma unroll
  for (int j = 0; j < 4; j++) hv[j] = (bf16)((v[j] - mean) * inv * wv[j] + bv[j]);
  *(bf16x4*)(ho + o + i) = hv;
}

// ---------------- reduce 3 bf16 partials + residual -> out f32 ----------------
__global__ __launch_bounds__(256) void reduce_out3(const bf16* __restrict__ p0,
                                                   const bf16* __restrict__ p1,
                                                   const bf16* __restrict__ p2,
                                                   const float* __restrict__ res,
                                                   float* __restrict__ out) {
  int i = (blockIdx.x * 256 + threadIdx.x) * 4;
  bf16x4 a = *(const bf16x4*)(p0 + i);
  bf16x4 c = *(const bf16x4*)(p1 + i);
  bf16x4 d = *(const bf16x4*)(p2 + i);
  f32x4 v = *(const f32x4*)(res + i);
#pragma unroll
  for (int j = 0; j < 4; j++) v[j] += (float)a[j] + (float)c[j] + (float)d[j];
  *(f32x4*)(out + i) = v;
}

// ---------------- reduce qkv bf16 partials + q/k rmsnorm + rope + gain -> bf16 ----------------
__global__ __launch_bounds__(256) void reduce_qkv(const bf16* __restrict__ P,
                                                  const float* __restrict__ q_gain,
                                                  bf16* __restrict__ q,
                                                  bf16* __restrict__ k,
                                                  bf16* __restrict__ v) {
  __shared__ float buf[1536];
  size_t row = blockIdx.x;
  size_t o = row * 1536;
  const bf16* p0 = P + o;
  const bf16* p1 = P + (size_t)ROWS * 1536 + o;
  int tid = threadIdx.x;
  for (int i = tid; i < 384; i += 256) {
    bf16x4 a = *(const bf16x4*)(p0 + i * 4);
    bf16x4 c = *(const bf16x4*)(p1 + i * 4);
    f32x4 vv;
#pragma unroll
    for (int j = 0; j < 4; j++) vv[j] = (float)a[j] + (float)c[j];
    *(f32x4*)(buf + i * 4) = vv;
  }
  __syncthreads();
  int lane = tid & 63, w = tid >> 6;
  int s = (int)(row & (S_ - 1));
  int ri = lane & 7;
  float rinv = __expf(-(float)ri * (0.125f * 9.210340371976184f)); // 10000^(-i/8)
  float ang = (float)s * rinv;
  float cs = cosf(ang), sn = sinf(ang);
#pragma unroll
  for (int j = 0; j < 6; j++) {
    int hh = w * 6 + j;
    float val = buf[hh * 64 + lane];
    if (hh < 20) {
      float ss = val * val;
#pragma unroll
      for (int off = 32; off > 0; off >>= 1) ss += __shfl_xor(ss, off, 64);
      val *= rsqrtf(ss / 64.f + 1.1920929e-7f);
      float other = __shfl_xor(val, 8, 64);
      float res = val;
      if (lane < RD) res = (lane < 8) ? (val * cs + other * sn) : (val * cs - other * sn);
      if (hh < 16) {
        res *= q_gain[hh];
        q[row * (HATT * HD) + hh * HD + lane] = (bf16)res;
      } else {
        k[row * (KVH * HD) + (hh - 16) * HD + lane] = (bf16)res;
      }
    } else {
      v[row * (KVH * HD) + (hh - 20) * HD + lane] = (bf16)val;
    }
  }
}

// ---------------- in_proj GEMM: R6-verified 3-buf/1-barrier core; light tail split-K=2 ----
// Heavy (bid<256): 256x256 tile, 96KB 3-buf rotation, 1-deep stage-before-vmcnt (R6: best).
// Light (bid>=256): 192 blocks = 96 tile-positions x 2 K-halves (K=512 each) writing bf16
// partials bcdtP[ks]; halves the serial tail (96-block K=1024 tail measured ~18us).
// Consumers (ssd_prep/bc_norm) sum the 2 partials.
__global__ __launch_bounds__(512, 2) void gemm256_inproj(const bf16* __restrict__ A,
                                                         const bf16* __restrict__ W,
                                                         bf16* __restrict__ zt,
                                                         bf16* __restrict__ xt,
                                                         bf16* __restrict__ bcdtP) {
  __shared__ bf16 lds[3 * 16384];          // 96 KB
  int tid = threadIdx.x;
  int lane = tid & 63, w = tid >> 6;       // 8 waves
  int fr = lane & 15, fq = lane >> 4;
  int rdswz = (fq ^ (fr & 3)) * 8;         // swizzled read offset
  int sswz = (lane & 3) ^ ((lane >> 2) & 3);   // inverse swizzle on global source
  int bid = blockIdx.x;
  if (bid < 256) {
    int sb = (bid & 7) * 32 + (bid >> 3);  // XCD swizzle (256 = 8*32, bijective)
    int bm = (sb & 15) * 256;
    int bn = (sb >> 4) * 256;
    int wm = w >> 2, wn = w & 3;           // 2M x 4N waves: per wave 128x64
    int srow = w * 32 + (lane >> 2);
    const bf16* gA = A + (size_t)(bm + srow) * 1024 + sswz * 8;
    const bf16* gW = W + (size_t)(bn + srow) * 1024 + sswz * 8;
    int sbase = w * 1024;
    f32x4 acc[8][4] = {};
    {
      bf16* bA = lds + sbase;
      bf16* bB = lds + 8192 + sbase;
      async_copy16(gA, bA);
      async_copy16(gA + 16 * 1024, bA + 512);
      async_copy16(gW, bB);
      async_copy16(gW + 16 * 1024, bB + 512);
    }
    int cur = 0, nxt = 1;
    for (int t = 0; t < 32; t++) {
      if (t + 1 < 32) {
        const bf16* ga = gA + (t + 1) * 32;
        const bf16* gw = gW + (t + 1) * 32;
        bf16* bA = lds + nxt * 16384 + sbase;
        bf16* bB = lds + nxt * 16384 + 8192 + sbase;
        async_copy16(ga, bA);
        async_copy16(ga + 16 * 1024, bA + 512);
        async_copy16(gw, bB);
        async_copy16(gw + 16 * 1024, bB + 512);
        asm volatile("s_waitcnt vmcnt(4)" ::: "memory");
      } else {
        asm volatile("s_waitcnt vmcnt(0)" ::: "memory");
      }
      __builtin_amdgcn_sched_barrier(0);
      __builtin_amdgcn_s_barrier();
      __builtin_amdgcn_sched_barrier(0);
      const bf16* cA = lds + cur * 16384;
      const bf16* cB = cA + 8192;
      bf16x8 af[8], bfv[4];
#pragma unroll
      for (int mi = 0; mi < 8; mi++)
        af[mi] = *(const bf16x8*)(cA + (wm * 128 + mi * 16 + fr) * 32 + rdswz);
#pragma unroll
      for (int ni = 0; ni < 4; ni++)
        bfv[ni] = *(const bf16x8*)(cB + (wn * 64 + ni * 16 + fr) * 32 + rdswz);
      __builtin_amdgcn_s_setprio(1);
#pragma unroll
      for (int mi = 0; mi < 8; mi++)
#pragma unroll
        for (int ni = 0; ni < 4; ni++)
          acc[mi][ni] = __builtin_amdgcn_mfma_f32_16x16x32_bf16(af[mi], bfv[ni], acc[mi][ni], 0, 0, 0);
      __builtin_amdgcn_s_setprio(0);
      cur = nxt; nxt = nxt + 1; if (nxt == 3) nxt = 0;
    }
    // epilogue: LDS-transposed coalesced Zt/Xt stores
    bf16* base = (bn < 2048) ? zt : xt;
    int bq = bm >> 11, bmS = bm & 2047;
    bf16* Ts = lds;
#pragma unroll 1
    for (int g = 0; g < 4; g++) {
      __syncthreads();
      if (wn == g) {
#pragma unroll
        for (int mi = 0; mi < 8; mi++)
#pragma unroll
          for (int ni = 0; ni < 4; ni++) {
            bf16x4 o;
#pragma unroll
            for (int r = 0; r < 4; r++) o[r] = (bf16)acc[mi][ni][r];
            *(bf16x4*)(Ts + (ni * 16 + fr) * 264 + wm * 128 + mi * 16 + fq * 4) = o;
          }
      }
      __syncthreads();
      int hh = ((bn & 2047) + g * 64) >> 6;
      bf16* dst = base + ((size_t)(bq * NH + hh) * HD) * S_ + bmS;
#pragma unroll
      for (int i = 0; i < 4; i++) {
        int idx = tid + i * 512;
        int p = idx >> 5, sc = (idx & 31) * 8;
        *(bf16x8*)(dst + (size_t)p * S_ + sc) = *(const bf16x8*)(Ts + p * 264 + sc);
      }
    }
  } else {
    // ---- light path: 192 blocks = 96 positions x 2 K-halves over bcdt cols ----
    int lb = bid - 256;
    int ks = lb / 96;                      // K-half
    int pos = lb - ks * 96;
    int bm = (pos & 31) * 128;
    int bn = 4096 + (pos >> 5) * 128;
    int kbeg = ks * 512;
    int wm = w >> 1, wn = w & 1;           // 4M x 2N waves: per wave 32x64
    int srow = w * 16 + (lane >> 2);
    const bf16* gA = A + (size_t)(bm + srow) * 1024 + kbeg + sswz * 8;
    const bf16* gW = W + (size_t)(bn + srow) * 1024 + kbeg + sswz * 8;
    int sbase = w * 512;
    f32x4 acc[2][4] = {};
    {
      async_copy16(gA, lds + sbase);
      async_copy16(gW, lds + 4096 + sbase);
    }
    int cur = 0, nxt = 1;
    for (int t = 0; t < 16; t++) {
      if (t + 1 < 16) {
        async_copy16(gA + (t + 1) * 32, lds + nxt * 8192 + sbase);
        async_copy16(gW + (t + 1) * 32, lds + nxt * 8192 + 4096 + sbase);
        asm volatile("s_waitcnt vmcnt(2)" ::: "memory");
      } else {
        asm volatile("s_waitcnt vmcnt(0)" ::: "memory");
      }
      __builtin_amdgcn_sched_barrier(0);
      __builtin_amdgcn_s_barrier();
      __builtin_amdgcn_sched_barrier(0);
      const bf16* cA = lds + cur * 8192;
      const bf16* cB = cA + 4096;
      bf16x8 af[2], bfv[4];
#pragma unroll
      for (int mi = 0; mi < 2; mi++)
        af[mi] = *(const bf16x8*)(cA + (wm * 32 + mi * 16 + fr) * 32 + rdswz);
#pragma unroll
      for (int ni = 0; ni < 4; ni++)
        bfv[ni] = *(const bf16x8*)(cB + (wn * 64 + ni * 16 + fr) * 32 + rdswz);
#pragma unroll
      for (int mi = 0; mi < 2; mi++)
#pragma unroll
        for (int ni = 0; ni < 4; ni++)
          acc[mi][ni] = __builtin_amdgcn_mfma_f32_16x16x32_bf16(af[mi], bfv[ni], acc[mi][ni], 0, 0, 0);
      cur = nxt; nxt = nxt + 1; if (nxt == 3) nxt = 0;
    }
    bf16* dst = bcdtP + (size_t)ks * PSB;
#pragma unroll
    for (int mi = 0; mi < 2; mi++) {
      int row = bm + wm * 32 + mi * 16 + fq * 4;
#pragma unroll
      for (int ni = 0; ni < 4; ni++) {
        int col = bn + wn * 64 + ni * 16 + fr;
        if (col < 4384) {
#pragma unroll
          for (int r = 0; r < 4; r++)
            dst[(size_t)(row + r) * 288 + (col - 4096)] = (bf16)acc[mi][ni][r];
        }
      }
    }
  }
}

// ---------------- generic 64x64 tiled transpose (bf16), out row stride 2048 ----------------
__global__ __launch_bounds__(256) void t64(const bf16* __restrict__ in, bf16* __restrict__ out,
                                           int istr, size_t io, size_t oo, int n_nt) {
  __shared__ bf16 T[64 * 72];
  int bid = blockIdx.x;
  int st = bid & 31;
  int nt = (bid >> 5) % n_nt;
  int outer = bid / (32 * n_nt);
  const bf16* ip = in + outer * io + (size_t)st * 64 * istr + nt * 64;
  int tid = threadIdx.x;
#pragma unroll
  for (int i = 0; i < 2; i++) {
    int cid = tid + i * 256; int s = cid >> 3, pc = (cid & 7) * 8;
    *(bf16x8*)(T + s * 72 + pc) = *(const bf16x8*)(ip + (size_t)s * istr + pc);
  }
  __syncthreads();
  bf16* op = out + outer * oo + (size_t)nt * 64 * 2048 + st * 64;
#pragma unroll
  for (int i = 0; i < 2; i++) {
    int cid = tid + i * 256; int p = cid >> 3, sc = (cid & 7) * 8;
    bf16x8 o;
#pragma unroll
    for (int j = 0; j < 8; j++) o[j] = T[(sc + j) * 72 + p];
    *(bf16x8*)(op + (size_t)p * 2048 + sc) = o;
  }
}

// ---------------- SSD prep: dt softplus, per-chunk cumsum, decay factors (2 bcdt partials) --
__global__ __launch_bounds__(64) void ssd_prep(const bf16* __restrict__ bcdtP,
                                               const float* __restrict__ dt_bias,
                                               const float* __restrict__ A_log,
                                               float* __restrict__ dt_c,
                                               float* __restrict__ ddc,
                                               float* __restrict__ ac_c,
                                               float* __restrict__ T_out) {
  int bid = blockIdx.x;
  int c = bid % NC, hh = (bid / NC) % NH, b = bid / (NC * NH);
  int l = threadIdx.x;
  size_t row = (size_t)b * S_ + c * 64 + l;
  float raw = (float)bcdtP[row * 288 + 256 + hh]
            + (float)bcdtP[(size_t)PSB + row * 288 + 256 + hh] + dt_bias[hh];
  float dtv = (raw > 20.f) ? raw : log1pf(__expf(raw));
  float a = -__expf(A_log[hh]) * dtv;
  float ps = a;
#pragma unroll
  for (int off = 1; off < 64; off <<= 1) {
    float t = __shfl_up(ps, off, 64);
    if (l >= off) ps += t;
  }
  float a63 = __shfl(ps, 63, 64);
  size_t o = ((size_t)b * NH + hh) * S_ + c * 64 + l;
  dt_c[o] = dtv;
  ac_c[o] = ps;
  ddc[o] = __expf(a63 - ps) * dtv;
  if (l == 63) T_out[(b * NH + hh) * NC + c] = ps;
}

// ---------------- B/C rmsnorm (bf16 out, 2 bcdt partials) ----------------
__global__ __launch_bounds__(128) void bc_norm(const bf16* __restrict__ bcdtP,
                                               const float* __restrict__ Bw,
                                               const float* __restrict__ Cw,
                                               bf16* __restrict__ Bn,
                                               bf16* __restrict__ Cn) {
  __shared__ float shb[2], shc[2];
  size_t row = blockIdx.x;
  int i = threadIdx.x;
  float bv = (float)bcdtP[row * 288 + i] + (float)bcdtP[(size_t)PSB + row * 288 + i];
  float cv = (float)bcdtP[row * 288 + 128 + i] + (float)bcdtP[(size_t)PSB + row * 288 + 128 + i];
  float sb = waveReduceSum(bv * bv);
  float sc = waveReduceSum(cv * cv);
  int lane = threadIdx.x & 63, wid = threadIdx.x >> 6;
  if (lane == 0) { shb[wid] = sb; shc[wid] = sc; }
  __syncthreads();
  float tb = shb[0] + shb[1];
  float tc = shc[0] + shc[1];
  Bn[row * DS + i] = (bf16)(bv * rsqrtf(tb / DS + 1e-5f) * Bw[i]);
  Cn[row * DS + i] = (bf16)(cv * rsqrtf(tc / DS + 1e-5f) * Cw[i]);
}

// ---------------- chunk states via MFMA (bf16 output) ----------------
__global__ __launch_bounds__(256) void ssd_states(const bf16* __restrict__ Xt,
                                                  const bf16* __restrict__ Btr,
                                                  const float* __restrict__ ddc,
                                                  bf16* __restrict__ states) {
  __shared__ bf16 Xs[64 * 72];    // [p][s]
  __shared__ bf16 Bs[128 * 72];   // [n][s]
  int bid = blockIdx.x;           // (b*NC + c)*NH + h
  int h = bid % NH;
  int c = (bid / NH) % NC;
  int b = bid / (NH * NC);
  int tid = threadIdx.x, lane = tid & 63, w = tid >> 6;
  int fr = lane & 15, fq = lane >> 4;
  const size_t xbase = (size_t)(b * NH + h) * HD * S_ + c * 64;
  const size_t dbase = (size_t)(b * NH + h) * S_ + c * 64;
#pragma unroll
  for (int i = 0; i < 2; i++) {
    int cid = tid + i * 256; int p = cid >> 3, sc = (cid & 7) * 8;
    bf16x8 xv = *(const bf16x8*)(Xt + xbase + (size_t)p * S_ + sc);
    f32x4 d0 = *(const f32x4*)(ddc + dbase + sc);
    f32x4 d1 = *(const f32x4*)(ddc + dbase + sc + 4);
    bf16x8 o;
#pragma unroll
    for (int j = 0; j < 4; j++) { o[j] = (bf16)((float)xv[j] * d0[j]); o[4 + j] = (bf16)((float)xv[4 + j] * d1[j]); }
    *(bf16x8*)(Xs + p * 72 + sc) = o;
  }
  const size_t bbase = (size_t)b * 128 * S_ + c * 64;
#pragma unroll
  for (int i = 0; i < 4; i++) {
    int cid = tid + i * 256; int n = cid >> 3, sc = (cid & 7) * 8;
    *(bf16x8*)(Bs + n * 72 + sc) = *(const bf16x8*)(Btr + bbase + (size_t)n * S_ + sc);
  }
  __syncthreads();
  f32x4 acc[4][2] = {};
#pragma unroll
  for (int ks = 0; ks < 2; ks++) {
    bf16x8 a[4], bb[2];
#pragma unroll
    for (int pt = 0; pt < 4; pt++) a[pt] = *(const bf16x8*)(Xs + (pt * 16 + fr) * 72 + ks * 32 + fq * 8);
#pragma unroll
    for (int n2 = 0; n2 < 2; n2++) bb[n2] = *(const bf16x8*)(Bs + ((2 * w + n2) * 16 + fr) * 72 + ks * 32 + fq * 8);
#pragma unroll
    for (int pt = 0; pt < 4; pt++)
#pragma unroll
      for (int n2 = 0; n2 < 2; n2++)
        acc[pt][n2] = __builtin_amdgcn_mfma_f32_16x16x32_bf16(a[pt], bb[n2], acc[pt][n2], 0, 0, 0);
  }
  bf16* outp = states + (size_t)bid * 8192;
#pragma unroll
  for (int pt = 0; pt < 4; pt++)
#pragma unroll
    for (int n2 = 0; n2 < 2; n2++) {
      int n = (2 * w + n2) * 16 + fr;
#pragma unroll
      for (int r = 0; r < 4; r++)
        outp[(size_t)(pt * 16 + fq * 4 + r) * 128 + n] = (bf16)acc[pt][n2][r];
    }
}

// ---------------- inter-chunk scan (in place, bf16 storage, f32 math) ----------------
__global__ __launch_bounds__(256) void ssd_scan(bf16* __restrict__ states,
                                                const float* __restrict__ T) {
  __shared__ float eT[NC];
  int part = blockIdx.x & 7;
  int bh = blockIdx.x >> 3;
  int b = bh / NH, h = bh % NH;
  if (threadIdx.x < NC) eT[threadIdx.x] = __expf(T[(size_t)(b * NH + h) * NC + threadIdx.x]);
  __syncthreads();
  const size_t cstride = (size_t)NH * HD * DS;
  size_t base = ((size_t)b * NC * NH + h) * (HD * DS);
#pragma unroll
  for (int j = 0; j < 4; j++) {
    int e = part * 1024 + threadIdx.x + j * 256;
    float carry = 0.f;
    size_t idx = base + e;
    for (int c = 0; c < NC; c++) {
      float sv = (float)states[idx];
      states[idx] = (bf16)carry;
      carry = sv + eT[c] * carry;
      idx += cstride;
    }
  }
}

// ---------------- fused SSD output: Ydiag + Yoff + D-skip + gate (all MFMA) ----------------
__global__ __launch_bounds__(256) void ssd_out(const bf16* __restrict__ Cn,
                                               const bf16* __restrict__ Bn,
                                               const bf16* __restrict__ Xt,
                                               const bf16* __restrict__ Zt,
                                               const float* __restrict__ dt_c,
                                               const float* __restrict__ ac_c,
                                               const bf16* __restrict__ states,
                                               const float* __restrict__ Dp,
                                               bf16* __restrict__ ybf) {
  __shared__ bf16 Cs[64 * 136];
  __shared__ bf16 BNs[64 * 136];
  __shared__ bf16 Xs[64 * 72];
  __shared__ bf16 G[64 * 72];
  __shared__ float acs[64];
  int bid = blockIdx.x;
  int h = bid % NH;
  int c = (bid / NH) % NC;
  int b = bid / (NH * NC);
  int tid = threadIdx.x, lane = tid & 63, w = tid >> 6;
  int fr = lane & 15, fq = lane >> 4;
  size_t row0 = (size_t)b * S_ + c * 64;
  const size_t abase = (size_t)(b * NH + h) * S_ + c * 64;
  if (tid < 64) acs[tid] = ac_c[abase + tid];
#pragma unroll
  for (int i = 0; i < 4; i++) {
    int cid = tid + i * 256; int l = cid >> 4, nc = (cid & 15) * 8;
    float e = __expf(ac_c[abase + l]);
    bf16x8 cv = *(const bf16x8*)(Cn + (row0 + l) * DS + nc);
    bf16x8 o;
#pragma unroll
    for (int j = 0; j < 8; j++) o[j] = (bf16)((float)cv[j] * e);
    *(bf16x8*)(Cs + l * 136 + nc) = o;
    *(bf16x8*)(BNs + l * 136 + nc) = *(const bf16x8*)(Bn + (row0 + l) * DS + nc);
  }
  const size_t xbase = (size_t)(b * NH + h) * HD * S_ + c * 64;
#pragma unroll
  for (int i = 0; i < 2; i++) {
    int cid = tid + i * 256; int p = cid >> 3, sc = (cid & 7) * 8;
    bf16x8 xv = *(const bf16x8*)(Xt + xbase + (size_t)p * S_ + sc);
    f32x4 d0 = *(const f32x4*)(dt_c + abase + sc);
    f32x4 d1 = *(const f32x4*)(dt_c + abase + sc + 4);
    bf16x8 o;
#pragma unroll
    for (int j = 0; j < 4; j++) { o[j] = (bf16)((float)xv[j] * d0[j]); o[4 + j] = (bf16)((float)xv[4 + j] * d1[j]); }
    *(bf16x8*)(Xs + p * 72 + sc) = o;
  }
  __syncthreads();
  bf16x8 ca[4];
#pragma unroll
  for (int ks = 0; ks < 4; ks++) ca[ks] = *(const bf16x8*)(Cs + (w * 16 + fr) * 136 + ks * 32 + fq * 8);
  f32x4 cb[4] = {};
  for (int st = 0; st <= w; st++)
#pragma unroll
    for (int ks = 0; ks < 4; ks++)
      cb[st] = __builtin_amdgcn_mfma_f32_16x16x32_bf16(ca[ks],
                 *(const bf16x8*)(BNs + (st * 16 + fr) * 136 + ks * 32 + fq * 8), cb[st], 0, 0, 0);
#pragma unroll
  for (int st = 0; st < 4; st++) {
    float es = (st <= w) ? __expf(-acs[st * 16 + fr]) : 0.f;
#pragma unroll
    for (int r = 0; r < 4; r++) {
      int lloc = fq * 4 + r;
      float g = 0.f;
      if (st < w) g = cb[st][r] * es;
      else if (st == w) g = (lloc >= fr) ? cb[st][r] * es : 0.f;
      G[(w * 16 + lloc) * 72 + st * 16 + fr] = (bf16)g;
    }
  }
  f32x4 acc[4] = {};
  {
    bf16x8 ga0 = *(const bf16x8*)(G + (w * 16 + fr) * 72 + fq * 8);
    bf16x8 ga1 = *(const bf16x8*)(G + (w * 16 + fr) * 72 + 32 + fq * 8);
#pragma unroll
    for (int pt = 0; pt < 4; pt++) {
      acc[pt] = __builtin_amdgcn_mfma_f32_16x16x32_bf16(ga0,
                  *(const bf16x8*)(Xs + (pt * 16 + fr) * 72 + fq * 8), acc[pt], 0, 0, 0);
      acc[pt] = __builtin_amdgcn_mfma_f32_16x16x32_bf16(ga1,
                  *(const bf16x8*)(Xs + (pt * 16 + fr) * 72 + 32 + fq * 8), acc[pt], 0, 0, 0);
    }
  }
  __syncthreads();
  const bf16* stp = states + (size_t)bid * 8192;
#pragma unroll
  for (int i = 0; i < 4; i++) {
    int cid = tid + i * 256; int p = cid >> 4, nc = (cid & 15) * 8;
    *(bf16x8*)(BNs + p * 136 + nc) = *(const bf16x8*)(stp + (size_t)p * 128 + nc);
  }
  __syncthreads();
#pragma unroll
  for (int pt = 0; pt < 4; pt++)
#pragma unroll
    for (int ks = 0; ks < 4; ks++)
      acc[pt] = __builtin_amdgcn_mfma_f32_16x16x32_bf16(ca[ks],
                  *(const bf16x8*)(BNs + (pt * 16 + fr) * 136 + ks * 32 + fq * 8), acc[pt], 0, 0, 0);
  float dph = Dp[h];
#pragma unroll
  for (int pt = 0; pt < 4; pt++) {
    int p = pt * 16 + fr;
    size_t tb = (xbase + (size_t)p * S_) + w * 16 + fq * 4;
    bf16x4 xs4 = *(const bf16x4*)(Xt + tb);
    bf16x4 z4  = *(const bf16x4*)(Zt + tb);
#pragma unroll
    for (int r = 0; r < 4; r++) {
      int l = w * 16 + fq * 4 + r;
      float yv = acc[pt][r] + (float)xs4[r] * dph;
      float z = (float)z4[r];
      yv *= z / (1.f + __expf(-z));
      ybf[((row0 + l) * NH + h) * HD + p] = (bf16)yv;
    }
  }
}

// ---------------- split-S MFMA flash attention (fixed-max softmax -> partials sum) ----------------
#define KSTR 72
#define PSTR 72
__global__ __launch_bounds__(256) void attn_mfma(const bf16* __restrict__ q,
                                                 const bf16* __restrict__ k,
                                                 const bf16* __restrict__ vtr,
                                                 bf16* __restrict__ Po,
                                                 float* __restrict__ Ls) {
  __shared__ bf16 Ks[64 * KSTR];
  __shared__ bf16 Vs[64 * KSTR];
  __shared__ bf16 Pl[4][32 * PSTR];
  int c = 39 - blockIdx.x;                 // full 8-iter chunks first
  int g = (c < 4) ? 0 : (c < 12) ? 1 : (c < 24) ? 2 : 3;
  int gbase = (g == 0) ? 0 : (g == 1) ? 4 : (g == 2) ? 12 : 24;
  int d = c - gbase;
  int qt = 4 * g + d / (g + 1);
  int sk = d % (g + 1);
  int h = blockIdx.y, b = blockIdx.z;
  int kvh = h >> 2;
  int tid = threadIdx.x, lane = tid & 63, w = tid >> 6;
  int fr = lane & 15, fq = lane >> 4;
  const float SC = 0.18033688011112042f;   // 0.125 * log2(e)
  const float M2 = 62.0f;
  int kt0 = sk * 8;
  int ktend = min(kt0 + 8, 2 * qt + 2);
  int qbase = qt * 128 + w * 32;           // wave's first q row
  int qmaxw = qbase + 31;
  bf16x8 bq[2][2];
#pragma unroll
  for (int qc = 0; qc < 2; qc++)
#pragma unroll
    for (int ks = 0; ks < 2; ks++)
      bq[qc][ks] = *(const bf16x8*)(q + (size_t)(b * S_ + qbase + qc * 16 + fr) * (HATT * HD)
                                      + h * HD + ks * 32 + fq * 8);
  int sr = tid >> 3, sc8 = (tid & 7) * 8;
  const bf16* kg = k + ((size_t)(b * S_) + sr) * (KVH * HD) + kvh * HD + sc8;
  const bf16* vg = vtr + ((size_t)(b * KVH + kvh) * HD + sr) * S_ + sc8;
  bf16x8 krg0, krg1, vrg0, vrg1;
  {
    const bf16* kp = kg + (size_t)kt0 * 64 * (KVH * HD);
    const bf16* vp = vg + (size_t)kt0 * 64;
    krg0 = *(const bf16x8*)(kp);
    krg1 = *(const bf16x8*)(kp + (size_t)32 * (KVH * HD));
    vrg0 = *(const bf16x8*)(vp);
    vrg1 = *(const bf16x8*)(vp + (size_t)32 * S_);
  }
  float lsum[2] = {0.f, 0.f};
  f32x4 yacc[2][4] = {};
  bf16* Plw = Pl[w];
  for (int kt = kt0; kt < ktend; kt++) {
    __syncthreads();   // previous iteration's LDS reads complete
    *(bf16x8*)(&Ks[sr * KSTR + sc8]) = krg0;
    *(bf16x8*)(&Ks[(sr + 32) * KSTR + sc8]) = krg1;
    *(bf16x8*)(&Vs[sr * KSTR + sc8]) = vrg0;
    *(bf16x8*)(&Vs[(sr + 32) * KSTR + sc8]) = vrg1;
    __syncthreads();   // tile visible
    if ((kt + 1) < ktend) {
      const bf16* kp = kg + (size_t)(kt + 1) * 64 * (KVH * HD);
      const bf16* vp = vg + (size_t)(kt + 1) * 64;
      krg0 = *(const bf16x8*)(kp);
      krg1 = *(const bf16x8*)(kp + (size_t)32 * (KVH * HD));
      vrg0 = *(const bf16x8*)(vp);
      vrg1 = *(const bf16x8*)(vp + (size_t)32 * S_);
    }
    if (kt * 64 <= qmaxw) {
      bool nomask = (kt * 64 + 63) <= qbase;
      if (nomask) {
#pragma unroll
        for (int mi = 0; mi < 4; mi++) {
          const bf16* krow = &Ks[(mi * 16 + fr) * KSTR];
          bf16x8 ak0 = *(const bf16x8*)(krow + fq * 8);
          bf16x8 ak1 = *(const bf16x8*)(krow + 32 + fq * 8);
#pragma unroll
          for (int qc = 0; qc < 2; qc++) {
            f32x4 s = {};
            s = __builtin_amdgcn_mfma_f32_16x16x32_bf16(ak0, bq[qc][0], s, 0, 0, 0);
            s = __builtin_amdgcn_mfma_f32_16x16x32_bf16(ak1, bq[qc][1], s, 0, 0, 0);
            bf16x4 pk;
#pragma unroll
            for (int r = 0; r < 4; r++) {
              float p = __builtin_amdgcn_exp2f(s[r] * SC - M2);
              lsum[qc] += p;
              pk[r] = (bf16)p;
            }
            *(bf16x4*)(Plw + (qc * 16 + fr) * PSTR + mi * 16 + fq * 4) = pk;
          }
        }
      } else {
#pragma unroll
        for (int mi = 0; mi < 4; mi++) {
          int s0 = kt * 64 + mi * 16;
          if (s0 > qmaxw) {
            bf16x4 zz = {};
#pragma unroll
            for (int qc = 0; qc < 2; qc++)
              *(bf16x4*)(Plw + (qc * 16 + fr) * PSTR + mi * 16 + fq * 4) = zz;
          } else {
            const bf16* krow = &Ks[(mi * 16 + fr) * KSTR];
            bf16x8 ak0 = *(const bf16x8*)(krow + fq * 8);
            bf16x8 ak1 = *(const bf16x8*)(krow + 32 + fq * 8);
#pragma unroll
            for (int qc = 0; qc < 2; qc++) {
              f32x4 s = {};
              s = __builtin_amdgcn_mfma_f32_16x16x32_bf16(ak0, bq[qc][0], s, 0, 0, 0);
              s = __builtin_amdgcn_mfma_f32_16x16x32_bf16(ak1, bq[qc][1], s, 0, 0, 0);
              int qq = qbase + qc * 16 + fr;
              bf16x4 pk;
#pragma unroll
              for (int r = 0; r < 4; r++) {
                int sp = s0 + fq * 4 + r;
                float p = (sp <= qq) ? __builtin_amdgcn_exp2f(s[r] * SC - M2) : 0.f;
                lsum[qc] += p;
                pk[r] = (bf16)p;
              }
              *(bf16x4*)(Plw + (qc * 16 + fr) * PSTR + mi * 16 + fq * 4) = pk;
            }
          }
        }
      }
#pragma unroll
      for (int ks2 = 0; ks2 < 2; ks2++) {
        bf16x8 bp[2];
#pragma unroll
        for (int qc = 0; qc < 2; qc++)
          bp[qc] = *(const bf16x8*)(Plw + (qc * 16 + fr) * PSTR + ks2 * 32 + fq * 8);
#pragma unroll
        for (int pi = 0; pi < 4; pi++) {
          bf16x8 av = *(const bf16x8*)(&Vs[(pi * 16 + fr) * KSTR + ks2 * 32 + fq * 8]);
#pragma unroll
          for (int qc = 0; qc < 2; qc++)
            yacc[qc][pi] = __builtin_amdgcn_mfma_f32_16x16x32_bf16(av, bp[qc], yacc[qc][pi], 0, 0, 0);
        }
      }
    }
  }
#pragma unroll
  for (int qc = 0; qc < 2; qc++) {
    lsum[qc] += __shfl_xor(lsum[qc], 16, 64);
    lsum[qc] += __shfl_xor(lsum[qc], 32, 64);
    int qrow = qt * 128 + w * 32 + qc * 16 + fr;
    if (fq == 0)
      Ls[((size_t)(b * 16 + h) * 2048 + qrow) * 4 + sk] = lsum[qc];
    bf16* pop = Po + ((((size_t)(b * 16 + h) * 16 + qt) * 4 + sk) * 128
                       + w * 32 + qc * 16 + fr) * 64 + fq * 4;
#pragma unroll
    for (int pi = 0; pi < 4; pi++) {
      bf16x4 o;
#pragma unroll
      for (int r = 0; r < 4; r++) o[r] = (bf16)yacc[qc][pi][r];
      *(bf16x4*)(pop + pi * 16) = o;
    }
  }
}

// ---------------- attention partial combine + normalize -> y2 bf16 ----------------
__global__ __launch_bounds__(256) void attn_red(const bf16* __restrict__ Po,
                                                const float* __restrict__ Ls,
                                                bf16* __restrict__ y2) {
  int row = blockIdx.x;            // 0..4095
  int b = row >> 11;
  int qrow = row & 2047;
  int qt = qrow >> 7, r = qrow & 127;
  int nch = (qt >> 2) + 1;
  int t = threadIdx.x;
  int h = t >> 4, e4 = (t & 15) << 2;
  const float* lp = Ls + ((size_t)(b * 16 + h) * 2048 + qrow) * 4;
  float ls = 0.f;
  f32x4 acc = {};
  for (int sk = 0; sk < nch; sk++) {
    ls += lp[sk];
    const bf16* pp = Po + ((((size_t)(b * 16 + h) * 16 + qt) * 4 + sk) * 128 + r) * 64 + e4;
    bf16x4 v = *(const bf16x4*)(pp);
#pragma unroll
    for (int j = 0; j < 4; j++) acc[j] += (float)v[j];
  }
  float inv = 1.f / ls;
  bf16x4 o;
#pragma unroll
  for (int j = 0; j < 4; j++) o[j] = (bf16)(acc[j] * inv);
  *(bf16x4*)(y2 + (size_t)row * 1024 + h * 64 + e4) = o;
}

// ---------------- workspace layout (byte offsets) ----------------
constexpr size_t OFF_WIN  = 0;                   // bf16 4480x1024
constexpr size_t OFF_WOUT = 9175040;             // bf16 1024x2048
constexpr size_t OFF_WQKV = 13369344;            // bf16 1536x1024 (q|k|v rows)
constexpr size_t OFF_WCP  = 16515072;            // bf16 1024x1024
constexpr size_t OFF_WFC  = 18612224;            // bf16 3072x1024
constexpr size_t OFF_WPR  = 24903680;            // bf16 1024x3072
constexpr size_t OFF_HBF  = 31195136;            // bf16 4096x1024
constexpr size_t OFF_BCDT = 39583744;            // (legacy region; reused: Ls f32)
constexpr size_t OFF_XT   = 41943040;            // bf16 [b][h][p][sg] (16.7 MB)
constexpr size_t OFF_ZT   = 58720256;            // bf16 [b][h][p][sg] (16.7 MB)
constexpr size_t OFF_DTC  = 75497472;            // f32 [b][h][sg]
constexpr size_t OFF_DDC  = 76546048;            // f32
constexpr size_t OFF_ACC  = 77594624;            // f32
constexpr size_t OFF_T    = 78643200;            // f32 2048
constexpr size_t OFF_BN   = 78651392;            // bf16 4096x128
constexpr size_t OFF_CN   = 79699968;            // bf16 4096x128
constexpr size_t OFF_BTR  = 80748544;            // bf16 [b][n][sg]
constexpr size_t OFF_ST   = 81797120;            // bf16 states (33.5 MB); early: bcdtP (4.7MB,
                                                 //   last read bc_norm, overwritten by ssd_states)
constexpr size_t OFF_YBF  = 148905984;           // bf16 4096x2048
constexpr size_t OFF_X1   = 165683200;           // f32 4096x1024 (end 182,460,416)
// phase-2 aliases
constexpr size_t OFF_P    = OFF_ST;              // bf16 split-K partials (<= 25.2 MB)
constexpr size_t OFF_PO   = OFF_ST;              // bf16 attn partials [b][h][qt][4][128][64] = 32 MiB
constexpr size_t OFF_LS   = OFF_BCDT;            // f32 attn lsums [b][h][2048][4] = 1 MiB
constexpr size_t OFF_QB   = OFF_XT;              // bf16 4096x1024 (8.4 MB)
constexpr size_t OFF_KB   = OFF_XT + 8388608;    // bf16 4096x256
constexpr size_t OFF_VB   = OFF_XT + 10485760;   // bf16 4096x256
constexpr size_t OFF_VTR  = OFF_XT + 12582912;   // bf16 [b][kvh][p][sg]
constexpr size_t OFF_Y2   = OFF_ZT;              // bf16 4096x1024
constexpr size_t OFF_X2   = 50331648;            // f32 4096x1024 (over dead kb/vb/vtr/y2)
constexpr size_t OFF_MLP  = 132128768;           // bf16 4096x3072 (over dead regions)

extern "C" void kernel_launch(void* const* d_in, const int* in_sizes, int n_in,
                              void* d_out, int out_size, void* d_ws, size_t ws_size,
                              hipStream_t stream) {
  (void)in_sizes; (void)n_in; (void)out_size; (void)ws_size;
  const float* x        = (const float*)d_in[0];
  const float* mnorm_w  = (const float*)d_in[1];
  const float* in_w     = (const float*)d_in[2];
  const float* out_w    = (const float*)d_in[3];
  const float* Dp       = (const float*)d_in[4];
  const float* dt_bias  = (const float*)d_in[5];
  const float* A_log    = (const float*)d_in[6];
  const float* Bn_w     = (const float*)d_in[7];
  const float* Cn_w     = (const float*)d_in[8];
  const float* ln1_w    = (const float*)d_in[9];
  const float* ln1_b    = (const float*)d_in[10];
  const float* cq_w     = (const float*)d_in[11];
  const float* ck_w     = (const float*)d_in[12];
  const float* cv_w     = (const float*)d_in[13];
  const float* cproj_w  = (const float*)d_in[14];
  const float* q_gain   = (const float*)d_in[15];
  const float* ln2_w    = (const float*)d_in[16];
  const float* ln2_b    = (const float*)d_in[17];
  const float* fc_w     = (const float*)d_in[18];
  const float* proj_w   = (const float*)d_in[19];
  float* out = (float*)d_out;
  char* W8 = (char*)d_ws;

  bf16* w_in   = (bf16*)(W8 + OFF_WIN);
  bf16* w_out  = (bf16*)(W8 + OFF_WOUT);
  bf16* w_qkv  = (bf16*)(W8 + OFF_WQKV);
  bf16* w_cp   = (bf16*)(W8 + OFF_WCP);
  bf16* w_fc   = (bf16*)(W8 + OFF_WFC);
  bf16* w_pr   = (bf16*)(W8 + OFF_WPR);
  bf16* h_bf   = (bf16*)(W8 + OFF_HBF);
  bf16* bcdtP  = (bf16*)(W8 + OFF_ST);     // 2 partials x 4096x288 (4.7 MB, pre-states)
  bf16* Xt     = (bf16*)(W8 + OFF_XT);
  bf16* Zt     = (bf16*)(W8 + OFF_ZT);
  float* dt_c  = (float*)(W8 + OFF_DTC);
  float* ddc   = (float*)(W8 + OFF_DDC);
  float* ac_c  = (float*)(W8 + OFF_ACC);
  float* Tb    = (float*)(W8 + OFF_T);
  bf16* Bn     = (bf16*)(W8 + OFF_BN);
  bf16* Cn     = (bf16*)(W8 + OFF_CN);
  bf16* Btr    = (bf16*)(W8 + OFF_BTR);
  bf16* st     = (bf16*)(W8 + OFF_ST);
  bf16* ybf    = (bf16*)(W8 + OFF_YBF);
  float* x1    = (float*)(W8 + OFF_X1);
  bf16* Pbuf   = (bf16*)(W8 + OFF_P);
  bf16* Po     = (bf16*)(W8 + OFF_PO);
  float* Ls    = (float*)(W8 + OFF_LS);
  bf16* qbf    = (bf16*)(W8 + OFF_QB);
  bf16* kbf    = (bf16*)(W8 + OFF_KB);
  bf16* vbf    = (bf16*)(W8 + OFF_VB);
  bf16* vtr    = (bf16*)(W8 + OFF_VTR);
  bf16* y2     = (bf16*)(W8 + OFF_Y2);
  float* x2    = (float*)(W8 + OFF_X2);
  bf16* mlp    = (bf16*)(W8 + OFF_MLP);

  // ---- weight casts (single launch; q/k/v cast into adjacent rows of w_qkv) ----
  CastArgs ca;
  ca.seg[0] = { in_w,    w_in,            4489216, 4587520, 0     };
  ca.seg[1] = { out_w,   w_out,           2097152, 2097152, 4480  };
  ca.seg[2] = { cq_w,    w_qkv,           1048576, 1048576, 6528  };
  ca.seg[3] = { ck_w,    w_qkv + 1048576,  262144,  262144, 7552  };
  ca.seg[4] = { cv_w,    w_qkv + 1310720,  262144,  262144, 7808  };
  ca.seg[5] = { cproj_w, w_cp,            1048576, 1048576, 8064  };
  ca.seg[6] = { fc_w,    w_fc,            3145728, 3145728, 9088  };
  ca.seg[7] = { proj_w,  w_pr,            3145728, 3145728, 12160 };
  castw_all<<<15232, 256, 0, stream>>>(ca);

  const size_t PS  = (size_t)ROWS * 1024;   // partial stride (elements) for N=1024 GEMMs

  // ---- mamba block ----
  rmsnorm_k<<<ROWS, 256, 0, stream>>>(x, mnorm_w, h_bf, D_);
  gemm256_inproj<<<448, 512, 0, stream>>>(h_bf, w_in, Zt, Xt, bcdtP);
  ssd_prep<<<B_ * NH * NC, 64, 0, stream>>>(bcdtP, dt_bias, A_log, dt_c, ddc, ac_c, Tb);
  bc_norm<<<ROWS, 128, 0, stream>>>(bcdtP, Bn_w, Cn_w, Bn, Cn);
  t64<<<2 * 2 * 32, 256, 0, stream>>>(Bn, Btr, 128, (size_t)2048 * 128, (size_t)128 * 2048, 2);
  ssd_states<<<B_ * NC * NH, 256, 0, stream>>>(Xt, Btr, ddc, st);
  ssd_scan<<<B_ * NH * 8, 256, 0, stream>>>(st, Tb);
  ssd_out<<<B_ * NC * NH, 256, 0, stream>>>(Cn, Bn, Xt, Zt, dt_c, ac_c, st, Dp, ybf);
  // out_proj: split-K=2 then fused reduce+residual+LN1
  gemm_sk<<<dim3(32 * 8, 1, 2), 256, 0, stream>>>(ybf, w_out, Pbuf, ROWS, D_, DI, 1024);
  reduce_ln2<<<ROWS, 256, 0, stream>>>(Pbuf, Pbuf + PS, x, ln1_w, ln1_b, x1, h_bf);

  // ---- attention block ----
  gemm_sk<<<dim3(32 * 12, 1, 2), 256, 0, stream>>>(h_bf, w_qkv, Pbuf, ROWS, 1536, D_, 512);
  reduce_qkv<<<ROWS, 256, 0, stream>>>(Pbuf, q_gain, qbf, kbf, vbf);
  t64<<<2 * 4 * 32, 256, 0, stream>>>(vbf, vtr, 256, (size_t)2048 * 256, (size_t)256 * 2048, 4);
  attn_mfma<<<dim3(40, HATT, B_), 256, 0, stream>>>(qbf, kbf, vtr, Po, Ls);
  attn_red<<<ROWS, 256, 0, stream>>>(Po, Ls, y2);
  gemm_sk<<<dim3(32 * 8, 1, 2), 256, 0, stream>>>(y2, w_cp, Pbuf, ROWS, D_, D_, 512);
  reduce_ln2<<<ROWS, 256, 0, stream>>>(Pbuf, Pbuf + PS, x1, ln2_w, ln2_b, x2, h_bf);

  // ---- MLP ----
  gemm_mfma<1, bf16><<<32 * 24, 256, 0, stream>>>(h_bf, w_fc, nullptr, mlp, ROWS, MLP, D_);
  gemm_sk<<<dim3(32 * 8, 1, 3), 256, 0, stream>>>(mlp, w_pr, Pbuf, ROWS, D_, MLP, 1024);
  reduce_out3<<<ROWS, 256, 0, stream>>>(Pbuf, Pbuf + PS, Pbuf + 2 * PS, x2, out);
}

// Round 10
// 489.142 us; speedup vs baseline: 1.5234x; 1.0141x over previous
//
#include <hip/hip_runtime.h>
#include <hip/hip_bf16.h>
#include <math.h>

// ---------------- problem constants ----------------
#define B_    2
#define S_    2048
#define D_    1024
#define DI    2048      // D_INNER
#define NH    32        // NHEADS (mamba)
#define HD    64        // HEADDIM
#define DS    128       // D_STATE
#define CH    64        // CHUNK
#define NC    32        // S_/CH
#define DP    4384      // D_PROJ
#define HATT  16        // attention heads
#define KVH   4         // kv heads
#define RD    16        // rope dims
#define MLP   3072
#define ROWS  (B_*S_)   // 4096
#define PSB   (ROWS*288)  // bcdt partial stride (elements)

typedef __bf16 bf16;
typedef __bf16 bf16x8 __attribute__((ext_vector_type(8)));
typedef __bf16 bf16x4 __attribute__((ext_vector_type(4)));
typedef float  f32x4  __attribute__((ext_vector_type(4)));

__device__ __forceinline__ void async_copy16(const void* g, void* l) {
  __builtin_amdgcn_global_load_lds(
      (const __attribute__((address_space(1))) unsigned int*)g,
      (__attribute__((address_space(3))) unsigned int*)l, 16, 0, 0);
}

// ---------------- reductions ----------------
__device__ __forceinline__ float waveReduceSum(float v) {
#pragma unroll
  for (int off = 32; off > 0; off >>= 1) v += __shfl_down(v, off, 64);
  return v;
}

template<int NW>
__device__ __forceinline__ float blockReduceSum(float v, float* sh) {
  v = waveReduceSum(v);
  int lane = threadIdx.x & 63, wid = threadIdx.x >> 6;
  if (lane == 0) sh[wid] = v;
  __syncthreads();
  float s = 0.f;
#pragma unroll
  for (int i = 0; i < NW; i++) s += sh[i];
  __syncthreads();
  return s;
}

// ---------------- merged weight cast f32 -> bf16 ----------------
struct CastSeg { const float* src; bf16* dst; int nval; int ntot; int blk0; };
struct CastArgs { CastSeg seg[8]; };

__global__ __launch_bounds__(256) void castw_all(CastArgs a) {
  int blk = blockIdx.x;
  int si = 0;
#pragma unroll
  for (int i = 1; i < 8; i++) if (blk >= a.seg[i].blk0) si = i;
  CastSeg s = a.seg[si];
  int i = ((blk - s.blk0) * 256 + threadIdx.x) * 4;
  if (i >= s.ntot) return;
  float4 v = {0.f, 0.f, 0.f, 0.f};
  if (i < s.nval) v = *(const float4*)(s.src + i);
  bf16x4 o;
  o[0] = (bf16)v.x; o[1] = (bf16)v.y; o[2] = (bf16)v.z; o[3] = (bf16)v.w;
  *(bf16x4*)(s.dst + i) = o;
}

// ---------------- rmsnorm (f32 in, bf16 out) ----------------
__global__ __launch_bounds__(256) void rmsnorm_k(const float* __restrict__ x,
                                                 const float* __restrict__ w,
                                                 bf16* __restrict__ y, int n) {
  __shared__ float sh[4];
  size_t row = blockIdx.x;
  const float* xr = x + row * n;
  bf16* yr = y + row * n;
  float ss = 0.f;
  for (int i = threadIdx.x; i < n; i += 256) { float v = xr[i]; ss += v * v; }
  ss = blockReduceSum<4>(ss, sh);
  float inv = rsqrtf(ss / n + 1e-5f);
  for (int i = threadIdx.x; i < n; i += 256) yr[i] = (bf16)(xr[i] * inv * w[i]);
}

// ---------------- generic 256x256 split-K GEMM: P[ks] = act(A @ W^T) (bf16 out) ----
// R6/R9-verified heavy core: 8 waves (2M x 4N), 3 x 32KB LDS bufs, per K-step
// {stage t+1 -> buf nxt; vmcnt(4); barrier; 12 swizzled ds_read_b128; setprio(1);
// 32 MFMA; setprio(0)}. Grid = 16 Mtiles x (N/256) x ksplit, nwg % 8 == 0 for the
// bijective XCD swizzle. ACT=1 applies silu (used by fc with ksplit=1).
// acc[mi][ni] -> row = bm + wm*128 + mi*16 + fq*4 + r, col = bn + wn*64 + ni*16 + fr
// (mapping verified via inproj's Ts epilogue + bcdt path).
template<int ACT>
__global__ __launch_bounds__(512, 2) void gemm256(const bf16* __restrict__ A,
                                                  const bf16* __restrict__ W,
                                                  bf16* __restrict__ P,
                                                  int N, int K, int kchunk, int nwg) {
  __shared__ bf16 lds[3 * 16384];          // 96 KB
  int tid = threadIdx.x;
  int lane = tid & 63, w = tid >> 6;       // 8 waves
  int fr = lane & 15, fq = lane >> 4;
  int rdswz = (fq ^ (fr & 3)) * 8;
  int sswz = (lane & 3) ^ ((lane >> 2) & 3);
  int bid = blockIdx.x;
  int cpx = nwg >> 3;
  bid = (bid & 7) * cpx + (bid >> 3);      // XCD swizzle (bijective: nwg%8==0)
  int bm = (bid & 15) * 256;               // M fastest (share W panel)
  int rest = bid >> 4;
  int nt = N >> 8;
  int bn = (rest % nt) * 256;
  int ks = rest / nt;
  int kbeg = ks * kchunk;
  int wm = w >> 2, wn = w & 3;
  int srow = w * 32 + (lane >> 2);
  const bf16* gA = A + (size_t)(bm + srow) * K + kbeg + sswz * 8;
  const bf16* gW = W + (size_t)(bn + srow) * K + kbeg + sswz * 8;
  int sbase = w * 1024;
  f32x4 acc[8][4] = {};
  {
    bf16* bA = lds + sbase;
    bf16* bB = lds + 8192 + sbase;
    async_copy16(gA, bA);
    async_copy16(gA + (size_t)16 * K, bA + 512);
    async_copy16(gW, bB);
    async_copy16(gW + (size_t)16 * K, bB + 512);
  }
  int cur = 0, nxt = 1;
  int nsteps = kchunk >> 5;
  for (int t = 0; t < nsteps; t++) {
    if (t + 1 < nsteps) {
      const bf16* ga = gA + (t + 1) * 32;
      const bf16* gw = gW + (t + 1) * 32;
      bf16* bA = lds + nxt * 16384 + sbase;
      bf16* bB = lds + nxt * 16384 + 8192 + sbase;
      async_copy16(ga, bA);
      async_copy16(ga + (size_t)16 * K, bA + 512);
      async_copy16(gw, bB);
      async_copy16(gw + (size_t)16 * K, bB + 512);
      asm volatile("s_waitcnt vmcnt(4)" ::: "memory");
    } else {
      asm volatile("s_waitcnt vmcnt(0)" ::: "memory");
    }
    __builtin_amdgcn_sched_barrier(0);
    __builtin_amdgcn_s_barrier();
    __builtin_amdgcn_sched_barrier(0);
    const bf16* cA = lds + cur * 16384;
    const bf16* cB = cA + 8192;
    bf16x8 af[8], bfv[4];
#pragma unroll
    for (int mi = 0; mi < 8; mi++)
      af[mi] = *(const bf16x8*)(cA + (wm * 128 + mi * 16 + fr) * 32 + rdswz);
#pragma unroll
    for (int ni = 0; ni < 4; ni++)
      bfv[ni] = *(const bf16x8*)(cB + (wn * 64 + ni * 16 + fr) * 32 + rdswz);
    __builtin_amdgcn_s_setprio(1);
#pragma unroll
    for (int mi = 0; mi < 8; mi++)
#pragma unroll
      for (int ni = 0; ni < 4; ni++)
        acc[mi][ni] = __builtin_amdgcn_mfma_f32_16x16x32_bf16(af[mi], bfv[ni], acc[mi][ni], 0, 0, 0);
    __builtin_amdgcn_s_setprio(0);
    cur = nxt; nxt = nxt + 1; if (nxt == 3) nxt = 0;
  }
  bf16* Pp = P + (size_t)ks * ROWS * N;
#pragma unroll
  for (int mi = 0; mi < 8; mi++) {
    int row = bm + wm * 128 + mi * 16 + fq * 4;
#pragma unroll
    for (int ni = 0; ni < 4; ni++) {
      int col = bn + wn * 64 + ni * 16 + fr;
#pragma unroll
      for (int r = 0; r < 4; r++) {
        float v = acc[mi][ni][r];
        if (ACT == 1) v = v / (1.f + __expf(-v));
        Pp[(size_t)(row + r) * N + col] = (bf16)v;
      }
    }
  }
}

// ---------------- reduce 4 bf16 partials + residual + layernorm -> x_out f32, h bf16 ----------------
__global__ __launch_bounds__(256) void reduce_ln4(const bf16* __restrict__ P,
                                                  const float* __restrict__ res,
                                                  const float* __restrict__ w,
                                                  const float* __restrict__ b,
                                                  float* __restrict__ xo,
                                                  bf16* __restrict__ ho) {
  __shared__ float sh[4];
  const size_t PS4 = (size_t)ROWS * 1024;
  size_t o = (size_t)blockIdx.x * 1024;
  int i = threadIdx.x * 4;
  f32x4 v = *(const f32x4*)(res + o + i);
#pragma unroll
  for (int p = 0; p < 4; p++) {
    bf16x4 a = *(const bf16x4*)(P + p * PS4 + o + i);
#pragma unroll
    for (int j = 0; j < 4; j++) v[j] += (float)a[j];
  }
  float s = 0.f, s2 = 0.f;
#pragma unroll
  for (int j = 0; j < 4; j++) { s += v[j]; s2 += v[j] * v[j]; }
  s  = blockReduceSum<4>(s,  sh);
  s2 = blockReduceSum<4>(s2, sh);
  float mean = s / 1024.f;
  float var  = s2 / 1024.f - mean * mean;
  float inv  = rsqrtf(var + 1e-5f);
  f32x4 wv = *(const f32x4*)(w + i);
  f32x4 bv = *(const f32x4*)(b + i);
  *(f32x4*)(xo + o + i) = v;
  bf16x4 hv;
#pragma unroll
  for (int j = 0; j < 4; j++) hv[j] = (bf16)((v[j] - mean) * inv * wv[j] + bv[j]);
  *(bf16x4*)(ho + o + i) = hv;
}

// ---------------- reduce 4 bf16 partials + residual -> out f32 ----------------
__global__ __launch_bounds__(256) void reduce_out4(const bf16* __restrict__ P,
                                                   const float* __restrict__ res,
                                                   float* __restrict__ out) {
  const size_t PS4 = (size_t)ROWS * 1024;
  size_t i = ((size_t)blockIdx.x * 256 + threadIdx.x) * 4;
  f32x4 v = *(const f32x4*)(res + i);
#pragma unroll
  for (int p = 0; p < 4; p++) {
    bf16x4 a = *(const bf16x4*)(P + p * PS4 + i);
#pragma unroll
    for (int j = 0; j < 4; j++) v[j] += (float)a[j];
  }
  *(f32x4*)(out + i) = v;
}

// ---------------- reduce qkv bf16 partials + q/k rmsnorm + rope + gain -> bf16 ----------------
__global__ __launch_bounds__(256) void reduce_qkv(const bf16* __restrict__ P,
                                                  const float* __restrict__ q_gain,
                                                  bf16* __restrict__ q,
                                                  bf16* __restrict__ k,
                                                  bf16* __restrict__ v) {
  __shared__ float buf[1536];
  size_t row = blockIdx.x;
  size_t o = row * 1536;
  const bf16* p0 = P + o;
  const bf16* p1 = P + (size_t)ROWS * 1536 + o;
  int tid = threadIdx.x;
  for (int i = tid; i < 384; i += 256) {
    bf16x4 a = *(const bf16x4*)(p0 + i * 4);
    bf16x4 c = *(const bf16x4*)(p1 + i * 4);
    f32x4 vv;
#pragma unroll
    for (int j = 0; j < 4; j++) vv[j] = (float)a[j] + (float)c[j];
    *(f32x4*)(buf + i * 4) = vv;
  }
  __syncthreads();
  int lane = tid & 63, w = tid >> 6;
  int s = (int)(row & (S_ - 1));
  int ri = lane & 7;
  float rinv = __expf(-(float)ri * (0.125f * 9.210340371976184f)); // 10000^(-i/8)
  float ang = (float)s * rinv;
  float cs = cosf(ang), sn = sinf(ang);
#pragma unroll
  for (int j = 0; j < 6; j++) {
    int hh = w * 6 + j;
    float val = buf[hh * 64 + lane];
    if (hh < 20) {
      float ss = val * val;
#pragma unroll
      for (int off = 32; off > 0; off >>= 1) ss += __shfl_xor(ss, off, 64);
      val *= rsqrtf(ss / 64.f + 1.1920929e-7f);
      float other = __shfl_xor(val, 8, 64);
      float res = val;
      if (lane < RD) res = (lane < 8) ? (val * cs + other * sn) : (val * cs - other * sn);
      if (hh < 16) {
        res *= q_gain[hh];
        q[row * (HATT * HD) + hh * HD + lane] = (bf16)res;
      } else {
        k[row * (KVH * HD) + (hh - 16) * HD + lane] = (bf16)res;
      }
    } else {
      v[row * (KVH * HD) + (hh - 20) * HD + lane] = (bf16)val;
    }
  }
}

// ---------------- in_proj GEMM: R9-verified (heavy 3-buf/1-barrier + light split-K=2) ----
__global__ __launch_bounds__(512, 2) void gemm256_inproj(const bf16* __restrict__ A,
                                                         const bf16* __restrict__ W,
                                                         bf16* __restrict__ zt,
                                                         bf16* __restrict__ xt,
                                                         bf16* __restrict__ bcdtP) {
  __shared__ bf16 lds[3 * 16384];          // 96 KB
  int tid = threadIdx.x;
  int lane = tid & 63, w = tid >> 6;       // 8 waves
  int fr = lane & 15, fq = lane >> 4;
  int rdswz = (fq ^ (fr & 3)) * 8;
  int sswz = (lane & 3) ^ ((lane >> 2) & 3);
  int bid = blockIdx.x;
  if (bid < 256) {
    int sb = (bid & 7) * 32 + (bid >> 3);  // XCD swizzle (256 = 8*32, bijective)
    int bm = (sb & 15) * 256;
    int bn = (sb >> 4) * 256;
    int wm = w >> 2, wn = w & 3;
    int srow = w * 32 + (lane >> 2);
    const bf16* gA = A + (size_t)(bm + srow) * 1024 + sswz * 8;
    const bf16* gW = W + (size_t)(bn + srow) * 1024 + sswz * 8;
    int sbase = w * 1024;
    f32x4 acc[8][4] = {};
    {
      bf16* bA = lds + sbase;
      bf16* bB = lds + 8192 + sbase;
      async_copy16(gA, bA);
      async_copy16(gA + 16 * 1024, bA + 512);
      async_copy16(gW, bB);
      async_copy16(gW + 16 * 1024, bB + 512);
    }
    int cur = 0, nxt = 1;
    for (int t = 0; t < 32; t++) {
      if (t + 1 < 32) {
        const bf16* ga = gA + (t + 1) * 32;
        const bf16* gw = gW + (t + 1) * 32;
        bf16* bA = lds + nxt * 16384 + sbase;
        bf16* bB = lds + nxt * 16384 + 8192 + sbase;
        async_copy16(ga, bA);
        async_copy16(ga + 16 * 1024, bA + 512);
        async_copy16(gw, bB);
        async_copy16(gw + 16 * 1024, bB + 512);
        asm volatile("s_waitcnt vmcnt(4)" ::: "memory");
      } else {
        asm volatile("s_waitcnt vmcnt(0)" ::: "memory");
      }
      __builtin_amdgcn_sched_barrier(0);
      __builtin_amdgcn_s_barrier();
      __builtin_amdgcn_sched_barrier(0);
      const bf16* cA = lds + cur * 16384;
      const bf16* cB = cA + 8192;
      bf16x8 af[8], bfv[4];
#pragma unroll
      for (int mi = 0; mi < 8; mi++)
        af[mi] = *(const bf16x8*)(cA + (wm * 128 + mi * 16 + fr) * 32 + rdswz);
#pragma unroll
      for (int ni = 0; ni < 4; ni++)
        bfv[ni] = *(const bf16x8*)(cB + (wn * 64 + ni * 16 + fr) * 32 + rdswz);
      __builtin_amdgcn_s_setprio(1);
#pragma unroll
      for (int mi = 0; mi < 8; mi++)
#pragma unroll
        for (int ni = 0; ni < 4; ni++)
          acc[mi][ni] = __builtin_amdgcn_mfma_f32_16x16x32_bf16(af[mi], bfv[ni], acc[mi][ni], 0, 0, 0);
      __builtin_amdgcn_s_setprio(0);
      cur = nxt; nxt = nxt + 1; if (nxt == 3) nxt = 0;
    }
    bf16* base = (bn < 2048) ? zt : xt;
    int bq = bm >> 11, bmS = bm & 2047;
    bf16* Ts = lds;
#pragma unroll 1
    for (int g = 0; g < 4; g++) {
      __syncthreads();
      if (wn == g) {
#pragma unroll
        for (int mi = 0; mi < 8; mi++)
#pragma unroll
          for (int ni = 0; ni < 4; ni++) {
            bf16x4 o;
#pragma unroll
            for (int r = 0; r < 4; r++) o[r] = (bf16)acc[mi][ni][r];
            *(bf16x4*)(Ts + (ni * 16 + fr) * 264 + wm * 128 + mi * 16 + fq * 4) = o;
          }
      }
      __syncthreads();
      int hh = ((bn & 2047) + g * 64) >> 6;
      bf16* dst = base + ((size_t)(bq * NH + hh) * HD) * S_ + bmS;
#pragma unroll
      for (int i = 0; i < 4; i++) {
        int idx = tid + i * 512;
        int p = idx >> 5, sc = (idx & 31) * 8;
        *(bf16x8*)(dst + (size_t)p * S_ + sc) = *(const bf16x8*)(Ts + p * 264 + sc);
      }
    }
  } else {
    int lb = bid - 256;
    int ks = lb / 96;
    int pos = lb - ks * 96;
    int bm = (pos & 31) * 128;
    int bn = 4096 + (pos >> 5) * 128;
    int kbeg = ks * 512;
    int wm = w >> 1, wn = w & 1;
    int srow = w * 16 + (lane >> 2);
    const bf16* gA = A + (size_t)(bm + srow) * 1024 + kbeg + sswz * 8;
    const bf16* gW = W + (size_t)(bn + srow) * 1024 + kbeg + sswz * 8;
    int sbase = w * 512;
    f32x4 acc[2][4] = {};
    {
      async_copy16(gA, lds + sbase);
      async_copy16(gW, lds + 4096 + sbase);
    }
    int cur = 0, nxt = 1;
    for (int t = 0; t < 16; t++) {
      if (t + 1 < 16) {
        async_copy16(gA + (t + 1) * 32, lds + nxt * 8192 + sbase);
        async_copy16(gW + (t + 1) * 32, lds + nxt * 8192 + 4096 + sbase);
        asm volatile("s_waitcnt vmcnt(2)" ::: "memory");
      } else {
        asm volatile("s_waitcnt vmcnt(0)" ::: "memory");
      }
      __builtin_amdgcn_sched_barrier(0);
      __builtin_amdgcn_s_barrier();
      __builtin_amdgcn_sched_barrier(0);
      const bf16* cA = lds + cur * 8192;
      const bf16* cB = cA + 4096;
      bf16x8 af[2], bfv[4];
#pragma unroll
      for (int mi = 0; mi < 2; mi++)
        af[mi] = *(const bf16x8*)(cA + (wm * 32 + mi * 16 + fr) * 32 + rdswz);
#pragma unroll
      for (int ni = 0; ni < 4; ni++)
        bfv[ni] = *(const bf16x8*)(cB + (wn * 64 + ni * 16 + fr) * 32 + rdswz);
#pragma unroll
      for (int mi = 0; mi < 2; mi++)
#pragma unroll
        for (int ni = 0; ni < 4; ni++)
          acc[mi][ni] = __builtin_amdgcn_mfma_f32_16x16x32_bf16(af[mi], bfv[ni], acc[mi][ni], 0, 0, 0);
      cur = nxt; nxt = nxt + 1; if (nxt == 3) nxt = 0;
    }
    bf16* dst = bcdtP + (size_t)ks * PSB;
#pragma unroll
    for (int mi = 0; mi < 2; mi++) {
      int row = bm + wm * 32 + mi * 16 + fq * 4;
#pragma unroll
      for (int ni = 0; ni < 4; ni++) {
        int col = bn + wn * 64 + ni * 16 + fr;
        if (col < 4384) {
#pragma unroll
          for (int r = 0; r < 4; r++)
            dst[(size_t)(row + r) * 288 + (col - 4096)] = (bf16)acc[mi][ni][r];
        }
      }
    }
  }
}

// ---------------- generic 64x64 tiled transpose (bf16), out row stride 2048 ----------------
__global__ __launch_bounds__(256) void t64(const bf16* __restrict__ in, bf16* __restrict__ out,
                                           int istr, size_t io, size_t oo, int n_nt) {
  __shared__ bf16 T[64 * 72];
  int bid = blockIdx.x;
  int st = bid & 31;
  int nt = (bid >> 5) % n_nt;
  int outer = bid / (32 * n_nt);
  const bf16* ip = in + outer * io + (size_t)st * 64 * istr + nt * 64;
  int tid = threadIdx.x;
#pragma unroll
  for (int i = 0; i < 2; i++) {
    int cid = tid + i * 256; int s = cid >> 3, pc = (cid & 7) * 8;
    *(bf16x8*)(T + s * 72 + pc) = *(const bf16x8*)(ip + (size_t)s * istr + pc);
  }
  __syncthreads();
  bf16* op = out + outer * oo + (size_t)nt * 64 * 2048 + st * 64;
#pragma unroll
  for (int i = 0; i < 2; i++) {
    int cid = tid + i * 256; int p = cid >> 3, sc = (cid & 7) * 8;
    bf16x8 o;
#pragma unroll
    for (int j = 0; j < 8; j++) o[j] = T[(sc + j) * 72 + p];
    *(bf16x8*)(op + (size_t)p * 2048 + sc) = o;
  }
}

// ---------------- SSD prep: dt softplus, per-chunk cumsum, decay factors (2 bcdt partials) --
__global__ __launch_bounds__(64) void ssd_prep(const bf16* __restrict__ bcdtP,
                                               const float* __restrict__ dt_bias,
                                               const float* __restrict__ A_log,
                                               float* __restrict__ dt_c,
                                               float* __restrict__ ddc,
                                               float* __restrict__ ac_c,
                                               float* __restrict__ T_out) {
  int bid = blockIdx.x;
  int c = bid % NC, hh = (bid / NC) % NH, b = bid / (NC * NH);
  int l = threadIdx.x;
  size_t row = (size_t)b * S_ + c * 64 + l;
  float raw = (float)bcdtP[row * 288 + 256 + hh]
            + (float)bcdtP[(size_t)PSB + row * 288 + 256 + hh] + dt_bias[hh];
  float dtv = (raw > 20.f) ? raw : log1pf(__expf(raw));
  float a = -__expf(A_log[hh]) * dtv;
  float ps = a;
#pragma unroll
  for (int off = 1; off < 64; off <<= 1) {
    float t = __shfl_up(ps, off, 64);
    if (l >= off) ps += t;
  }
  float a63 = __shfl(ps, 63, 64);
  size_t o = ((size_t)b * NH + hh) * S_ + c * 64 + l;
  dt_c[o] = dtv;
  ac_c[o] = ps;
  ddc[o] = __expf(a63 - ps) * dtv;
  if (l == 63) T_out[(b * NH + hh) * NC + c] = ps;
}

// ---------------- B/C rmsnorm (bf16 out, 2 bcdt partials) ----------------
__global__ __launch_bounds__(128) void bc_norm(const bf16* __restrict__ bcdtP,
                                               const float* __restrict__ Bw,
                                               const float* __restrict__ Cw,
                                               bf16* __restrict__ Bn,
                                               bf16* __restrict__ Cn) {
  __shared__ float shb[2], shc[2];
  size_t row = blockIdx.x;
  int i = threadIdx.x;
  float bv = (float)bcdtP[row * 288 + i] + (float)bcdtP[(size_t)PSB + row * 288 + i];
  float cv = (float)bcdtP[row * 288 + 128 + i] + (float)bcdtP[(size_t)PSB + row * 288 + 128 + i];
  float sb = waveReduceSum(bv * bv);
  float sc = waveReduceSum(cv * cv);
  int lane = threadIdx.x & 63, wid = threadIdx.x >> 6;
  if (lane == 0) { shb[wid] = sb; shc[wid] = sc; }
  __syncthreads();
  float tb = shb[0] + shb[1];
  float tc = shc[0] + shc[1];
  Bn[row * DS + i] = (bf16)(bv * rsqrtf(tb / DS + 1e-5f) * Bw[i]);
  Cn[row * DS + i] = (bf16)(cv * rsqrtf(tc / DS + 1e-5f) * Cw[i]);
}

// ---------------- chunk states via MFMA (bf16 output) ----------------
__global__ __launch_bounds__(256) void ssd_states(const bf16* __restrict__ Xt,
                                                  const bf16* __restrict__ Btr,
                                                  const float* __restrict__ ddc,
                                                  bf16* __restrict__ states) {
  __shared__ bf16 Xs[64 * 72];    // [p][s]
  __shared__ bf16 Bs[128 * 72];   // [n][s]
  int bid = blockIdx.x;           // (b*NC + c)*NH + h
  int h = bid % NH;
  int c = (bid / NH) % NC;
  int b = bid / (NH * NC);
  int tid = threadIdx.x, lane = tid & 63, w = tid >> 6;
  int fr = lane & 15, fq = lane >> 4;
  const size_t xbase = (size_t)(b * NH + h) * HD * S_ + c * 64;
  const size_t dbase = (size_t)(b * NH + h) * S_ + c * 64;
#pragma unroll
  for (int i = 0; i < 2; i++) {
    int cid = tid + i * 256; int p = cid >> 3, sc = (cid & 7) * 8;
    bf16x8 xv = *(const bf16x8*)(Xt + xbase + (size_t)p * S_ + sc);
    f32x4 d0 = *(const f32x4*)(ddc + dbase + sc);
    f32x4 d1 = *(const f32x4*)(ddc + dbase + sc + 4);
    bf16x8 o;
#pragma unroll
    for (int j = 0; j < 4; j++) { o[j] = (bf16)((float)xv[j] * d0[j]); o[4 + j] = (bf16)((float)xv[4 + j] * d1[j]); }
    *(bf16x8*)(Xs + p * 72 + sc) = o;
  }
  const size_t bbase = (size_t)b * 128 * S_ + c * 64;
#pragma unroll
  for (int i = 0; i < 4; i++) {
    int cid = tid + i * 256; int n = cid >> 3, sc = (cid & 7) * 8;
    *(bf16x8*)(Bs + n * 72 + sc) = *(const bf16x8*)(Btr + bbase + (size_t)n * S_ + sc);
  }
  __syncthreads();
  f32x4 acc[4][2] = {};
#pragma unroll
  for (int ks = 0; ks < 2; ks++) {
    bf16x8 a[4], bb[2];
#pragma unroll
    for (int pt = 0; pt < 4; pt++) a[pt] = *(const bf16x8*)(Xs + (pt * 16 + fr) * 72 + ks * 32 + fq * 8);
#pragma unroll
    for (int n2 = 0; n2 < 2; n2++) bb[n2] = *(const bf16x8*)(Bs + ((2 * w + n2) * 16 + fr) * 72 + ks * 32 + fq * 8);
#pragma unroll
    for (int pt = 0; pt < 4; pt++)
#pragma unroll
      for (int n2 = 0; n2 < 2; n2++)
        acc[pt][n2] = __builtin_amdgcn_mfma_f32_16x16x32_bf16(a[pt], bb[n2], acc[pt][n2], 0, 0, 0);
  }
  bf16* outp = states + (size_t)bid * 8192;
#pragma unroll
  for (int pt = 0; pt < 4; pt++)
#pragma unroll
    for (int n2 = 0; n2 < 2; n2++) {
      int n = (2 * w + n2) * 16 + fr;
#pragma unroll
      for (int r = 0; r < 4; r++)
        outp[(size_t)(pt * 16 + fq * 4 + r) * 128 + n] = (bf16)acc[pt][n2][r];
    }
}

// ---------------- inter-chunk scan (in place, bf16 storage, f32 math) ----------------
__global__ __launch_bounds__(256) void ssd_scan(bf16* __restrict__ states,
                                                const float* __restrict__ T) {
  __shared__ float eT[NC];
  int part = blockIdx.x & 7;
  int bh = blockIdx.x >> 3;
  int b = bh / NH, h = bh % NH;
  if (threadIdx.x < NC) eT[threadIdx.x] = __expf(T[(size_t)(b * NH + h) * NC + threadIdx.x]);
  __syncthreads();
  const size_t cstride = (size_t)NH * HD * DS;
  size_t base = ((size_t)b * NC * NH + h) * (HD * DS);
#pragma unroll
  for (int j = 0; j < 4; j++) {
    int e = part * 1024 + threadIdx.x + j * 256;
    float carry = 0.f;
    size_t idx = base + e;
    for (int c = 0; c < NC; c++) {
      float sv = (float)states[idx];
      states[idx] = (bf16)carry;
      carry = sv + eT[c] * carry;
      idx += cstride;
    }
  }
}

// ---------------- fused SSD output: Ydiag + Yoff + D-skip + gate (all MFMA) ----------------
__global__ __launch_bounds__(256) void ssd_out(const bf16* __restrict__ Cn,
                                               const bf16* __restrict__ Bn,
                                               const bf16* __restrict__ Xt,
                                               const bf16* __restrict__ Zt,
                                               const float* __restrict__ dt_c,
                                               const float* __restrict__ ac_c,
                                               const bf16* __restrict__ states,
                                               const float* __restrict__ Dp,
                                               bf16* __restrict__ ybf) {
  __shared__ bf16 Cs[64 * 136];
  __shared__ bf16 BNs[64 * 136];
  __shared__ bf16 Xs[64 * 72];
  __shared__ bf16 G[64 * 72];
  __shared__ float acs[64];
  int bid = blockIdx.x;
  int h = bid % NH;
  int c = (bid / NH) % NC;
  int b = bid / (NH * NC);
  int tid = threadIdx.x, lane = tid & 63, w = tid >> 6;
  int fr = lane & 15, fq = lane >> 4;
  size_t row0 = (size_t)b * S_ + c * 64;
  const size_t abase = (size_t)(b * NH + h) * S_ + c * 64;
  if (tid < 64) acs[tid] = ac_c[abase + tid];
#pragma unroll
  for (int i = 0; i < 4; i++) {
    int cid = tid + i * 256; int l = cid >> 4, nc = (cid & 15) * 8;
    float e = __expf(ac_c[abase + l]);
    bf16x8 cv = *(const bf16x8*)(Cn + (row0 + l) * DS + nc);
    bf16x8 o;
#pragma unroll
    for (int j = 0; j < 8; j++) o[j] = (bf16)((float)cv[j] * e);
    *(bf16x8*)(Cs + l * 136 + nc) = o;
    *(bf16x8*)(BNs + l * 136 + nc) = *(const bf16x8*)(Bn + (row0 + l) * DS + nc);
  }
  const size_t xbase = (size_t)(b * NH + h) * HD * S_ + c * 64;
#pragma unroll
  for (int i = 0; i < 2; i++) {
    int cid = tid + i * 256; int p = cid >> 3, sc = (cid & 7) * 8;
    bf16x8 xv = *(const bf16x8*)(Xt + xbase + (size_t)p * S_ + sc);
    f32x4 d0 = *(const f32x4*)(dt_c + abase + sc);
    f32x4 d1 = *(const f32x4*)(dt_c + abase + sc + 4);
    bf16x8 o;
#pragma unroll
    for (int j = 0; j < 4; j++) { o[j] = (bf16)((float)xv[j] * d0[j]); o[4 + j] = (bf16)((float)xv[4 + j] * d1[j]); }
    *(bf16x8*)(Xs + p * 72 + sc) = o;
  }
  __syncthreads();
  bf16x8 ca[4];
#pragma unroll
  for (int ks = 0; ks < 4; ks++) ca[ks] = *(const bf16x8*)(Cs + (w * 16 + fr) * 136 + ks * 32 + fq * 8);
  f32x4 cb[4] = {};
  for (int st = 0; st <= w; st++)
#pragma unroll
    for (int ks = 0; ks < 4; ks++)
      cb[st] = __builtin_amdgcn_mfma_f32_16x16x32_bf16(ca[ks],
                 *(const bf16x8*)(BNs + (st * 16 + fr) * 136 + ks * 32 + fq * 8), cb[st], 0, 0, 0);
#pragma unroll
  for (int st = 0; st < 4; st++) {
    float es = (st <= w) ? __expf(-acs[st * 16 + fr]) : 0.f;
#pragma unroll
    for (int r = 0; r < 4; r++) {
      int lloc = fq * 4 + r;
      float g = 0.f;
      if (st < w) g = cb[st][r] * es;
      else if (st == w) g = (lloc >= fr) ? cb[st][r] * es : 0.f;
      G[(w * 16 + lloc) * 72 + st * 16 + fr] = (bf16)g;
    }
  }
  f32x4 acc[4] = {};
  {
    bf16x8 ga0 = *(const bf16x8*)(G + (w * 16 + fr) * 72 + fq * 8);
    bf16x8 ga1 = *(const bf16x8*)(G + (w * 16 + fr) * 72 + 32 + fq * 8);
#pragma unroll
    for (int pt = 0; pt < 4; pt++) {
      acc[pt] = __builtin_amdgcn_mfma_f32_16x16x32_bf16(ga0,
                  *(const bf16x8*)(Xs + (pt * 16 + fr) * 72 + fq * 8), acc[pt], 0, 0, 0);
      acc[pt] = __builtin_amdgcn_mfma_f32_16x16x32_bf16(ga1,
                  *(const bf16x8*)(Xs + (pt * 16 + fr) * 72 + 32 + fq * 8), acc[pt], 0, 0, 0);
    }
  }
  __syncthreads();
  const bf16* stp = states + (size_t)bid * 8192;
#pragma unroll
  for (int i = 0; i < 4; i++) {
    int cid = tid + i * 256; int p = cid >> 4, nc = (cid & 15) * 8;
    *(bf16x8*)(BNs + p * 136 + nc) = *(const bf16x8*)(stp + (size_t)p * 128 + nc);
  }
  __syncthreads();
#pragma unroll
  for (int pt = 0; pt < 4; pt++)
#pragma unroll
    for (int ks = 0; ks < 4; ks++)
      acc[pt] = __builtin_amdgcn_mfma_f32_16x16x32_bf16(ca[ks],
                  *(const bf16x8*)(BNs + (pt * 16 + fr) * 136 + ks * 32 + fq * 8), acc[pt], 0, 0, 0);
  float dph = Dp[h];
#pragma unroll
  for (int pt = 0; pt < 4; pt++) {
    int p = pt * 16 + fr;
    size_t tb = (xbase + (size_t)p * S_) + w * 16 + fq * 4;
    bf16x4 xs4 = *(const bf16x4*)(Xt + tb);
    bf16x4 z4  = *(const bf16x4*)(Zt + tb);
#pragma unroll
    for (int r = 0; r < 4; r++) {
      int l = w * 16 + fq * 4 + r;
      float yv = acc[pt][r] + (float)xs4[r] * dph;
      float z = (float)z4[r];
      yv *= z / (1.f + __expf(-z));
      ybf[((row0 + l) * NH + h) * HD + p] = (bf16)yv;
    }
  }
}

// ---------------- split-S MFMA flash attention (fixed-max softmax -> partials sum) ----------------
#define KSTR 72
#define PSTR 72
__global__ __launch_bounds__(256) void attn_mfma(const bf16* __restrict__ q,
                                                 const bf16* __restrict__ k,
                                                 const bf16* __restrict__ vtr,
                                                 bf16* __restrict__ Po,
                                                 float* __restrict__ Ls) {
  __shared__ bf16 Ks[64 * KSTR];
  __shared__ bf16 Vs[64 * KSTR];
  __shared__ bf16 Pl[4][32 * PSTR];
  int c = 39 - blockIdx.x;                 // full 8-iter chunks first
  int g = (c < 4) ? 0 : (c < 12) ? 1 : (c < 24) ? 2 : 3;
  int gbase = (g == 0) ? 0 : (g == 1) ? 4 : (g == 2) ? 12 : 24;
  int d = c - gbase;
  int qt = 4 * g + d / (g + 1);
  int sk = d % (g + 1);
  int h = blockIdx.y, b = blockIdx.z;
  int kvh = h >> 2;
  int tid = threadIdx.x, lane = tid & 63, w = tid >> 6;
  int fr = lane & 15, fq = lane >> 4;
  const float SC = 0.18033688011112042f;   // 0.125 * log2(e)
  const float M2 = 62.0f;
  int kt0 = sk * 8;
  int ktend = min(kt0 + 8, 2 * qt + 2);
  int qbase = qt * 128 + w * 32;           // wave's first q row
  int qmaxw = qbase + 31;
  bf16x8 bq[2][2];
#pragma unroll
  for (int qc = 0; qc < 2; qc++)
#pragma unroll
    for (int ks = 0; ks < 2; ks++)
      bq[qc][ks] = *(const bf16x8*)(q + (size_t)(b * S_ + qbase + qc * 16 + fr) * (HATT * HD)
                                      + h * HD + ks * 32 + fq * 8);
  int sr = tid >> 3, sc8 = (tid & 7) * 8;
  const bf16* kg = k + ((size_t)(b * S_) + sr) * (KVH * HD) + kvh * HD + sc8;
  const bf16* vg = vtr + ((size_t)(b * KVH + kvh) * HD + sr) * S_ + sc8;
  bf16x8 krg0, krg1, vrg0, vrg1;
  {
    const bf16* kp = kg + (size_t)kt0 * 64 * (KVH * HD);
    const bf16* vp = vg + (size_t)kt0 * 64;
    krg0 = *(const bf16x8*)(kp);
    krg1 = *(const bf16x8*)(kp + (size_t)32 * (KVH * HD));
    vrg0 = *(const bf16x8*)(vp);
    vrg1 = *(const bf16x8*)(vp + (size_t)32 * S_);
  }
  float lsum[2] = {0.f, 0.f};
  f32x4 yacc[2][4] = {};
  bf16* Plw = Pl[w];
  for (int kt = kt0; kt < ktend; kt++) {
    __syncthreads();   // previous iteration's LDS reads complete
    *(bf16x8*)(&Ks[sr * KSTR + sc8]) = krg0;
    *(bf16x8*)(&Ks[(sr + 32) * KSTR + sc8]) = krg1;
    *(bf16x8*)(&Vs[sr * KSTR + sc8]) = vrg0;
    *(bf16x8*)(&Vs[(sr + 32) * KSTR + sc8]) = vrg1;
    __syncthreads();   // tile visible
    if ((kt + 1) < ktend) {
      const bf16* kp = kg + (size_t)(kt + 1) * 64 * (KVH * HD);
      const bf16* vp = vg + (size_t)(kt + 1) * 64;
      krg0 = *(const bf16x8*)(kp);
      krg1 = *(const bf16x8*)(kp + (size_t)32 * (KVH * HD));
      vrg0 = *(const bf16x8*)(vp);
      vrg1 = *(const bf16x8*)(vp + (size_t)32 * S_);
    }
    if (kt * 64 <= qmaxw) {
      bool nomask = (kt * 64 + 63) <= qbase;
      if (nomask) {
#pragma unroll
        for (int mi = 0; mi < 4; mi++) {
          const bf16* krow = &Ks[(mi * 16 + fr) * KSTR];
          bf16x8 ak0 = *(const bf16x8*)(krow + fq * 8);
          bf16x8 ak1 = *(const bf16x8*)(krow + 32 + fq * 8);
#pragma unroll
          for (int qc = 0; qc < 2; qc++) {
            f32x4 s = {};
            s = __builtin_amdgcn_mfma_f32_16x16x32_bf16(ak0, bq[qc][0], s, 0, 0, 0);
            s = __builtin_amdgcn_mfma_f32_16x16x32_bf16(ak1, bq[qc][1], s, 0, 0, 0);
            bf16x4 pk;
#pragma unroll
            for (int r = 0; r < 4; r++) {
              float p = __builtin_amdgcn_exp2f(s[r] * SC - M2);
              lsum[qc] += p;
              pk[r] = (bf16)p;
            }
            *(bf16x4*)(Plw + (qc * 16 + fr) * PSTR + mi * 16 + fq * 4) = pk;
          }
        }
      } else {
#pragma unroll
        for (int mi = 0; mi < 4; mi++) {
          int s0 = kt * 64 + mi * 16;
          if (s0 > qmaxw) {
            bf16x4 zz = {};
#pragma unroll
            for (int qc = 0; qc < 2; qc++)
              *(bf16x4*)(Plw + (qc * 16 + fr) * PSTR + mi * 16 + fq * 4) = zz;
          } else {
            const bf16* krow = &Ks[(mi * 16 + fr) * KSTR];
            bf16x8 ak0 = *(const bf16x8*)(krow + fq * 8);
            bf16x8 ak1 = *(const bf16x8*)(krow + 32 + fq * 8);
#pragma unroll
            for (int qc = 0; qc < 2; qc++) {
              f32x4 s = {};
              s = __builtin_amdgcn_mfma_f32_16x16x32_bf16(ak0, bq[qc][0], s, 0, 0, 0);
              s = __builtin_amdgcn_mfma_f32_16x16x32_bf16(ak1, bq[qc][1], s, 0, 0, 0);
              int qq = qbase + qc * 16 + fr;
              bf16x4 pk;
#pragma unroll
              for (int r = 0; r < 4; r++) {
                int sp = s0 + fq * 4 + r;
                float p = (sp <= qq) ? __builtin_amdgcn_exp2f(s[r] * SC - M2) : 0.f;
                lsum[qc] += p;
                pk[r] = (bf16)p;
              }
              *(bf16x4*)(Plw + (qc * 16 + fr) * PSTR + mi * 16 + fq * 4) = pk;
            }
          }
        }
      }
#pragma unroll
      for (int ks2 = 0; ks2 < 2; ks2++) {
        bf16x8 bp[2];
#pragma unroll
        for (int qc = 0; qc < 2; qc++)
          bp[qc] = *(const bf16x8*)(Plw + (qc * 16 + fr) * PSTR + ks2 * 32 + fq * 8);
#pragma unroll
        for (int pi = 0; pi < 4; pi++) {
          bf16x8 av = *(const bf16x8*)(&Vs[(pi * 16 + fr) * KSTR + ks2 * 32 + fq * 8]);
#pragma unroll
          for (int qc = 0; qc < 2; qc++)
            yacc[qc][pi] = __builtin_amdgcn_mfma_f32_16x16x32_bf16(av, bp[qc], yacc[qc][pi], 0, 0, 0);
        }
      }
    }
  }
#pragma unroll
  for (int qc = 0; qc < 2; qc++) {
    lsum[qc] += __shfl_xor(lsum[qc], 16, 64);
    lsum[qc] += __shfl_xor(lsum[qc], 32, 64);
    int qrow = qt * 128 + w * 32 + qc * 16 + fr;
    if (fq == 0)
      Ls[((size_t)(b * 16 + h) * 2048 + qrow) * 4 + sk] = lsum[qc];
    bf16* pop = Po + ((((size_t)(b * 16 + h) * 16 + qt) * 4 + sk) * 128
                       + w * 32 + qc * 16 + fr) * 64 + fq * 4;
#pragma unroll
    for (int pi = 0; pi < 4; pi++) {
      bf16x4 o;
#pragma unroll
      for (int r = 0; r < 4; r++) o[r] = (bf16)yacc[qc][pi][r];
      *(bf16x4*)(pop + pi * 16) = o;
    }
  }
}

// ---------------- attention partial combine + normalize -> y2 bf16 ----------------
__global__ __launch_bounds__(256) void attn_red(const bf16* __restrict__ Po,
                                                const float* __restrict__ Ls,
                                                bf16* __restrict__ y2) {
  int row = blockIdx.x;            // 0..4095
  int b = row >> 11;
  int qrow = row & 2047;
  int qt = qrow >> 7, r = qrow & 127;
  int nch = (qt >> 2) + 1;
  int t = threadIdx.x;
  int h = t >> 4, e4 = (t & 15) << 2;
  const float* lp = Ls + ((size_t)(b * 16 + h) * 2048 + qrow) * 4;
  float ls = 0.f;
  f32x4 acc = {};
  for (int sk = 0; sk < nch; sk++) {
    ls += lp[sk];
    const bf16* pp = Po + ((((size_t)(b * 16 + h) * 16 + qt) * 4 + sk) * 128 + r) * 64 + e4;
    bf16x4 v = *(const bf16x4*)(pp);
#pragma unroll
    for (int j = 0; j < 4; j++) acc[j] += (float)v[j];
  }
  float inv = 1.f / ls;
  bf16x4 o;
#pragma unroll
  for (int j = 0; j < 4; j++) o[j] = (bf16)(acc[j] * inv);
  *(bf16x4*)(y2 + (size_t)row * 1024 + h * 64 + e4) = o;
}

// ---------------- workspace layout (byte offsets) ----------------
constexpr size_t OFF_WIN  = 0;                   // bf16 4480x1024
constexpr size_t OFF_WOUT = 9175040;             // bf16 1024x2048
constexpr size_t OFF_WQKV = 13369344;            // bf16 1536x1024 (q|k|v rows)
constexpr size_t OFF_WCP  = 16515072;            // bf16 1024x1024
constexpr size_t OFF_WFC  = 18612224;            // bf16 3072x1024
constexpr size_t OFF_WPR  = 24903680;            // bf16 1024x3072
constexpr size_t OFF_HBF  = 31195136;            // bf16 4096x1024
constexpr size_t OFF_BCDT = 39583744;            // (legacy region; reused: Ls f32)
constexpr size_t OFF_XT   = 41943040;            // bf16 [b][h][p][sg] (16.7 MB)
constexpr size_t OFF_ZT   = 58720256;            // bf16 [b][h][p][sg] (16.7 MB)
constexpr size_t OFF_DTC  = 75497472;            // f32 [b][h][sg]
constexpr size_t OFF_DDC  = 76546048;            // f32
constexpr size_t OFF_ACC  = 77594624;            // f32
constexpr size_t OFF_T    = 78643200;            // f32 2048
constexpr size_t OFF_BN   = 78651392;            // bf16 4096x128
constexpr size_t OFF_CN   = 79699968;            // bf16 4096x128
constexpr size_t OFF_BTR  = 80748544;            // bf16 [b][n][sg]
constexpr size_t OFF_ST   = 81797120;            // bf16 states (33.5 MB); early: bcdtP; later: P/Po
constexpr size_t OFF_YBF  = 148905984;           // bf16 4096x2048
constexpr size_t OFF_X1   = 165683200;           // f32 4096x1024 (end 182,460,416)
// phase-2 aliases
constexpr size_t OFF_P    = OFF_ST;              // bf16 split-K partials (<= 33.5 MB)
constexpr size_t OFF_PO   = OFF_ST;              // bf16 attn partials = 32 MiB
constexpr size_t OFF_LS   = OFF_BCDT;            // f32 attn lsums = 1 MiB
constexpr size_t OFF_QB   = OFF_XT;              // bf16 4096x1024 (8.4 MB)
constexpr size_t OFF_KB   = OFF_XT + 8388608;    // bf16 4096x256
constexpr size_t OFF_VB   = OFF_XT + 10485760;   // bf16 4096x256
constexpr size_t OFF_VTR  = OFF_XT + 12582912;   // bf16 [b][kvh][p][sg]
constexpr size_t OFF_Y2   = OFF_ZT;              // bf16 4096x1024
constexpr size_t OFF_X2   = 50331648;            // f32 4096x1024 (over dead kb/vb/vtr/y2)
constexpr size_t OFF_MLP  = 132128768;           // bf16 4096x3072 (over dead regions)

extern "C" void kernel_launch(void* const* d_in, const int* in_sizes, int n_in,
                              void* d_out, int out_size, void* d_ws, size_t ws_size,
                              hipStream_t stream) {
  (void)in_sizes; (void)n_in; (void)out_size; (void)ws_size;
  const float* x        = (const float*)d_in[0];
  const float* mnorm_w  = (const float*)d_in[1];
  const float* in_w     = (const float*)d_in[2];
  const float* out_w    = (const float*)d_in[3];
  const float* Dp       = (const float*)d_in[4];
  const float* dt_bias  = (const float*)d_in[5];
  const float* A_log    = (const float*)d_in[6];
  const float* Bn_w     = (const float*)d_in[7];
  const float* Cn_w     = (const float*)d_in[8];
  const float* ln1_w    = (const float*)d_in[9];
  const float* ln1_b    = (const float*)d_in[10];
  const float* cq_w     = (const float*)d_in[11];
  const float* ck_w     = (const float*)d_in[12];
  const float* cv_w     = (const float*)d_in[13];
  const float* cproj_w  = (const float*)d_in[14];
  const float* q_gain   = (const float*)d_in[15];
  const float* ln2_w    = (const float*)d_in[16];
  const float* ln2_b    = (const float*)d_in[17];
  const float* fc_w     = (const float*)d_in[18];
  const float* proj_w   = (const float*)d_in[19];
  float* out = (float*)d_out;
  char* W8 = (char*)d_ws;

  bf16* w_in   = (bf16*)(W8 + OFF_WIN);
  bf16* w_out  = (bf16*)(W8 + OFF_WOUT);
  bf16* w_qkv  = (bf16*)(W8 + OFF_WQKV);
  bf16* w_cp   = (bf16*)(W8 + OFF_WCP);
  bf16* w_fc   = (bf16*)(W8 + OFF_WFC);
  bf16* w_pr   = (bf16*)(W8 + OFF_WPR);
  bf16* h_bf   = (bf16*)(W8 + OFF_HBF);
  bf16* bcdtP  = (bf16*)(W8 + OFF_ST);
  bf16* Xt     = (bf16*)(W8 + OFF_XT);
  bf16* Zt     = (bf16*)(W8 + OFF_ZT);
  float* dt_c  = (float*)(W8 + OFF_DTC);
  float* ddc   = (float*)(W8 + OFF_DDC);
  float* ac_c  = (float*)(W8 + OFF_ACC);
  float* Tb    = (float*)(W8 + OFF_T);
  bf16* Bn     = (bf16*)(W8 + OFF_BN);
  bf16* Cn     = (bf16*)(W8 + OFF_CN);
  bf16* Btr    = (bf16*)(W8 + OFF_BTR);
  bf16* st     = (bf16*)(W8 + OFF_ST);
  bf16* ybf    = (bf16*)(W8 + OFF_YBF);
  float* x1    = (float*)(W8 + OFF_X1);
  bf16* Pbuf   = (bf16*)(W8 + OFF_P);
  bf16* Po     = (bf16*)(W8 + OFF_PO);
  float* Ls    = (float*)(W8 + OFF_LS);
  bf16* qbf    = (bf16*)(W8 + OFF_QB);
  bf16* kbf    = (bf16*)(W8 + OFF_KB);
  bf16* vbf    = (bf16*)(W8 + OFF_VB);
  bf16* vtr    = (bf16*)(W8 + OFF_VTR);
  bf16* y2     = (bf16*)(W8 + OFF_Y2);
  float* x2    = (float*)(W8 + OFF_X2);
  bf16* mlp    = (bf16*)(W8 + OFF_MLP);

  // ---- weight casts (single launch; q/k/v cast into adjacent rows of w_qkv) ----
  CastArgs ca;
  ca.seg[0] = { in_w,    w_in,            4489216, 4587520, 0     };
  ca.seg[1] = { out_w,   w_out,           2097152, 2097152, 4480  };
  ca.seg[2] = { cq_w,    w_qkv,           1048576, 1048576, 6528  };
  ca.seg[3] = { ck_w,    w_qkv + 1048576,  262144,  262144, 7552  };
  ca.seg[4] = { cv_w,    w_qkv + 1310720,  262144,  262144, 7808  };
  ca.seg[5] = { cproj_w, w_cp,            1048576, 1048576, 8064  };
  ca.seg[6] = { fc_w,    w_fc,            3145728, 3145728, 9088  };
  ca.seg[7] = { proj_w,  w_pr,            3145728, 3145728, 12160 };
  castw_all<<<15232, 256, 0, stream>>>(ca);

  // ---- mamba block ----
  rmsnorm_k<<<ROWS, 256, 0, stream>>>(x, mnorm_w, h_bf, D_);
  gemm256_inproj<<<448, 512, 0, stream>>>(h_bf, w_in, Zt, Xt, bcdtP);
  ssd_prep<<<B_ * NH * NC, 64, 0, stream>>>(bcdtP, dt_bias, A_log, dt_c, ddc, ac_c, Tb);
  bc_norm<<<ROWS, 128, 0, stream>>>(bcdtP, Bn_w, Cn_w, Bn, Cn);
  t64<<<2 * 2 * 32, 256, 0, stream>>>(Bn, Btr, 128, (size_t)2048 * 128, (size_t)128 * 2048, 2);
  ssd_states<<<B_ * NC * NH, 256, 0, stream>>>(Xt, Btr, ddc, st);
  ssd_scan<<<B_ * NH * 8, 256, 0, stream>>>(st, Tb);
  ssd_out<<<B_ * NC * NH, 256, 0, stream>>>(Cn, Bn, Xt, Zt, dt_c, ac_c, st, Dp, ybf);
  // out_proj: 256^2 split-K=4 (grid 16x4x4 = 256, one round) then reduce+res+LN1
  gemm256<0><<<256, 512, 0, stream>>>(ybf, w_out, Pbuf, 1024, 2048, 512, 256);
  reduce_ln4<<<ROWS, 256, 0, stream>>>(Pbuf, x, ln1_w, ln1_b, x1, h_bf);

  // ---- attention block ----
  // qkv: 256^2 split-K=2 (grid 16x6x2 = 192)
  gemm256<0><<<192, 512, 0, stream>>>(h_bf, w_qkv, Pbuf, 1536, 1024, 512, 192);
  reduce_qkv<<<ROWS, 256, 0, stream>>>(Pbuf, q_gain, qbf, kbf, vbf);
  t64<<<2 * 4 * 32, 256, 0, stream>>>(vbf, vtr, 256, (size_t)2048 * 256, (size_t)256 * 2048, 4);
  attn_mfma<<<dim3(40, HATT, B_), 256, 0, stream>>>(qbf, kbf, vtr, Po, Ls);
  attn_red<<<ROWS, 256, 0, stream>>>(Po, Ls, y2);
  // cproj: 256^2 split-K=4 (grid 16x4x4 = 256)
  gemm256<0><<<256, 512, 0, stream>>>(y2, w_cp, Pbuf, 1024, 1024, 256, 256);
  reduce_ln4<<<ROWS, 256, 0, stream>>>(Pbuf, x1, ln2_w, ln2_b, x2, h_bf);

  // ---- MLP ----
  // fc: 256^2 no-split + fused silu (grid 16x12 = 192)
  gemm256<1><<<192, 512, 0, stream>>>(h_bf, w_fc, mlp, 3072, 1024, 1024, 192);
  // proj: 256^2 split-K=4, K=768 each (grid 16x4x4 = 256)
  gemm256<0><<<256, 512, 0, stream>>>(mlp, w_pr, Pbuf, 1024, 3072, 768, 256);
  reduce_out4<<<ROWS * 4 / 4, 256, 0, stream>>>(Pbuf, x2, out);
}